// Round 4
// baseline (10292.651 us; speedup 1.0000x reference)
//
#include <hip/hip_runtime.h>
#include <hip/hip_bf16.h>
#include <cmath>
#include <stdint.h>

// Round 4: d_out is FLOAT32 (reference output dtype is f32; out_npz size confirms).
// Inputs: floats f32, indices int32, bools normalized at runtime (u8/int32/f32/bf16 all handled).
// B=2 S=1024 D_TEXT=384 D_MODEL=768 H=12 DH=64 DFF=3072 L=4

#define BB 2
#define SS 1024
#define DT 384
#define DM 768
#define NH 12
#define DH 64
#define DFF 3072
#define NL 4
#define NROW (BB*SS)
#define EPSF 1e-6f
#define NEGF (-1e9f)

typedef unsigned short u16;
typedef unsigned char u8;

__device__ __forceinline__ u16 f2bu(float f){
    unsigned int x = __float_as_uint(f);
    unsigned int r = (x + 0x7fffu + ((x>>16)&1u)) >> 16;   // RNE
    return (u16)r;
}

// ------------------------------------------------- bool-buffer normalizer
// Classifies the device encoding of a numpy-bool input and expands to u8.
// Probe reads only the first n bytes (min possible buffer size).
__global__ void norm_bool_kernel(const void* __restrict__ src, u8* __restrict__ dst, int n)
{
    __shared__ int cls;   // 0=all-false 1=word(int32/f32) 2=byte(u8) 3=u16(bf16)
    if (threadIdx.x==0){
        const unsigned int* w = (const unsigned int*)src;
        const int nw = n/4;
        bool bytes01=true, hiPos=false, low3f80=false, any=false;
        for (int i=0;i<nw;i++){
            unsigned int v=w[i];
            if (!v) continue;
            any=true;
            #pragma unroll
            for (int b=0;b<4;b++){
                unsigned int by=(v>>(8*b))&0xffu;
                if (by>1u) bytes01=false;
                if (by==1u && b!=0) hiPos=true;
            }
            if ((v&0xffffu)==0x3f80u) low3f80=true;
        }
        int c;
        if (!any) c=0;                     // nothing set in probe window -> treat all-false
        else if (bytes01) c = hiPos ? 2 : 1;
        else if (low3f80) c = 3;
        else c = 1;                        // f32 pattern -> word read
        cls=c;
    }
    __syncthreads();
    const int c=cls;
    for (int i=threadIdx.x;i<n;i+=blockDim.x){
        u8 v;
        if (c==0)      v=0;
        else if (c==1) v = (((const unsigned int*)src)[i]!=0u);
        else if (c==2) v = (((const u8*)src)[i]!=0u);
        else           v = (((const u16*)src)[i]!=0u);
        dst[i]=v;
    }
}

// ---------------------------------------------------------------- encoders
__global__ __launch_bounds__(256) void encode_kernel(
    const float* __restrict__ numv, const float* __restrict__ dtv, const float* __restrict__ boolv,
    const float* __restrict__ textv, const float* __restrict__ cnamev,
    const float* __restrict__ Wcn, const float* __restrict__ bcn,
    const float* __restrict__ Wnum, const float* __restrict__ bnum,
    const float* __restrict__ Wtext, const float* __restrict__ btext,
    const float* __restrict__ Wdt, const float* __restrict__ bdt,
    const float* __restrict__ Wbool, const float* __restrict__ bbool,
    const float* __restrict__ gcn, const float* __restrict__ gnum, const float* __restrict__ gtext,
    const float* __restrict__ gdt, const float* __restrict__ gbool,
    const float* __restrict__ memb, const int* __restrict__ stypes, const u8* __restrict__ masks,
    float* __restrict__ x)
{
    const int row = blockIdx.x;
    const int t = threadIdx.x;
    __shared__ float vin[DT];
    __shared__ float red[256];

    // phase A: cn = RMS(cname @ Wcn + bcn, gcn)
    for (int i=t;i<DT;i+=256) vin[i] = cnamev[(size_t)row*DT+i];
    __syncthreads();
    float cn[3]; float ss=0.f;
    #pragma unroll
    for (int j=0;j<3;j++){
        int e = t + j*256;
        float acc = bcn[e];
        for (int k=0;k<DT;k++) acc += vin[k]*Wcn[(size_t)k*DM+e];
        cn[j]=acc; ss += acc*acc;
    }
    red[t]=ss; __syncthreads();
    for (int s=128;s>0;s>>=1){ if(t<s) red[t]+=red[t+s]; __syncthreads(); }
    {
        float r = rsqrtf(red[0]/(float)DM + EPSF);
        #pragma unroll
        for (int j=0;j<3;j++){ int e=t+j*256; cn[j] *= r*gcn[e]; }
    }
    __syncthreads();

    // phase B: semantic-type value encoder (st uniform per row/block)
    const int st = stypes[row];
    float val[3]; ss=0.f;
    if (st==1){
        for (int i=t;i<DT;i+=256) vin[i] = textv[(size_t)row*DT+i];
        __syncthreads();
        #pragma unroll
        for (int j=0;j<3;j++){
            int e=t+j*256;
            float acc = btext[e];
            for (int k=0;k<DT;k++) acc += vin[k]*Wtext[(size_t)k*DM+e];
            val[j]=acc; ss+=acc*acc;
        }
    } else {
        const float* Wp = (st==0)?Wnum:((st==2)?Wdt:Wbool);
        const float* bp = (st==0)?bnum:((st==2)?bdt:bbool);
        const float* vp = (st==0)?numv:((st==2)?dtv:boolv);
        float v = vp[row];
        #pragma unroll
        for (int j=0;j<3;j++){
            int e=t+j*256;
            float acc = v*Wp[e] + bp[e];
            val[j]=acc; ss+=acc*acc;
        }
    }
    red[t]=ss; __syncthreads();
    for (int s=128;s>0;s>>=1){ if(t<s) red[t]+=red[t+s]; __syncthreads(); }
    const float* gp = (st==0)?gnum:((st==1)?gtext:((st==2)?gdt:gbool));
    float r2 = rsqrtf(red[0]/(float)DM + EPSF);
    bool mk = masks[row]!=0;
    #pragma unroll
    for (int j=0;j<3;j++){
        int e=t+j*256;
        float vv = val[j]*r2*gp[e];
        if (mk) vv = memb[st*DM+e];
        x[(size_t)row*DM+e] = vv + cn[j];
    }
}

// ---------------------------------------------------------------- rmsnorm
__global__ __launch_bounds__(256) void rms_kernel(const float* __restrict__ x,
                                                  const float* __restrict__ g,
                                                  float* __restrict__ y)
{
    const int row = blockIdx.x;
    const int t = threadIdx.x;
    __shared__ float red[256];
    const float* xr = x + (size_t)row*DM;
    float v0=xr[t], v1=xr[t+256], v2=xr[t+512];
    red[t] = v0*v0+v1*v1+v2*v2; __syncthreads();
    for (int s=128;s>0;s>>=1){ if(t<s) red[t]+=red[t+s]; __syncthreads(); }
    float r = rsqrtf(red[0]/(float)DM + EPSF);
    float* yr = y + (size_t)row*DM;
    yr[t]     = v0*r*g[t];
    yr[t+256] = v1*r*g[t+256];
    yr[t+512] = v2*r*g[t+512];
}

// ---------------------------------------------------------------- GEMM  C[M,N] (+)= A[M,K] @ W[K,N]
__global__ __launch_bounds__(256) void gemm_kernel(
    const float* __restrict__ A, const float* __restrict__ W, float* __restrict__ C,
    int M, int N, int K, int acc)
{
    __shared__ float As[16][64];
    __shared__ float Ws[16][64];
    const int tid = threadIdx.x;
    const int m0 = blockIdx.y*64, n0 = blockIdx.x*64;
    const int ar = tid>>2, ac = tid&3;
    const int wr = tid>>4, wc = tid&15;
    const int tx = tid&15, ty = tid>>4;
    float acc4[4][4];
    #pragma unroll
    for (int i=0;i<4;i++){
        #pragma unroll
        for (int j=0;j<4;j++) acc4[i][j]=0.f;
    }
    for (int k0=0;k0<K;k0+=16){
        float4 a4 = *(const float4*)(A + (size_t)(m0+ar)*K + k0 + ac*4);
        As[ac*4+0][ar]=a4.x; As[ac*4+1][ar]=a4.y; As[ac*4+2][ar]=a4.z; As[ac*4+3][ar]=a4.w;
        float4 w4 = *(const float4*)(W + (size_t)(k0+wr)*N + n0 + wc*4);
        *(float4*)&Ws[wr][wc*4] = w4;
        __syncthreads();
        #pragma unroll
        for (int kk=0;kk<16;kk++){
            float4 av = *(const float4*)&As[kk][ty*4];
            float4 wv = *(const float4*)&Ws[kk][tx*4];
            float aa[4]={av.x,av.y,av.z,av.w};
            float ww[4]={wv.x,wv.y,wv.z,wv.w};
            #pragma unroll
            for (int i=0;i<4;i++){
                #pragma unroll
                for (int j=0;j<4;j++) acc4[i][j] += aa[i]*ww[j];
            }
        }
        __syncthreads();
    }
    #pragma unroll
    for (int i=0;i<4;i++){
        float* cp = C + (size_t)(m0+ty*4+i)*N + n0 + tx*4;
        float4 res = make_float4(acc4[i][0],acc4[i][1],acc4[i][2],acc4[i][3]);
        if (acc){
            float4 old = *(const float4*)cp;
            res.x+=old.x; res.y+=old.y; res.z+=old.z; res.w+=old.w;
        }
        *(float4*)cp = res;
    }
}

// ---------------------------------------------------------------- flash attention (one block = one (b,h,q-tile64))
template<int MT>
__global__ __launch_bounds__(256) void attn_kernel(
    const float* __restrict__ qb, const float* __restrict__ kb, const float* __restrict__ vb,
    const int* __restrict__ node, const int* __restrict__ tbl, const int* __restrict__ colx,
    const int* __restrict__ f2p, const u8* __restrict__ pad,
    float* __restrict__ ob)
{
    const int bh = blockIdx.y;
    const int b = bh / NH, h = bh % NH;
    const int q0 = blockIdx.x * 64;
    const int tid = threadIdx.x;
    const int r = tid >> 2, sub = tid & 3;   // 4 lanes (a quad) per q-row

    __shared__ float Qs[64][65];
    __shared__ u16   Ks[64][66];
    __shared__ u16   Vs[64][64];
    __shared__ float Ps[64][65];
    __shared__ int qN[64], qC[64], qT[64], qF[64][5];
    __shared__ int kN[64], kC[64], kT[64];
    __shared__ u8 qP[64], kP[64];

    { // stage Q tile (f32)
        const float4* src = (const float4*)(qb + (size_t)(b*SS+q0+r)*DM + h*DH + sub*16);
        #pragma unroll
        for (int j4=0;j4<4;j4++){
            float4 tv = src[j4];
            int c = sub*16 + j4*4;
            Qs[r][c]=tv.x; Qs[r][c+1]=tv.y; Qs[r][c+2]=tv.z; Qs[r][c+3]=tv.w;
        }
    }
    if (tid<64){
        int gi = b*SS+q0+tid;
        qN[tid]=node[gi]; qC[tid]=colx[gi]; qT[tid]=tbl[gi]; qP[tid]=pad[gi];
        #pragma unroll
        for (int f=0;f<5;f++) qF[tid][f]=f2p[gi*5+f];
    }

    float o[16];
    #pragma unroll
    for (int j=0;j<16;j++) o[j]=0.f;
    float mrun=-INFINITY, lrun=0.f;

    for (int kc=0;kc<16;kc++){
        const int k0 = kc*64;
        __syncthreads();               // prev-iter LDS reads done before overwrite
        {
            const float4* ksrc = (const float4*)(kb + (size_t)(b*SS+k0+r)*DM + h*DH + sub*16);
            const float4* vsrc = (const float4*)(vb + (size_t)(b*SS+k0+r)*DM + h*DH + sub*16);
            #pragma unroll
            for (int j4=0;j4<4;j4++){
                float4 tk = ksrc[j4];
                float4 tv = vsrc[j4];
                int c = sub*16 + j4*4;
                Ks[r][c]=f2bu(tk.x); Ks[r][c+1]=f2bu(tk.y); Ks[r][c+2]=f2bu(tk.z); Ks[r][c+3]=f2bu(tk.w);
                Vs[r][c]=f2bu(tv.x); Vs[r][c+1]=f2bu(tv.y); Vs[r][c+2]=f2bu(tv.z); Vs[r][c+3]=f2bu(tv.w);
            }
        }
        if (tid<64){
            int gi = b*SS+k0+tid;
            kN[tid]=node[gi]; kC[tid]=colx[gi]; kT[tid]=tbl[gi]; kP[tid]=pad[gi];
        }
        __syncthreads();

        // scores: this thread owns 16 keys (sub*16+j) of its row r
        float s[16];
        #pragma unroll
        for (int j=0;j<16;j++) s[j]=0.f;
        for (int d=0;d<64;d+=2){
            float qa = Qs[r][d], qc = Qs[r][d+1];
            #pragma unroll
            for (int j=0;j<16;j++){
                unsigned int u = *(const unsigned int*)&Ks[sub*16+j][d];
                s[j] += qa*__uint_as_float(u<<16) + qc*__uint_as_float(u & 0xffff0000u);
            }
        }

        // mask + online softmax
        float smax = -INFINITY;
        const bool qpv = (qP[r]==0);
        #pragma unroll
        for (int j=0;j<16;j++){
            const int kk = sub*16+j;
            const bool eye = (q0+r) == (k0+kk);
            const bool pv = qpv && (kP[kk]==0);
            bool m;
            if (MT==0)      m = ((qC[r]==kC[kk]) && (qT[r]==kT[kk]) && pv) || eye;
            else if (MT==1) m = ((qN[r]==kN[kk]) && pv) || eye;
            else if (MT==2){
                int kn = kN[kk];
                bool nei = (qF[r][0]==kn)||(qF[r][1]==kn)||(qF[r][2]==kn)||(qF[r][3]==kn)||(qF[r][4]==kn);
                m = ((nei || (qN[r]==kn)) && pv) || eye;
            } else          m = pv || eye;
            float sc = s[j]*0.125f;
            sc = m ? sc : NEGF;
            s[j]=sc;
            smax = fmaxf(smax, sc);
        }
        smax = fmaxf(smax, __shfl_xor(smax,1));
        smax = fmaxf(smax, __shfl_xor(smax,2));
        const float mnew = fmaxf(mrun, smax);
        const float alpha = __expf(mrun - mnew);
        float ls = 0.f;
        #pragma unroll
        for (int j=0;j<16;j++){
            float p = __expf(s[j]-mnew);
            Ps[r][sub*16+j]=p;
            ls += p;
        }
        lrun = lrun*alpha + ls;
        mrun = mnew;
        #pragma unroll
        for (int j=0;j<16;j++) o[j]*=alpha;

        // o += P @ V  (Ps row is quad-private, same wave -> LDS ops in-order within wave)
        for (int kk=0;kk<64;kk++){
            float p = Ps[r][kk];
            const unsigned int* vrow = (const unsigned int*)&Vs[kk][sub*16];
            #pragma unroll
            for (int j2=0;j2<8;j2++){
                unsigned int u = vrow[j2];
                o[j2*2]   += p*__uint_as_float(u<<16);
                o[j2*2+1] += p*__uint_as_float(u & 0xffff0000u);
            }
        }
    }

    float lt = lrun + __shfl_xor(lrun,1);
    lt = lt + __shfl_xor(lt,2);
    const float inv = 1.f/lt;
    float* dst = ob + (size_t)(b*SS+q0+r)*DM + h*DH + sub*16;
    #pragma unroll
    for (int j=0;j<16;j++) dst[j] = o[j]*inv;
}

// ---------------------------------------------------------------- silu(g)*u -> g
__global__ void silu_mul_kernel(float* __restrict__ g, const float* __restrict__ u, int n)
{
    int i = blockIdx.x*blockDim.x + threadIdx.x;
    const int stride = gridDim.x*blockDim.x;
    for (; i<n; i+=stride){
        float x = g[i];
        float s = x / (1.f + __expf(-x));
        g[i] = s * u[i];
    }
}

// ---------------------------------------------------------------- final rms + 4 decode heads (f32 out)
__global__ __launch_bounds__(256) void decode_kernel(
    const float* __restrict__ x, const float* __restrict__ gout,
    const float* __restrict__ Wn, const float* __restrict__ bn,
    const float* __restrict__ Wd, const float* __restrict__ bd,
    const float* __restrict__ Wb, const float* __restrict__ bb,
    const float* __restrict__ Wt, const float* __restrict__ bt,
    float* __restrict__ out)
{
    const int row = blockIdx.x;
    const int t = threadIdx.x;
    __shared__ float h[DM];
    __shared__ float red[256];
    const float* xr = x + (size_t)row*DM;
    float v0=xr[t], v1=xr[t+256], v2=xr[t+512];
    red[t]=v0*v0+v1*v1+v2*v2; __syncthreads();
    for (int s=128;s>0;s>>=1){ if(t<s) red[t]+=red[t+s]; __syncthreads(); }
    float r = rsqrtf(red[0]/(float)DM + EPSF);
    h[t]     = v0*r*gout[t];
    h[t+256] = v1*r*gout[t+256];
    h[t+512] = v2*r*gout[t+512];
    __syncthreads();

    float pn=0.f,pd=0.f,pb=0.f;
    for (int k=t;k<DM;k+=256){ float hv=h[k]; pn+=hv*Wn[k]; pd+=hv*Wd[k]; pb+=hv*Wb[k]; }
    red[t]=pn; __syncthreads();
    for (int s=128;s>0;s>>=1){ if(t<s) red[t]+=red[t+s]; __syncthreads(); }
    float tn=red[0]; __syncthreads();
    red[t]=pd; __syncthreads();
    for (int s=128;s>0;s>>=1){ if(t<s) red[t]+=red[t+s]; __syncthreads(); }
    float td=red[0]; __syncthreads();
    red[t]=pb; __syncthreads();
    for (int s=128;s>0;s>>=1){ if(t<s) red[t]+=red[t+s]; __syncthreads(); }
    float tb=red[0];
    if (t==0){
        out[row]          = tn + bn[0];
        out[NROW + row]   = td + bd[0];
        out[2*NROW + row] = tb + bb[0];
    }
    for (int e=t;e<DT;e+=256){
        float acc = bt[e];
        for (int k=0;k<DM;k++) acc += h[k]*Wt[(size_t)k*DT+e];
        out[3*NROW + (size_t)row*DT + e] = acc;
    }
}

// ---------------------------------------------------------------- launcher
extern "C" void kernel_launch(void* const* d_in, const int* in_sizes, int n_in,
                              void* d_out, int out_size, void* d_ws, size_t ws_size,
                              hipStream_t stream)
{
    const float* numv   = (const float*)d_in[0];
    const float* dtval  = (const float*)d_in[1];
    const float* boolv  = (const float*)d_in[2];
    const float* textv  = (const float*)d_in[3];
    const float* cnamev = (const float*)d_in[4];
    const float* Wcn=(const float*)d_in[5];  const float* bcn=(const float*)d_in[6];
    const float* Wnum=(const float*)d_in[7]; const float* bnum=(const float*)d_in[8];
    const float* Wtext=(const float*)d_in[9];const float* btext=(const float*)d_in[10];
    const float* Wdt=(const float*)d_in[11]; const float* bdt=(const float*)d_in[12];
    const float* Wbool=(const float*)d_in[13];const float* bbool=(const float*)d_in[14];
    const float* gcn=(const float*)d_in[15]; const float* gnum=(const float*)d_in[16];
    const float* gtext=(const float*)d_in[17];const float* gdt=(const float*)d_in[18];
    const float* gbool=(const float*)d_in[19];
    const float* memb=(const float*)d_in[20];
    const float* norms_all=(const float*)d_in[21];
    const float* attw_all=(const float*)d_in[22];
    const float* up_all=(const float*)d_in[23];
    const float* gate_all=(const float*)d_in[24];
    const float* down_all=(const float*)d_in[25];
    const float* gout=(const float*)d_in[26];
    const float* Wdn=(const float*)d_in[27]; const float* bdn=(const float*)d_in[28];
    const float* Wdd=(const float*)d_in[29]; const float* bdd=(const float*)d_in[30];
    const float* Wdb=(const float*)d_in[31]; const float* bdb=(const float*)d_in[32];
    const float* Wdtx=(const float*)d_in[33];const float* bdtx=(const float*)d_in[34];
    const int* node=(const int*)d_in[35];
    const int* tbl =(const int*)d_in[36];
    const int* colx=(const int*)d_in[37];
    const int* f2p =(const int*)d_in[38];
    const int* styp=(const int*)d_in[39];

    float* ws = (float*)d_ws;
    const size_t NX = (size_t)NROW*DM;   // 1,572,864
    float* x    = ws;
    float* xn   = ws + NX;
    float* qb   = ws + 2*NX;
    float* kbuf = ws + 3*NX;
    float* vbuf = ws + 4*NX;
    float* obuf = ws + 5*NX;
    float* gbuf = ws + 6*NX;             // 4*NX (2048 x 3072)
    float* ubuf = qb;                    // alias q/k/v/o pool (exactly 4*NX)
    u8* nmask = (u8*)(ws + 10*NX);
    u8* npad  = nmask + NROW;

    norm_bool_kernel<<<1,256,0,stream>>>(d_in[40], nmask, NROW);
    norm_bool_kernel<<<1,256,0,stream>>>(d_in[41], npad,  NROW);

    encode_kernel<<<NROW,256,0,stream>>>(numv,dtval,boolv,textv,cnamev,
        Wcn,bcn,Wnum,bnum,Wtext,btext,Wdt,bdt,Wbool,bbool,
        gcn,gnum,gtext,gdt,gbool,memb,styp,nmask,x);

    const dim3 g1(DM/64, NROW/64);       // 12 x 32
    const dim3 g2(DFF/64, NROW/64);      // 48 x 32
    const dim3 ga(SS/64, BB*NH);         // 16 x 24

    for (int l=0; l<NL; l++){
        const float* norms = norms_all + (size_t)l*5*DM;
        for (int a=0; a<4; a++){
            rms_kernel<<<NROW,256,0,stream>>>(x, norms + a*DM, xn);
            const float* aw = attw_all + (((size_t)l*4 + a)*4)*(size_t)DM*DM;
            gemm_kernel<<<g1,256,0,stream>>>(xn, aw + 0*(size_t)DM*DM, qb,   NROW, DM, DM, 0);
            gemm_kernel<<<g1,256,0,stream>>>(xn, aw + 1*(size_t)DM*DM, kbuf, NROW, DM, DM, 0);
            gemm_kernel<<<g1,256,0,stream>>>(xn, aw + 2*(size_t)DM*DM, vbuf, NROW, DM, DM, 0);
            if (a==0)      attn_kernel<0><<<ga,256,0,stream>>>(qb,kbuf,vbuf,node,tbl,colx,f2p,npad,obuf);
            else if (a==1) attn_kernel<1><<<ga,256,0,stream>>>(qb,kbuf,vbuf,node,tbl,colx,f2p,npad,obuf);
            else if (a==2) attn_kernel<2><<<ga,256,0,stream>>>(qb,kbuf,vbuf,node,tbl,colx,f2p,npad,obuf);
            else           attn_kernel<3><<<ga,256,0,stream>>>(qb,kbuf,vbuf,node,tbl,colx,f2p,npad,obuf);
            gemm_kernel<<<g1,256,0,stream>>>(obuf, aw + 3*(size_t)DM*DM, x, NROW, DM, DM, 1);
        }
        rms_kernel<<<NROW,256,0,stream>>>(x, norms + 4*DM, xn);
        gemm_kernel<<<g2,256,0,stream>>>(xn, gate_all + (size_t)l*DM*DFF, gbuf, NROW, DFF, DM, 0);
        gemm_kernel<<<g2,256,0,stream>>>(xn, up_all   + (size_t)l*DM*DFF, ubuf, NROW, DFF, DM, 0);
        silu_mul_kernel<<<2048,256,0,stream>>>(gbuf, ubuf, NROW*DFF);
        gemm_kernel<<<g1,256,0,stream>>>(gbuf, down_all + (size_t)l*DFF*DM, x, NROW, DM, DFF, 1);
    }

    decode_kernel<<<NROW,256,0,stream>>>(x, gout, Wdn,bdn, Wdd,bdd, Wdb,bdb, Wdtx,bdtx, (float*)d_out);
}

// Round 5
// 3362.968 us; speedup vs baseline: 3.0606x; 3.0606x over previous
//
#include <hip/hip_runtime.h>
#include <hip/hip_bf16.h>
#include <cmath>
#include <stdint.h>

// Round 5: bf16 MFMA GEMMs + MFMA flash attention. f32 in, f32 out.
// Fallback to round-4 scalar path if ws_size < ~197MB.

#define BB 2
#define SS 1024
#define DT 384
#define DM 768
#define NH 12
#define DH 64
#define DFF 3072
#define NL 4
#define NROW (BB*SS)
#define EPSF 1e-6f
#define NEGF (-1e9f)

typedef unsigned short u16;
typedef unsigned char u8;
typedef __attribute__((ext_vector_type(8))) short s16x8;
typedef __attribute__((ext_vector_type(4))) float f32x4;

__device__ __forceinline__ u16 f2bu(float f){
    unsigned int x = __float_as_uint(f);
    unsigned int r = (x + 0x7fffu + ((x>>16)&1u)) >> 16;   // RNE
    return (u16)r;
}
__device__ __forceinline__ unsigned int pk2(float lo, float hi){
    return (unsigned int)f2bu(lo) | ((unsigned int)f2bu(hi)<<16);
}
// u16 index within a [rows][64] bf16 LDS tile, 128B row pitch, 16B-unit XOR swizzle
__device__ __forceinline__ int swz(int row, int c){
    return (row<<6) + (((((c>>3) ^ row) & 7))<<3) + (c&7);
}
__device__ __forceinline__ float rmax16(float v){
    v = fmaxf(v, __shfl_xor(v,1)); v = fmaxf(v, __shfl_xor(v,2));
    v = fmaxf(v, __shfl_xor(v,4)); v = fmaxf(v, __shfl_xor(v,8));
    return v;
}
__device__ __forceinline__ float rsum16(float v){
    v += __shfl_xor(v,1); v += __shfl_xor(v,2);
    v += __shfl_xor(v,4); v += __shfl_xor(v,8);
    return v;
}

// ------------------------------------------------- bool-buffer normalizer
__global__ void norm_bool_kernel(const void* __restrict__ src, u8* __restrict__ dst, int n)
{
    __shared__ int cls;
    if (threadIdx.x==0){
        const unsigned int* w = (const unsigned int*)src;
        const int nw = n/4;
        bool bytes01=true, hiPos=false, low3f80=false, any=false;
        for (int i=0;i<nw;i++){
            unsigned int v=w[i];
            if (!v) continue;
            any=true;
            #pragma unroll
            for (int b=0;b<4;b++){
                unsigned int by=(v>>(8*b))&0xffu;
                if (by>1u) bytes01=false;
                if (by==1u && b!=0) hiPos=true;
            }
            if ((v&0xffffu)==0x3f80u) low3f80=true;
        }
        int c;
        if (!any) c=0;
        else if (bytes01) c = hiPos ? 2 : 1;
        else if (low3f80) c = 3;
        else c = 1;
        cls=c;
    }
    __syncthreads();
    const int c=cls;
    for (int i=threadIdx.x;i<n;i+=blockDim.x){
        u8 v;
        if (c==0)      v=0;
        else if (c==1) v = (((const unsigned int*)src)[i]!=0u);
        else if (c==2) v = (((const u8*)src)[i]!=0u);
        else           v = (((const u16*)src)[i]!=0u);
        dst[i]=v;
    }
}

// ------------------------------------------------- weight transpose+convert: f32 [K][N] -> bf16 [N][K]
__global__ __launch_bounds__(256) void transpose_cvt(const float* __restrict__ src, u16* __restrict__ dst,
                                                     int K, int N)
{
    const int z = blockIdx.z;
    src += (size_t)z*K*N;
    dst += (size_t)z*K*N;
    const int n0 = blockIdx.x*32, k0 = blockIdx.y*32;
    __shared__ float t[32][33];
    const int tid = threadIdx.x;
    const int r = tid>>3, c4 = tid&7;
    float4 v = *(const float4*)(src + (size_t)(k0+r)*N + n0 + c4*4);
    t[r][c4*4+0]=v.x; t[r][c4*4+1]=v.y; t[r][c4*4+2]=v.z; t[r][c4*4+3]=v.w;
    __syncthreads();
    uint2 o;
    o.x = pk2(t[c4*4+0][r], t[c4*4+1][r]);
    o.y = pk2(t[c4*4+2][r], t[c4*4+3][r]);
    *(uint2*)(dst + (size_t)(n0+r)*K + k0 + c4*4) = o;
}

// ------------------------------------------------- MFMA GEMM: C[M,N] = A[M,K](f32) @ WT[N,K](bf16)
// flags: 1=accumulate into C, 2=add bias[n], 4=qkv split epilogue (bf16 qk + transposed bf16 v)
__global__ __launch_bounds__(256) void gemm_bf16(
    const float* __restrict__ A, const u16* __restrict__ WT, float* __restrict__ C,
    int M, int N, int K, int flags, const float* __restrict__ bias,
    u16* __restrict__ qk16, u16* __restrict__ vt16)
{
    __shared__ u16 As[128*64];
    __shared__ u16 Bs[128*64];
    const int tid = threadIdx.x;
    const int lane = tid&63, w = tid>>6;
    const int wm = w>>1, wn = w&1;
    const int cg = lane>>4, cl = lane&15;
    const int m0 = blockIdx.y*128, n0 = blockIdx.x*128;

    f32x4 acc[4][4];
    #pragma unroll
    for (int i=0;i<4;i++)
        #pragma unroll
        for (int j=0;j<4;j++) acc[i][j] = (f32x4){0.f,0.f,0.f,0.f};

    const int mrow = tid>>1, half = tid&1;
    for (int k0=0;k0<K;k0+=64){
        // stage A (f32 -> bf16)
        const float* ap = A + (size_t)(m0+mrow)*K + k0 + half*32;
        #pragma unroll
        for (int i=0;i<8;i+=2){
            float4 a0 = *(const float4*)(ap + i*4);
            float4 a1 = *(const float4*)(ap + i*4 + 4);
            uint4 pw;
            pw.x = pk2(a0.x,a0.y); pw.y = pk2(a0.z,a0.w);
            pw.z = pk2(a1.x,a1.y); pw.w = pk2(a1.z,a1.w);
            *(uint4*)&As[swz(mrow, half*32 + i*4)] = pw;
        }
        // stage B (already bf16)
        const u16* wp = WT + (size_t)(n0+mrow)*K + k0 + half*32;
        #pragma unroll
        for (int i=0;i<4;i++){
            uint4 wv = *(const uint4*)(wp + i*8);
            *(uint4*)&Bs[swz(mrow, half*32 + i*8)] = wv;
        }
        __syncthreads();
        #pragma unroll
        for (int ks=0;ks<2;ks++){
            s16x8 af[4], bf[4];
            #pragma unroll
            for (int mt=0;mt<4;mt++)
                af[mt] = *(const s16x8*)&As[swz(wm*64+mt*16+cl, ks*32+cg*8)];
            #pragma unroll
            for (int nt=0;nt<4;nt++)
                bf[nt] = *(const s16x8*)&Bs[swz(wn*64+nt*16+cl, ks*32+cg*8)];
            #pragma unroll
            for (int mt=0;mt<4;mt++)
                #pragma unroll
                for (int nt=0;nt<4;nt++)
                    acc[mt][nt] = __builtin_amdgcn_mfma_f32_16x16x32_bf16(af[mt], bf[nt], acc[mt][nt], 0,0,0);
        }
        __syncthreads();
    }

    // epilogue
    const bool do_acc = (flags&1), do_bias = (flags&2), do_split = (flags&4);
    #pragma unroll
    for (int mt=0;mt<4;mt++){
        const int grow0 = m0 + wm*64 + mt*16 + cg*4;
        #pragma unroll
        for (int nt=0;nt<4;nt++){
            const int col = n0 + wn*64 + nt*16 + cl;
            float bv = do_bias ? bias[col] : 0.f;
            if (do_split){
                if (col < 1536){
                    #pragma unroll
                    for (int j=0;j<4;j++)
                        qk16[(size_t)(grow0+j)*1536 + col] = f2bu(acc[mt][nt][j]);
                } else {
                    const int b = grow0>>10, s0 = grow0&1023;
                    const int dhg = col - 1536;
                    uint2 o;
                    o.x = pk2(acc[mt][nt][0], acc[mt][nt][1]);
                    o.y = pk2(acc[mt][nt][2], acc[mt][nt][3]);
                    *(uint2*)(vt16 + ((size_t)(b*768 + dhg)<<10) + s0) = o;
                }
            } else {
                #pragma unroll
                for (int j=0;j<4;j++){
                    float v = acc[mt][nt][j] + bv;
                    float* cp = C + (size_t)(grow0+j)*N + col;
                    if (do_acc) v += *cp;
                    *cp = v;
                }
            }
        }
    }
}

// ------------------------------------------------- MFMA flash attention
template<int MT>
__global__ __launch_bounds__(256) void attn_mfma(
    const u16* __restrict__ qk16, const u16* __restrict__ vt16,
    const int* __restrict__ node, const int* __restrict__ tbl, const int* __restrict__ colx,
    const int* __restrict__ f2p, const u8* __restrict__ pad,
    float* __restrict__ obuf)
{
    const int bh = blockIdx.y;
    const int b = bh / NH, h = bh % NH;
    const int q0 = blockIdx.x * 64;
    const int tid = threadIdx.x;
    const int w = tid>>6, lane = tid&63, cg = lane>>4, cl = lane&15;

    __shared__ u16 Qs[64*64], Ks[64*64], Vt[64*64], Ps[64*64];
    __shared__ int kNs[64], kCs[64], kTs[64], kPs[64];

    // Q stage (bf16 passthrough)
    #pragma unroll
    for (int p=0;p<2;p++){
        int idx = tid + p*256; int row = idx>>3, seg = idx&7;
        uint4 d = *(const uint4*)(qk16 + (size_t)(b*SS+q0+row)*1536 + h*64 + seg*8);
        *(uint4*)&Qs[(row<<6) + (((seg ^ row)&7)<<3)] = d;
    }
    // q-meta -> registers
    int qn[4],qcx[4],qt[4],qp[4],qf[4][5];
    #pragma unroll
    for (int j=0;j<4;j++){
        int gq = b*SS + q0 + w*16 + cg*4 + j;
        qn[j]=node[gq]; qcx[j]=colx[gq]; qt[j]=tbl[gq]; qp[j]=pad[gq];
        if (MT==2){
            #pragma unroll
            for (int f=0;f<5;f++) qf[j][f]=f2p[gq*5+f];
        }
    }

    f32x4 o[4];
    #pragma unroll
    for (int nt=0;nt<4;nt++) o[nt] = (f32x4){0.f,0.f,0.f,0.f};
    float mrun[4], lrun[4];
    #pragma unroll
    for (int j=0;j<4;j++){ mrun[j]=-INFINITY; lrun[j]=0.f; }

    for (int kc=0;kc<16;kc++){
        const int k0 = kc*64;
        __syncthreads();
        #pragma unroll
        for (int p=0;p<2;p++){
            int idx = tid + p*256; int row = idx>>3, seg = idx&7;
            uint4 dk = *(const uint4*)(qk16 + (size_t)(b*SS+k0+row)*1536 + 768 + h*64 + seg*8);
            *(uint4*)&Ks[(row<<6) + (((seg ^ row)&7)<<3)] = dk;
            uint4 dv = *(const uint4*)(vt16 + ((size_t)(b*768 + h*64 + row)<<10) + k0 + seg*8);
            *(uint4*)&Vt[(row<<6) + (((seg ^ row)&7)<<3)] = dv;
        }
        if (tid<64){
            int gi = b*SS+k0+tid;
            kNs[tid]=node[gi]; kCs[tid]=colx[gi]; kTs[tid]=tbl[gi]; kPs[tid]=pad[gi];
        }
        __syncthreads();

        // QK^T
        f32x4 sc[4];
        #pragma unroll
        for (int nt=0;nt<4;nt++) sc[nt] = (f32x4){0.f,0.f,0.f,0.f};
        #pragma unroll
        for (int ks=0;ks<2;ks++){
            s16x8 qa = *(const s16x8*)&Qs[swz(w*16+cl, ks*32+cg*8)];
            #pragma unroll
            for (int nt=0;nt<4;nt++){
                s16x8 kb = *(const s16x8*)&Ks[swz(nt*16+cl, ks*32+cg*8)];
                sc[nt] = __builtin_amdgcn_mfma_f32_16x16x32_bf16(qa, kb, sc[nt], 0,0,0);
            }
        }

        // scale + mask
        float pP[4][4];
        #pragma unroll
        for (int nt=0;nt<4;nt++){
            const int key = k0 + nt*16 + cl;
            const int kn = kNs[nt*16+cl], kcv = kCs[nt*16+cl], ktv = kTs[nt*16+cl], kp = kPs[nt*16+cl];
            #pragma unroll
            for (int j=0;j<4;j++){
                float sv = sc[nt][j]*0.125f;
                const int qrow = q0 + w*16 + cg*4 + j;
                const bool eye = (qrow == key);
                const bool pv = (qp[j]==0) && (kp==0);
                bool m;
                if (MT==0)      m = ((qcx[j]==kcv) && (qt[j]==ktv) && pv) || eye;
                else if (MT==1) m = ((qn[j]==kn) && pv) || eye;
                else if (MT==2){
                    bool nei = (qf[j][0]==kn)||(qf[j][1]==kn)||(qf[j][2]==kn)||(qf[j][3]==kn)||(qf[j][4]==kn);
                    m = ((nei || (qn[j]==kn)) && pv) || eye;
                } else          m = pv || eye;
                pP[nt][j] = m ? sv : NEGF;
            }
        }

        // online softmax (row reductions across 16-lane col groups)
        #pragma unroll
        for (int j=0;j<4;j++){
            float mx = fmaxf(fmaxf(pP[0][j],pP[1][j]), fmaxf(pP[2][j],pP[3][j]));
            mx = rmax16(mx);
            float mnew = fmaxf(mrun[j], mx);
            float al = __expf(mrun[j]-mnew);
            mrun[j] = mnew;
            float ps = 0.f;
            #pragma unroll
            for (int nt=0;nt<4;nt++){
                float pe = __expf(pP[nt][j]-mnew);
                pP[nt][j]=pe; ps += pe;
            }
            ps = rsum16(ps);
            lrun[j] = lrun[j]*al + ps;
            #pragma unroll
            for (int nt=0;nt<4;nt++) o[nt][j] *= al;
        }

        // P -> LDS (wave-private rows)
        #pragma unroll
        for (int nt=0;nt<4;nt++)
            #pragma unroll
            for (int j=0;j<4;j++)
                Ps[swz(w*16+cg*4+j, nt*16+cl)] = f2bu(pP[nt][j]);

        // PV
        #pragma unroll
        for (int ks=0;ks<2;ks++){
            s16x8 pa = *(const s16x8*)&Ps[swz(w*16+cl, ks*32+cg*8)];
            #pragma unroll
            for (int nt=0;nt<4;nt++){
                s16x8 vb = *(const s16x8*)&Vt[swz(nt*16+cl, ks*32+cg*8)];
                o[nt] = __builtin_amdgcn_mfma_f32_16x16x32_bf16(pa, vb, o[nt], 0,0,0);
            }
        }
    }

    #pragma unroll
    for (int j=0;j<4;j++){
        const float inv = 1.f/lrun[j];
        #pragma unroll
        for (int nt=0;nt<4;nt++)
            obuf[(size_t)(b*SS+q0+w*16+cg*4+j)*DM + h*64 + nt*16 + cl] = o[nt][j]*inv;
    }
}

// ------------------------------------------------- rmsnorm
__global__ __launch_bounds__(256) void rms_kernel(const float* __restrict__ x,
                                                  const float* __restrict__ g,
                                                  float* __restrict__ y)
{
    const int row = blockIdx.x;
    const int t = threadIdx.x;
    __shared__ float red[256];
    const float* xr = x + (size_t)row*DM;
    float v0=xr[t], v1=xr[t+256], v2=xr[t+512];
    red[t] = v0*v0+v1*v1+v2*v2; __syncthreads();
    for (int s=128;s>0;s>>=1){ if(t<s) red[t]+=red[t+s]; __syncthreads(); }
    float r = rsqrtf(red[0]/(float)DM + EPSF);
    float* yr = y + (size_t)row*DM;
    yr[t]     = v0*r*g[t];
    yr[t+256] = v1*r*g[t+256];
    yr[t+512] = v2*r*g[t+512];
}

// ------------------------------------------------- encode fuse (after cn/text GEMMs)
__global__ __launch_bounds__(256) void fuse_encode(
    const float* __restrict__ cnbuf, const float* __restrict__ textbuf,
    const float* __restrict__ numv, const float* __restrict__ dtv, const float* __restrict__ boolv,
    const float* __restrict__ Wnum, const float* __restrict__ bnum,
    const float* __restrict__ Wdt, const float* __restrict__ bdt,
    const float* __restrict__ Wbool, const float* __restrict__ bbool,
    const float* __restrict__ gcn, const float* __restrict__ gnum, const float* __restrict__ gtext,
    const float* __restrict__ gdt, const float* __restrict__ gbool,
    const float* __restrict__ memb, const int* __restrict__ stypes, const u8* __restrict__ masks,
    float* __restrict__ x)
{
    const int row = blockIdx.x;
    const int t = threadIdx.x;
    __shared__ float red[256];

    float cn3[3]; float ss=0.f;
    #pragma unroll
    for (int j=0;j<3;j++){
        cn3[j] = cnbuf[(size_t)row*DM + t + j*256];
        ss += cn3[j]*cn3[j];
    }
    red[t]=ss; __syncthreads();
    for (int s=128;s>0;s>>=1){ if(t<s) red[t]+=red[t+s]; __syncthreads(); }
    {
        float r = rsqrtf(red[0]/(float)DM + EPSF);
        #pragma unroll
        for (int j=0;j<3;j++) cn3[j] *= r*gcn[t+j*256];
    }
    __syncthreads();

    const int st = stypes[row];
    float val[3]; ss=0.f;
    if (st==1){
        #pragma unroll
        for (int j=0;j<3;j++){
            val[j] = textbuf[(size_t)row*DM + t + j*256];
            ss += val[j]*val[j];
        }
    } else {
        const float* Wp = (st==0)?Wnum:((st==2)?Wdt:Wbool);
        const float* bp = (st==0)?bnum:((st==2)?bdt:bbool);
        const float* vp = (st==0)?numv:((st==2)?dtv:boolv);
        float v = vp[row];
        #pragma unroll
        for (int j=0;j<3;j++){
            int e=t+j*256;
            val[j] = v*Wp[e] + bp[e];
            ss += val[j]*val[j];
        }
    }
    red[t]=ss; __syncthreads();
    for (int s=128;s>0;s>>=1){ if(t<s) red[t]+=red[t+s]; __syncthreads(); }
    const float* gp = (st==0)?gnum:((st==1)?gtext:((st==2)?gdt:gbool));
    float r2 = rsqrtf(red[0]/(float)DM + EPSF);
    bool mk = masks[row]!=0;
    #pragma unroll
    for (int j=0;j<3;j++){
        int e=t+j*256;
        float vv = val[j]*r2*gp[e];
        if (mk) vv = memb[st*DM+e];
        x[(size_t)row*DM+e] = vv + cn3[j];
    }
}

// ------------------------------------------------- silu(g)*u -> g
__global__ void silu_mul_kernel(float* __restrict__ g, const float* __restrict__ u, int n)
{
    int i = blockIdx.x*blockDim.x + threadIdx.x;
    const int stride = gridDim.x*blockDim.x;
    for (; i<n; i+=stride){
        float x = g[i];
        float s = x / (1.f + __expf(-x));
        g[i] = s * u[i];
    }
}

// ------------------------------------------------- final rms + 3 scalar heads; h -> hout (text head via GEMM)
__global__ __launch_bounds__(256) void decode2(
    const float* __restrict__ x, const float* __restrict__ gout,
    const float* __restrict__ Wn, const float* __restrict__ bn,
    const float* __restrict__ Wd, const float* __restrict__ bd,
    const float* __restrict__ Wb, const float* __restrict__ bb,
    float* __restrict__ out, float* __restrict__ hout)
{
    const int row = blockIdx.x;
    const int t = threadIdx.x;
    __shared__ float h[DM];
    __shared__ float red[256];
    const float* xr = x + (size_t)row*DM;
    float v0=xr[t], v1=xr[t+256], v2=xr[t+512];
    red[t]=v0*v0+v1*v1+v2*v2; __syncthreads();
    for (int s=128;s>0;s>>=1){ if(t<s) red[t]+=red[t+s]; __syncthreads(); }
    float r = rsqrtf(red[0]/(float)DM + EPSF);
    float h0 = v0*r*gout[t], h1 = v1*r*gout[t+256], h2 = v2*r*gout[t+512];
    h[t]=h0; h[t+256]=h1; h[t+512]=h2;
    float* hr = hout + (size_t)row*DM;
    hr[t]=h0; hr[t+256]=h1; hr[t+512]=h2;
    __syncthreads();

    float pn=0.f,pd=0.f,pb=0.f;
    for (int k=t;k<DM;k+=256){ float hv=h[k]; pn+=hv*Wn[k]; pd+=hv*Wd[k]; pb+=hv*Wb[k]; }
    red[t]=pn; __syncthreads();
    for (int s=128;s>0;s>>=1){ if(t<s) red[t]+=red[t+s]; __syncthreads(); }
    float tn=red[0]; __syncthreads();
    red[t]=pd; __syncthreads();
    for (int s=128;s>0;s>>=1){ if(t<s) red[t]+=red[t+s]; __syncthreads(); }
    float td=red[0]; __syncthreads();
    red[t]=pb; __syncthreads();
    for (int s=128;s>0;s>>=1){ if(t<s) red[t]+=red[t+s]; __syncthreads(); }
    float tb=red[0];
    if (t==0){
        out[row]          = tn + bn[0];
        out[NROW + row]   = td + bd[0];
        out[2*NROW + row] = tb + bb[0];
    }
}

// =================================================================
// ===== round-4 fallback kernels (proven correct, f32 path)  ======
// =================================================================
__global__ __launch_bounds__(256) void encode_kernel(
    const float* __restrict__ numv, const float* __restrict__ dtv, const float* __restrict__ boolv,
    const float* __restrict__ textv, const float* __restrict__ cnamev,
    const float* __restrict__ Wcn, const float* __restrict__ bcn,
    const float* __restrict__ Wnum, const float* __restrict__ bnum,
    const float* __restrict__ Wtext, const float* __restrict__ btext,
    const float* __restrict__ Wdt, const float* __restrict__ bdt,
    const float* __restrict__ Wbool, const float* __restrict__ bbool,
    const float* __restrict__ gcn, const float* __restrict__ gnum, const float* __restrict__ gtext,
    const float* __restrict__ gdt, const float* __restrict__ gbool,
    const float* __restrict__ memb, const int* __restrict__ stypes, const u8* __restrict__ masks,
    float* __restrict__ x)
{
    const int row = blockIdx.x;
    const int t = threadIdx.x;
    __shared__ float vin[DT];
    __shared__ float red[256];
    for (int i=t;i<DT;i+=256) vin[i] = cnamev[(size_t)row*DT+i];
    __syncthreads();
    float cn[3]; float ss=0.f;
    #pragma unroll
    for (int j=0;j<3;j++){
        int e = t + j*256;
        float acc = bcn[e];
        for (int k=0;k<DT;k++) acc += vin[k]*Wcn[(size_t)k*DM+e];
        cn[j]=acc; ss += acc*acc;
    }
    red[t]=ss; __syncthreads();
    for (int s=128;s>0;s>>=1){ if(t<s) red[t]+=red[t+s]; __syncthreads(); }
    {
        float r = rsqrtf(red[0]/(float)DM + EPSF);
        #pragma unroll
        for (int j=0;j<3;j++){ int e=t+j*256; cn[j] *= r*gcn[e]; }
    }
    __syncthreads();
    const int st = stypes[row];
    float val[3]; ss=0.f;
    if (st==1){
        for (int i=t;i<DT;i+=256) vin[i] = textv[(size_t)row*DT+i];
        __syncthreads();
        #pragma unroll
        for (int j=0;j<3;j++){
            int e=t+j*256;
            float acc = btext[e];
            for (int k=0;k<DT;k++) acc += vin[k]*Wtext[(size_t)k*DM+e];
            val[j]=acc; ss+=acc*acc;
        }
    } else {
        const float* Wp = (st==0)?Wnum:((st==2)?Wdt:Wbool);
        const float* bp = (st==0)?bnum:((st==2)?bdt:bbool);
        const float* vp = (st==0)?numv:((st==2)?dtv:boolv);
        float v = vp[row];
        #pragma unroll
        for (int j=0;j<3;j++){
            int e=t+j*256;
            float acc = v*Wp[e] + bp[e];
            val[j]=acc; ss+=acc*acc;
        }
    }
    red[t]=ss; __syncthreads();
    for (int s=128;s>0;s>>=1){ if(t<s) red[t]+=red[t+s]; __syncthreads(); }
    const float* gp = (st==0)?gnum:((st==1)?gtext:((st==2)?gdt:gbool));
    float r2 = rsqrtf(red[0]/(float)DM + EPSF);
    bool mk = masks[row]!=0;
    #pragma unroll
    for (int j=0;j<3;j++){
        int e=t+j*256;
        float vv = val[j]*r2*gp[e];
        if (mk) vv = memb[st*DM+e];
        x[(size_t)row*DM+e] = vv + cn[j];
    }
}

__global__ __launch_bounds__(256) void gemm_kernel(
    const float* __restrict__ A, const float* __restrict__ W, float* __restrict__ C,
    int M, int N, int K, int acc)
{
    __shared__ float As[16][64];
    __shared__ float Ws[16][64];
    const int tid = threadIdx.x;
    const int m0 = blockIdx.y*64, n0 = blockIdx.x*64;
    const int ar = tid>>2, ac = tid&3;
    const int wr = tid>>4, wc = tid&15;
    const int tx = tid&15, ty = tid>>4;
    float acc4[4][4];
    #pragma unroll
    for (int i=0;i<4;i++)
        #pragma unroll
        for (int j=0;j<4;j++) acc4[i][j]=0.f;
    for (int k0=0;k0<K;k0+=16){
        float4 a4 = *(const float4*)(A + (size_t)(m0+ar)*K + k0 + ac*4);
        As[ac*4+0][ar]=a4.x; As[ac*4+1][ar]=a4.y; As[ac*4+2][ar]=a4.z; As[ac*4+3][ar]=a4.w;
        float4 w4 = *(const float4*)(W + (size_t)(k0+wr)*N + n0 + wc*4);
        *(float4*)&Ws[wr][wc*4] = w4;
        __syncthreads();
        #pragma unroll
        for (int kk=0;kk<16;kk++){
            float4 av = *(const float4*)&As[kk][ty*4];
            float4 wv = *(const float4*)&Ws[kk][tx*4];
            float aa[4]={av.x,av.y,av.z,av.w};
            float ww[4]={wv.x,wv.y,wv.z,wv.w};
            #pragma unroll
            for (int i=0;i<4;i++)
                #pragma unroll
                for (int j=0;j<4;j++) acc4[i][j] += aa[i]*ww[j];
        }
        __syncthreads();
    }
    #pragma unroll
    for (int i=0;i<4;i++){
        float* cp = C + (size_t)(m0+ty*4+i)*N + n0 + tx*4;
        float4 res = make_float4(acc4[i][0],acc4[i][1],acc4[i][2],acc4[i][3]);
        if (acc){
            float4 old = *(const float4*)cp;
            res.x+=old.x; res.y+=old.y; res.z+=old.z; res.w+=old.w;
        }
        *(float4*)cp = res;
    }
}

template<int MT>
__global__ __launch_bounds__(256) void attn_kernel(
    const float* __restrict__ qb, const float* __restrict__ kb, const float* __restrict__ vb,
    const int* __restrict__ node, const int* __restrict__ tbl, const int* __restrict__ colx,
    const int* __restrict__ f2p, const u8* __restrict__ pad,
    float* __restrict__ ob)
{
    const int bh = blockIdx.y;
    const int b = bh / NH, h = bh % NH;
    const int q0 = blockIdx.x * 64;
    const int tid = threadIdx.x;
    const int r = tid >> 2, sub = tid & 3;
    __shared__ float Qs[64][65];
    __shared__ u16   Ks[64][66];
    __shared__ u16   Vs[64][64];
    __shared__ float Ps[64][65];
    __shared__ int qN[64], qC[64], qT[64], qF[64][5];
    __shared__ int kN[64], kC[64], kT[64];
    __shared__ u8 qP[64], kP[64];
    {
        const float4* src = (const float4*)(qb + (size_t)(b*SS+q0+r)*DM + h*DH + sub*16);
        #pragma unroll
        for (int j4=0;j4<4;j4++){
            float4 tv = src[j4];
            int c = sub*16 + j4*4;
            Qs[r][c]=tv.x; Qs[r][c+1]=tv.y; Qs[r][c+2]=tv.z; Qs[r][c+3]=tv.w;
        }
    }
    if (tid<64){
        int gi = b*SS+q0+tid;
        qN[tid]=node[gi]; qC[tid]=colx[gi]; qT[tid]=tbl[gi]; qP[tid]=pad[gi];
        #pragma unroll
        for (int f=0;f<5;f++) qF[tid][f]=f2p[gi*5+f];
    }
    float o[16];
    #pragma unroll
    for (int j=0;j<16;j++) o[j]=0.f;
    float mrun=-INFINITY, lrun=0.f;
    for (int kc=0;kc<16;kc++){
        const int k0 = kc*64;
        __syncthreads();
        {
            const float4* ksrc = (const float4*)(kb + (size_t)(b*SS+k0+r)*DM + h*DH + sub*16);
            const float4* vsrc = (const float4*)(vb + (size_t)(b*SS+k0+r)*DM + h*DH + sub*16);
            #pragma unroll
            for (int j4=0;j4<4;j4++){
                float4 tk = ksrc[j4];
                float4 tv = vsrc[j4];
                int c = sub*16 + j4*4;
                Ks[r][c]=f2bu(tk.x); Ks[r][c+1]=f2bu(tk.y); Ks[r][c+2]=f2bu(tk.z); Ks[r][c+3]=f2bu(tk.w);
                Vs[r][c]=f2bu(tv.x); Vs[r][c+1]=f2bu(tv.y); Vs[r][c+2]=f2bu(tv.z); Vs[r][c+3]=f2bu(tv.w);
            }
        }
        if (tid<64){
            int gi = b*SS+k0+tid;
            kN[tid]=node[gi]; kC[tid]=colx[gi]; kT[tid]=tbl[gi]; kP[tid]=pad[gi];
        }
        __syncthreads();
        float s[16];
        #pragma unroll
        for (int j=0;j<16;j++) s[j]=0.f;
        for (int d=0;d<64;d+=2){
            float qa = Qs[r][d], qc = Qs[r][d+1];
            #pragma unroll
            for (int j=0;j<16;j++){
                unsigned int u = *(const unsigned int*)&Ks[sub*16+j][d];
                s[j] += qa*__uint_as_float(u<<16) + qc*__uint_as_float(u & 0xffff0000u);
            }
        }
        float smax = -INFINITY;
        const bool qpv = (qP[r]==0);
        #pragma unroll
        for (int j=0;j<16;j++){
            const int kk = sub*16+j;
            const bool eye = (q0+r) == (k0+kk);
            const bool pv = qpv && (kP[kk]==0);
            bool m;
            if (MT==0)      m = ((qC[r]==kC[kk]) && (qT[r]==kT[kk]) && pv) || eye;
            else if (MT==1) m = ((qN[r]==kN[kk]) && pv) || eye;
            else if (MT==2){
                int kn = kN[kk];
                bool nei = (qF[r][0]==kn)||(qF[r][1]==kn)||(qF[r][2]==kn)||(qF[r][3]==kn)||(qF[r][4]==kn);
                m = ((nei || (qN[r]==kn)) && pv) || eye;
            } else          m = pv || eye;
            float scv = s[j]*0.125f;
            scv = m ? scv : NEGF;
            s[j]=scv;
            smax = fmaxf(smax, scv);
        }
        smax = fmaxf(smax, __shfl_xor(smax,1));
        smax = fmaxf(smax, __shfl_xor(smax,2));
        const float mnew = fmaxf(mrun, smax);
        const float alpha = __expf(mrun - mnew);
        float ls = 0.f;
        #pragma unroll
        for (int j=0;j<16;j++){
            float p = __expf(s[j]-mnew);
            Ps[r][sub*16+j]=p;
            ls += p;
        }
        lrun = lrun*alpha + ls;
        mrun = mnew;
        #pragma unroll
        for (int j=0;j<16;j++) o[j]*=alpha;
        for (int kk=0;kk<64;kk++){
            float p = Ps[r][kk];
            const unsigned int* vrow = (const unsigned int*)&Vs[kk][sub*16];
            #pragma unroll
            for (int j2=0;j2<8;j2++){
                unsigned int u = vrow[j2];
                o[j2*2]   += p*__uint_as_float(u<<16);
                o[j2*2+1] += p*__uint_as_float(u & 0xffff0000u);
            }
        }
    }
    float lt = lrun + __shfl_xor(lrun,1);
    lt = lt + __shfl_xor(lt,2);
    const float inv = 1.f/lt;
    float* dst = ob + (size_t)(b*SS+q0+r)*DM + h*DH + sub*16;
    #pragma unroll
    for (int j=0;j<16;j++) dst[j] = o[j]*inv;
}

__global__ __launch_bounds__(256) void decode_kernel(
    const float* __restrict__ x, const float* __restrict__ gout,
    const float* __restrict__ Wn, const float* __restrict__ bn,
    const float* __restrict__ Wd, const float* __restrict__ bd,
    const float* __restrict__ Wb, const float* __restrict__ bb,
    const float* __restrict__ Wt, const float* __restrict__ bt,
    float* __restrict__ out)
{
    const int row = blockIdx.x;
    const int t = threadIdx.x;
    __shared__ float h[DM];
    __shared__ float red[256];
    const float* xr = x + (size_t)row*DM;
    float v0=xr[t], v1=xr[t+256], v2=xr[t+512];
    red[t]=v0*v0+v1*v1+v2*v2; __syncthreads();
    for (int s=128;s>0;s>>=1){ if(t<s) red[t]+=red[t+s]; __syncthreads(); }
    float r = rsqrtf(red[0]/(float)DM + EPSF);
    h[t]     = v0*r*gout[t];
    h[t+256] = v1*r*gout[t+256];
    h[t+512] = v2*r*gout[t+512];
    __syncthreads();
    float pn=0.f,pd=0.f,pb=0.f;
    for (int k=t;k<DM;k+=256){ float hv=h[k]; pn+=hv*Wn[k]; pd+=hv*Wd[k]; pb+=hv*Wb[k]; }
    red[t]=pn; __syncthreads();
    for (int s=128;s>0;s>>=1){ if(t<s) red[t]+=red[t+s]; __syncthreads(); }
    float tn=red[0]; __syncthreads();
    red[t]=pd; __syncthreads();
    for (int s=128;s>0;s>>=1){ if(t<s) red[t]+=red[t+s]; __syncthreads(); }
    float td=red[0]; __syncthreads();
    red[t]=pb; __syncthreads();
    for (int s=128;s>0;s>>=1){ if(t<s) red[t]+=red[t+s]; __syncthreads(); }
    float tb=red[0];
    if (t==0){
        out[row]          = tn + bn[0];
        out[NROW + row]   = td + bd[0];
        out[2*NROW + row] = tb + bb[0];
    }
    for (int e=t;e<DT;e+=256){
        float acc = bt[e];
        for (int k=0;k<DM;k++) acc += h[k]*Wt[(size_t)k*DT+e];
        out[3*NROW + (size_t)row*DT + e] = acc;
    }
}

// ---------------------------------------------------------------- launcher
extern "C" void kernel_launch(void* const* d_in, const int* in_sizes, int n_in,
                              void* d_out, int out_size, void* d_ws, size_t ws_size,
                              hipStream_t stream)
{
    const float* numv   = (const float*)d_in[0];
    const float* dtval  = (const float*)d_in[1];
    const float* boolv  = (const float*)d_in[2];
    const float* textv  = (const float*)d_in[3];
    const float* cnamev = (const float*)d_in[4];
    const float* Wcn=(const float*)d_in[5];  const float* bcn=(const float*)d_in[6];
    const float* Wnum=(const float*)d_in[7]; const float* bnum=(const float*)d_in[8];
    const float* Wtext=(const float*)d_in[9];const float* btext=(const float*)d_in[10];
    const float* Wdt=(const float*)d_in[11]; const float* bdt=(const float*)d_in[12];
    const float* Wbool=(const float*)d_in[13];const float* bbool=(const float*)d_in[14];
    const float* gcn=(const float*)d_in[15]; const float* gnum=(const float*)d_in[16];
    const float* gtext=(const float*)d_in[17];const float* gdt=(const float*)d_in[18];
    const float* gbool=(const float*)d_in[19];
    const float* memb=(const float*)d_in[20];
    const float* norms_all=(const float*)d_in[21];
    const float* attw_all=(const float*)d_in[22];
    const float* up_all=(const float*)d_in[23];
    const float* gate_all=(const float*)d_in[24];
    const float* down_all=(const float*)d_in[25];
    const float* gout=(const float*)d_in[26];
    const float* Wdn=(const float*)d_in[27]; const float* bdn=(const float*)d_in[28];
    const float* Wdd=(const float*)d_in[29]; const float* bdd=(const float*)d_in[30];
    const float* Wdb=(const float*)d_in[31]; const float* bdb=(const float*)d_in[32];
    const float* Wdtx=(const float*)d_in[33];const float* bdtx=(const float*)d_in[34];
    const int* node=(const int*)d_in[35];
    const int* tbl =(const int*)d_in[36];
    const int* colx=(const int*)d_in[37];
    const int* f2p =(const int*)d_in[38];
    const int* styp=(const int*)d_in[39];

    float* ws = (float*)d_ws;
    const size_t NX = (size_t)NROW*DM;   // 1,572,864

    // new-path layout
    float* x    = ws;
    float* xn   = ws + NX;
    float* pool = ws + 2*NX;             // 8*NX floats
    u16* qk16   = (u16*)pool;                        // 2048*1536 u16
    u16* vt16   = (u16*)(pool + NX);                 // 2*768*1024 u16
    float* obuf = pool + NX + NX/2;
    float* gbuf = pool;                  // MLP phase (aliases qk/vt/obuf)
    float* ubuf = pool + 4*NX;
    float* cnbuf  = pool;                // encode phase
    float* textbuf= pool + NX;

    u16* wT0 = (u16*)(ws + 10*NX);
    const size_t SA = (size_t)768*768;
    const size_t SG = (size_t)768*3072;
    const size_t SC = (size_t)384*768;
    u16* wA  = wT0;
    u16* wG  = wA + 64*SA;
    u16* wU  = wG + 4*SG;
    u16* wD  = wU + 4*SG;
    u16* wCN = wD + 4*SG;
    u16* wTX = wCN + SC;
    u16* wDX = wTX + SC;
    u8* nmask_new = (u8*)(wDX + SC);
    u8* npad_new  = nmask_new + NROW;
    size_t need = (size_t)((u8*)npad_new + NROW - (u8*)d_ws) + 256;

    float* out = (float*)d_out;

    if (ws_size >= need){
        // ---------------- MFMA path ----------------
        norm_bool_kernel<<<1,256,0,stream>>>(d_in[40], nmask_new, NROW);
        norm_bool_kernel<<<1,256,0,stream>>>(d_in[41], npad_new,  NROW);

        // weight prep
        transpose_cvt<<<dim3(24,24,64),256,0,stream>>>(attw_all, wA, 768, 768);
        transpose_cvt<<<dim3(96,24,4),256,0,stream>>>(gate_all, wG, 768, 3072);
        transpose_cvt<<<dim3(96,24,4),256,0,stream>>>(up_all,   wU, 768, 3072);
        transpose_cvt<<<dim3(24,96,4),256,0,stream>>>(down_all, wD, 3072, 768);
        transpose_cvt<<<dim3(24,12,1),256,0,stream>>>(Wcn,   wCN, 384, 768);
        transpose_cvt<<<dim3(24,12,1),256,0,stream>>>(Wtext, wTX, 384, 768);
        transpose_cvt<<<dim3(12,24,1),256,0,stream>>>(Wdtx,  wDX, 768, 384);

        // encode
        gemm_bf16<<<dim3(6,16),256,0,stream>>>(cnamev, wCN, cnbuf, NROW, 768, 384, 2, bcn, nullptr, nullptr);
        gemm_bf16<<<dim3(6,16),256,0,stream>>>(textv,  wTX, textbuf, NROW, 768, 384, 2, btext, nullptr, nullptr);
        fuse_encode<<<NROW,256,0,stream>>>(cnbuf, textbuf, numv, dtval, boolv,
            Wnum,bnum,Wdt,bdt,Wbool,bbool, gcn,gnum,gtext,gdt,gbool,
            memb, styp, nmask_new, x);

        const dim3 ga(SS/64, BB*NH);     // 16 x 24
        for (int l=0; l<NL; l++){
            const float* norms = norms_all + (size_t)l*5*DM;
            for (int a=0; a<4; a++){
                rms_kernel<<<NROW,256,0,stream>>>(x, norms + a*DM, xn);
                const u16* wqkv = wA + (size_t)((l*4+a)*4)*SA;
                gemm_bf16<<<dim3(18,16),256,0,stream>>>(xn, wqkv, nullptr, NROW, 2304, 768, 4, nullptr, qk16, vt16);
                if (a==0)      attn_mfma<0><<<ga,256,0,stream>>>(qk16,vt16,node,tbl,colx,f2p,npad_new,obuf);
                else if (a==1) attn_mfma<1><<<ga,256,0,stream>>>(qk16,vt16,node,tbl,colx,f2p,npad_new,obuf);
                else if (a==2) attn_mfma<2><<<ga,256,0,stream>>>(qk16,vt16,node,tbl,colx,f2p,npad_new,obuf);
                else           attn_mfma<3><<<ga,256,0,stream>>>(qk16,vt16,node,tbl,colx,f2p,npad_new,obuf);
                gemm_bf16<<<dim3(6,16),256,0,stream>>>(obuf, wqkv + 3*SA, x, NROW, 768, 768, 1, nullptr, nullptr, nullptr);
            }
            rms_kernel<<<NROW,256,0,stream>>>(x, norms + 4*DM, xn);
            gemm_bf16<<<dim3(24,16),256,0,stream>>>(xn, wG + (size_t)l*SG, gbuf, NROW, 3072, 768, 0, nullptr, nullptr, nullptr);
            gemm_bf16<<<dim3(24,16),256,0,stream>>>(xn, wU + (size_t)l*SG, ubuf, NROW, 3072, 768, 0, nullptr, nullptr, nullptr);
            silu_mul_kernel<<<2048,256,0,stream>>>(gbuf, ubuf, NROW*DFF);
            gemm_bf16<<<dim3(6,16),256,0,stream>>>(gbuf, wD + (size_t)l*SG, x, NROW, 768, 3072, 1, nullptr, nullptr, nullptr);
        }

        decode2<<<NROW,256,0,stream>>>(x, gout, Wdn,bdn, Wdd,bdd, Wdb,bdb, out, xn);
        gemm_bf16<<<dim3(3,16),256,0,stream>>>(xn, wDX, out + 3*NROW, NROW, 384, 768, 2, bdtx, nullptr, nullptr);
    } else {
        // ---------------- round-4 fallback ----------------
        float* qb   = ws + 2*NX;
        float* kbuf = ws + 3*NX;
        float* vbuf = ws + 4*NX;
        float* obufo= ws + 5*NX;
        float* gbufo= ws + 6*NX;
        float* ubufo= qb;
        u8* nmask = (u8*)(ws + 10*NX);
        u8* npad  = nmask + NROW;

        norm_bool_kernel<<<1,256,0,stream>>>(d_in[40], nmask, NROW);
        norm_bool_kernel<<<1,256,0,stream>>>(d_in[41], npad,  NROW);

        encode_kernel<<<NROW,256,0,stream>>>(numv,dtval,boolv,textv,cnamev,
            Wcn,bcn,Wnum,bnum,Wtext,btext,Wdt,bdt,Wbool,bbool,
            gcn,gnum,gtext,gdt,gbool,memb,styp,nmask,x);

        const dim3 g1(DM/64, NROW/64);
        const dim3 g2(DFF/64, NROW/64);
        const dim3 ga(SS/64, BB*NH);
        for (int l=0; l<NL; l++){
            const float* norms = norms_all + (size_t)l*5*DM;
            for (int a=0; a<4; a++){
                rms_kernel<<<NROW,256,0,stream>>>(x, norms + a*DM, xn);
                const float* aw = attw_all + (((size_t)l*4 + a)*4)*(size_t)DM*DM;
                gemm_kernel<<<g1,256,0,stream>>>(xn, aw + 0*(size_t)DM*DM, qb,   NROW, DM, DM, 0);
                gemm_kernel<<<g1,256,0,stream>>>(xn, aw + 1*(size_t)DM*DM, kbuf, NROW, DM, DM, 0);
                gemm_kernel<<<g1,256,0,stream>>>(xn, aw + 2*(size_t)DM*DM, vbuf, NROW, DM, DM, 0);
                if (a==0)      attn_kernel<0><<<ga,256,0,stream>>>(qb,kbuf,vbuf,node,tbl,colx,f2p,npad,obufo);
                else if (a==1) attn_kernel<1><<<ga,256,0,stream>>>(qb,kbuf,vbuf,node,tbl,colx,f2p,npad,obufo);
                else if (a==2) attn_kernel<2><<<ga,256,0,stream>>>(qb,kbuf,vbuf,node,tbl,colx,f2p,npad,obufo);
                else           attn_kernel<3><<<ga,256,0,stream>>>(qb,kbuf,vbuf,node,tbl,colx,f2p,npad,obufo);
                gemm_kernel<<<g1,256,0,stream>>>(obufo, aw + 3*(size_t)DM*DM, x, NROW, DM, DM, 1);
            }
            rms_kernel<<<NROW,256,0,stream>>>(x, norms + 4*DM, xn);
            gemm_kernel<<<g2,256,0,stream>>>(xn, gate_all + (size_t)l*DM*DFF, gbufo, NROW, DFF, DM, 0);
            gemm_kernel<<<g2,256,0,stream>>>(xn, up_all   + (size_t)l*DM*DFF, ubufo, NROW, DFF, DM, 0);
            silu_mul_kernel<<<2048,256,0,stream>>>(gbufo, ubufo, NROW*DFF);
            gemm_kernel<<<g1,256,0,stream>>>(gbufo, down_all + (size_t)l*DFF*DM, x, NROW, DM, DFF, 1);
        }
        decode_kernel<<<NROW,256,0,stream>>>(x, gout, Wdn,bdn, Wdd,bdd, Wdb,bdb, Wdtx,bdtx, out);
    }
}

// Round 6
// 2173.222 us; speedup vs baseline: 4.7361x; 1.5475x over previous
//
#include <hip/hip_runtime.h>
#include <hip/hip_bf16.h>
#include <cmath>
#include <stdint.h>

// Round 6: tiled-bf16 operands + global_load_lds direct staging + 2-phase dbuf pipeline.
// Tiled layout: [M/128][K/64][128][64] bf16, XOR-swizzled 16B units within each 128B row.

#define BB 2
#define SS 1024
#define DT 384
#define DM 768
#define NH 12
#define DH 64
#define DFF 3072
#define NL 4
#define NROW (BB*SS)
#define EPSF 1e-6f
#define NEGF (-1e9f)

typedef unsigned short u16;
typedef unsigned char u8;
typedef unsigned int u32;
typedef __attribute__((ext_vector_type(8))) short s16x8;
typedef __attribute__((ext_vector_type(4))) float f32x4;

__device__ __forceinline__ u16 f2bu(float f){
    u32 x = __float_as_uint(f);
    u32 r = (x + 0x7fffu + ((x>>16)&1u)) >> 16;   // RNE
    return (u16)r;
}
__device__ __forceinline__ float bfu(u16 u){ return __uint_as_float(((u32)u)<<16); }
__device__ __forceinline__ u32 pk2(float lo, float hi){
    return (u32)f2bu(lo) | ((u32)f2bu(hi)<<16);
}
// tiled element index: tile [128][64], row-major, 16B-unit XOR swizzle within row
__device__ __forceinline__ int swz(int row, int c){
    return (row<<6) + (((((c>>3) ^ row) & 7))<<3) + (c&7);
}
__device__ __forceinline__ float rmax16(float v){
    v = fmaxf(v, __shfl_xor(v,1)); v = fmaxf(v, __shfl_xor(v,2));
    v = fmaxf(v, __shfl_xor(v,4)); v = fmaxf(v, __shfl_xor(v,8));
    return v;
}
__device__ __forceinline__ float rsum16(float v){
    v += __shfl_xor(v,1); v += __shfl_xor(v,2);
    v += __shfl_xor(v,4); v += __shfl_xor(v,8);
    return v;
}

// ------------------------------------------------- bool-buffer normalizer
__global__ void norm_bool_kernel(const void* __restrict__ src, u8* __restrict__ dst, int n)
{
    __shared__ int cls;
    if (threadIdx.x==0){
        const u32* w = (const u32*)src;
        const int nw = n/4;
        bool bytes01=true, hiPos=false, low3f80=false, any=false;
        for (int i=0;i<nw;i++){
            u32 v=w[i];
            if (!v) continue;
            any=true;
            #pragma unroll
            for (int b=0;b<4;b++){
                u32 by=(v>>(8*b))&0xffu;
                if (by>1u) bytes01=false;
                if (by==1u && b!=0) hiPos=true;
            }
            if ((v&0xffffu)==0x3f80u) low3f80=true;
        }
        int c;
        if (!any) c=0;
        else if (bytes01) c = hiPos ? 2 : 1;
        else if (low3f80) c = 3;
        else c = 1;
        cls=c;
    }
    __syncthreads();
    const int c=cls;
    for (int i=threadIdx.x;i<n;i+=blockDim.x){
        u8 v;
        if (c==0)      v=0;
        else if (c==1) v = (((const u32*)src)[i]!=0u);
        else if (c==2) v = (((const u8*)src)[i]!=0u);
        else           v = (((const u16*)src)[i]!=0u);
        dst[i]=v;
    }
}

// ------------------------------------------------- weight f32 [K][N] -> tiled bf16 [N/128][K/64][128][64]
__global__ __launch_bounds__(256) void transpose_cvt(const float* __restrict__ src, u16* __restrict__ dst,
                                                     int K, int N)
{
    const int z = blockIdx.z;
    src += (size_t)z*K*N;
    dst += (size_t)z*K*N;
    const int n0 = blockIdx.x*32, k0 = blockIdx.y*32;
    __shared__ float t[32][33];
    const int tid = threadIdx.x;
    const int r = tid>>3, c4 = tid&7;
    float4 v = *(const float4*)(src + (size_t)(k0+r)*N + n0 + c4*4);
    t[r][c4*4+0]=v.x; t[r][c4*4+1]=v.y; t[r][c4*4+2]=v.z; t[r][c4*4+3]=v.w;
    __syncthreads();
    const int n = n0 + r, k = k0 + c4*4;
    uint2 o;
    o.x = pk2(t[c4*4+0][r], t[c4*4+1][r]);
    o.y = pk2(t[c4*4+2][r], t[c4*4+3][r]);
    *(uint2*)(dst + (((size_t)(n>>7)*(K>>6) + (k>>6))<<13) + (size_t)((n&127)<<6) + (k&63)) = o;
}

// ------------------------------------------------- activation f32 [M][K] -> tiled bf16
__global__ __launch_bounds__(256) void cvt_tiled(const float* __restrict__ src, u16* __restrict__ dst, int K)
{
    const int gid = blockIdx.x*256 + threadIdx.x;
    const int base = gid*8;
    const int row = base / K, col = base - row*K;
    float4 a = *(const float4*)(src + base);
    float4 b = *(const float4*)(src + base + 4);
    uint4 o;
    o.x = pk2(a.x,a.y); o.y = pk2(a.z,a.w);
    o.z = pk2(b.x,b.y); o.w = pk2(b.z,b.w);
    *(uint4*)&dst[(((size_t)(row>>7)*(K>>6) + (col>>6))<<13) + ((row&127)<<6) + (col&63)] = o;
}

// ------------------------------------------------- tiled-bf16 MFMA GEMM, 128x128xBK64, 2-phase dbuf
// flags: 1=acc into f32 C, 2=+bias, 4=qkv split, 8=bf16-tiled out
__device__ __forceinline__ void stage_pair(const u16* at, const u16* bt, u16* la, u16* lb,
                                           int w, int srow, int sgu)
{
    #pragma unroll
    for (int i=0;i<4;i++){
        const int c = (w<<2)+i;
        const int off = ((c<<3)+srow)*64 + (sgu<<3);
        __builtin_amdgcn_global_load_lds((const __attribute__((address_space(1))) u32*)(at+off),
            (__attribute__((address_space(3))) u32*)(la + (c<<9)), 16, 0, 0);
        __builtin_amdgcn_global_load_lds((const __attribute__((address_space(1))) u32*)(bt+off),
            (__attribute__((address_space(3))) u32*)(lb + (c<<9)), 16, 0, 0);
    }
}

__global__ __launch_bounds__(256) void gemm_t(
    const u16* __restrict__ At, const u16* __restrict__ Bt, float* __restrict__ C,
    int N, int K, int flags, const float* __restrict__ bias,
    u16* __restrict__ o16, u16* __restrict__ qk16, u16* __restrict__ vt16)
{
    __shared__ u16 lds[2][2][8192];     // 64KB
    const int tid = threadIdx.x;
    const int lane = tid & 63, w = tid >> 6;
    const int wm = w >> 1, wn = w & 1;
    const int cg = lane >> 4, cl = lane & 15;
    const int NT = K >> 6;
    const int srow = lane >> 3, sunit = lane & 7;
    const int sgu = (sunit ^ srow) & 7;

    const u16* aB = At + ((size_t)blockIdx.y * NT << 13);
    const u16* bB = Bt + ((size_t)blockIdx.x * NT << 13);

    f32x4 acc[4][4];
    #pragma unroll
    for (int i=0;i<4;i++)
        #pragma unroll
        for (int j=0;j<4;j++) acc[i][j] = (f32x4){0.f,0.f,0.f,0.f};

    stage_pair(aB, bB, &lds[0][0][0], &lds[0][1][0], w, srow, sgu);
    __syncthreads();
    int cur = 0;
    for (int kt=0; kt<NT; kt++){
        if (kt+1 < NT)
            stage_pair(aB + ((size_t)(kt+1)<<13), bB + ((size_t)(kt+1)<<13),
                       &lds[cur^1][0][0], &lds[cur^1][1][0], w, srow, sgu);
        #pragma unroll
        for (int ks=0; ks<2; ks++){
            s16x8 af[4], bf[4];
            #pragma unroll
            for (int t4=0;t4<4;t4++){
                const int ra = wm*64 + t4*16 + cl;
                af[t4] = *(const s16x8*)&lds[cur][0][(ra<<6) + ((((ks<<2)+cg) ^ ra)&7)*8];
                const int rb = wn*64 + t4*16 + cl;
                bf[t4] = *(const s16x8*)&lds[cur][1][(rb<<6) + ((((ks<<2)+cg) ^ rb)&7)*8];
            }
            #pragma unroll
            for (int mt=0;mt<4;mt++)
                #pragma unroll
                for (int nt=0;nt<4;nt++)
                    acc[mt][nt] = __builtin_amdgcn_mfma_f32_16x16x32_bf16(af[mt], bf[nt], acc[mt][nt], 0,0,0);
        }
        __syncthreads();
        cur ^= 1;
    }

    const int m0 = blockIdx.y*128, n0 = blockIdx.x*128;
    const bool do_acc = (flags&1), do_bias = (flags&2);
    if (flags & 4){
        // QKV split: cols<1536 -> qk16 linear [row][1536]; else transposed V [b*768+dh][1024]
        #pragma unroll
        for (int mt=0;mt<4;mt++){
            const int grow0 = m0 + wm*64 + mt*16 + cg*4;
            #pragma unroll
            for (int nt=0;nt<4;nt++){
                const int col = n0 + wn*64 + nt*16 + cl;
                if (col < 1536){
                    #pragma unroll
                    for (int j=0;j<4;j++)
                        qk16[(size_t)(grow0+j)*1536 + col] = f2bu(acc[mt][nt][j]);
                } else {
                    const int b = grow0>>10, s0 = grow0&1023;
                    const int dhg = col - 1536;
                    uint2 o;
                    o.x = pk2(acc[mt][nt][0], acc[mt][nt][1]);
                    o.y = pk2(acc[mt][nt][2], acc[mt][nt][3]);
                    *(uint2*)(vt16 + ((size_t)(b*768 + dhg)<<10) + s0) = o;
                }
            }
        }
    } else if (flags & 8){
        // bf16-tiled out [M/128][N/64][128][64]
        const int NC = N>>6;
        #pragma unroll
        for (int mt=0;mt<4;mt++){
            const int grow0 = m0 + wm*64 + mt*16 + cg*4;
            #pragma unroll
            for (int nt=0;nt<4;nt++){
                const int col = n0 + wn*64 + nt*16 + cl;
                const size_t tb = (((size_t)(grow0>>7)*NC + (col>>6))<<13) + (col&63);
                #pragma unroll
                for (int j=0;j<4;j++)
                    o16[tb + (((grow0+j)&127)<<6)] = f2bu(acc[mt][nt][j]);
            }
        }
    } else {
        #pragma unroll
        for (int mt=0;mt<4;mt++){
            const int grow0 = m0 + wm*64 + mt*16 + cg*4;
            #pragma unroll
            for (int nt=0;nt<4;nt++){
                const int col = n0 + wn*64 + nt*16 + cl;
                float bv = do_bias ? bias[col] : 0.f;
                #pragma unroll
                for (int j=0;j<4;j++){
                    float v = acc[mt][nt][j] + bv;
                    float* cp = C + (size_t)(grow0+j)*N + col;
                    if (do_acc) v += *cp;
                    *cp = v;
                }
            }
        }
    }
}

// ------------------------------------------------- MFMA flash attention (out: tiled bf16)
template<int MT>
__global__ __launch_bounds__(256) void attn_mfma(
    const u16* __restrict__ qk16, const u16* __restrict__ vt16,
    const int* __restrict__ node, const int* __restrict__ tbl, const int* __restrict__ colx,
    const int* __restrict__ f2p, const u8* __restrict__ pad,
    u16* __restrict__ ob16)
{
    const int bh = blockIdx.y;
    const int b = bh / NH, h = bh % NH;
    const int q0 = blockIdx.x * 64;
    const int tid = threadIdx.x;
    const int w = tid>>6, lane = tid&63, cg = lane>>4, cl = lane&15;

    __shared__ u16 Qs[64*64], Ks[64*64], Vt[64*64], Ps[64*64];
    __shared__ int kNs[64], kCs[64], kTs[64], kPs[64];

    #pragma unroll
    for (int p=0;p<2;p++){
        int idx = tid + p*256; int row = idx>>3, seg = idx&7;
        uint4 d = *(const uint4*)(qk16 + (size_t)(b*SS+q0+row)*1536 + h*64 + seg*8);
        *(uint4*)&Qs[(row<<6) + (((seg ^ row)&7)<<3)] = d;
    }
    int qn[4],qcx[4],qt[4],qp[4],qf[4][5];
    #pragma unroll
    for (int j=0;j<4;j++){
        int gq = b*SS + q0 + w*16 + cg*4 + j;
        qn[j]=node[gq]; qcx[j]=colx[gq]; qt[j]=tbl[gq]; qp[j]=pad[gq];
        if (MT==2){
            #pragma unroll
            for (int f=0;f<5;f++) qf[j][f]=f2p[gq*5+f];
        }
    }

    f32x4 o[4];
    #pragma unroll
    for (int nt=0;nt<4;nt++) o[nt] = (f32x4){0.f,0.f,0.f,0.f};
    float mrun[4], lrun[4];
    #pragma unroll
    for (int j=0;j<4;j++){ mrun[j]=-INFINITY; lrun[j]=0.f; }

    for (int kc=0;kc<16;kc++){
        const int k0 = kc*64;
        __syncthreads();
        #pragma unroll
        for (int p=0;p<2;p++){
            int idx = tid + p*256; int row = idx>>3, seg = idx&7;
            uint4 dk = *(const uint4*)(qk16 + (size_t)(b*SS+k0+row)*1536 + 768 + h*64 + seg*8);
            *(uint4*)&Ks[(row<<6) + (((seg ^ row)&7)<<3)] = dk;
            uint4 dv = *(const uint4*)(vt16 + ((size_t)(b*768 + h*64 + row)<<10) + k0 + seg*8);
            *(uint4*)&Vt[(row<<6) + (((seg ^ row)&7)<<3)] = dv;
        }
        if (tid<64){
            int gi = b*SS+k0+tid;
            kNs[tid]=node[gi]; kCs[tid]=colx[gi]; kTs[tid]=tbl[gi]; kPs[tid]=pad[gi];
        }
        __syncthreads();

        f32x4 sc[4];
        #pragma unroll
        for (int nt=0;nt<4;nt++) sc[nt] = (f32x4){0.f,0.f,0.f,0.f};
        #pragma unroll
        for (int ks=0;ks<2;ks++){
            s16x8 qa = *(const s16x8*)&Qs[swz(w*16+cl, ks*32+cg*8)];
            #pragma unroll
            for (int nt=0;nt<4;nt++){
                s16x8 kb = *(const s16x8*)&Ks[swz(nt*16+cl, ks*32+cg*8)];
                sc[nt] = __builtin_amdgcn_mfma_f32_16x16x32_bf16(qa, kb, sc[nt], 0,0,0);
            }
        }

        float pP[4][4];
        #pragma unroll
        for (int nt=0;nt<4;nt++){
            const int key = k0 + nt*16 + cl;
            const int kn = kNs[nt*16+cl], kcv = kCs[nt*16+cl], ktv = kTs[nt*16+cl], kp = kPs[nt*16+cl];
            #pragma unroll
            for (int j=0;j<4;j++){
                float sv = sc[nt][j]*0.125f;
                const int qrow = q0 + w*16 + cg*4 + j;
                const bool eye = (qrow == key);
                const bool pv = (qp[j]==0) && (kp==0);
                bool m;
                if (MT==0)      m = ((qcx[j]==kcv) && (qt[j]==ktv) && pv) || eye;
                else if (MT==1) m = ((qn[j]==kn) && pv) || eye;
                else if (MT==2){
                    bool nei = (qf[j][0]==kn)||(qf[j][1]==kn)||(qf[j][2]==kn)||(qf[j][3]==kn)||(qf[j][4]==kn);
                    m = ((nei || (qn[j]==kn)) && pv) || eye;
                } else          m = pv || eye;
                pP[nt][j] = m ? sv : NEGF;
            }
        }

        #pragma unroll
        for (int j=0;j<4;j++){
            float mx = fmaxf(fmaxf(pP[0][j],pP[1][j]), fmaxf(pP[2][j],pP[3][j]));
            mx = rmax16(mx);
            float mnew = fmaxf(mrun[j], mx);
            float al = __expf(mrun[j]-mnew);
            mrun[j] = mnew;
            float ps = 0.f;
            #pragma unroll
            for (int nt=0;nt<4;nt++){
                float pe = __expf(pP[nt][j]-mnew);
                pP[nt][j]=pe; ps += pe;
            }
            ps = rsum16(ps);
            lrun[j] = lrun[j]*al + ps;
            #pragma unroll
            for (int nt=0;nt<4;nt++) o[nt][j] *= al;
        }

        #pragma unroll
        for (int nt=0;nt<4;nt++)
            #pragma unroll
            for (int j=0;j<4;j++)
                Ps[swz(w*16+cg*4+j, nt*16+cl)] = f2bu(pP[nt][j]);

        #pragma unroll
        for (int ks=0;ks<2;ks++){
            s16x8 pa = *(const s16x8*)&Ps[swz(w*16+cl, ks*32+cg*8)];
            #pragma unroll
            for (int nt=0;nt<4;nt++){
                s16x8 vb = *(const s16x8*)&Vt[swz(nt*16+cl, ks*32+cg*8)];
                o[nt] = __builtin_amdgcn_mfma_f32_16x16x32_bf16(pa, vb, o[nt], 0,0,0);
            }
        }
    }

    #pragma unroll
    for (int j=0;j<4;j++){
        const float inv = 1.f/lrun[j];
        const int row = b*SS + q0 + w*16 + cg*4 + j;
        const size_t rb = ((size_t)(row>>7)*12 + h)*8192 + ((row&127)<<6);
        #pragma unroll
        for (int nt=0;nt<4;nt++)
            ob16[rb + nt*16 + cl] = f2bu(o[nt][j]*inv);
    }
}

// ------------------------------------------------- rmsnorm: f32 in -> tiled bf16 out (K=768)
__global__ __launch_bounds__(256) void rms_kernel(const float* __restrict__ x,
                                                  const float* __restrict__ g,
                                                  u16* __restrict__ y)
{
    const int row = blockIdx.x;
    const int t = threadIdx.x;
    __shared__ float red[256];
    const float* xr = x + (size_t)row*DM;
    float v0=xr[t], v1=xr[t+256], v2=xr[t+512];
    red[t] = v0*v0+v1*v1+v2*v2; __syncthreads();
    for (int s=128;s>0;s>>=1){ if(t<s) red[t]+=red[t+s]; __syncthreads(); }
    float r = rsqrtf(red[0]/(float)DM + EPSF);
    const size_t mb = (size_t)(row>>7)*12;
    const int rr = (row&127)<<6;
    #pragma unroll
    for (int j=0;j<3;j++){
        const int c = t + j*256;
        const float v = (j==0?v0:(j==1?v1:v2)) * r * g[c];
        y[((mb + (c>>6))<<13) + rr + (c&63)] = f2bu(v);
    }
}

// ------------------------------------------------- encode fuse (f32 linear in, f32 x out)
__global__ __launch_bounds__(256) void fuse_encode(
    const float* __restrict__ cnbuf, const float* __restrict__ textbuf,
    const float* __restrict__ numv, const float* __restrict__ dtv, const float* __restrict__ boolv,
    const float* __restrict__ Wnum, const float* __restrict__ bnum,
    const float* __restrict__ Wdt, const float* __restrict__ bdt,
    const float* __restrict__ Wbool, const float* __restrict__ bbool,
    const float* __restrict__ gcn, const float* __restrict__ gnum, const float* __restrict__ gtext,
    const float* __restrict__ gdt, const float* __restrict__ gbool,
    const float* __restrict__ memb, const int* __restrict__ stypes, const u8* __restrict__ masks,
    float* __restrict__ x)
{
    const int row = blockIdx.x;
    const int t = threadIdx.x;
    __shared__ float red[256];

    float cn3[3]; float ss=0.f;
    #pragma unroll
    for (int j=0;j<3;j++){
        cn3[j] = cnbuf[(size_t)row*DM + t + j*256];
        ss += cn3[j]*cn3[j];
    }
    red[t]=ss; __syncthreads();
    for (int s=128;s>0;s>>=1){ if(t<s) red[t]+=red[t+s]; __syncthreads(); }
    {
        float r = rsqrtf(red[0]/(float)DM + EPSF);
        #pragma unroll
        for (int j=0;j<3;j++) cn3[j] *= r*gcn[t+j*256];
    }
    __syncthreads();

    const int st = stypes[row];
    float val[3]; ss=0.f;
    if (st==1){
        #pragma unroll
        for (int j=0;j<3;j++){
            val[j] = textbuf[(size_t)row*DM + t + j*256];
            ss += val[j]*val[j];
        }
    } else {
        const float* Wp = (st==0)?Wnum:((st==2)?Wdt:Wbool);
        const float* bp = (st==0)?bnum:((st==2)?bdt:bbool);
        const float* vp = (st==0)?numv:((st==2)?dtv:boolv);
        float v = vp[row];
        #pragma unroll
        for (int j=0;j<3;j++){
            int e=t+j*256;
            val[j] = v*Wp[e] + bp[e];
            ss += val[j]*val[j];
        }
    }
    red[t]=ss; __syncthreads();
    for (int s=128;s>0;s>>=1){ if(t<s) red[t]+=red[t+s]; __syncthreads(); }
    const float* gp = (st==0)?gnum:((st==1)?gtext:((st==2)?gdt:gbool));
    float r2 = rsqrtf(red[0]/(float)DM + EPSF);
    bool mk = masks[row]!=0;
    #pragma unroll
    for (int j=0;j<3;j++){
        int e=t+j*256;
        float vv = val[j]*r2*gp[e];
        if (mk) vv = memb[st*DM+e];
        x[(size_t)row*DM+e] = vv + cn3[j];
    }
}

// ------------------------------------------------- silu on identical tiled layouts (flat)
__global__ void silu_flat(u16* __restrict__ g, const u16* __restrict__ u, int n8)
{
    int i = blockIdx.x*blockDim.x + threadIdx.x;
    const int stride = gridDim.x*blockDim.x;
    for (; i<n8; i+=stride){
        uint4 gv = ((const uint4*)g)[i];
        uint4 uv = ((const uint4*)u)[i];
        u32 go[4]; const u32* gp=(const u32*)&gv; const u32* up=(const u32*)&uv;
        #pragma unroll
        for (int k=0;k<4;k++){
            float g0 = __uint_as_float(gp[k]<<16), g1 = __uint_as_float(gp[k]&0xffff0000u);
            float u0 = __uint_as_float(up[k]<<16), u1 = __uint_as_float(up[k]&0xffff0000u);
            float s0 = g0/(1.f+__expf(-g0))*u0;
            float s1 = g1/(1.f+__expf(-g1))*u1;
            go[k] = pk2(s0, s1);
        }
        ((uint4*)g)[i] = make_uint4(go[0],go[1],go[2],go[3]);
    }
}

// ------------------------------------------------- final rms + 3 scalar heads; h -> tiled bf16
__global__ __launch_bounds__(256) void decode2(
    const float* __restrict__ x, const float* __restrict__ gout,
    const float* __restrict__ Wn, const float* __restrict__ bn,
    const float* __restrict__ Wd, const float* __restrict__ bd,
    const float* __restrict__ Wb, const float* __restrict__ bb,
    float* __restrict__ out, u16* __restrict__ h16)
{
    const int row = blockIdx.x;
    const int t = threadIdx.x;
    __shared__ float h[DM];
    __shared__ float red[256];
    const float* xr = x + (size_t)row*DM;
    float v0=xr[t], v1=xr[t+256], v2=xr[t+512];
    red[t]=v0*v0+v1*v1+v2*v2; __syncthreads();
    for (int s=128;s>0;s>>=1){ if(t<s) red[t]+=red[t+s]; __syncthreads(); }
    float r = rsqrtf(red[0]/(float)DM + EPSF);
    float h0 = v0*r*gout[t], h1 = v1*r*gout[t+256], h2 = v2*r*gout[t+512];
    h[t]=h0; h[t+256]=h1; h[t+512]=h2;
    const size_t mb = (size_t)(row>>7)*12;
    const int rr = (row&127)<<6;
    #pragma unroll
    for (int j=0;j<3;j++){
        const int c = t + j*256;
        const float v = (j==0?h0:(j==1?h1:h2));
        h16[((mb + (c>>6))<<13) + rr + (c&63)] = f2bu(v);
    }
    __syncthreads();

    float pn=0.f,pd=0.f,pb=0.f;
    for (int k=t;k<DM;k+=256){ float hv=h[k]; pn+=hv*Wn[k]; pd+=hv*Wd[k]; pb+=hv*Wb[k]; }
    red[t]=pn; __syncthreads();
    for (int s=128;s>0;s>>=1){ if(t<s) red[t]+=red[t+s]; __syncthreads(); }
    float tn=red[0]; __syncthreads();
    red[t]=pd; __syncthreads();
    for (int s=128;s>0;s>>=1){ if(t<s) red[t]+=red[t+s]; __syncthreads(); }
    float td=red[0]; __syncthreads();
    red[t]=pb; __syncthreads();
    for (int s=128;s>0;s>>=1){ if(t<s) red[t]+=red[t+s]; __syncthreads(); }
    float tb=red[0];
    if (t==0){
        out[row]          = tn + bn[0];
        out[NROW + row]   = td + bd[0];
        out[2*NROW + row] = tb + bb[0];
    }
}

// ---------------------------------------------------------------- launcher
extern "C" void kernel_launch(void* const* d_in, const int* in_sizes, int n_in,
                              void* d_out, int out_size, void* d_ws, size_t ws_size,
                              hipStream_t stream)
{
    const float* numv   = (const float*)d_in[0];
    const float* dtval  = (const float*)d_in[1];
    const float* boolv  = (const float*)d_in[2];
    const float* textv  = (const float*)d_in[3];
    const float* cnamev = (const float*)d_in[4];
    const float* Wcn=(const float*)d_in[5];  const float* bcn=(const float*)d_in[6];
    const float* Wnum=(const float*)d_in[7]; const float* bnum=(const float*)d_in[8];
    const float* Wtext=(const float*)d_in[9];const float* btext=(const float*)d_in[10];
    const float* Wdt=(const float*)d_in[11]; const float* bdt=(const float*)d_in[12];
    const float* Wbool=(const float*)d_in[13];const float* bbool=(const float*)d_in[14];
    const float* gcn=(const float*)d_in[15]; const float* gnum=(const float*)d_in[16];
    const float* gtext=(const float*)d_in[17];const float* gdt=(const float*)d_in[18];
    const float* gbool=(const float*)d_in[19];
    const float* memb=(const float*)d_in[20];
    const float* norms_all=(const float*)d_in[21];
    const float* attw_all=(const float*)d_in[22];
    const float* up_all=(const float*)d_in[23];
    const float* gate_all=(const float*)d_in[24];
    const float* down_all=(const float*)d_in[25];
    const float* gout=(const float*)d_in[26];
    const float* Wdn=(const float*)d_in[27]; const float* bdn=(const float*)d_in[28];
    const float* Wdd=(const float*)d_in[29]; const float* bdd=(const float*)d_in[30];
    const float* Wdb=(const float*)d_in[31]; const float* bdb=(const float*)d_in[32];
    const float* Wdtx=(const float*)d_in[33];const float* bdtx=(const float*)d_in[34];
    const int* node=(const int*)d_in[35];
    const int* tbl =(const int*)d_in[36];
    const int* colx=(const int*)d_in[37];
    const int* f2p =(const int*)d_in[38];
    const int* styp=(const int*)d_in[39];

    u8* base = (u8*)d_ws;
    float* x  = (float*)base;                        // 6,291,456 B
    u16* xn16 = (u16*)(base + 6291456);              // 3,145,728
    u16* ob16 = (u16*)(base + 9437184);              // 3,145,728
    u16* qk16 = (u16*)(base + 12582912);             // 6,291,456
    u16* vt16 = (u16*)(base + 18874368);             // 3,145,728
    u16* g16  = (u16*)(base + 22020096);             // 12,582,912
    u16* u16b = (u16*)(base + 34603008);             // 12,582,912
    u16* wA   = (u16*)(base + 47185920);             // 64*589824*2
    const size_t SA = (size_t)768*768;
    const size_t SG = (size_t)768*3072;
    const size_t SC = (size_t)384*768;
    u16* wG  = wA + 64*SA;
    u16* wU  = wG + 4*SG;
    u16* wD  = wU + 4*SG;
    u16* wCN = wD + 4*SG;
    u16* wTX = wCN + SC;
    u16* wDX = wTX + SC;
    u8* nmask = (u8*)(wDX + SC);
    u8* npad  = nmask + NROW;

    // encode-phase aliases
    u16* cnT16   = qk16;            // 2048x384 tiled
    u16* textT16 = vt16;
    float* cnbuf   = (float*)g16;   // 2048x768 f32
    float* textbuf = (float*)u16b;

    float* out = (float*)d_out;

    norm_bool_kernel<<<1,256,0,stream>>>(d_in[40], nmask, NROW);
    norm_bool_kernel<<<1,256,0,stream>>>(d_in[41], npad,  NROW);

    // weight prep (tiled bf16)
    transpose_cvt<<<dim3(24,24,64),256,0,stream>>>(attw_all, wA, 768, 768);
    transpose_cvt<<<dim3(96,24,4),256,0,stream>>>(gate_all, wG, 768, 3072);
    transpose_cvt<<<dim3(96,24,4),256,0,stream>>>(up_all,   wU, 768, 3072);
    transpose_cvt<<<dim3(24,96,4),256,0,stream>>>(down_all, wD, 3072, 768);
    transpose_cvt<<<dim3(24,12,1),256,0,stream>>>(Wcn,   wCN, 384, 768);
    transpose_cvt<<<dim3(24,12,1),256,0,stream>>>(Wtext, wTX, 384, 768);
    transpose_cvt<<<dim3(12,24,1),256,0,stream>>>(Wdtx,  wDX, 768, 384);

    // encode
    cvt_tiled<<<384,256,0,stream>>>(cnamev, cnT16, 384);
    cvt_tiled<<<384,256,0,stream>>>(textv,  textT16, 384);
    gemm_t<<<dim3(6,16),256,0,stream>>>(cnT16, wCN, cnbuf, 768, 384, 2, bcn, nullptr, nullptr, nullptr);
    gemm_t<<<dim3(6,16),256,0,stream>>>(textT16, wTX, textbuf, 768, 384, 2, btext, nullptr, nullptr, nullptr);
    fuse_encode<<<NROW,256,0,stream>>>(cnbuf, textbuf, numv, dtval, boolv,
        Wnum,bnum,Wdt,bdt,Wbool,bbool, gcn,gnum,gtext,gdt,gbool,
        memb, styp, nmask, x);

    const dim3 ga(SS/64, BB*NH);     // 16 x 24
    for (int l=0; l<NL; l++){
        const float* norms = norms_all + (size_t)l*5*DM;
        for (int a=0; a<4; a++){
            rms_kernel<<<NROW,256,0,stream>>>(x, norms + a*DM, xn16);
            const u16* wqkv = wA + (size_t)((l*4+a)*4)*SA;
            gemm_t<<<dim3(18,16),256,0,stream>>>(xn16, wqkv, nullptr, 2304, 768, 4, nullptr, nullptr, qk16, vt16);
            if (a==0)      attn_mfma<0><<<ga,256,0,stream>>>(qk16,vt16,node,tbl,colx,f2p,npad,ob16);
            else if (a==1) attn_mfma<1><<<ga,256,0,stream>>>(qk16,vt16,node,tbl,colx,f2p,npad,ob16);
            else if (a==2) attn_mfma<2><<<ga,256,0,stream>>>(qk16,vt16,node,tbl,colx,f2p,npad,ob16);
            else           attn_mfma<3><<<ga,256,0,stream>>>(qk16,vt16,node,tbl,colx,f2p,npad,ob16);
            gemm_t<<<dim3(6,16),256,0,stream>>>(ob16, wqkv + 3*SA, x, 768, 768, 1, nullptr, nullptr, nullptr, nullptr);
        }
        rms_kernel<<<NROW,256,0,stream>>>(x, norms + 4*DM, xn16);
        gemm_t<<<dim3(24,16),256,0,stream>>>(xn16, wG + (size_t)l*SG, nullptr, 3072, 768, 8, nullptr, g16, nullptr, nullptr);
        gemm_t<<<dim3(24,16),256,0,stream>>>(xn16, wU + (size_t)l*SG, nullptr, 3072, 768, 8, nullptr, u16b, nullptr, nullptr);
        silu_flat<<<1024,256,0,stream>>>(g16, u16b, NROW*DFF/8);
        gemm_t<<<dim3(6,16),256,0,stream>>>(g16, wD + (size_t)l*SG, x, 768, 3072, 1, nullptr, nullptr, nullptr, nullptr);
    }

    decode2<<<NROW,256,0,stream>>>(x, gout, Wdn,bdn, Wdd,bdd, Wdb,bdb, out, xn16);
    gemm_t<<<dim3(3,16),256,0,stream>>>(xn16, wDX, out + 3*NROW, 384, 768, 2, bdtx, nullptr, nullptr, nullptr);
}

// Round 7
// 1959.852 us; speedup vs baseline: 5.2517x; 1.1089x over previous
//
#include <hip/hip_runtime.h>
#include <hip/hip_bf16.h>
#include <cmath>
#include <stdint.h>

// Round 7: counted-vmcnt GEMM pipeline (T4), fused gate+up (N=6144), coalesced weight prep,
// global_load_lds attention staging, parallel bool-probe.

#define BB 2
#define SS 1024
#define DT 384
#define DM 768
#define NH 12
#define DH 64
#define DFF 3072
#define NL 4
#define NROW (BB*SS)
#define EPSF 1e-6f
#define NEGF (-1e9f)

typedef unsigned short u16;
typedef unsigned char u8;
typedef unsigned int u32;
typedef __attribute__((ext_vector_type(8))) short s16x8;
typedef __attribute__((ext_vector_type(4))) float f32x4;

__device__ __forceinline__ u16 f2bu(float f){
    u32 x = __float_as_uint(f);
    u32 r = (x + 0x7fffu + ((x>>16)&1u)) >> 16;   // RNE
    return (u16)r;
}
__device__ __forceinline__ u32 pk2(float lo, float hi){
    return (u32)f2bu(lo) | ((u32)f2bu(hi)<<16);
}
// tiled element index: tile [128][64], row-major, 16B-unit XOR swizzle within row
__device__ __forceinline__ int swz(int row, int c){
    return (row<<6) + (((((c>>3) ^ row) & 7))<<3) + (c&7);
}
__device__ __forceinline__ float rmax16(float v){
    v = fmaxf(v, __shfl_xor(v,1)); v = fmaxf(v, __shfl_xor(v,2));
    v = fmaxf(v, __shfl_xor(v,4)); v = fmaxf(v, __shfl_xor(v,8));
    return v;
}
__device__ __forceinline__ float rsum16(float v){
    v += __shfl_xor(v,1); v += __shfl_xor(v,2);
    v += __shfl_xor(v,4); v += __shfl_xor(v,8);
    return v;
}
#define SBAR() __builtin_amdgcn_sched_barrier(0)

// ------------------------------------------------- bool-buffer normalizer (parallel probe)
__global__ void norm_bool_kernel(const void* __restrict__ src, u8* __restrict__ dst, int n)
{
    __shared__ int fl[4];   // any, non-bytes01, hiPos, low3f80
    if (threadIdx.x<4) fl[threadIdx.x]=0;
    __syncthreads();
    const u32* wsrc = (const u32*)src;
    const int nw = n/4;
    int any=0, nb=0, hi=0, lo=0;
    for (int i=threadIdx.x;i<nw;i+=blockDim.x){
        u32 v=wsrc[i];
        if (!v) continue;
        any=1;
        #pragma unroll
        for (int b=0;b<4;b++){
            u32 by=(v>>(8*b))&0xffu;
            if (by>1u) nb=1;
            if (by==1u && b!=0) hi=1;
        }
        if ((v&0xffffu)==0x3f80u) lo=1;
    }
    if (any) atomicOr(&fl[0],1);
    if (nb)  atomicOr(&fl[1],1);
    if (hi)  atomicOr(&fl[2],1);
    if (lo)  atomicOr(&fl[3],1);
    __syncthreads();
    int c;
    if (!fl[0]) c=0;
    else if (!fl[1]) c = fl[2] ? 2 : 1;
    else if (fl[3]) c = 3;
    else c = 1;
    for (int i=threadIdx.x;i<n;i+=blockDim.x){
        u8 v;
        if (c==0)      v=0;
        else if (c==1) v = (((const u32*)src)[i]!=0u);
        else if (c==2) v = (((const u8*)src)[i]!=0u);
        else           v = (((const u16*)src)[i]!=0u);
        dst[i]=v;
    }
}

// ------------------------------------------------- weight f32 [K][N] -> tiled bf16 [N/128][K/64][128][64]
// coalesced: block = 32 n-rows x 64 k; writes full 128B tile rows
__global__ __launch_bounds__(256) void transpose_cvt2(const float* __restrict__ src, u16* __restrict__ dst,
                                                      int K, int N, size_t dz)
{
    src += (size_t)blockIdx.z*K*N;
    dst += (size_t)blockIdx.z*dz;
    const int n0 = blockIdx.x*32, k0 = blockIdx.y*64;
    __shared__ float t[64][33];
    const int tid = threadIdx.x;
    const int kr = tid>>3, n4 = (tid&7)*4;
    #pragma unroll
    for (int p=0;p<2;p++){
        const int k = p*32 + kr;
        float4 v = *(const float4*)(src + (size_t)(k0+k)*N + n0 + n4);
        t[k][n4]=v.x; t[k][n4+1]=v.y; t[k][n4+2]=v.z; t[k][n4+3]=v.w;
    }
    __syncthreads();
    const int n = tid>>3, ks = (tid&7)*8;
    const int ng = n0 + n;
    uint4 o;
    u32* op = (u32*)&o;
    #pragma unroll
    for (int i=0;i<4;i++)
        op[i] = pk2(t[ks+2*i][n], t[ks+2*i+1][n]);
    *(uint4*)&dst[(((size_t)(ng>>7)*(K>>6) + (k0>>6))<<13) + ((ng&127)<<6) + ks] = o;
}

// ------------------------------------------------- activation f32 [M][K] -> tiled bf16
__global__ __launch_bounds__(256) void cvt_tiled(const float* __restrict__ src, u16* __restrict__ dst, int K)
{
    const int gid = blockIdx.x*256 + threadIdx.x;
    const int base = gid*8;
    const int row = base / K, col = base - row*K;
    float4 a = *(const float4*)(src + base);
    float4 b = *(const float4*)(src + base + 4);
    uint4 o;
    o.x = pk2(a.x,a.y); o.y = pk2(a.z,a.w);
    o.z = pk2(b.x,b.y); o.w = pk2(b.z,b.w);
    *(uint4*)&dst[(((size_t)(row>>7)*(K>>6) + (col>>6))<<13) + ((row&127)<<6) + (col&63)] = o;
}

// ------------------------------------------------- tiled-bf16 MFMA GEMM, 128x128xBK64, counted-vmcnt dbuf
// flags: 1=acc into f32 C, 2=+bias, 4=qkv split, 8=bf16-tiled out
__device__ __forceinline__ void stage_pair(const u16* at, const u16* bt, u16* la, u16* lb,
                                           int w, int srow, int sgu)
{
    #pragma unroll
    for (int i=0;i<4;i++){
        const int c = (w<<2)+i;
        const int off = ((c<<3)+srow)*64 + (sgu<<3);
        __builtin_amdgcn_global_load_lds((const __attribute__((address_space(1))) u32*)(at+off),
            (__attribute__((address_space(3))) u32*)(la + (c<<9)), 16, 0, 0);
        __builtin_amdgcn_global_load_lds((const __attribute__((address_space(1))) u32*)(bt+off),
            (__attribute__((address_space(3))) u32*)(lb + (c<<9)), 16, 0, 0);
    }
}

__global__ __launch_bounds__(256) void gemm_t(
    const u16* __restrict__ At, const u16* __restrict__ Bt, float* __restrict__ C,
    int N, int K, int AMS, int flags, const float* __restrict__ bias,
    u16* __restrict__ o16, u16* __restrict__ qk16, u16* __restrict__ vt16)
{
    __shared__ u16 lds[2][2][8192];     // 64KB
    const int tid = threadIdx.x;
    const int lane = tid & 63, w = tid >> 6;
    const int wm = w >> 1, wn = w & 1;
    const int cg = lane >> 4, cl = lane & 15;
    const int NT = K >> 6;
    const int srow = lane >> 3, sunit = lane & 7;
    const int sgu = (sunit ^ srow) & 7;

    const u16* aB = At + ((size_t)blockIdx.y * AMS << 13);
    const u16* bB = Bt + ((size_t)blockIdx.x * NT << 13);

    f32x4 acc[4][4];
    #pragma unroll
    for (int i=0;i<4;i++)
        #pragma unroll
        for (int j=0;j<4;j++) acc[i][j] = (f32x4){0.f,0.f,0.f,0.f};

    stage_pair(aB, bB, &lds[0][0][0], &lds[0][1][0], w, srow, sgu);
    int cur = 0;
    for (int kt=0; kt<NT; kt++){
        if (kt+1 < NT){
            stage_pair(aB + ((size_t)(kt+1)<<13), bB + ((size_t)(kt+1)<<13),
                       &lds[cur^1][0][0], &lds[cur^1][1][0], w, srow, sgu);
            asm volatile("s_waitcnt vmcnt(8)" ::: "memory");   // wait only tile kt's 8 loads
        } else {
            asm volatile("s_waitcnt vmcnt(0)" ::: "memory");
        }
        SBAR(); __builtin_amdgcn_s_barrier(); SBAR();
        #pragma unroll
        for (int ks=0; ks<2; ks++){
            s16x8 af[4], bf[4];
            #pragma unroll
            for (int t4=0;t4<4;t4++){
                const int ra = wm*64 + t4*16 + cl;
                af[t4] = *(const s16x8*)&lds[cur][0][(ra<<6) + ((((ks<<2)+cg) ^ ra)&7)*8];
                const int rb = wn*64 + t4*16 + cl;
                bf[t4] = *(const s16x8*)&lds[cur][1][(rb<<6) + ((((ks<<2)+cg) ^ rb)&7)*8];
            }
            #pragma unroll
            for (int mt=0;mt<4;mt++)
                #pragma unroll
                for (int nt=0;nt<4;nt++)
                    acc[mt][nt] = __builtin_amdgcn_mfma_f32_16x16x32_bf16(af[mt], bf[nt], acc[mt][nt], 0,0,0);
        }
        SBAR(); __builtin_amdgcn_s_barrier(); SBAR();
        cur ^= 1;
    }

    const int m0 = blockIdx.y*128, n0 = blockIdx.x*128;
    const bool do_acc = (flags&1), do_bias = (flags&2);
    if (flags & 4){
        #pragma unroll
        for (int mt=0;mt<4;mt++){
            const int grow0 = m0 + wm*64 + mt*16 + cg*4;
            #pragma unroll
            for (int nt=0;nt<4;nt++){
                const int col = n0 + wn*64 + nt*16 + cl;
                if (col < 1536){
                    #pragma unroll
                    for (int j=0;j<4;j++)
                        qk16[(size_t)(grow0+j)*1536 + col] = f2bu(acc[mt][nt][j]);
                } else {
                    const int b = grow0>>10, s0 = grow0&1023;
                    const int dhg = col - 1536;
                    uint2 o;
                    o.x = pk2(acc[mt][nt][0], acc[mt][nt][1]);
                    o.y = pk2(acc[mt][nt][2], acc[mt][nt][3]);
                    *(uint2*)(vt16 + ((size_t)(b*768 + dhg)<<10) + s0) = o;
                }
            }
        }
    } else if (flags & 8){
        const int NC = N>>6;
        #pragma unroll
        for (int mt=0;mt<4;mt++){
            const int grow0 = m0 + wm*64 + mt*16 + cg*4;
            #pragma unroll
            for (int nt=0;nt<4;nt++){
                const int col = n0 + wn*64 + nt*16 + cl;
                const size_t tb = (((size_t)(grow0>>7)*NC + (col>>6))<<13) + (col&63);
                #pragma unroll
                for (int j=0;j<4;j++)
                    o16[tb + (((grow0+j)&127)<<6)] = f2bu(acc[mt][nt][j]);
            }
        }
    } else {
        #pragma unroll
        for (int mt=0;mt<4;mt++){
            const int grow0 = m0 + wm*64 + mt*16 + cg*4;
            #pragma unroll
            for (int nt=0;nt<4;nt++){
                const int col = n0 + wn*64 + nt*16 + cl;
                float bv = do_bias ? bias[col] : 0.f;
                #pragma unroll
                for (int j=0;j<4;j++){
                    float v = acc[mt][nt][j] + bv;
                    float* cp = C + (size_t)(grow0+j)*N + col;
                    if (do_acc) v += *cp;
                    *cp = v;
                }
            }
        }
    }
}

// ------------------------------------------------- MFMA flash attention (gload_lds staging)
template<int MT>
__global__ __launch_bounds__(256) void attn_mfma(
    const u16* __restrict__ qk16, const u16* __restrict__ vt16,
    const int* __restrict__ node, const int* __restrict__ tbl, const int* __restrict__ colx,
    const int* __restrict__ f2p, const u8* __restrict__ pad,
    u16* __restrict__ ob16)
{
    const int bh = blockIdx.y;
    const int b = bh / NH, h = bh % NH;
    const int q0 = blockIdx.x * 64;
    const int tid = threadIdx.x;
    const int w = tid>>6, lane = tid&63, cg = lane>>4, cl = lane&15;
    const int srow = lane>>3;                 // row within wave's 8-row group
    const int sseg = (lane&7) ^ srow;         // pre-swizzled source unit

    __shared__ u16 Qs[64*64], Ks[64*64], Vt[64*64], Ps[64*64];
    __shared__ int kNs[64], kCs[64], kTs[64], kPs[64];

    // Q stage via global_load_lds (linear dest, pre-swizzled source)
    {
        const u16* qbase = qk16 + (size_t)(b*SS+q0)*1536 + h*64;
        #pragma unroll
        for (int p=0;p<2;p++){
            const int row = p*32 + w*8 + srow;
            __builtin_amdgcn_global_load_lds(
                (const __attribute__((address_space(1))) u32*)(qbase + (size_t)row*1536 + sseg*8),
                (__attribute__((address_space(3))) u32*)(Qs + p*2048 + w*512), 16, 0, 0);
        }
    }
    int qn[4],qcx[4],qt[4],qp[4],qf[4][5];
    #pragma unroll
    for (int j=0;j<4;j++){
        int gq = b*SS + q0 + w*16 + cg*4 + j;
        qn[j]=node[gq]; qcx[j]=colx[gq]; qt[j]=tbl[gq]; qp[j]=pad[gq];
        if (MT==2){
            #pragma unroll
            for (int f=0;f<5;f++) qf[j][f]=f2p[gq*5+f];
        }
    }

    f32x4 o[4];
    #pragma unroll
    for (int nt=0;nt<4;nt++) o[nt] = (f32x4){0.f,0.f,0.f,0.f};
    float mrun[4], lrun[4];
    #pragma unroll
    for (int j=0;j<4;j++){ mrun[j]=-INFINITY; lrun[j]=0.f; }

    for (int kc=0;kc<16;kc++){
        const int k0 = kc*64;
        __syncthreads();
        {
            const u16* kbase = qk16 + (size_t)(b*SS+k0)*1536 + 768 + h*64;
            const u16* vbase = vt16 + (((size_t)(b*768 + h*64))<<10) + k0;
            #pragma unroll
            for (int p=0;p<2;p++){
                const int row = p*32 + w*8 + srow;
                __builtin_amdgcn_global_load_lds(
                    (const __attribute__((address_space(1))) u32*)(kbase + (size_t)row*1536 + sseg*8),
                    (__attribute__((address_space(3))) u32*)(Ks + p*2048 + w*512), 16, 0, 0);
                __builtin_amdgcn_global_load_lds(
                    (const __attribute__((address_space(1))) u32*)(vbase + ((size_t)row<<10) + sseg*8),
                    (__attribute__((address_space(3))) u32*)(Vt + p*2048 + w*512), 16, 0, 0);
            }
        }
        if (tid<64){
            int gi = b*SS+k0+tid;
            kNs[tid]=node[gi]; kCs[tid]=colx[gi]; kTs[tid]=tbl[gi]; kPs[tid]=pad[gi];
        }
        __syncthreads();

        f32x4 sc[4];
        #pragma unroll
        for (int nt=0;nt<4;nt++) sc[nt] = (f32x4){0.f,0.f,0.f,0.f};
        #pragma unroll
        for (int ks=0;ks<2;ks++){
            s16x8 qa = *(const s16x8*)&Qs[swz(w*16+cl, ks*32+cg*8)];
            #pragma unroll
            for (int nt=0;nt<4;nt++){
                s16x8 kb = *(const s16x8*)&Ks[swz(nt*16+cl, ks*32+cg*8)];
                sc[nt] = __builtin_amdgcn_mfma_f32_16x16x32_bf16(qa, kb, sc[nt], 0,0,0);
            }
        }

        float pP[4][4];
        #pragma unroll
        for (int nt=0;nt<4;nt++){
            const int key = k0 + nt*16 + cl;
            const int kn = kNs[nt*16+cl], kcv = kCs[nt*16+cl], ktv = kTs[nt*16+cl], kp = kPs[nt*16+cl];
            #pragma unroll
            for (int j=0;j<4;j++){
                float sv = sc[nt][j]*0.125f;
                const int qrow = q0 + w*16 + cg*4 + j;
                const bool eye = (qrow == key);
                const bool pv = (qp[j]==0) && (kp==0);
                bool m;
                if (MT==0)      m = ((qcx[j]==kcv) && (qt[j]==ktv) && pv) || eye;
                else if (MT==1) m = ((qn[j]==kn) && pv) || eye;
                else if (MT==2){
                    bool nei = (qf[j][0]==kn)||(qf[j][1]==kn)||(qf[j][2]==kn)||(qf[j][3]==kn)||(qf[j][4]==kn);
                    m = ((nei || (qn[j]==kn)) && pv) || eye;
                } else          m = pv || eye;
                pP[nt][j] = m ? sv : NEGF;
            }
        }

        #pragma unroll
        for (int j=0;j<4;j++){
            float mx = fmaxf(fmaxf(pP[0][j],pP[1][j]), fmaxf(pP[2][j],pP[3][j]));
            mx = rmax16(mx);
            float mnew = fmaxf(mrun[j], mx);
            float al = __expf(mrun[j]-mnew);
            mrun[j] = mnew;
            float ps = 0.f;
            #pragma unroll
            for (int nt=0;nt<4;nt++){
                float pe = __expf(pP[nt][j]-mnew);
                pP[nt][j]=pe; ps += pe;
            }
            ps = rsum16(ps);
            lrun[j] = lrun[j]*al + ps;
            #pragma unroll
            for (int nt=0;nt<4;nt++) o[nt][j] *= al;
        }

        #pragma unroll
        for (int nt=0;nt<4;nt++)
            #pragma unroll
            for (int j=0;j<4;j++)
                Ps[swz(w*16+cg*4+j, nt*16+cl)] = f2bu(pP[nt][j]);

        #pragma unroll
        for (int ks=0;ks<2;ks++){
            s16x8 pa = *(const s16x8*)&Ps[swz(w*16+cl, ks*32+cg*8)];
            #pragma unroll
            for (int nt=0;nt<4;nt++){
                s16x8 vb = *(const s16x8*)&Vt[swz(nt*16+cl, ks*32+cg*8)];
                o[nt] = __builtin_amdgcn_mfma_f32_16x16x32_bf16(pa, vb, o[nt], 0,0,0);
            }
        }
    }

    #pragma unroll
    for (int j=0;j<4;j++){
        const float inv = 1.f/lrun[j];
        const int row = b*SS + q0 + w*16 + cg*4 + j;
        const size_t rb = ((size_t)(row>>7)*12 + h)*8192 + ((row&127)<<6);
        #pragma unroll
        for (int nt=0;nt<4;nt++)
            ob16[rb + nt*16 + cl] = f2bu(o[nt][j]*inv);
    }
}

// ------------------------------------------------- rmsnorm: f32 in -> tiled bf16 out (K=768)
__global__ __launch_bounds__(256) void rms_kernel(const float* __restrict__ x,
                                                  const float* __restrict__ g,
                                                  u16* __restrict__ y)
{
    const int row = blockIdx.x;
    const int t = threadIdx.x;
    __shared__ float red[256];
    const float* xr = x + (size_t)row*DM;
    float v0=xr[t], v1=xr[t+256], v2=xr[t+512];
    red[t] = v0*v0+v1*v1+v2*v2; __syncthreads();
    for (int s=128;s>0;s>>=1){ if(t<s) red[t]+=red[t+s]; __syncthreads(); }
    float r = rsqrtf(red[0]/(float)DM + EPSF);
    const size_t mb = (size_t)(row>>7)*12;
    const int rr = (row&127)<<6;
    #pragma unroll
    for (int j=0;j<3;j++){
        const int c = t + j*256;
        const float v = (j==0?v0:(j==1?v1:v2)) * r * g[c];
        y[((mb + (c>>6))<<13) + rr + (c&63)] = f2bu(v);
    }
}

// ------------------------------------------------- encode fuse
__global__ __launch_bounds__(256) void fuse_encode(
    const float* __restrict__ cnbuf, const float* __restrict__ textbuf,
    const float* __restrict__ numv, const float* __restrict__ dtv, const float* __restrict__ boolv,
    const float* __restrict__ Wnum, const float* __restrict__ bnum,
    const float* __restrict__ Wdt, const float* __restrict__ bdt,
    const float* __restrict__ Wbool, const float* __restrict__ bbool,
    const float* __restrict__ gcn, const float* __restrict__ gnum, const float* __restrict__ gtext,
    const float* __restrict__ gdt, const float* __restrict__ gbool,
    const float* __restrict__ memb, const int* __restrict__ stypes, const u8* __restrict__ masks,
    float* __restrict__ x)
{
    const int row = blockIdx.x;
    const int t = threadIdx.x;
    __shared__ float red[256];

    float cn3[3]; float ss=0.f;
    #pragma unroll
    for (int j=0;j<3;j++){
        cn3[j] = cnbuf[(size_t)row*DM + t + j*256];
        ss += cn3[j]*cn3[j];
    }
    red[t]=ss; __syncthreads();
    for (int s=128;s>0;s>>=1){ if(t<s) red[t]+=red[t+s]; __syncthreads(); }
    {
        float r = rsqrtf(red[0]/(float)DM + EPSF);
        #pragma unroll
        for (int j=0;j<3;j++) cn3[j] *= r*gcn[t+j*256];
    }
    __syncthreads();

    const int st = stypes[row];
    float val[3]; ss=0.f;
    if (st==1){
        #pragma unroll
        for (int j=0;j<3;j++){
            val[j] = textbuf[(size_t)row*DM + t + j*256];
            ss += val[j]*val[j];
        }
    } else {
        const float* Wp = (st==0)?Wnum:((st==2)?Wdt:Wbool);
        const float* bp = (st==0)?bnum:((st==2)?bdt:bbool);
        const float* vp = (st==0)?numv:((st==2)?dtv:boolv);
        float v = vp[row];
        #pragma unroll
        for (int j=0;j<3;j++){
            int e=t+j*256;
            val[j] = v*Wp[e] + bp[e];
            ss += val[j]*val[j];
        }
    }
    red[t]=ss; __syncthreads();
    for (int s=128;s>0;s>>=1){ if(t<s) red[t]+=red[t+s]; __syncthreads(); }
    const float* gp = (st==0)?gnum:((st==1)?gtext:((st==2)?gdt:gbool));
    float r2 = rsqrtf(red[0]/(float)DM + EPSF);
    bool mk = masks[row]!=0;
    #pragma unroll
    for (int j=0;j<3;j++){
        int e=t+j*256;
        float vv = val[j]*r2*gp[e];
        if (mk) vv = memb[st*DM+e];
        x[(size_t)row*DM+e] = vv + cn3[j];
    }
}

// ------------------------------------------------- silu on fused gate-up tiled buffer [16][96][8192]
__global__ void silu_gu(u16* __restrict__ gu, int nu)   // nu = units over gate half (uint4)
{
    int i = blockIdx.x*blockDim.x + threadIdx.x;
    const int stride = gridDim.x*blockDim.x;
    for (; i<nu; i+=stride){
        const int mt = i / (48*1024);
        const int r  = i - mt*48*1024;
        const size_t gi = (size_t)(mt*96)*1024 + r;
        const size_t ui = gi + 48*1024;
        uint4 gv = ((const uint4*)gu)[gi];
        uint4 uv = ((const uint4*)gu)[ui];
        u32 go[4]; const u32* gp=(const u32*)&gv; const u32* up=(const u32*)&uv;
        #pragma unroll
        for (int k=0;k<4;k++){
            float g0 = __uint_as_float(gp[k]<<16), g1 = __uint_as_float(gp[k]&0xffff0000u);
            float u0 = __uint_as_float(up[k]<<16), u1 = __uint_as_float(up[k]&0xffff0000u);
            float s0 = g0/(1.f+__expf(-g0))*u0;
            float s1 = g1/(1.f+__expf(-g1))*u1;
            go[k] = pk2(s0, s1);
        }
        ((uint4*)gu)[gi] = make_uint4(go[0],go[1],go[2],go[3]);
    }
}

// ------------------------------------------------- final rms + 3 scalar heads; h -> tiled bf16
__global__ __launch_bounds__(256) void decode2(
    const float* __restrict__ x, const float* __restrict__ gout,
    const float* __restrict__ Wn, const float* __restrict__ bn,
    const float* __restrict__ Wd, const float* __restrict__ bd,
    const float* __restrict__ Wb, const float* __restrict__ bb,
    float* __restrict__ out, u16* __restrict__ h16)
{
    const int row = blockIdx.x;
    const int t = threadIdx.x;
    __shared__ float h[DM];
    __shared__ float red[256];
    const float* xr = x + (size_t)row*DM;
    float v0=xr[t], v1=xr[t+256], v2=xr[t+512];
    red[t]=v0*v0+v1*v1+v2*v2; __syncthreads();
    for (int s=128;s>0;s>>=1){ if(t<s) red[t]+=red[t+s]; __syncthreads(); }
    float r = rsqrtf(red[0]/(float)DM + EPSF);
    float h0 = v0*r*gout[t], h1 = v1*r*gout[t+256], h2 = v2*r*gout[t+512];
    h[t]=h0; h[t+256]=h1; h[t+512]=h2;
    const size_t mb = (size_t)(row>>7)*12;
    const int rr = (row&127)<<6;
    #pragma unroll
    for (int j=0;j<3;j++){
        const int c = t + j*256;
        const float v = (j==0?h0:(j==1?h1:h2));
        h16[((mb + (c>>6))<<13) + rr + (c&63)] = f2bu(v);
    }
    __syncthreads();

    float pn=0.f,pd=0.f,pb=0.f;
    for (int k=t;k<DM;k+=256){ float hv=h[k]; pn+=hv*Wn[k]; pd+=hv*Wd[k]; pb+=hv*Wb[k]; }
    red[t]=pn; __syncthreads();
    for (int s=128;s>0;s>>=1){ if(t<s) red[t]+=red[t+s]; __syncthreads(); }
    float tn=red[0]; __syncthreads();
    red[t]=pd; __syncthreads();
    for (int s=128;s>0;s>>=1){ if(t<s) red[t]+=red[t+s]; __syncthreads(); }
    float td=red[0]; __syncthreads();
    red[t]=pb; __syncthreads();
    for (int s=128;s>0;s>>=1){ if(t<s) red[t]+=red[t+s]; __syncthreads(); }
    float tb=red[0];
    if (t==0){
        out[row]          = tn + bn[0];
        out[NROW + row]   = td + bd[0];
        out[2*NROW + row] = tb + bb[0];
    }
}

// ---------------------------------------------------------------- launcher
extern "C" void kernel_launch(void* const* d_in, const int* in_sizes, int n_in,
                              void* d_out, int out_size, void* d_ws, size_t ws_size,
                              hipStream_t stream)
{
    const float* numv   = (const float*)d_in[0];
    const float* dtval  = (const float*)d_in[1];
    const float* boolv  = (const float*)d_in[2];
    const float* textv  = (const float*)d_in[3];
    const float* cnamev = (const float*)d_in[4];
    const float* Wcn=(const float*)d_in[5];  const float* bcn=(const float*)d_in[6];
    const float* Wnum=(const float*)d_in[7]; const float* bnum=(const float*)d_in[8];
    const float* Wtext=(const float*)d_in[9];const float* btext=(const float*)d_in[10];
    const float* Wdt=(const float*)d_in[11]; const float* bdt=(const float*)d_in[12];
    const float* Wbool=(const float*)d_in[13];const float* bbool=(const float*)d_in[14];
    const float* gcn=(const float*)d_in[15]; const float* gnum=(const float*)d_in[16];
    const float* gtext=(const float*)d_in[17];const float* gdt=(const float*)d_in[18];
    const float* gbool=(const float*)d_in[19];
    const float* memb=(const float*)d_in[20];
    const float* norms_all=(const float*)d_in[21];
    const float* attw_all=(const float*)d_in[22];
    const float* up_all=(const float*)d_in[23];
    const float* gate_all=(const float*)d_in[24];
    const float* down_all=(const float*)d_in[25];
    const float* gout=(const float*)d_in[26];
    const float* Wdn=(const float*)d_in[27]; const float* bdn=(const float*)d_in[28];
    const float* Wdd=(const float*)d_in[29]; const float* bdd=(const float*)d_in[30];
    const float* Wdb=(const float*)d_in[31]; const float* bdb=(const float*)d_in[32];
    const float* Wdtx=(const float*)d_in[33];const float* bdtx=(const float*)d_in[34];
    const int* node=(const int*)d_in[35];
    const int* tbl =(const int*)d_in[36];
    const int* colx=(const int*)d_in[37];
    const int* f2p =(const int*)d_in[38];
    const int* styp=(const int*)d_in[39];

    const size_t SA = (size_t)768*768;
    const size_t SG = (size_t)768*3072;
    const size_t SC = (size_t)384*768;
    const size_t NX = (size_t)NROW*DM;

    u8* base = (u8*)d_ws;
    float* x  = (float*)base;                        // 6,291,456 B
    u16* xn16 = (u16*)(base + 6291456);
    u16* ob16 = (u16*)(base + 9437184);
    u16* qk16 = (u16*)(base + 12582912);
    u16* vt16 = (u16*)(base + 18874368);
    u16* gu16 = (u16*)(base + 22020096);             // 25,165,824 B (2048 x 6144 bf16 tiled)
    u16* wA   = (u16*)(base + 47185920);
    u16* wGU  = wA + 64*SA;                          // 4 layers x [gate|up] = 4 x 2SG
    u16* wD   = wGU + 8*SG;
    u16* wCN  = wD + 4*SG;
    u16* wTX  = wCN + SC;
    u16* wDX  = wTX + SC;
    u8* nmask = (u8*)(wDX + SC);
    u8* npad  = nmask + NROW;

    // encode-phase aliases
    u16* cnT16   = qk16;
    u16* textT16 = vt16;
    float* cnbuf   = (float*)gu16;
    float* textbuf = cnbuf + NX;

    float* out = (float*)d_out;

    norm_bool_kernel<<<1,256,0,stream>>>(d_in[40], nmask, NROW);
    norm_bool_kernel<<<1,256,0,stream>>>(d_in[41], npad,  NROW);

    // weight prep (tiled bf16, coalesced writes)
    transpose_cvt2<<<dim3(24,12,64),256,0,stream>>>(attw_all, wA, 768, 768, SA);
    transpose_cvt2<<<dim3(96,12,4),256,0,stream>>>(gate_all, wGU,      768, 3072, 2*SG);
    transpose_cvt2<<<dim3(96,12,4),256,0,stream>>>(up_all,   wGU + SG, 768, 3072, 2*SG);
    transpose_cvt2<<<dim3(24,48,4),256,0,stream>>>(down_all, wD, 3072, 768, SG);
    transpose_cvt2<<<dim3(24,6,1),256,0,stream>>>(Wcn,   wCN, 384, 768, 0);
    transpose_cvt2<<<dim3(24,6,1),256,0,stream>>>(Wtext, wTX, 384, 768, 0);
    transpose_cvt2<<<dim3(12,12,1),256,0,stream>>>(Wdtx, wDX, 768, 384, 0);

    // encode
    cvt_tiled<<<384,256,0,stream>>>(cnamev, cnT16, 384);
    cvt_tiled<<<384,256,0,stream>>>(textv,  textT16, 384);
    gemm_t<<<dim3(6,16),256,0,stream>>>(cnT16,   wCN, cnbuf,   768, 384, 6, 2, bcn,   nullptr, nullptr, nullptr);
    gemm_t<<<dim3(6,16),256,0,stream>>>(textT16, wTX, textbuf, 768, 384, 6, 2, btext, nullptr, nullptr, nullptr);
    fuse_encode<<<NROW,256,0,stream>>>(cnbuf, textbuf, numv, dtval, boolv,
        Wnum,bnum,Wdt,bdt,Wbool,bbool, gcn,gnum,gtext,gdt,gbool,
        memb, styp, nmask, x);

    const dim3 ga(SS/64, BB*NH);     // 16 x 24
    for (int l=0; l<NL; l++){
        const float* norms = norms_all + (size_t)l*5*DM;
        for (int a=0; a<4; a++){
            rms_kernel<<<NROW,256,0,stream>>>(x, norms + a*DM, xn16);
            const u16* wqkv = wA + (size_t)((l*4+a)*4)*SA;
            gemm_t<<<dim3(18,16),256,0,stream>>>(xn16, wqkv, nullptr, 2304, 768, 12, 4, nullptr, nullptr, qk16, vt16);
            if (a==0)      attn_mfma<0><<<ga,256,0,stream>>>(qk16,vt16,node,tbl,colx,f2p,npad,ob16);
            else if (a==1) attn_mfma<1><<<ga,256,0,stream>>>(qk16,vt16,node,tbl,colx,f2p,npad,ob16);
            else if (a==2) attn_mfma<2><<<ga,256,0,stream>>>(qk16,vt16,node,tbl,colx,f2p,npad,ob16);
            else           attn_mfma<3><<<ga,256,0,stream>>>(qk16,vt16,node,tbl,colx,f2p,npad,ob16);
            gemm_t<<<dim3(6,16),256,0,stream>>>(ob16, wqkv + 3*SA, x, 768, 768, 12, 1, nullptr, nullptr, nullptr, nullptr);
        }
        rms_kernel<<<NROW,256,0,stream>>>(x, norms + 4*DM, xn16);
        gemm_t<<<dim3(48,16),256,0,stream>>>(xn16, wGU + (size_t)l*2*SG, nullptr, 6144, 768, 12, 8, nullptr, gu16, nullptr, nullptr);
        silu_gu<<<1024,256,0,stream>>>(gu16, 16*48*1024);
        gemm_t<<<dim3(6,16),256,0,stream>>>(gu16, wD + (size_t)l*SG, x, 768, 3072, 96, 1, nullptr, nullptr, nullptr, nullptr);
    }

    decode2<<<NROW,256,0,stream>>>(x, gout, Wdn,bdn, Wdd,bdd, Wdb,bdb, out, xn16);
    gemm_t<<<dim3(3,16),256,0,stream>>>(xn16, wDX, out + 3*NROW, 384, 768, 12, 2, bdtx, nullptr, nullptr, nullptr);
}

// Round 8
// 1832.365 us; speedup vs baseline: 5.6171x; 1.0696x over previous
//
#include <hip/hip_runtime.h>
#include <hip/hip_bf16.h>
#include <cmath>
#include <stdint.h>

// Round 8: GEMM 128x64xBK32 triple-buffer counted-vmcnt (4 blocks/CU); attention packed-meta +
// K/V dbuf counted-vmcnt; all stored operand tiles remain [128][64] bf16 linear.

#define BB 2
#define SS 1024
#define DT 384
#define DM 768
#define NH 12
#define DH 64
#define DFF 3072
#define NL 4
#define NROW (BB*SS)
#define EPSF 1e-6f
#define NEGF (-1e9f)

typedef unsigned short u16;
typedef unsigned char u8;
typedef unsigned int u32;
typedef __attribute__((ext_vector_type(8))) short s16x8;
typedef __attribute__((ext_vector_type(4))) float f32x4;

__device__ __forceinline__ u16 f2bu(float f){
    u32 x = __float_as_uint(f);
    u32 r = (x + 0x7fffu + ((x>>16)&1u)) >> 16;   // RNE
    return (u16)r;
}
__device__ __forceinline__ u32 pk2(float lo, float hi){
    return (u32)f2bu(lo) | ((u32)f2bu(hi)<<16);
}
// 64-col tile swizzle (8 units of 16B, XOR row&7)
__device__ __forceinline__ int swz(int row, int c){
    return (row<<6) + (((((c>>3) ^ row) & 7))<<3) + (c&7);
}
__device__ __forceinline__ float rmax16(float v){
    v = fmaxf(v, __shfl_xor(v,1)); v = fmaxf(v, __shfl_xor(v,2));
    v = fmaxf(v, __shfl_xor(v,4)); v = fmaxf(v, __shfl_xor(v,8));
    return v;
}
__device__ __forceinline__ float rsum16(float v){
    v += __shfl_xor(v,1); v += __shfl_xor(v,2);
    v += __shfl_xor(v,4); v += __shfl_xor(v,8);
    return v;
}
#define SBAR() __builtin_amdgcn_sched_barrier(0)
#define GLDS(src,dst) __builtin_amdgcn_global_load_lds((const __attribute__((address_space(1))) u32*)(src), (__attribute__((address_space(3))) u32*)(dst), 16, 0, 0)

// ------------------------------------------------- bool-buffer normalizer
__global__ void norm_bool_kernel(const void* __restrict__ src, u8* __restrict__ dst, int n)
{
    __shared__ int fl[4];
    if (threadIdx.x<4) fl[threadIdx.x]=0;
    __syncthreads();
    const u32* wsrc = (const u32*)src;
    const int nw = n/4;
    int any=0, nb=0, hi=0, lo=0;
    for (int i=threadIdx.x;i<nw;i+=blockDim.x){
        u32 v=wsrc[i];
        if (!v) continue;
        any=1;
        #pragma unroll
        for (int b=0;b<4;b++){
            u32 by=(v>>(8*b))&0xffu;
            if (by>1u) nb=1;
            if (by==1u && b!=0) hi=1;
        }
        if ((v&0xffffu)==0x3f80u) lo=1;
    }
    if (any) atomicOr(&fl[0],1);
    if (nb)  atomicOr(&fl[1],1);
    if (hi)  atomicOr(&fl[2],1);
    if (lo)  atomicOr(&fl[3],1);
    __syncthreads();
    int c;
    if (!fl[0]) c=0;
    else if (!fl[1]) c = fl[2] ? 2 : 1;
    else if (fl[3]) c = 3;
    else c = 1;
    for (int i=threadIdx.x;i<n;i+=blockDim.x){
        u8 v;
        if (c==0)      v=0;
        else if (c==1) v = (((const u32*)src)[i]!=0u);
        else if (c==2) v = (((const u8*)src)[i]!=0u);
        else           v = (((const u16*)src)[i]!=0u);
        dst[i]=v;
    }
}

// ------------------------------------------------- pack per-token metadata: node|col<<8|tbl<<16|pad<<24
__global__ void pack_meta(const int* __restrict__ node, const int* __restrict__ colx,
                          const int* __restrict__ tbl, const u8* __restrict__ pad,
                          u32* __restrict__ pm, int n)
{
    int i = blockIdx.x*256 + threadIdx.x;
    if (i<n)
        pm[i] = (u32)(node[i]&0xff) | ((u32)(colx[i]&0xff)<<8) | ((u32)(tbl[i]&0xff)<<16) | ((u32)(pad[i]&1)<<24);
}

// ------------------------------------------------- weight f32 [K][N] -> tiled bf16 [N/128][K/64][128][64]
__global__ __launch_bounds__(256) void transpose_cvt2(const float* __restrict__ src, u16* __restrict__ dst,
                                                      int K, int N, size_t dz)
{
    src += (size_t)blockIdx.z*K*N;
    dst += (size_t)blockIdx.z*dz;
    const int n0 = blockIdx.x*32, k0 = blockIdx.y*64;
    __shared__ float t[64][33];
    const int tid = threadIdx.x;
    const int kr = tid>>3, n4 = (tid&7)*4;
    #pragma unroll
    for (int p=0;p<2;p++){
        const int k = p*32 + kr;
        float4 v = *(const float4*)(src + (size_t)(k0+k)*N + n0 + n4);
        t[k][n4]=v.x; t[k][n4+1]=v.y; t[k][n4+2]=v.z; t[k][n4+3]=v.w;
    }
    __syncthreads();
    const int n = tid>>3, ks = (tid&7)*8;
    const int ng = n0 + n;
    uint4 o;
    u32* op = (u32*)&o;
    #pragma unroll
    for (int i=0;i<4;i++)
        op[i] = pk2(t[ks+2*i][n], t[ks+2*i+1][n]);
    *(uint4*)&dst[(((size_t)(ng>>7)*(K>>6) + (k0>>6))<<13) + ((ng&127)<<6) + ks] = o;
}

// ------------------------------------------------- activation f32 [M][K] -> tiled bf16
__global__ __launch_bounds__(256) void cvt_tiled(const float* __restrict__ src, u16* __restrict__ dst, int K)
{
    const int gid = blockIdx.x*256 + threadIdx.x;
    const int base = gid*8;
    const int row = base / K, col = base - row*K;
    float4 a = *(const float4*)(src + base);
    float4 b = *(const float4*)(src + base + 4);
    uint4 o;
    o.x = pk2(a.x,a.y); o.y = pk2(a.z,a.w);
    o.z = pk2(b.x,b.y); o.w = pk2(b.z,b.w);
    *(uint4*)&dst[(((size_t)(row>>7)*(K>>6) + (col>>6))<<13) + ((row&127)<<6) + (col&63)] = o;
}

// ------------------------------------------------- MFMA GEMM: BM=128 BN=64 BK=32, 3-deep prefetch
// flags: 1=acc into f32 C, 2=+bias, 4=qkv split, 8=bf16-tiled out
// stage one BK=32 slice: A 2 loads + B 1 load per thread
__device__ __forceinline__ void stage3(const u16* aT, const u16* bT, int cb, int brow,
                                       u16* la, u16* lb, int w, int l)
{
    #pragma unroll
    for (int p=0;p<2;p++){
        const int q = p*256 + w*64 + l;
        const int row = q>>2, u = q&3;
        const int so = row*64 + cb + (((u ^ ((row>>1)&3))&3)<<3);
        GLDS(aT+so, la + p*2048 + w*512);
    }
    {
        const int q = w*64 + l;
        const int row = q>>2, u = q&3;
        const int so = (brow+row)*64 + cb + (((u ^ ((row>>1)&3))&3)<<3);
        GLDS(bT+so, lb + w*512);
    }
}

__global__ __launch_bounds__(256,4) void gemm_t(
    const u16* __restrict__ At, const u16* __restrict__ Bt, float* __restrict__ C,
    int N, int K, int AMS, int flags, const float* __restrict__ bias,
    u16* __restrict__ o16, u16* __restrict__ qk16, u16* __restrict__ vt16)
{
    __shared__ u16 lds[3][6144];   // per buf: A[0..4095], B[4096..6143]; 36 KB total
    const int tid = threadIdx.x;
    const int lane = tid & 63, w = tid >> 6;
    const int cg = lane >> 4, cl = lane & 15;
    const int NT = K >> 5;                 // BK=32 steps
    const int n0 = blockIdx.x*64;
    const int brow = n0 & 64;
    const size_t bNb = (size_t)(n0>>7)*(K>>6);

    const u16* aB = At + ((size_t)blockIdx.y * AMS << 13);
    const u16* bB = Bt + (bNb << 13);

    f32x4 acc[2][4];
    #pragma unroll
    for (int i=0;i<2;i++)
        #pragma unroll
        for (int j=0;j<4;j++) acc[i][j] = (f32x4){0.f,0.f,0.f,0.f};

    // prologue: stage slices 0,1
    stage3(aB,              bB,              0,  brow, &lds[0][0], &lds[0][4096], w, lane);
    stage3(aB + (0<<13),    bB + (0<<13),    32, brow, &lds[1][0], &lds[1][4096], w, lane);  // kt=1: tile 0, colbase 32

    for (int kt=0; kt<NT; kt++){
        const int buf = kt % 3;
        if (kt+2 < NT){
            const int k2 = kt+2;
            stage3(aB + ((size_t)(k2>>1)<<13), bB + ((size_t)(k2>>1)<<13),
                   (k2&1)<<5, brow, &lds[(k2)%3][0], &lds[(k2)%3][4096], w, lane);
            asm volatile("s_waitcnt vmcnt(6)" ::: "memory");
        } else if (kt+1 < NT){
            asm volatile("s_waitcnt vmcnt(3)" ::: "memory");
        } else {
            asm volatile("s_waitcnt vmcnt(0)" ::: "memory");
        }
        SBAR(); __builtin_amdgcn_s_barrier(); SBAR();
        s16x8 af[2], bf[4];
        #pragma unroll
        for (int mt=0;mt<2;mt++){
            const int ra = w*32 + mt*16 + cl;
            af[mt] = *(const s16x8*)&lds[buf][ra*32 + (((cg ^ ((ra>>1)&3))&3)<<3)];
        }
        #pragma unroll
        for (int nt=0;nt<4;nt++){
            const int rb = nt*16 + cl;
            bf[nt] = *(const s16x8*)&lds[buf][4096 + rb*32 + (((cg ^ ((rb>>1)&3))&3)<<3)];
        }
        #pragma unroll
        for (int mt=0;mt<2;mt++)
            #pragma unroll
            for (int nt=0;nt<4;nt++)
                acc[mt][nt] = __builtin_amdgcn_mfma_f32_16x16x32_bf16(af[mt], bf[nt], acc[mt][nt], 0,0,0);
        SBAR(); __builtin_amdgcn_s_barrier(); SBAR();
    }

    const int m0 = blockIdx.y*128;
    const bool do_acc = (flags&1), do_bias = (flags&2);
    if (flags & 4){
        #pragma unroll
        for (int mt=0;mt<2;mt++){
            const int grow0 = m0 + w*32 + mt*16 + cg*4;
            #pragma unroll
            for (int nt=0;nt<4;nt++){
                const int col = n0 + nt*16 + cl;
                if (col < 1536){
                    #pragma unroll
                    for (int j=0;j<4;j++)
                        qk16[(size_t)(grow0+j)*1536 + col] = f2bu(acc[mt][nt][j]);
                } else {
                    const int b = grow0>>10, s0 = grow0&1023;
                    const int dhg = col - 1536;
                    uint2 o;
                    o.x = pk2(acc[mt][nt][0], acc[mt][nt][1]);
                    o.y = pk2(acc[mt][nt][2], acc[mt][nt][3]);
                    *(uint2*)(vt16 + ((size_t)(b*768 + dhg)<<10) + s0) = o;
                }
            }
        }
    } else if (flags & 8){
        const int NC = N>>6;
        #pragma unroll
        for (int mt=0;mt<2;mt++){
            const int grow0 = m0 + w*32 + mt*16 + cg*4;
            #pragma unroll
            for (int nt=0;nt<4;nt++){
                const int col = n0 + nt*16 + cl;
                const size_t tb = (((size_t)(grow0>>7)*NC + (col>>6))<<13) + (col&63);
                #pragma unroll
                for (int j=0;j<4;j++)
                    o16[tb + (((grow0+j)&127)<<6)] = f2bu(acc[mt][nt][j]);
            }
        }
    } else {
        #pragma unroll
        for (int mt=0;mt<2;mt++){
            const int grow0 = m0 + w*32 + mt*16 + cg*4;
            #pragma unroll
            for (int nt=0;nt<4;nt++){
                const int col = n0 + nt*16 + cl;
                float bv = do_bias ? bias[col] : 0.f;
                #pragma unroll
                for (int j=0;j<4;j++){
                    float v = acc[mt][nt][j] + bv;
                    float* cp = C + (size_t)(grow0+j)*N + col;
                    if (do_acc) v += *cp;
                    *cp = v;
                }
            }
        }
    }
}

// ------------------------------------------------- MFMA flash attention (packed meta, K/V dbuf, counted vmcnt)
template<int MT>
__global__ __launch_bounds__(256,3) void attn_mfma(
    const u16* __restrict__ qk16, const u16* __restrict__ vt16,
    const u32* __restrict__ pmeta, const int* __restrict__ f2p,
    u16* __restrict__ ob16)
{
    const int bh = blockIdx.y;
    const int b = bh / NH, h = bh % NH;
    const int q0 = blockIdx.x * 64;
    const int tid = threadIdx.x;
    const int w = tid>>6, lane = tid&63, cg = lane>>4, cl = lane&15;
    const int srow = lane>>3;
    const int sseg = (lane&7) ^ srow;

    __shared__ u16 Qs[4096], Ks[2][4096], Vt[2][4096], Ps[4096];
    __shared__ u32 kM[1024];

    // --- one-time: metadata (regular loads, fully consumed before any gload_lds) ---
    #pragma unroll
    for (int i=0;i<4;i++){
        const int idx = tid + i*256;
        kM[idx] = pmeta[b*SS + idx];
    }
    int qf[4][5];
    if (MT==2){
        #pragma unroll
        for (int j=0;j<4;j++){
            const int gq = b*SS + q0 + w*16 + cg*4 + j;
            #pragma unroll
            for (int f=0;f<5;f++) qf[j][f]=f2p[gq*5+f];
        }
    }
    __syncthreads();   // kM visible; vmcnt drained (meta loads done)

    u32 qm[4];
    #pragma unroll
    for (int j=0;j<4;j++) qm[j] = kM[q0 + w*16 + cg*4 + j];

    // --- stage Q + chunk0 ---
    const u16* qbase = qk16 + (size_t)(b*SS+q0)*1536 + h*64;
    const u16* kbase = qk16 + (size_t)(b*SS)*1536 + 768 + h*64;
    const u16* vbase = vt16 + ((size_t)(b*768 + h*64)<<10);
    #pragma unroll
    for (int p=0;p<2;p++){
        const int row = p*32 + w*8 + srow;
        GLDS(qbase + (size_t)row*1536 + sseg*8, Qs + p*2048 + w*512);
    }
    #pragma unroll
    for (int p=0;p<2;p++){
        const int row = p*32 + w*8 + srow;
        GLDS(kbase + (size_t)row*1536 + sseg*8, Ks[0] + p*2048 + w*512);
        GLDS(vbase + ((size_t)row<<10) + sseg*8, Vt[0] + p*2048 + w*512);
    }

    f32x4 o[4];
    #pragma unroll
    for (int nt=0;nt<4;nt++) o[nt] = (f32x4){0.f,0.f,0.f,0.f};
    float mrun[4], lrun[4];
    #pragma unroll
    for (int j=0;j<4;j++){ mrun[j]=-INFINITY; lrun[j]=0.f; }

    for (int kc=0;kc<16;kc++){
        const int k0 = kc*64;
        const int buf = kc & 1;
        if (kc < 15){
            const int kn0 = k0 + 64;
            #pragma unroll
            for (int p=0;p<2;p++){
                const int row = p*32 + w*8 + srow;
                GLDS(kbase + (size_t)(kn0+row)*1536 + sseg*8, Ks[buf^1] + p*2048 + w*512);
                GLDS(vbase + ((size_t)row<<10) + kn0 + sseg*8, Vt[buf^1] + p*2048 + w*512);
            }
            asm volatile("s_waitcnt vmcnt(4)" ::: "memory");
        } else {
            asm volatile("s_waitcnt vmcnt(0)" ::: "memory");
        }
        SBAR(); __builtin_amdgcn_s_barrier(); SBAR();

        // QK^T
        f32x4 sc[4];
        #pragma unroll
        for (int nt=0;nt<4;nt++) sc[nt] = (f32x4){0.f,0.f,0.f,0.f};
        #pragma unroll
        for (int ks=0;ks<2;ks++){
            s16x8 qa = *(const s16x8*)&Qs[swz(w*16+cl, ks*32+cg*8)];
            #pragma unroll
            for (int nt=0;nt<4;nt++){
                s16x8 kb = *(const s16x8*)&Ks[buf][swz(nt*16+cl, ks*32+cg*8)];
                sc[nt] = __builtin_amdgcn_mfma_f32_16x16x32_bf16(qa, kb, sc[nt], 0,0,0);
            }
        }

        // mask + online softmax
        float pP[4][4];
        #pragma unroll
        for (int nt=0;nt<4;nt++){
            const int key = k0 + nt*16 + cl;
            const u32 km = kM[key];
            #pragma unroll
            for (int j=0;j<4;j++){
                float sv = sc[nt][j]*0.125f;
                const int qrow = q0 + w*16 + cg*4 + j;
                const bool eye = (qrow == key);
                const u32 qm_ = qm[j];
                const bool pv = (((qm_|km)>>24)&1u)==0u;
                bool m;
                if (MT==0)      m = ((((qm_^km)&0x00ffff00u)==0u) && pv) || eye;
                else if (MT==1) m = ((((qm_^km)&0xffu)==0u) && pv) || eye;
                else if (MT==2){
                    const int kn = (int)(km&0xffu);
                    bool nei = (qf[j][0]==kn)||(qf[j][1]==kn)||(qf[j][2]==kn)||(qf[j][3]==kn)||(qf[j][4]==kn)
                               ||((int)(qm_&0xffu)==kn);
                    m = (nei && pv) || eye;
                } else          m = pv || eye;
                pP[nt][j] = m ? sv : NEGF;
            }
        }

        #pragma unroll
        for (int j=0;j<4;j++){
            float mx = fmaxf(fmaxf(pP[0][j],pP[1][j]), fmaxf(pP[2][j],pP[3][j]));
            mx = rmax16(mx);
            float mnew = fmaxf(mrun[j], mx);
            float al = __expf(mrun[j]-mnew);
            mrun[j] = mnew;
            float ps = 0.f;
            #pragma unroll
            for (int nt=0;nt<4;nt++){
                float pe = __expf(pP[nt][j]-mnew);
                pP[nt][j]=pe; ps += pe;
            }
            ps = rsum16(ps);
            lrun[j] = lrun[j]*al + ps;
            #pragma unroll
            for (int nt=0;nt<4;nt++) o[nt][j] *= al;
        }

        // P -> LDS (wave-private rows; same-wave read => compiler lgkm ordering suffices)
        #pragma unroll
        for (int nt=0;nt<4;nt++)
            #pragma unroll
            for (int j=0;j<4;j++)
                Ps[swz(w*16+cg*4+j, nt*16+cl)] = f2bu(pP[nt][j]);

        // PV
        #pragma unroll
        for (int ks=0;ks<2;ks++){
            s16x8 pa = *(const s16x8*)&Ps[swz(w*16+cl, ks*32+cg*8)];
            #pragma unroll
            for (int nt=0;nt<4;nt++){
                s16x8 vb = *(const s16x8*)&Vt[buf][swz(nt*16+cl, ks*32+cg*8)];
                o[nt] = __builtin_amdgcn_mfma_f32_16x16x32_bf16(pa, vb, o[nt], 0,0,0);
            }
        }
        SBAR(); __builtin_amdgcn_s_barrier(); SBAR();
    }

    #pragma unroll
    for (int j=0;j<4;j++){
        const float inv = 1.f/lrun[j];
        const int row = b*SS + q0 + w*16 + cg*4 + j;
        const size_t rb = ((size_t)(row>>7)*12 + h)*8192 + ((row&127)<<6);
        #pragma unroll
        for (int nt=0;nt<4;nt++)
            ob16[rb + nt*16 + cl] = f2bu(o[nt][j]*inv);
    }
}

// ------------------------------------------------- rmsnorm: f32 in -> tiled bf16 out (K=768)
__global__ __launch_bounds__(256) void rms_kernel(const float* __restrict__ x,
                                                  const float* __restrict__ g,
                                                  u16* __restrict__ y)
{
    const int row = blockIdx.x;
    const int t = threadIdx.x;
    __shared__ float red[256];
    const float* xr = x + (size_t)row*DM;
    float v0=xr[t], v1=xr[t+256], v2=xr[t+512];
    red[t] = v0*v0+v1*v1+v2*v2; __syncthreads();
    for (int s=128;s>0;s>>=1){ if(t<s) red[t]+=red[t+s]; __syncthreads(); }
    float r = rsqrtf(red[0]/(float)DM + EPSF);
    const size_t mb = (size_t)(row>>7)*12;
    const int rr = (row&127)<<6;
    #pragma unroll
    for (int j=0;j<3;j++){
        const int c = t + j*256;
        const float v = (j==0?v0:(j==1?v1:v2)) * r * g[c];
        y[((mb + (c>>6))<<13) + rr + (c&63)] = f2bu(v);
    }
}

// ------------------------------------------------- encode fuse
__global__ __launch_bounds__(256) void fuse_encode(
    const float* __restrict__ cnbuf, const float* __restrict__ textbuf,
    const float* __restrict__ numv, const float* __restrict__ dtv, const float* __restrict__ boolv,
    const float* __restrict__ Wnum, const float* __restrict__ bnum,
    const float* __restrict__ Wdt, const float* __restrict__ bdt,
    const float* __restrict__ Wbool, const float* __restrict__ bbool,
    const float* __restrict__ gcn, const float* __restrict__ gnum, const float* __restrict__ gtext,
    const float* __restrict__ gdt, const float* __restrict__ gbool,
    const float* __restrict__ memb, const int* __restrict__ stypes, const u8* __restrict__ masks,
    float* __restrict__ x)
{
    const int row = blockIdx.x;
    const int t = threadIdx.x;
    __shared__ float red[256];

    float cn3[3]; float ss=0.f;
    #pragma unroll
    for (int j=0;j<3;j++){
        cn3[j] = cnbuf[(size_t)row*DM + t + j*256];
        ss += cn3[j]*cn3[j];
    }
    red[t]=ss; __syncthreads();
    for (int s=128;s>0;s>>=1){ if(t<s) red[t]+=red[t+s]; __syncthreads(); }
    {
        float r = rsqrtf(red[0]/(float)DM + EPSF);
        #pragma unroll
        for (int j=0;j<3;j++) cn3[j] *= r*gcn[t+j*256];
    }
    __syncthreads();

    const int st = stypes[row];
    float val[3]; ss=0.f;
    if (st==1){
        #pragma unroll
        for (int j=0;j<3;j++){
            val[j] = textbuf[(size_t)row*DM + t + j*256];
            ss += val[j]*val[j];
        }
    } else {
        const float* Wp = (st==0)?Wnum:((st==2)?Wdt:Wbool);
        const float* bp = (st==0)?bnum:((st==2)?bdt:bbool);
        const float* vp = (st==0)?numv:((st==2)?dtv:boolv);
        float v = vp[row];
        #pragma unroll
        for (int j=0;j<3;j++){
            int e=t+j*256;
            val[j] = v*Wp[e] + bp[e];
            ss += val[j]*val[j];
        }
    }
    red[t]=ss; __syncthreads();
    for (int s=128;s>0;s>>=1){ if(t<s) red[t]+=red[t+s]; __syncthreads(); }
    const float* gp = (st==0)?gnum:((st==1)?gtext:((st==2)?gdt:gbool));
    float r2 = rsqrtf(red[0]/(float)DM + EPSF);
    bool mk = masks[row]!=0;
    #pragma unroll
    for (int j=0;j<3;j++){
        int e=t+j*256;
        float vv = val[j]*r2*gp[e];
        if (mk) vv = memb[st*DM+e];
        x[(size_t)row*DM+e] = vv + cn3[j];
    }
}

// ------------------------------------------------- silu on fused gate-up tiled buffer
__global__ void silu_gu(u16* __restrict__ gu, int nu)
{
    int i = blockIdx.x*blockDim.x + threadIdx.x;
    const int stride = gridDim.x*blockDim.x;
    for (; i<nu; i+=stride){
        const int mt = i / (48*1024);
        const int r  = i - mt*48*1024;
        const size_t gi = (size_t)(mt*96)*1024 + r;
        const size_t ui = gi + 48*1024;
        uint4 gv = ((const uint4*)gu)[gi];
        uint4 uv = ((const uint4*)gu)[ui];
        u32 go[4]; const u32* gp=(const u32*)&gv; const u32* up=(const u32*)&uv;
        #pragma unroll
        for (int k=0;k<4;k++){
            float g0 = __uint_as_float(gp[k]<<16), g1 = __uint_as_float(gp[k]&0xffff0000u);
            float u0 = __uint_as_float(up[k]<<16), u1 = __uint_as_float(up[k]&0xffff0000u);
            float s0 = g0/(1.f+__expf(-g0))*u0;
            float s1 = g1/(1.f+__expf(-g1))*u1;
            go[k] = pk2(s0, s1);
        }
        ((uint4*)gu)[gi] = make_uint4(go[0],go[1],go[2],go[3]);
    }
}

// ------------------------------------------------- final rms + 3 scalar heads; h -> tiled bf16
__global__ __launch_bounds__(256) void decode2(
    const float* __restrict__ x, const float* __restrict__ gout,
    const float* __restrict__ Wn, const float* __restrict__ bn,
    const float* __restrict__ Wd, const float* __restrict__ bd,
    const float* __restrict__ Wb, const float* __restrict__ bb,
    float* __restrict__ out, u16* __restrict__ h16)
{
    const int row = blockIdx.x;
    const int t = threadIdx.x;
    __shared__ float h[DM];
    __shared__ float red[256];
    const float* xr = x + (size_t)row*DM;
    float v0=xr[t], v1=xr[t+256], v2=xr[t+512];
    red[t]=v0*v0+v1*v1+v2*v2; __syncthreads();
    for (int s=128;s>0;s>>=1){ if(t<s) red[t]+=red[t+s]; __syncthreads(); }
    float r = rsqrtf(red[0]/(float)DM + EPSF);
    float h0 = v0*r*gout[t], h1 = v1*r*gout[t+256], h2 = v2*r*gout[t+512];
    h[t]=h0; h[t+256]=h1; h[t+512]=h2;
    const size_t mb = (size_t)(row>>7)*12;
    const int rr = (row&127)<<6;
    #pragma unroll
    for (int j=0;j<3;j++){
        const int c = t + j*256;
        const float v = (j==0?h0:(j==1?h1:h2));
        h16[((mb + (c>>6))<<13) + rr + (c&63)] = f2bu(v);
    }
    __syncthreads();

    float pn=0.f,pd=0.f,pb=0.f;
    for (int k=t;k<DM;k+=256){ float hv=h[k]; pn+=hv*Wn[k]; pd+=hv*Wd[k]; pb+=hv*Wb[k]; }
    red[t]=pn; __syncthreads();
    for (int s=128;s>0;s>>=1){ if(t<s) red[t]+=red[t+s]; __syncthreads(); }
    float tn=red[0]; __syncthreads();
    red[t]=pd; __syncthreads();
    for (int s=128;s>0;s>>=1){ if(t<s) red[t]+=red[t+s]; __syncthreads(); }
    float td=red[0]; __syncthreads();
    red[t]=pb; __syncthreads();
    for (int s=128;s>0;s>>=1){ if(t<s) red[t]+=red[t+s]; __syncthreads(); }
    float tb=red[0];
    if (t==0){
        out[row]          = tn + bn[0];
        out[NROW + row]   = td + bd[0];
        out[2*NROW + row] = tb + bb[0];
    }
}

// ---------------------------------------------------------------- launcher
extern "C" void kernel_launch(void* const* d_in, const int* in_sizes, int n_in,
                              void* d_out, int out_size, void* d_ws, size_t ws_size,
                              hipStream_t stream)
{
    const float* numv   = (const float*)d_in[0];
    const float* dtval  = (const float*)d_in[1];
    const float* boolv  = (const float*)d_in[2];
    const float* textv  = (const float*)d_in[3];
    const float* cnamev = (const float*)d_in[4];
    const float* Wcn=(const float*)d_in[5];  const float* bcn=(const float*)d_in[6];
    const float* Wnum=(const float*)d_in[7]; const float* bnum=(const float*)d_in[8];
    const float* Wtext=(const float*)d_in[9];const float* btext=(const float*)d_in[10];
    const float* Wdt=(const float*)d_in[11]; const float* bdt=(const float*)d_in[12];
    const float* Wbool=(const float*)d_in[13];const float* bbool=(const float*)d_in[14];
    const float* gcn=(const float*)d_in[15]; const float* gnum=(const float*)d_in[16];
    const float* gtext=(const float*)d_in[17];const float* gdt=(const float*)d_in[18];
    const float* gbool=(const float*)d_in[19];
    const float* memb=(const float*)d_in[20];
    const float* norms_all=(const float*)d_in[21];
    const float* attw_all=(const float*)d_in[22];
    const float* up_all=(const float*)d_in[23];
    const float* gate_all=(const float*)d_in[24];
    const float* down_all=(const float*)d_in[25];
    const float* gout=(const float*)d_in[26];
    const float* Wdn=(const float*)d_in[27]; const float* bdn=(const float*)d_in[28];
    const float* Wdd=(const float*)d_in[29]; const float* bdd=(const float*)d_in[30];
    const float* Wdb=(const float*)d_in[31]; const float* bdb=(const float*)d_in[32];
    const float* Wdtx=(const float*)d_in[33];const float* bdtx=(const float*)d_in[34];
    const int* node=(const int*)d_in[35];
    const int* tbl =(const int*)d_in[36];
    const int* colx=(const int*)d_in[37];
    const int* f2p =(const int*)d_in[38];
    const int* styp=(const int*)d_in[39];

    const size_t SA = (size_t)768*768;
    const size_t SG = (size_t)768*3072;
    const size_t SC = (size_t)384*768;
    const size_t NX = (size_t)NROW*DM;

    u8* base = (u8*)d_ws;
    float* x  = (float*)base;
    u16* xn16 = (u16*)(base + 6291456);
    u16* ob16 = (u16*)(base + 9437184);
    u16* qk16 = (u16*)(base + 12582912);
    u16* vt16 = (u16*)(base + 18874368);
    u16* gu16 = (u16*)(base + 22020096);
    u16* wA   = (u16*)(base + 47185920);
    u16* wGU  = wA + 64*SA;
    u16* wD   = wGU + 8*SG;
    u16* wCN  = wD + 4*SG;
    u16* wTX  = wCN + SC;
    u16* wDX  = wTX + SC;
    u8* nmask = (u8*)(wDX + SC);
    u8* npad  = nmask + NROW;
    u32* pmeta = (u32*)(npad + NROW + 64);

    // encode-phase aliases
    u16* cnT16   = qk16;
    u16* textT16 = vt16;
    float* cnbuf   = (float*)gu16;
    float* textbuf = cnbuf + NX;

    float* out = (float*)d_out;

    norm_bool_kernel<<<1,256,0,stream>>>(d_in[40], nmask, NROW);
    norm_bool_kernel<<<1,256,0,stream>>>(d_in[41], npad,  NROW);
    pack_meta<<<NROW/256,256,0,stream>>>(node, colx, tbl, npad, pmeta, NROW);

    // weight prep (tiled bf16, coalesced writes)
    transpose_cvt2<<<dim3(24,12,64),256,0,stream>>>(attw_all, wA, 768, 768, SA);
    transpose_cvt2<<<dim3(96,12,4),256,0,stream>>>(gate_all, wGU,      768, 3072, 2*SG);
    transpose_cvt2<<<dim3(96,12,4),256,0,stream>>>(up_all,   wGU + SG, 768, 3072, 2*SG);
    transpose_cvt2<<<dim3(24,48,4),256,0,stream>>>(down_all, wD, 3072, 768, SG);
    transpose_cvt2<<<dim3(24,6,1),256,0,stream>>>(Wcn,   wCN, 384, 768, 0);
    transpose_cvt2<<<dim3(24,6,1),256,0,stream>>>(Wtext, wTX, 384, 768, 0);
    transpose_cvt2<<<dim3(12,12,1),256,0,stream>>>(Wdtx, wDX, 768, 384, 0);

    // encode
    cvt_tiled<<<384,256,0,stream>>>(cnamev, cnT16, 384);
    cvt_tiled<<<384,256,0,stream>>>(textv,  textT16, 384);
    gemm_t<<<dim3(12,16),256,0,stream>>>(cnT16,   wCN, cnbuf,   768, 384, 6, 2, bcn,   nullptr, nullptr, nullptr);
    gemm_t<<<dim3(12,16),256,0,stream>>>(textT16, wTX, textbuf, 768, 384, 6, 2, btext, nullptr, nullptr, nullptr);
    fuse_encode<<<NROW,256,0,stream>>>(cnbuf, textbuf, numv, dtval, boolv,
        Wnum,bnum,Wdt,bdt,Wbool,bbool, gcn,gnum,gtext,gdt,gbool,
        memb, styp, nmask, x);

    const dim3 ga(SS/64, BB*NH);     // 16 x 24
    for (int l=0; l<NL; l++){
        const float* norms = norms_all + (size_t)l*5*DM;
        for (int a=0; a<4; a++){
            rms_kernel<<<NROW,256,0,stream>>>(x, norms + a*DM, xn16);
            const u16* wqkv = wA + (size_t)((l*4+a)*4)*SA;
            gemm_t<<<dim3(36,16),256,0,stream>>>(xn16, wqkv, nullptr, 2304, 768, 12, 4, nullptr, nullptr, qk16, vt16);
            if (a==0)      attn_mfma<0><<<ga,256,0,stream>>>(qk16,vt16,pmeta,f2p,ob16);
            else if (a==1) attn_mfma<1><<<ga,256,0,stream>>>(qk16,vt16,pmeta,f2p,ob16);
            else if (a==2) attn_mfma<2><<<ga,256,0,stream>>>(qk16,vt16,pmeta,f2p,ob16);
            else           attn_mfma<3><<<ga,256,0,stream>>>(qk16,vt16,pmeta,f2p,ob16);
            gemm_t<<<dim3(12,16),256,0,stream>>>(ob16, wqkv + 3*SA, x, 768, 768, 12, 1, nullptr, nullptr, nullptr, nullptr);
        }
        rms_kernel<<<NROW,256,0,stream>>>(x, norms + 4*DM, xn16);
        gemm_t<<<dim3(96,16),256,0,stream>>>(xn16, wGU + (size_t)l*2*SG, nullptr, 6144, 768, 12, 8, nullptr, gu16, nullptr, nullptr);
        silu_gu<<<1024,256,0,stream>>>(gu16, 16*48*1024);
        gemm_t<<<dim3(12,16),256,0,stream>>>(gu16, wD + (size_t)l*SG, x, 768, 3072, 96, 1, nullptr, nullptr, nullptr, nullptr);
    }

    decode2<<<NROW,256,0,stream>>>(x, gout, Wdn,bdn, Wdd,bdd, Wdb,bdb, out, xn16);
    gemm_t<<<dim3(6,16),256,0,stream>>>(xn16, wDX, out + 3*NROW, 384, 768, 12, 2, bdtx, nullptr, nullptr, nullptr);
}

// Round 9
// 1801.791 us; speedup vs baseline: 5.7125x; 1.0170x over previous
//
#include <hip/hip_runtime.h>
#include <hip/hip_bf16.h>
#include <cmath>
#include <stdint.h>

// Round 9: delete the RMS pass. gamma folded into weights at prep; residual-producing GEMMs
// (o-proj/down) emit x(f32) + raw-x bf16 tiles + per-row sumsq (atomic); consumer GEMMs
// (qkv, gate/up) apply r=rsqrt(sumsq/768+eps) in the epilogue.

#define BB 2
#define SS 1024
#define DT 384
#define DM 768
#define NH 12
#define DH 64
#define DFF 3072
#define NL 4
#define NROW (BB*SS)
#define EPSF 1e-6f
#define NEGF (-1e9f)

typedef unsigned short u16;
typedef unsigned char u8;
typedef unsigned int u32;
typedef __attribute__((ext_vector_type(8))) short s16x8;
typedef __attribute__((ext_vector_type(4))) float f32x4;

__device__ __forceinline__ u16 f2bu(float f){
    u32 x = __float_as_uint(f);
    u32 r = (x + 0x7fffu + ((x>>16)&1u)) >> 16;   // RNE
    return (u16)r;
}
__device__ __forceinline__ u32 pk2(float lo, float hi){
    return (u32)f2bu(lo) | ((u32)f2bu(hi)<<16);
}
__device__ __forceinline__ int swz(int row, int c){
    return (row<<6) + (((((c>>3) ^ row) & 7))<<3) + (c&7);
}
__device__ __forceinline__ float rmax16(float v){
    v = fmaxf(v, __shfl_xor(v,1)); v = fmaxf(v, __shfl_xor(v,2));
    v = fmaxf(v, __shfl_xor(v,4)); v = fmaxf(v, __shfl_xor(v,8));
    return v;
}
__device__ __forceinline__ float rsum16(float v){
    v += __shfl_xor(v,1); v += __shfl_xor(v,2);
    v += __shfl_xor(v,4); v += __shfl_xor(v,8);
    return v;
}
#define SBAR() __builtin_amdgcn_sched_barrier(0)
#define GLDS(src,dst) __builtin_amdgcn_global_load_lds((const __attribute__((address_space(1))) u32*)(src), (__attribute__((address_space(3))) u32*)(dst), 16, 0, 0)

// ------------------------------------------------- zero helper (rs slots; re-run every launch)
__global__ void zero_f(float* __restrict__ p, int n){
    int i = blockIdx.x*256 + threadIdx.x;
    if (i<n) p[i]=0.f;
}

// ------------------------------------------------- bool-buffer normalizer
__global__ void norm_bool_kernel(const void* __restrict__ src, u8* __restrict__ dst, int n)
{
    __shared__ int fl[4];
    if (threadIdx.x<4) fl[threadIdx.x]=0;
    __syncthreads();
    const u32* wsrc = (const u32*)src;
    const int nw = n/4;
    int any=0, nb=0, hi=0, lo=0;
    for (int i=threadIdx.x;i<nw;i+=blockDim.x){
        u32 v=wsrc[i];
        if (!v) continue;
        any=1;
        #pragma unroll
        for (int b=0;b<4;b++){
            u32 by=(v>>(8*b))&0xffu;
            if (by>1u) nb=1;
            if (by==1u && b!=0) hi=1;
        }
        if ((v&0xffffu)==0x3f80u) lo=1;
    }
    if (any) atomicOr(&fl[0],1);
    if (nb)  atomicOr(&fl[1],1);
    if (hi)  atomicOr(&fl[2],1);
    if (lo)  atomicOr(&fl[3],1);
    __syncthreads();
    int c;
    if (!fl[0]) c=0;
    else if (!fl[1]) c = fl[2] ? 2 : 1;
    else if (fl[3]) c = 3;
    else c = 1;
    for (int i=threadIdx.x;i<n;i+=blockDim.x){
        u8 v;
        if (c==0)      v=0;
        else if (c==1) v = (((const u32*)src)[i]!=0u);
        else if (c==2) v = (((const u8*)src)[i]!=0u);
        else           v = (((const u16*)src)[i]!=0u);
        dst[i]=v;
    }
}

// ------------------------------------------------- pack per-token metadata
__global__ void pack_meta(const int* __restrict__ node, const int* __restrict__ colx,
                          const int* __restrict__ tbl, const u8* __restrict__ pad,
                          u32* __restrict__ pm, int n)
{
    int i = blockIdx.x*256 + threadIdx.x;
    if (i<n)
        pm[i] = (u32)(node[i]&0xff) | ((u32)(colx[i]&0xff)<<8) | ((u32)(tbl[i]&0xff)<<16) | ((u32)(pad[i]&1)<<24);
}

// ------------------------------------------------- weight f32 [K][N] -> tiled bf16, optional gamma fold
// gmode: 0=none; 1=attn (z=(l*4+a)*4+m, fold norms[(l*5+a)] if m<3); 2=per-z g = gbase + z*5*768
__global__ __launch_bounds__(256) void transpose_cvt2(const float* __restrict__ src, u16* __restrict__ dst,
                                                      int K, int N, size_t dz,
                                                      const float* __restrict__ gbase, int gmode)
{
    const int z = blockIdx.z;
    src += (size_t)z*K*N;
    dst += (size_t)z*dz;
    const float* g = nullptr;
    if (gmode==1){ int m = z&3; if (m<3) g = gbase + (size_t)((z>>4)*5 + ((z>>2)&3))*768; }
    else if (gmode==2){ g = gbase + (size_t)z*5*768; }
    const int n0 = blockIdx.x*32, k0 = blockIdx.y*64;
    __shared__ float t[64][33];
    const int tid = threadIdx.x;
    const int kr = tid>>3, n4 = (tid&7)*4;
    #pragma unroll
    for (int p=0;p<2;p++){
        const int k = p*32 + kr;
        float gk = g ? g[k0+k] : 1.f;
        float4 v = *(const float4*)(src + (size_t)(k0+k)*N + n0 + n4);
        t[k][n4]=v.x*gk; t[k][n4+1]=v.y*gk; t[k][n4+2]=v.z*gk; t[k][n4+3]=v.w*gk;
    }
    __syncthreads();
    const int n = tid>>3, ks = (tid&7)*8;
    const int ng = n0 + n;
    uint4 o;
    u32* op = (u32*)&o;
    #pragma unroll
    for (int i=0;i<4;i++)
        op[i] = pk2(t[ks+2*i][n], t[ks+2*i+1][n]);
    *(uint4*)&dst[(((size_t)(ng>>7)*(K>>6) + (k0>>6))<<13) + ((ng&127)<<6) + ks] = o;
}

// ------------------------------------------------- activation f32 [M][K] -> tiled bf16 (encode inputs)
__global__ __launch_bounds__(256) void cvt_tiled(const float* __restrict__ src, u16* __restrict__ dst, int K)
{
    const int gid = blockIdx.x*256 + threadIdx.x;
    const int base = gid*8;
    const int row = base / K, col = base - row*K;
    float4 a = *(const float4*)(src + base);
    float4 b = *(const float4*)(src + base + 4);
    uint4 o;
    o.x = pk2(a.x,a.y); o.y = pk2(a.z,a.w);
    o.z = pk2(b.x,b.y); o.w = pk2(b.z,b.w);
    *(uint4*)&dst[(((size_t)(row>>7)*(K>>6) + (col>>6))<<13) + ((row&127)<<6) + (col&63)] = o;
}

// ------------------------------------------------- MFMA GEMM: BM=128 BN=64 BK=32, 3-deep prefetch
// flags: 1=acc into f32 C (+ o16 xt16-out + rs_out sumsq), 2=+bias, 4=qkv split (rs_in scale),
//        8=bf16-tiled out (rs_in scale)
__device__ __forceinline__ void stage3(const u16* aT, const u16* bT, int cb, int brow,
                                       u16* la, u16* lb, int w, int l)
{
    #pragma unroll
    for (int p=0;p<2;p++){
        const int q = p*256 + w*64 + l;
        const int row = q>>2, u = q&3;
        const int so = row*64 + cb + (((u ^ ((row>>1)&3))&3)<<3);
        GLDS(aT+so, la + p*2048 + w*512);
    }
    {
        const int q = w*64 + l;
        const int row = q>>2, u = q&3;
        const int so = (brow+row)*64 + cb + (((u ^ ((row>>1)&3))&3)<<3);
        GLDS(bT+so, lb + w*512);
    }
}

__global__ __launch_bounds__(256,4) void gemm_t(
    const u16* __restrict__ At, const u16* __restrict__ Bt, float* __restrict__ C,
    int N, int K, int AMS, int flags, const float* __restrict__ bias,
    u16* __restrict__ o16, u16* __restrict__ qk16, u16* __restrict__ vt16,
    const float* __restrict__ rs_in, float* __restrict__ rs_out)
{
    __shared__ u16 lds[3][6144];
    const int tid = threadIdx.x;
    const int lane = tid & 63, w = tid >> 6;
    const int cg = lane >> 4, cl = lane & 15;
    const int NT = K >> 5;
    const int n0 = blockIdx.x*64;
    const int brow = n0 & 64;
    const size_t bNb = (size_t)(n0>>7)*(K>>6);

    const u16* aB = At + ((size_t)blockIdx.y * AMS << 13);
    const u16* bB = Bt + (bNb << 13);

    f32x4 acc[2][4];
    #pragma unroll
    for (int i=0;i<2;i++)
        #pragma unroll
        for (int j=0;j<4;j++) acc[i][j] = (f32x4){0.f,0.f,0.f,0.f};

    stage3(aB,           bB,           0,  brow, &lds[0][0], &lds[0][4096], w, lane);
    stage3(aB,           bB,           32, brow, &lds[1][0], &lds[1][4096], w, lane);

    for (int kt=0; kt<NT; kt++){
        const int buf = kt % 3;
        if (kt+2 < NT){
            const int k2 = kt+2;
            stage3(aB + ((size_t)(k2>>1)<<13), bB + ((size_t)(k2>>1)<<13),
                   (k2&1)<<5, brow, &lds[k2%3][0], &lds[k2%3][4096], w, lane);
            asm volatile("s_waitcnt vmcnt(6)" ::: "memory");
        } else if (kt+1 < NT){
            asm volatile("s_waitcnt vmcnt(3)" ::: "memory");
        } else {
            asm volatile("s_waitcnt vmcnt(0)" ::: "memory");
        }
        SBAR(); __builtin_amdgcn_s_barrier(); SBAR();
        s16x8 af[2], bf[4];
        #pragma unroll
        for (int mt=0;mt<2;mt++){
            const int ra = w*32 + mt*16 + cl;
            af[mt] = *(const s16x8*)&lds[buf][ra*32 + (((cg ^ ((ra>>1)&3))&3)<<3)];
        }
        #pragma unroll
        for (int nt=0;nt<4;nt++){
            const int rb = nt*16 + cl;
            bf[nt] = *(const s16x8*)&lds[buf][4096 + rb*32 + (((cg ^ ((rb>>1)&3))&3)<<3)];
        }
        #pragma unroll
        for (int mt=0;mt<2;mt++)
            #pragma unroll
            for (int nt=0;nt<4;nt++)
                acc[mt][nt] = __builtin_amdgcn_mfma_f32_16x16x32_bf16(af[mt], bf[nt], acc[mt][nt], 0,0,0);
        SBAR(); __builtin_amdgcn_s_barrier(); SBAR();
    }

    const int m0 = blockIdx.y*128;
    const bool do_acc = (flags&1), do_bias = (flags&2);
    if (flags & 4){
        #pragma unroll
        for (int mt=0;mt<2;mt++){
            const int grow0 = m0 + w*32 + mt*16 + cg*4;
            float rr[4];
            #pragma unroll
            for (int j=0;j<4;j++) rr[j] = rsqrtf(rs_in[grow0+j]*(1.f/768.f) + EPSF);
            #pragma unroll
            for (int nt=0;nt<4;nt++){
                const int col = n0 + nt*16 + cl;
                if (col < 1536){
                    #pragma unroll
                    for (int j=0;j<4;j++)
                        qk16[(size_t)(grow0+j)*1536 + col] = f2bu(acc[mt][nt][j]*rr[j]);
                } else {
                    const int b = grow0>>10, s0 = grow0&1023;
                    const int dhg = col - 1536;
                    uint2 o;
                    o.x = pk2(acc[mt][nt][0]*rr[0], acc[mt][nt][1]*rr[1]);
                    o.y = pk2(acc[mt][nt][2]*rr[2], acc[mt][nt][3]*rr[3]);
                    *(uint2*)(vt16 + ((size_t)(b*768 + dhg)<<10) + s0) = o;
                }
            }
        }
    } else if (flags & 8){
        const int NC = N>>6;
        #pragma unroll
        for (int mt=0;mt<2;mt++){
            const int grow0 = m0 + w*32 + mt*16 + cg*4;
            float rr[4];
            #pragma unroll
            for (int j=0;j<4;j++) rr[j] = rs_in ? rsqrtf(rs_in[grow0+j]*(1.f/768.f) + EPSF) : 1.f;
            #pragma unroll
            for (int nt=0;nt<4;nt++){
                const int col = n0 + nt*16 + cl;
                const size_t tb = (((size_t)(grow0>>7)*NC + (col>>6))<<13) + (col&63);
                #pragma unroll
                for (int j=0;j<4;j++)
                    o16[tb + (((grow0+j)&127)<<6)] = f2bu(acc[mt][nt][j]*rr[j]);
            }
        }
    } else {
        #pragma unroll
        for (int mt=0;mt<2;mt++){
            const int grow0 = m0 + w*32 + mt*16 + cg*4;
            float tmp[4][4];
            #pragma unroll
            for (int nt=0;nt<4;nt++){
                const int col = n0 + nt*16 + cl;
                float bv = do_bias ? bias[col] : 0.f;
                #pragma unroll
                for (int j=0;j<4;j++){
                    float v = acc[mt][nt][j] + bv;
                    float* cp = C + (size_t)(grow0+j)*N + col;
                    if (do_acc) v += *cp;
                    *cp = v;
                    tmp[nt][j] = v;
                }
            }
            if (o16){   // raw-x bf16 tiles (N=768 -> NC=12)
                #pragma unroll
                for (int nt=0;nt<4;nt++){
                    const int col = n0 + nt*16 + cl;
                    const size_t tb = (((size_t)(grow0>>7)*12 + (col>>6))<<13) + (col&63);
                    #pragma unroll
                    for (int j=0;j<4;j++)
                        o16[tb + (((grow0+j)&127)<<6)] = f2bu(tmp[nt][j]);
                }
            }
            if (rs_out){
                #pragma unroll
                for (int j=0;j<4;j++){
                    float s = tmp[0][j]*tmp[0][j] + tmp[1][j]*tmp[1][j]
                            + tmp[2][j]*tmp[2][j] + tmp[3][j]*tmp[3][j];
                    s = rsum16(s);
                    if (cl==0) atomicAdd(rs_out + grow0 + j, s);
                }
            }
        }
    }
}

// ------------------------------------------------- MFMA flash attention (unchanged from r8)
template<int MT>
__global__ __launch_bounds__(256,3) void attn_mfma(
    const u16* __restrict__ qk16, const u16* __restrict__ vt16,
    const u32* __restrict__ pmeta, const int* __restrict__ f2p,
    u16* __restrict__ ob16)
{
    const int bh = blockIdx.y;
    const int b = bh / NH, h = bh % NH;
    const int q0 = blockIdx.x * 64;
    const int tid = threadIdx.x;
    const int w = tid>>6, lane = tid&63, cg = lane>>4, cl = lane&15;
    const int srow = lane>>3;
    const int sseg = (lane&7) ^ srow;

    __shared__ u16 Qs[4096], Ks[2][4096], Vt[2][4096], Ps[4096];
    __shared__ u32 kM[1024];

    #pragma unroll
    for (int i=0;i<4;i++){
        const int idx = tid + i*256;
        kM[idx] = pmeta[b*SS + idx];
    }
    int qf[4][5];
    if (MT==2){
        #pragma unroll
        for (int j=0;j<4;j++){
            const int gq = b*SS + q0 + w*16 + cg*4 + j;
            #pragma unroll
            for (int f=0;f<5;f++) qf[j][f]=f2p[gq*5+f];
        }
    }
    __syncthreads();

    u32 qm[4];
    #pragma unroll
    for (int j=0;j<4;j++) qm[j] = kM[q0 + w*16 + cg*4 + j];

    const u16* qbase = qk16 + (size_t)(b*SS+q0)*1536 + h*64;
    const u16* kbase = qk16 + (size_t)(b*SS)*1536 + 768 + h*64;
    const u16* vbase = vt16 + ((size_t)(b*768 + h*64)<<10);
    #pragma unroll
    for (int p=0;p<2;p++){
        const int row = p*32 + w*8 + srow;
        GLDS(qbase + (size_t)row*1536 + sseg*8, Qs + p*2048 + w*512);
    }
    #pragma unroll
    for (int p=0;p<2;p++){
        const int row = p*32 + w*8 + srow;
        GLDS(kbase + (size_t)row*1536 + sseg*8, Ks[0] + p*2048 + w*512);
        GLDS(vbase + ((size_t)row<<10) + sseg*8, Vt[0] + p*2048 + w*512);
    }

    f32x4 o[4];
    #pragma unroll
    for (int nt=0;nt<4;nt++) o[nt] = (f32x4){0.f,0.f,0.f,0.f};
    float mrun[4], lrun[4];
    #pragma unroll
    for (int j=0;j<4;j++){ mrun[j]=-INFINITY; lrun[j]=0.f; }

    for (int kc=0;kc<16;kc++){
        const int k0 = kc*64;
        const int buf = kc & 1;
        if (kc < 15){
            const int kn0 = k0 + 64;
            #pragma unroll
            for (int p=0;p<2;p++){
                const int row = p*32 + w*8 + srow;
                GLDS(kbase + (size_t)(kn0+row)*1536 + sseg*8, Ks[buf^1] + p*2048 + w*512);
                GLDS(vbase + ((size_t)row<<10) + kn0 + sseg*8, Vt[buf^1] + p*2048 + w*512);
            }
            asm volatile("s_waitcnt vmcnt(4)" ::: "memory");
        } else {
            asm volatile("s_waitcnt vmcnt(0)" ::: "memory");
        }
        SBAR(); __builtin_amdgcn_s_barrier(); SBAR();

        f32x4 sc[4];
        #pragma unroll
        for (int nt=0;nt<4;nt++) sc[nt] = (f32x4){0.f,0.f,0.f,0.f};
        #pragma unroll
        for (int ks=0;ks<2;ks++){
            s16x8 qa = *(const s16x8*)&Qs[swz(w*16+cl, ks*32+cg*8)];
            #pragma unroll
            for (int nt=0;nt<4;nt++){
                s16x8 kb = *(const s16x8*)&Ks[buf][swz(nt*16+cl, ks*32+cg*8)];
                sc[nt] = __builtin_amdgcn_mfma_f32_16x16x32_bf16(qa, kb, sc[nt], 0,0,0);
            }
        }

        float pP[4][4];
        #pragma unroll
        for (int nt=0;nt<4;nt++){
            const int key = k0 + nt*16 + cl;
            const u32 km = kM[key];
            #pragma unroll
            for (int j=0;j<4;j++){
                float sv = sc[nt][j]*0.125f;
                const int qrow = q0 + w*16 + cg*4 + j;
                const bool eye = (qrow == key);
                const u32 qm_ = qm[j];
                const bool pv = (((qm_|km)>>24)&1u)==0u;
                bool m;
                if (MT==0)      m = ((((qm_^km)&0x00ffff00u)==0u) && pv) || eye;
                else if (MT==1) m = ((((qm_^km)&0xffu)==0u) && pv) || eye;
                else if (MT==2){
                    const int kn = (int)(km&0xffu);
                    bool nei = (qf[j][0]==kn)||(qf[j][1]==kn)||(qf[j][2]==kn)||(qf[j][3]==kn)||(qf[j][4]==kn)
                               ||((int)(qm_&0xffu)==kn);
                    m = (nei && pv) || eye;
                } else          m = pv || eye;
                pP[nt][j] = m ? sv : NEGF;
            }
        }

        #pragma unroll
        for (int j=0;j<4;j++){
            float mx = fmaxf(fmaxf(pP[0][j],pP[1][j]), fmaxf(pP[2][j],pP[3][j]));
            mx = rmax16(mx);
            float mnew = fmaxf(mrun[j], mx);
            float al = __expf(mrun[j]-mnew);
            mrun[j] = mnew;
            float ps = 0.f;
            #pragma unroll
            for (int nt=0;nt<4;nt++){
                float pe = __expf(pP[nt][j]-mnew);
                pP[nt][j]=pe; ps += pe;
            }
            ps = rsum16(ps);
            lrun[j] = lrun[j]*al + ps;
            #pragma unroll
            for (int nt=0;nt<4;nt++) o[nt][j] *= al;
        }

        #pragma unroll
        for (int nt=0;nt<4;nt++)
            #pragma unroll
            for (int j=0;j<4;j++)
                Ps[swz(w*16+cg*4+j, nt*16+cl)] = f2bu(pP[nt][j]);

        #pragma unroll
        for (int ks=0;ks<2;ks++){
            s16x8 pa = *(const s16x8*)&Ps[swz(w*16+cl, ks*32+cg*8)];
            #pragma unroll
            for (int nt=0;nt<4;nt++){
                s16x8 vb = *(const s16x8*)&Vt[buf][swz(nt*16+cl, ks*32+cg*8)];
                o[nt] = __builtin_amdgcn_mfma_f32_16x16x32_bf16(pa, vb, o[nt], 0,0,0);
            }
        }
        SBAR(); __builtin_amdgcn_s_barrier(); SBAR();
    }

    #pragma unroll
    for (int j=0;j<4;j++){
        const float inv = 1.f/lrun[j];
        const int row = b*SS + q0 + w*16 + cg*4 + j;
        const size_t rb = ((size_t)(row>>7)*12 + h)*8192 + ((row&127)<<6);
        #pragma unroll
        for (int nt=0;nt<4;nt++)
            ob16[rb + nt*16 + cl] = f2bu(o[nt][j]*inv);
    }
}

// ------------------------------------------------- encode fuse: x f32 + xt16 tiled + rs slot0
__global__ __launch_bounds__(256) void fuse_encode(
    const float* __restrict__ cnbuf, const float* __restrict__ textbuf,
    const float* __restrict__ numv, const float* __restrict__ dtv, const float* __restrict__ boolv,
    const float* __restrict__ Wnum, const float* __restrict__ bnum,
    const float* __restrict__ Wdt, const float* __restrict__ bdt,
    const float* __restrict__ Wbool, const float* __restrict__ bbool,
    const float* __restrict__ gcn, const float* __restrict__ gnum, const float* __restrict__ gtext,
    const float* __restrict__ gdt, const float* __restrict__ gbool,
    const float* __restrict__ memb, const int* __restrict__ stypes, const u8* __restrict__ masks,
    float* __restrict__ x, u16* __restrict__ xt16, float* __restrict__ rs0)
{
    const int row = blockIdx.x;
    const int t = threadIdx.x;
    __shared__ float red[256];

    float cn3[3]; float ss=0.f;
    #pragma unroll
    for (int j=0;j<3;j++){
        cn3[j] = cnbuf[(size_t)row*DM + t + j*256];
        ss += cn3[j]*cn3[j];
    }
    red[t]=ss; __syncthreads();
    for (int s=128;s>0;s>>=1){ if(t<s) red[t]+=red[t+s]; __syncthreads(); }
    {
        float r = rsqrtf(red[0]/(float)DM + EPSF);
        #pragma unroll
        for (int j=0;j<3;j++) cn3[j] *= r*gcn[t+j*256];
    }
    __syncthreads();

    const int st = stypes[row];
    float val[3]; ss=0.f;
    if (st==1){
        #pragma unroll
        for (int j=0;j<3;j++){
            val[j] = textbuf[(size_t)row*DM + t + j*256];
            ss += val[j]*val[j];
        }
    } else {
        const float* Wp = (st==0)?Wnum:((st==2)?Wdt:Wbool);
        const float* bp = (st==0)?bnum:((st==2)?bdt:bbool);
        const float* vp = (st==0)?numv:((st==2)?dtv:boolv);
        float v = vp[row];
        #pragma unroll
        for (int j=0;j<3;j++){
            int e=t+j*256;
            val[j] = v*Wp[e] + bp[e];
            ss += val[j]*val[j];
        }
    }
    red[t]=ss; __syncthreads();
    for (int s=128;s>0;s>>=1){ if(t<s) red[t]+=red[t+s]; __syncthreads(); }
    const float* gp = (st==0)?gnum:((st==1)?gtext:((st==2)?gdt:gbool));
    float r2 = rsqrtf(red[0]/(float)DM + EPSF);
    bool mk = masks[row]!=0;
    float xv[3]; float sx=0.f;
    #pragma unroll
    for (int j=0;j<3;j++){
        int e=t+j*256;
        float vv = val[j]*r2*gp[e];
        if (mk) vv = memb[st*DM+e];
        xv[j] = vv + cn3[j];
        x[(size_t)row*DM+e] = xv[j];
        sx += xv[j]*xv[j];
    }
    __syncthreads();
    red[t]=sx; __syncthreads();
    for (int s=128;s>0;s>>=1){ if(t<s) red[t]+=red[t+s]; __syncthreads(); }
    if (t==0) rs0[row] = red[0];
    const size_t mb = (size_t)(row>>7)*12;
    const int rr = (row&127)<<6;
    #pragma unroll
    for (int j=0;j<3;j++){
        const int c = t + j*256;
        xt16[((mb + (c>>6))<<13) + rr + (c&63)] = f2bu(xv[j]);
    }
}

// ------------------------------------------------- silu on fused gate-up tiled buffer
__global__ void silu_gu(u16* __restrict__ gu, int nu)
{
    int i = blockIdx.x*blockDim.x + threadIdx.x;
    const int stride = gridDim.x*blockDim.x;
    for (; i<nu; i+=stride){
        const int mt = i / (48*1024);
        const int r  = i - mt*48*1024;
        const size_t gi = (size_t)(mt*96)*1024 + r;
        const size_t ui = gi + 48*1024;
        uint4 gv = ((const uint4*)gu)[gi];
        uint4 uv = ((const uint4*)gu)[ui];
        u32 go[4]; const u32* gp=(const u32*)&gv; const u32* up=(const u32*)&uv;
        #pragma unroll
        for (int k=0;k<4;k++){
            float g0 = __uint_as_float(gp[k]<<16), g1 = __uint_as_float(gp[k]&0xffff0000u);
            float u0 = __uint_as_float(up[k]<<16), u1 = __uint_as_float(up[k]&0xffff0000u);
            float s0 = g0/(1.f+__expf(-g0))*u0;
            float s1 = g1/(1.f+__expf(-g1))*u1;
            go[k] = pk2(s0, s1);
        }
        ((uint4*)gu)[gi] = make_uint4(go[0],go[1],go[2],go[3]);
    }
}

// ------------------------------------------------- final rms + 3 scalar heads; h -> tiled bf16
__global__ __launch_bounds__(256) void decode2(
    const float* __restrict__ x, const float* __restrict__ gout,
    const float* __restrict__ Wn, const float* __restrict__ bn,
    const float* __restrict__ Wd, const float* __restrict__ bd,
    const float* __restrict__ Wb, const float* __restrict__ bb,
    float* __restrict__ out, u16* __restrict__ h16)
{
    const int row = blockIdx.x;
    const int t = threadIdx.x;
    __shared__ float h[DM];
    __shared__ float red[256];
    const float* xr = x + (size_t)row*DM;
    float v0=xr[t], v1=xr[t+256], v2=xr[t+512];
    red[t]=v0*v0+v1*v1+v2*v2; __syncthreads();
    for (int s=128;s>0;s>>=1){ if(t<s) red[t]+=red[t+s]; __syncthreads(); }
    float r = rsqrtf(red[0]/(float)DM + EPSF);
    float h0 = v0*r*gout[t], h1 = v1*r*gout[t+256], h2 = v2*r*gout[t+512];
    h[t]=h0; h[t+256]=h1; h[t+512]=h2;
    const size_t mb = (size_t)(row>>7)*12;
    const int rr = (row&127)<<6;
    #pragma unroll
    for (int j=0;j<3;j++){
        const int c = t + j*256;
        const float v = (j==0?h0:(j==1?h1:h2));
        h16[((mb + (c>>6))<<13) + rr + (c&63)] = f2bu(v);
    }
    __syncthreads();

    float pn=0.f,pd=0.f,pb=0.f;
    for (int k=t;k<DM;k+=256){ float hv=h[k]; pn+=hv*Wn[k]; pd+=hv*Wd[k]; pb+=hv*Wb[k]; }
    red[t]=pn; __syncthreads();
    for (int s=128;s>0;s>>=1){ if(t<s) red[t]+=red[t+s]; __syncthreads(); }
    float tn=red[0]; __syncthreads();
    red[t]=pd; __syncthreads();
    for (int s=128;s>0;s>>=1){ if(t<s) red[t]+=red[t+s]; __syncthreads(); }
    float td=red[0]; __syncthreads();
    red[t]=pb; __syncthreads();
    for (int s=128;s>0;s>>=1){ if(t<s) red[t]+=red[t+s]; __syncthreads(); }
    float tb=red[0];
    if (t==0){
        out[row]          = tn + bn[0];
        out[NROW + row]   = td + bd[0];
        out[2*NROW + row] = tb + bb[0];
    }
}

// ---------------------------------------------------------------- launcher
extern "C" void kernel_launch(void* const* d_in, const int* in_sizes, int n_in,
                              void* d_out, int out_size, void* d_ws, size_t ws_size,
                              hipStream_t stream)
{
    const float* numv   = (const float*)d_in[0];
    const float* dtval  = (const float*)d_in[1];
    const float* boolv  = (const float*)d_in[2];
    const float* textv  = (const float*)d_in[3];
    const float* cnamev = (const float*)d_in[4];
    const float* Wcn=(const float*)d_in[5];  const float* bcn=(const float*)d_in[6];
    const float* Wnum=(const float*)d_in[7]; const float* bnum=(const float*)d_in[8];
    const float* Wtext=(const float*)d_in[9];const float* btext=(const float*)d_in[10];
    const float* Wdt=(const float*)d_in[11]; const float* bdt=(const float*)d_in[12];
    const float* Wbool=(const float*)d_in[13];const float* bbool=(const float*)d_in[14];
    const float* gcn=(const float*)d_in[15]; const float* gnum=(const float*)d_in[16];
    const float* gtext=(const float*)d_in[17];const float* gdt=(const float*)d_in[18];
    const float* gbool=(const float*)d_in[19];
    const float* memb=(const float*)d_in[20];
    const float* norms_all=(const float*)d_in[21];
    const float* attw_all=(const float*)d_in[22];
    const float* up_all=(const float*)d_in[23];
    const float* gate_all=(const float*)d_in[24];
    const float* down_all=(const float*)d_in[25];
    const float* gout=(const float*)d_in[26];
    const float* Wdn=(const float*)d_in[27]; const float* bdn=(const float*)d_in[28];
    const float* Wdd=(const float*)d_in[29]; const float* bdd=(const float*)d_in[30];
    const float* Wdb=(const float*)d_in[31]; const float* bdb=(const float*)d_in[32];
    const float* Wdtx=(const float*)d_in[33];const float* bdtx=(const float*)d_in[34];
    const int* node=(const int*)d_in[35];
    const int* tbl =(const int*)d_in[36];
    const int* colx=(const int*)d_in[37];
    const int* f2p =(const int*)d_in[38];
    const int* styp=(const int*)d_in[39];

    const size_t SA = (size_t)768*768;
    const size_t SG = (size_t)768*3072;
    const size_t SC = (size_t)384*768;
    const size_t NX = (size_t)NROW*DM;

    u8* base = (u8*)d_ws;
    float* x  = (float*)base;
    u16* xt16 = (u16*)(base + 6291456);
    u16* ob16 = (u16*)(base + 9437184);
    u16* qk16 = (u16*)(base + 12582912);
    u16* vt16 = (u16*)(base + 18874368);
    u16* gu16 = (u16*)(base + 22020096);
    u16* wA   = (u16*)(base + 47185920);
    u16* wGU  = wA + 64*SA;
    u16* wD   = wGU + 8*SG;
    u16* wCN  = wD + 4*SG;
    u16* wTX  = wCN + SC;
    u16* wDX  = wTX + SC;
    u8* nmask = (u8*)(wDX + SC);
    u8* npad  = nmask + NROW;
    u32* pmeta = (u32*)(npad + NROW + 64);
    float* rsbuf = (float*)(pmeta + NROW);     // 21 slots x 2048

    // encode-phase aliases
    u16* cnT16   = qk16;
    u16* textT16 = vt16;
    float* cnbuf   = (float*)gu16;
    float* textbuf = cnbuf + NX;

    float* out = (float*)d_out;

    zero_f<<<(21*2048)/256,256,0,stream>>>(rsbuf, 21*2048);
    norm_bool_kernel<<<1,256,0,stream>>>(d_in[40], nmask, NROW);
    norm_bool_kernel<<<1,256,0,stream>>>(d_in[41], npad,  NROW);
    pack_meta<<<NROW/256,256,0,stream>>>(node, colx, tbl, npad, pmeta, NROW);

    // weight prep (tiled bf16; gamma folded)
    transpose_cvt2<<<dim3(24,12,64),256,0,stream>>>(attw_all, wA, 768, 768, SA, norms_all, 1);
    transpose_cvt2<<<dim3(96,12,4),256,0,stream>>>(gate_all, wGU,      768, 3072, 2*SG, norms_all + 4*768, 2);
    transpose_cvt2<<<dim3(96,12,4),256,0,stream>>>(up_all,   wGU + SG, 768, 3072, 2*SG, norms_all + 4*768, 2);
    transpose_cvt2<<<dim3(24,48,4),256,0,stream>>>(down_all, wD, 3072, 768, SG, nullptr, 0);
    transpose_cvt2<<<dim3(24,6,1),256,0,stream>>>(Wcn,   wCN, 384, 768, 0, nullptr, 0);
    transpose_cvt2<<<dim3(24,6,1),256,0,stream>>>(Wtext, wTX, 384, 768, 0, nullptr, 0);
    transpose_cvt2<<<dim3(12,12,1),256,0,stream>>>(Wdtx, wDX, 768, 384, 0, nullptr, 0);

    // encode
    cvt_tiled<<<384,256,0,stream>>>(cnamev, cnT16, 384);
    cvt_tiled<<<384,256,0,stream>>>(textv,  textT16, 384);
    gemm_t<<<dim3(12,16),256,0,stream>>>(cnT16,   wCN, cnbuf,   768, 384, 6, 2, bcn,   nullptr, nullptr, nullptr, nullptr, nullptr);
    gemm_t<<<dim3(12,16),256,0,stream>>>(textT16, wTX, textbuf, 768, 384, 6, 2, btext, nullptr, nullptr, nullptr, nullptr, nullptr);
    fuse_encode<<<NROW,256,0,stream>>>(cnbuf, textbuf, numv, dtval, boolv,
        Wnum,bnum,Wdt,bdt,Wbool,bbool, gcn,gnum,gtext,gdt,gbool,
        memb, styp, nmask, x, xt16, rsbuf);

    const dim3 ga(SS/64, BB*NH);
    for (int l=0; l<NL; l++){
        for (int a=0; a<4; a++){
            const int slot = l*5 + a;
            const u16* wqkv = wA + (size_t)((l*4+a)*4)*SA;
            gemm_t<<<dim3(36,16),256,0,stream>>>(xt16, wqkv, nullptr, 2304, 768, 12, 4, nullptr,
                nullptr, qk16, vt16, rsbuf + (size_t)slot*2048, nullptr);
            if (a==0)      attn_mfma<0><<<ga,256,0,stream>>>(qk16,vt16,pmeta,f2p,ob16);
            else if (a==1) attn_mfma<1><<<ga,256,0,stream>>>(qk16,vt16,pmeta,f2p,ob16);
            else if (a==2) attn_mfma<2><<<ga,256,0,stream>>>(qk16,vt16,pmeta,f2p,ob16);
            else           attn_mfma<3><<<ga,256,0,stream>>>(qk16,vt16,pmeta,f2p,ob16);
            gemm_t<<<dim3(12,16),256,0,stream>>>(ob16, wqkv + 3*SA, x, 768, 768, 12, 1, nullptr,
                xt16, nullptr, nullptr, nullptr, rsbuf + (size_t)(slot+1)*2048);
        }
        gemm_t<<<dim3(96,16),256,0,stream>>>(xt16, wGU + (size_t)l*2*SG, nullptr, 6144, 768, 12, 8, nullptr,
            gu16, nullptr, nullptr, rsbuf + (size_t)(l*5+4)*2048, nullptr);
        silu_gu<<<1024,256,0,stream>>>(gu16, 16*48*1024);
        gemm_t<<<dim3(12,16),256,0,stream>>>(gu16, wD + (size_t)l*SG, x, 768, 3072, 96, 1, nullptr,
            xt16, nullptr, nullptr, nullptr, rsbuf + (size_t)((l+1)*5)*2048);
    }

    decode2<<<NROW,256,0,stream>>>(x, gout, Wdn,bdn, Wdd,bdd, Wdb,bdb, out, xt16);
    gemm_t<<<dim3(6,16),256,0,stream>>>(xt16, wDX, out + 3*NROW, 384, 768, 12, 2, bdtx,
        nullptr, nullptr, nullptr, nullptr, nullptr);
}

// Round 10
// 1671.357 us; speedup vs baseline: 6.1583x; 1.0780x over previous
//
#include <hip/hip_runtime.h>
#include <hip/hip_bf16.h>
#include <cmath>
#include <stdint.h>

// Round 10: precomputed bit-packed masks (m4[b][k][q], bit t = mask type t) staged via
// global_load_lds in attention; BM=64 GEMM variant for narrow (N<=768) GEMMs.

#define BB 2
#define SS 1024
#define DT 384
#define DM 768
#define NH 12
#define DH 64
#define DFF 3072
#define NL 4
#define NROW (BB*SS)
#define EPSF 1e-6f
#define NEGF (-1e9f)

typedef unsigned short u16;
typedef unsigned char u8;
typedef unsigned int u32;
typedef __attribute__((ext_vector_type(8))) short s16x8;
typedef __attribute__((ext_vector_type(4))) float f32x4;

__device__ __forceinline__ u16 f2bu(float f){
    u32 x = __float_as_uint(f);
    u32 r = (x + 0x7fffu + ((x>>16)&1u)) >> 16;   // RNE
    return (u16)r;
}
__device__ __forceinline__ u32 pk2(float lo, float hi){
    return (u32)f2bu(lo) | ((u32)f2bu(hi)<<16);
}
__device__ __forceinline__ int swz(int row, int c){
    return (row<<6) + (((((c>>3) ^ row) & 7))<<3) + (c&7);
}
__device__ __forceinline__ float rmax16(float v){
    v = fmaxf(v, __shfl_xor(v,1)); v = fmaxf(v, __shfl_xor(v,2));
    v = fmaxf(v, __shfl_xor(v,4)); v = fmaxf(v, __shfl_xor(v,8));
    return v;
}
__device__ __forceinline__ float rsum16(float v){
    v += __shfl_xor(v,1); v += __shfl_xor(v,2);
    v += __shfl_xor(v,4); v += __shfl_xor(v,8);
    return v;
}
#define SBAR() __builtin_amdgcn_sched_barrier(0)
#define GLDS(src,dst) __builtin_amdgcn_global_load_lds((const __attribute__((address_space(1))) u32*)(src), (__attribute__((address_space(3))) u32*)(dst), 16, 0, 0)
#define GLDS4(src,dst) __builtin_amdgcn_global_load_lds((const __attribute__((address_space(1))) u32*)(src), (__attribute__((address_space(3))) u32*)(dst), 4, 0, 0)

// ------------------------------------------------- zero helper
__global__ void zero_f(float* __restrict__ p, int n){
    int i = blockIdx.x*256 + threadIdx.x;
    if (i<n) p[i]=0.f;
}

// ------------------------------------------------- bool-buffer normalizer
__global__ void norm_bool_kernel(const void* __restrict__ src, u8* __restrict__ dst, int n)
{
    __shared__ int fl[4];
    if (threadIdx.x<4) fl[threadIdx.x]=0;
    __syncthreads();
    const u32* wsrc = (const u32*)src;
    const int nw = n/4;
    int any=0, nb=0, hi=0, lo=0;
    for (int i=threadIdx.x;i<nw;i+=blockDim.x){
        u32 v=wsrc[i];
        if (!v) continue;
        any=1;
        #pragma unroll
        for (int b=0;b<4;b++){
            u32 by=(v>>(8*b))&0xffu;
            if (by>1u) nb=1;
            if (by==1u && b!=0) hi=1;
        }
        if ((v&0xffffu)==0x3f80u) lo=1;
    }
    if (any) atomicOr(&fl[0],1);
    if (nb)  atomicOr(&fl[1],1);
    if (hi)  atomicOr(&fl[2],1);
    if (lo)  atomicOr(&fl[3],1);
    __syncthreads();
    int c;
    if (!fl[0]) c=0;
    else if (!fl[1]) c = fl[2] ? 2 : 1;
    else if (fl[3]) c = 3;
    else c = 1;
    for (int i=threadIdx.x;i<n;i+=blockDim.x){
        u8 v;
        if (c==0)      v=0;
        else if (c==1) v = (((const u32*)src)[i]!=0u);
        else if (c==2) v = (((const u8*)src)[i]!=0u);
        else           v = (((const u16*)src)[i]!=0u);
        dst[i]=v;
    }
}

// ------------------------------------------------- pack per-token metadata
__global__ void pack_meta(const int* __restrict__ node, const int* __restrict__ colx,
                          const int* __restrict__ tbl, const u8* __restrict__ pad,
                          u32* __restrict__ pm, int n)
{
    int i = blockIdx.x*256 + threadIdx.x;
    if (i<n)
        pm[i] = (u32)(node[i]&0xff) | ((u32)(colx[i]&0xff)<<8) | ((u32)(tbl[i]&0xff)<<16) | ((u32)(pad[i]&1)<<24);
}

// ------------------------------------------------- mask table: m4[b][k][q] bit t = mask_t(q,k)
__global__ __launch_bounds__(256) void mask4_kernel(const u32* __restrict__ pm, const int* __restrict__ f2p,
                                                    u8* __restrict__ m4)
{
    const int b = blockIdx.y, kg = blockIdx.x;   // kg in [0,64): 16 k-rows each
    const int t = threadIdx.x;
    __shared__ u32 qm[1024];
    __shared__ int qf[1024*5];
    for (int i=t;i<1024;i+=256) qm[i] = pm[b*SS+i];
    for (int i=t;i<5*1024;i+=256) qf[i] = f2p[b*SS*5 + i];
    __syncthreads();
    const int q0 = t*4;
    u32 qmv[4]; int qn[4]; int qfv[4][5];
    #pragma unroll
    for (int j=0;j<4;j++){
        qmv[j]=qm[q0+j]; qn[j]=(int)(qmv[j]&0xffu);
        #pragma unroll
        for (int f=0;f<5;f++) qfv[j][f]=qf[(q0+j)*5+f];
    }
    for (int kk=0;kk<16;kk++){
        const int k = kg*16+kk;
        const u32 km = qm[k];
        const int kn = (int)(km&0xffu);
        u32 outw=0;
        #pragma unroll
        for (int j=0;j<4;j++){
            const u32 qmw = qmv[j];
            const bool pv = (((qmw|km)>>24)&1u)==0u;
            u32 by=0;
            if ((((qmw^km)&0x00ffff00u)==0u) && pv) by|=1;
            if ((((qmw^km)&0xffu)==0u) && pv) by|=2;
            bool nei = (qfv[j][0]==kn)||(qfv[j][1]==kn)||(qfv[j][2]==kn)||(qfv[j][3]==kn)||(qfv[j][4]==kn)
                       ||(qn[j]==kn);
            if (nei && pv) by|=4;
            if (pv) by|=8;
            if ((q0+j)==k) by=15;
            outw |= by<<(8*j);
        }
        ((u32*)(m4 + ((size_t)b<<20) + ((size_t)k<<10)))[t] = outw;
    }
}

// ------------------------------------------------- weight f32 [K][N] -> tiled bf16 (+gamma fold)
__global__ __launch_bounds__(256) void transpose_cvt2(const float* __restrict__ src, u16* __restrict__ dst,
                                                      int K, int N, size_t dz,
                                                      const float* __restrict__ gbase, int gmode)
{
    const int z = blockIdx.z;
    src += (size_t)z*K*N;
    dst += (size_t)z*dz;
    const float* g = nullptr;
    if (gmode==1){ int m = z&3; if (m<3) g = gbase + (size_t)((z>>4)*5 + ((z>>2)&3))*768; }
    else if (gmode==2){ g = gbase + (size_t)z*5*768; }
    const int n0 = blockIdx.x*32, k0 = blockIdx.y*64;
    __shared__ float t[64][33];
    const int tid = threadIdx.x;
    const int kr = tid>>3, n4 = (tid&7)*4;
    #pragma unroll
    for (int p=0;p<2;p++){
        const int k = p*32 + kr;
        float gk = g ? g[k0+k] : 1.f;
        float4 v = *(const float4*)(src + (size_t)(k0+k)*N + n0 + n4);
        t[k][n4]=v.x*gk; t[k][n4+1]=v.y*gk; t[k][n4+2]=v.z*gk; t[k][n4+3]=v.w*gk;
    }
    __syncthreads();
    const int n = tid>>3, ks = (tid&7)*8;
    const int ng = n0 + n;
    uint4 o;
    u32* op = (u32*)&o;
    #pragma unroll
    for (int i=0;i<4;i++)
        op[i] = pk2(t[ks+2*i][n], t[ks+2*i+1][n]);
    *(uint4*)&dst[(((size_t)(ng>>7)*(K>>6) + (k0>>6))<<13) + ((ng&127)<<6) + ks] = o;
}

// ------------------------------------------------- activation f32 [M][K] -> tiled bf16
__global__ __launch_bounds__(256) void cvt_tiled(const float* __restrict__ src, u16* __restrict__ dst, int K)
{
    const int gid = blockIdx.x*256 + threadIdx.x;
    const int base = gid*8;
    const int row = base / K, col = base - row*K;
    float4 a = *(const float4*)(src + base);
    float4 b = *(const float4*)(src + base + 4);
    uint4 o;
    o.x = pk2(a.x,a.y); o.y = pk2(a.z,a.w);
    o.z = pk2(b.x,b.y); o.w = pk2(b.z,b.w);
    *(uint4*)&dst[(((size_t)(row>>7)*(K>>6) + (col>>6))<<13) + ((row&127)<<6) + (col&63)] = o;
}

// ------------------------------------------------- BM=128 GEMM (qkv / gate-up)
__device__ __forceinline__ void stage3(const u16* aT, const u16* bT, int cb, int brow,
                                       u16* la, u16* lb, int w, int l)
{
    #pragma unroll
    for (int p=0;p<2;p++){
        const int q = p*256 + w*64 + l;
        const int row = q>>2, u = q&3;
        const int so = row*64 + cb + (((u ^ ((row>>1)&3))&3)<<3);
        GLDS(aT+so, la + p*2048 + w*512);
    }
    {
        const int q = w*64 + l;
        const int row = q>>2, u = q&3;
        const int so = (brow+row)*64 + cb + (((u ^ ((row>>1)&3))&3)<<3);
        GLDS(bT+so, lb + w*512);
    }
}

__global__ __launch_bounds__(256,4) void gemm_t(
    const u16* __restrict__ At, const u16* __restrict__ Bt, float* __restrict__ C,
    int N, int K, int AMS, int flags, const float* __restrict__ bias,
    u16* __restrict__ o16, u16* __restrict__ qk16, u16* __restrict__ vt16,
    const float* __restrict__ rs_in, float* __restrict__ rs_out)
{
    __shared__ u16 lds[3][6144];
    const int tid = threadIdx.x;
    const int lane = tid & 63, w = tid >> 6;
    const int cg = lane >> 4, cl = lane & 15;
    const int NT = K >> 5;
    const int n0 = blockIdx.x*64;
    const int brow = n0 & 64;
    const size_t bNb = (size_t)(n0>>7)*(K>>6);

    const u16* aB = At + ((size_t)blockIdx.y * AMS << 13);
    const u16* bB = Bt + (bNb << 13);

    f32x4 acc[2][4];
    #pragma unroll
    for (int i=0;i<2;i++)
        #pragma unroll
        for (int j=0;j<4;j++) acc[i][j] = (f32x4){0.f,0.f,0.f,0.f};

    stage3(aB, bB, 0,  brow, &lds[0][0], &lds[0][4096], w, lane);
    stage3(aB, bB, 32, brow, &lds[1][0], &lds[1][4096], w, lane);

    for (int kt=0; kt<NT; kt++){
        const int buf = kt % 3;
        if (kt+2 < NT){
            const int k2 = kt+2;
            stage3(aB + ((size_t)(k2>>1)<<13), bB + ((size_t)(k2>>1)<<13),
                   (k2&1)<<5, brow, &lds[k2%3][0], &lds[k2%3][4096], w, lane);
            asm volatile("s_waitcnt vmcnt(6)" ::: "memory");
        } else if (kt+1 < NT){
            asm volatile("s_waitcnt vmcnt(3)" ::: "memory");
        } else {
            asm volatile("s_waitcnt vmcnt(0)" ::: "memory");
        }
        SBAR(); __builtin_amdgcn_s_barrier(); SBAR();
        s16x8 af[2], bf[4];
        #pragma unroll
        for (int mt=0;mt<2;mt++){
            const int ra = w*32 + mt*16 + cl;
            af[mt] = *(const s16x8*)&lds[buf][ra*32 + (((cg ^ ((ra>>1)&3))&3)<<3)];
        }
        #pragma unroll
        for (int nt=0;nt<4;nt++){
            const int rb = nt*16 + cl;
            bf[nt] = *(const s16x8*)&lds[buf][4096 + rb*32 + (((cg ^ ((rb>>1)&3))&3)<<3)];
        }
        #pragma unroll
        for (int mt=0;mt<2;mt++)
            #pragma unroll
            for (int nt=0;nt<4;nt++)
                acc[mt][nt] = __builtin_amdgcn_mfma_f32_16x16x32_bf16(af[mt], bf[nt], acc[mt][nt], 0,0,0);
        SBAR(); __builtin_amdgcn_s_barrier(); SBAR();
    }

    const int m0 = blockIdx.y*128;
    if (flags & 4){
        #pragma unroll
        for (int mt=0;mt<2;mt++){
            const int grow0 = m0 + w*32 + mt*16 + cg*4;
            float rr[4];
            #pragma unroll
            for (int j=0;j<4;j++) rr[j] = rsqrtf(rs_in[grow0+j]*(1.f/768.f) + EPSF);
            #pragma unroll
            for (int nt=0;nt<4;nt++){
                const int col = n0 + nt*16 + cl;
                if (col < 1536){
                    #pragma unroll
                    for (int j=0;j<4;j++)
                        qk16[(size_t)(grow0+j)*1536 + col] = f2bu(acc[mt][nt][j]*rr[j]);
                } else {
                    const int b = grow0>>10, s0 = grow0&1023;
                    const int dhg = col - 1536;
                    uint2 o;
                    o.x = pk2(acc[mt][nt][0]*rr[0], acc[mt][nt][1]*rr[1]);
                    o.y = pk2(acc[mt][nt][2]*rr[2], acc[mt][nt][3]*rr[3]);
                    *(uint2*)(vt16 + ((size_t)(b*768 + dhg)<<10) + s0) = o;
                }
            }
        }
    } else {   // flags & 8: bf16-tiled out with rs_in scale
        const int NC = N>>6;
        #pragma unroll
        for (int mt=0;mt<2;mt++){
            const int grow0 = m0 + w*32 + mt*16 + cg*4;
            float rr[4];
            #pragma unroll
            for (int j=0;j<4;j++) rr[j] = rs_in ? rsqrtf(rs_in[grow0+j]*(1.f/768.f) + EPSF) : 1.f;
            #pragma unroll
            for (int nt=0;nt<4;nt++){
                const int col = n0 + nt*16 + cl;
                const size_t tb = (((size_t)(grow0>>7)*NC + (col>>6))<<13) + (col&63);
                #pragma unroll
                for (int j=0;j<4;j++)
                    o16[tb + (((grow0+j)&127)<<6)] = f2bu(acc[mt][nt][j]*rr[j]);
            }
        }
    }
}

// ------------------------------------------------- BM=64 GEMM (narrow N): flags 1=acc(+o16/rs), 2=bias
__device__ __forceinline__ void stage64(const u16* aT, int arow, const u16* bT, int brow, int cb,
                                        u16* la, u16* lb, int w, int l)
{
    const int q = w*64 + l;
    const int row = q>>2, u = q&3;
    const int sw = (((u ^ ((row>>1)&3))&3)<<3);
    GLDS(aT + (arow+row)*64 + cb + sw, la + w*512);
    GLDS(bT + (brow+row)*64 + cb + sw, lb + w*512);
}

__global__ __launch_bounds__(256,6) void gemm_t64(
    const u16* __restrict__ At, const u16* __restrict__ Bt, float* __restrict__ C,
    int N, int K, int AMS, int flags, const float* __restrict__ bias,
    u16* __restrict__ o16, float* __restrict__ rs_out)
{
    __shared__ u16 lds[3][4096];   // A[0..2047], B[2048..4095]
    const int tid = threadIdx.x;
    const int lane = tid & 63, w = tid >> 6;
    const int cg = lane >> 4, cl = lane & 15;
    const int NT = K >> 5;
    const int n0 = blockIdx.x*64;
    const int m0 = blockIdx.y*64;
    const int brow = n0 & 64, arow = m0 & 64;

    const u16* aB = At + ((size_t)(m0>>7) * AMS << 13);
    const u16* bB = Bt + ((size_t)(n0>>7) * (K>>6) << 13);

    f32x4 acc[4];
    #pragma unroll
    for (int j=0;j<4;j++) acc[j] = (f32x4){0.f,0.f,0.f,0.f};

    stage64(aB, arow, bB, brow, 0,  &lds[0][0], &lds[0][2048], w, lane);
    stage64(aB, arow, bB, brow, 32, &lds[1][0], &lds[1][2048], w, lane);

    for (int kt=0; kt<NT; kt++){
        const int buf = kt % 3;
        if (kt+2 < NT){
            const int k2 = kt+2;
            stage64(aB + ((size_t)(k2>>1)<<13), arow, bB + ((size_t)(k2>>1)<<13), brow,
                    (k2&1)<<5, &lds[k2%3][0], &lds[k2%3][2048], w, lane);
            asm volatile("s_waitcnt vmcnt(4)" ::: "memory");
        } else if (kt+1 < NT){
            asm volatile("s_waitcnt vmcnt(2)" ::: "memory");
        } else {
            asm volatile("s_waitcnt vmcnt(0)" ::: "memory");
        }
        SBAR(); __builtin_amdgcn_s_barrier(); SBAR();
        const int ra = w*16 + cl;
        s16x8 af = *(const s16x8*)&lds[buf][ra*32 + (((cg ^ ((ra>>1)&3))&3)<<3)];
        s16x8 bf[4];
        #pragma unroll
        for (int nt=0;nt<4;nt++){
            const int rb = nt*16 + cl;
            bf[nt] = *(const s16x8*)&lds[buf][2048 + rb*32 + (((cg ^ ((rb>>1)&3))&3)<<3)];
        }
        #pragma unroll
        for (int nt=0;nt<4;nt++)
            acc[nt] = __builtin_amdgcn_mfma_f32_16x16x32_bf16(af, bf[nt], acc[nt], 0,0,0);
        SBAR(); __builtin_amdgcn_s_barrier(); SBAR();
    }

    const int grow0 = m0 + w*16 + cg*4;
    const bool do_acc = (flags&1), do_bias = (flags&2);
    float tmp[4][4];
    #pragma unroll
    for (int nt=0;nt<4;nt++){
        const int col = n0 + nt*16 + cl;
        float bv = do_bias ? bias[col] : 0.f;
        #pragma unroll
        for (int j=0;j<4;j++){
            float v = acc[nt][j] + bv;
            float* cp = C + (size_t)(grow0+j)*N + col;
            if (do_acc) v += *cp;
            *cp = v;
            tmp[nt][j] = v;
        }
    }
    if (o16){
        #pragma unroll
        for (int nt=0;nt<4;nt++){
            const int col = n0 + nt*16 + cl;
            const size_t tb = (((size_t)(grow0>>7)*12 + (col>>6))<<13) + (col&63);
            #pragma unroll
            for (int j=0;j<4;j++)
                o16[tb + (((grow0+j)&127)<<6)] = f2bu(tmp[nt][j]);
        }
    }
    if (rs_out){
        #pragma unroll
        for (int j=0;j<4;j++){
            float s = tmp[0][j]*tmp[0][j] + tmp[1][j]*tmp[1][j]
                    + tmp[2][j]*tmp[2][j] + tmp[3][j]*tmp[3][j];
            s = rsum16(s);
            if (cl==0) atomicAdd(rs_out + grow0 + j, s);
        }
    }
}

// ------------------------------------------------- MFMA flash attention (bit-mask table, runtime mt)
__global__ __launch_bounds__(256,3) void attn_mfma2(
    const u16* __restrict__ qk16, const u16* __restrict__ vt16,
    const u8* __restrict__ m4, int mt,
    u16* __restrict__ ob16)
{
    const int bh = blockIdx.y;
    const int b = bh / NH, h = bh % NH;
    const int q0 = blockIdx.x * 64;
    const int tid = threadIdx.x;
    const int w = tid>>6, lane = tid&63, cg = lane>>4, cl = lane&15;
    const int srow = lane>>3;
    const int sseg = (lane&7) ^ srow;
    const int mk = lane>>4, mq = lane&15;   // mask stage lane mapping

    __shared__ u16 Qs[4096], Ks[2][4096], Vt[2][4096], Ps[4096];
    __shared__ u32 Ms[2][1024];             // [64 keys][64 q] bytes, double-buffered

    const u16* qbase = qk16 + (size_t)(b*SS+q0)*1536 + h*64;
    const u16* kbase = qk16 + (size_t)(b*SS)*1536 + 768 + h*64;
    const u16* vbase = vt16 + ((size_t)(b*768 + h*64)<<10);
    const u8*  mbase = m4 + ((size_t)b<<20) + q0;

    // prologue: Q (2) + KV0 (4) + M0 (4)  => 10 outstanding
    #pragma unroll
    for (int p=0;p<2;p++){
        const int row = p*32 + w*8 + srow;
        GLDS(qbase + (size_t)row*1536 + sseg*8, Qs + p*2048 + w*512);
    }
    #pragma unroll
    for (int p=0;p<2;p++){
        const int row = p*32 + w*8 + srow;
        GLDS(kbase + (size_t)row*1536 + sseg*8, Ks[0] + p*2048 + w*512);
        GLDS(vbase + ((size_t)row<<10) + sseg*8, Vt[0] + p*2048 + w*512);
    }
    #pragma unroll
    for (int i=0;i<4;i++){
        const int key = w*16 + i*4 + mk;
        GLDS4(mbase + ((size_t)key<<10) + mq*4, (u8*)Ms[0] + w*1024 + i*256);
    }

    f32x4 o[4];
    #pragma unroll
    for (int nt=0;nt<4;nt++) o[nt] = (f32x4){0.f,0.f,0.f,0.f};
    float mrun[4], lrun[4];
    #pragma unroll
    for (int j=0;j<4;j++){ mrun[j]=-INFINITY; lrun[j]=0.f; }

    for (int kc=0;kc<16;kc++){
        const int k0 = kc*64;
        const int buf = kc & 1;
        if (kc < 15){
            const int kn0 = k0 + 64;
            #pragma unroll
            for (int p=0;p<2;p++){
                const int row = p*32 + w*8 + srow;
                GLDS(kbase + (size_t)(kn0+row)*1536 + sseg*8, Ks[buf^1] + p*2048 + w*512);
                GLDS(vbase + ((size_t)row<<10) + kn0 + sseg*8, Vt[buf^1] + p*2048 + w*512);
            }
            #pragma unroll
            for (int i=0;i<4;i++){
                const int key = kn0 + w*16 + i*4 + mk;
                GLDS4(mbase + ((size_t)key<<10) + mq*4, (u8*)Ms[buf^1] + w*1024 + i*256);
            }
            asm volatile("s_waitcnt vmcnt(8)" ::: "memory");
        } else {
            asm volatile("s_waitcnt vmcnt(0)" ::: "memory");
        }
        SBAR(); __builtin_amdgcn_s_barrier(); SBAR();

        // QK^T
        f32x4 sc[4];
        #pragma unroll
        for (int nt=0;nt<4;nt++) sc[nt] = (f32x4){0.f,0.f,0.f,0.f};
        #pragma unroll
        for (int ks=0;ks<2;ks++){
            s16x8 qa = *(const s16x8*)&Qs[swz(w*16+cl, ks*32+cg*8)];
            #pragma unroll
            for (int nt=0;nt<4;nt++){
                s16x8 kb = *(const s16x8*)&Ks[buf][swz(nt*16+cl, ks*32+cg*8)];
                sc[nt] = __builtin_amdgcn_mfma_f32_16x16x32_bf16(qa, kb, sc[nt], 0,0,0);
            }
        }

        // mask from bit table
        float pP[4][4];
        #pragma unroll
        for (int nt=0;nt<4;nt++){
            const u32 w4 = Ms[buf][(nt*16+cl)*16 + w*4 + cg];
            #pragma unroll
            for (int j=0;j<4;j++){
                float sv = sc[nt][j]*0.125f;
                const bool m = (w4 >> (8*j + mt)) & 1u;
                pP[nt][j] = m ? sv : NEGF;
            }
        }

        // online softmax
        #pragma unroll
        for (int j=0;j<4;j++){
            float mx = fmaxf(fmaxf(pP[0][j],pP[1][j]), fmaxf(pP[2][j],pP[3][j]));
            mx = rmax16(mx);
            float mnew = fmaxf(mrun[j], mx);
            float al = __expf(mrun[j]-mnew);
            mrun[j] = mnew;
            float ps = 0.f;
            #pragma unroll
            for (int nt=0;nt<4;nt++){
                float pe = __expf(pP[nt][j]-mnew);
                pP[nt][j]=pe; ps += pe;
            }
            ps = rsum16(ps);
            lrun[j] = lrun[j]*al + ps;
            #pragma unroll
            for (int nt=0;nt<4;nt++) o[nt][j] *= al;
        }

        #pragma unroll
        for (int nt=0;nt<4;nt++)
            #pragma unroll
            for (int j=0;j<4;j++)
                Ps[swz(w*16+cg*4+j, nt*16+cl)] = f2bu(pP[nt][j]);

        // PV
        #pragma unroll
        for (int ks=0;ks<2;ks++){
            s16x8 pa = *(const s16x8*)&Ps[swz(w*16+cl, ks*32+cg*8)];
            #pragma unroll
            for (int nt=0;nt<4;nt++){
                s16x8 vb = *(const s16x8*)&Vt[buf][swz(nt*16+cl, ks*32+cg*8)];
                o[nt] = __builtin_amdgcn_mfma_f32_16x16x32_bf16(pa, vb, o[nt], 0,0,0);
            }
        }
        SBAR(); __builtin_amdgcn_s_barrier(); SBAR();
    }

    #pragma unroll
    for (int j=0;j<4;j++){
        const float inv = 1.f/lrun[j];
        const int row = b*SS + q0 + w*16 + cg*4 + j;
        const size_t rb = ((size_t)(row>>7)*12 + h)*8192 + ((row&127)<<6);
        #pragma unroll
        for (int nt=0;nt<4;nt++)
            ob16[rb + nt*16 + cl] = f2bu(o[nt][j]*inv);
    }
}

// ------------------------------------------------- encode fuse
__global__ __launch_bounds__(256) void fuse_encode(
    const float* __restrict__ cnbuf, const float* __restrict__ textbuf,
    const float* __restrict__ numv, const float* __restrict__ dtv, const float* __restrict__ boolv,
    const float* __restrict__ Wnum, const float* __restrict__ bnum,
    const float* __restrict__ Wdt, const float* __restrict__ bdt,
    const float* __restrict__ Wbool, const float* __restrict__ bbool,
    const float* __restrict__ gcn, const float* __restrict__ gnum, const float* __restrict__ gtext,
    const float* __restrict__ gdt, const float* __restrict__ gbool,
    const float* __restrict__ memb, const int* __restrict__ stypes, const u8* __restrict__ masks,
    float* __restrict__ x, u16* __restrict__ xt16, float* __restrict__ rs0)
{
    const int row = blockIdx.x;
    const int t = threadIdx.x;
    __shared__ float red[256];

    float cn3[3]; float ss=0.f;
    #pragma unroll
    for (int j=0;j<3;j++){
        cn3[j] = cnbuf[(size_t)row*DM + t + j*256];
        ss += cn3[j]*cn3[j];
    }
    red[t]=ss; __syncthreads();
    for (int s=128;s>0;s>>=1){ if(t<s) red[t]+=red[t+s]; __syncthreads(); }
    {
        float r = rsqrtf(red[0]/(float)DM + EPSF);
        #pragma unroll
        for (int j=0;j<3;j++) cn3[j] *= r*gcn[t+j*256];
    }
    __syncthreads();

    const int st = stypes[row];
    float val[3]; ss=0.f;
    if (st==1){
        #pragma unroll
        for (int j=0;j<3;j++){
            val[j] = textbuf[(size_t)row*DM + t + j*256];
            ss += val[j]*val[j];
        }
    } else {
        const float* Wp = (st==0)?Wnum:((st==2)?Wdt:Wbool);
        const float* bp = (st==0)?bnum:((st==2)?bdt:bbool);
        const float* vp = (st==0)?numv:((st==2)?dtv:boolv);
        float v = vp[row];
        #pragma unroll
        for (int j=0;j<3;j++){
            int e=t+j*256;
            val[j] = v*Wp[e] + bp[e];
            ss += val[j]*val[j];
        }
    }
    red[t]=ss; __syncthreads();
    for (int s=128;s>0;s>>=1){ if(t<s) red[t]+=red[t+s]; __syncthreads(); }
    const float* gp = (st==0)?gnum:((st==1)?gtext:((st==2)?gdt:gbool));
    float r2 = rsqrtf(red[0]/(float)DM + EPSF);
    bool mk = masks[row]!=0;
    float xv[3]; float sx=0.f;
    #pragma unroll
    for (int j=0;j<3;j++){
        int e=t+j*256;
        float vv = val[j]*r2*gp[e];
        if (mk) vv = memb[st*DM+e];
        xv[j] = vv + cn3[j];
        x[(size_t)row*DM+e] = xv[j];
        sx += xv[j]*xv[j];
    }
    __syncthreads();
    red[t]=sx; __syncthreads();
    for (int s=128;s>0;s>>=1){ if(t<s) red[t]+=red[t+s]; __syncthreads(); }
    if (t==0) rs0[row] = red[0];
    const size_t mb = (size_t)(row>>7)*12;
    const int rr = (row&127)<<6;
    #pragma unroll
    for (int j=0;j<3;j++){
        const int c = t + j*256;
        xt16[((mb + (c>>6))<<13) + rr + (c&63)] = f2bu(xv[j]);
    }
}

// ------------------------------------------------- silu on fused gate-up tiled buffer
__global__ void silu_gu(u16* __restrict__ gu, int nu)
{
    int i = blockIdx.x*blockDim.x + threadIdx.x;
    const int stride = gridDim.x*blockDim.x;
    for (; i<nu; i+=stride){
        const int mt = i / (48*1024);
        const int r  = i - mt*48*1024;
        const size_t gi = (size_t)(mt*96)*1024 + r;
        const size_t ui = gi + 48*1024;
        uint4 gv = ((const uint4*)gu)[gi];
        uint4 uv = ((const uint4*)gu)[ui];
        u32 go[4]; const u32* gp=(const u32*)&gv; const u32* up=(const u32*)&uv;
        #pragma unroll
        for (int k=0;k<4;k++){
            float g0 = __uint_as_float(gp[k]<<16), g1 = __uint_as_float(gp[k]&0xffff0000u);
            float u0 = __uint_as_float(up[k]<<16), u1 = __uint_as_float(up[k]&0xffff0000u);
            float s0 = g0/(1.f+__expf(-g0))*u0;
            float s1 = g1/(1.f+__expf(-g1))*u1;
            go[k] = pk2(s0, s1);
        }
        ((uint4*)gu)[gi] = make_uint4(go[0],go[1],go[2],go[3]);
    }
}

// ------------------------------------------------- final rms + 3 scalar heads; h -> tiled bf16
__global__ __launch_bounds__(256) void decode2(
    const float* __restrict__ x, const float* __restrict__ gout,
    const float* __restrict__ Wn, const float* __restrict__ bn,
    const float* __restrict__ Wd, const float* __restrict__ bd,
    const float* __restrict__ Wb, const float* __restrict__ bb,
    float* __restrict__ out, u16* __restrict__ h16)
{
    const int row = blockIdx.x;
    const int t = threadIdx.x;
    __shared__ float h[DM];
    __shared__ float red[256];
    const float* xr = x + (size_t)row*DM;
    float v0=xr[t], v1=xr[t+256], v2=xr[t+512];
    red[t]=v0*v0+v1*v1+v2*v2; __syncthreads();
    for (int s=128;s>0;s>>=1){ if(t<s) red[t]+=red[t+s]; __syncthreads(); }
    float r = rsqrtf(red[0]/(float)DM + EPSF);
    float h0 = v0*r*gout[t], h1 = v1*r*gout[t+256], h2 = v2*r*gout[t+512];
    h[t]=h0; h[t+256]=h1; h[t+512]=h2;
    const size_t mb = (size_t)(row>>7)*12;
    const int rr = (row&127)<<6;
    #pragma unroll
    for (int j=0;j<3;j++){
        const int c = t + j*256;
        const float v = (j==0?h0:(j==1?h1:h2));
        h16[((mb + (c>>6))<<13) + rr + (c&63)] = f2bu(v);
    }
    __syncthreads();

    float pn=0.f,pd=0.f,pb=0.f;
    for (int k=t;k<DM;k+=256){ float hv=h[k]; pn+=hv*Wn[k]; pd+=hv*Wd[k]; pb+=hv*Wb[k]; }
    red[t]=pn; __syncthreads();
    for (int s=128;s>0;s>>=1){ if(t<s) red[t]+=red[t+s]; __syncthreads(); }
    float tn=red[0]; __syncthreads();
    red[t]=pd; __syncthreads();
    for (int s=128;s>0;s>>=1){ if(t<s) red[t]+=red[t+s]; __syncthreads(); }
    float td=red[0]; __syncthreads();
    red[t]=pb; __syncthreads();
    for (int s=128;s>0;s>>=1){ if(t<s) red[t]+=red[t+s]; __syncthreads(); }
    float tb=red[0];
    if (t==0){
        out[row]          = tn + bn[0];
        out[NROW + row]   = td + bd[0];
        out[2*NROW + row] = tb + bb[0];
    }
}

// ---------------------------------------------------------------- launcher
extern "C" void kernel_launch(void* const* d_in, const int* in_sizes, int n_in,
                              void* d_out, int out_size, void* d_ws, size_t ws_size,
                              hipStream_t stream)
{
    const float* numv   = (const float*)d_in[0];
    const float* dtval  = (const float*)d_in[1];
    const float* boolv  = (const float*)d_in[2];
    const float* textv  = (const float*)d_in[3];
    const float* cnamev = (const float*)d_in[4];
    const float* Wcn=(const float*)d_in[5];  const float* bcn=(const float*)d_in[6];
    const float* Wnum=(const float*)d_in[7]; const float* bnum=(const float*)d_in[8];
    const float* Wtext=(const float*)d_in[9];const float* btext=(const float*)d_in[10];
    const float* Wdt=(const float*)d_in[11]; const float* bdt=(const float*)d_in[12];
    const float* Wbool=(const float*)d_in[13];const float* bbool=(const float*)d_in[14];
    const float* gcn=(const float*)d_in[15]; const float* gnum=(const float*)d_in[16];
    const float* gtext=(const float*)d_in[17];const float* gdt=(const float*)d_in[18];
    const float* gbool=(const float*)d_in[19];
    const float* memb=(const float*)d_in[20];
    const float* norms_all=(const float*)d_in[21];
    const float* attw_all=(const float*)d_in[22];
    const float* up_all=(const float*)d_in[23];
    const float* gate_all=(const float*)d_in[24];
    const float* down_all=(const float*)d_in[25];
    const float* gout=(const float*)d_in[26];
    const float* Wdn=(const float*)d_in[27]; const float* bdn=(const float*)d_in[28];
    const float* Wdd=(const float*)d_in[29]; const float* bdd=(const float*)d_in[30];
    const float* Wdb=(const float*)d_in[31]; const float* bdb=(const float*)d_in[32];
    const float* Wdtx=(const float*)d_in[33];const float* bdtx=(const float*)d_in[34];
    const int* node=(const int*)d_in[35];
    const int* tbl =(const int*)d_in[36];
    const int* colx=(const int*)d_in[37];
    const int* f2p =(const int*)d_in[38];
    const int* styp=(const int*)d_in[39];

    const size_t SA = (size_t)768*768;
    const size_t SG = (size_t)768*3072;
    const size_t SC = (size_t)384*768;
    const size_t NX = (size_t)NROW*DM;

    u8* base = (u8*)d_ws;
    float* x  = (float*)base;
    u16* xt16 = (u16*)(base + 6291456);
    u16* ob16 = (u16*)(base + 9437184);
    u16* qk16 = (u16*)(base + 12582912);
    u16* vt16 = (u16*)(base + 18874368);
    u16* gu16 = (u16*)(base + 22020096);
    u16* wA   = (u16*)(base + 47185920);
    u16* wGU  = wA + 64*SA;
    u16* wD   = wGU + 8*SG;
    u16* wCN  = wD + 4*SG;
    u16* wTX  = wCN + SC;
    u16* wDX  = wTX + SC;
    u8* nmask = (u8*)(wDX + SC);
    u8* npad  = nmask + NROW;
    u32* pmeta = (u32*)(npad + NROW + 64);
    float* rsbuf = (float*)(pmeta + NROW);     // 21 slots x 2048
    u8* m4 = (u8*)(rsbuf + 21*2048);           // 2 MB

    // encode-phase aliases
    u16* cnT16   = qk16;
    u16* textT16 = vt16;
    float* cnbuf   = (float*)gu16;
    float* textbuf = cnbuf + NX;

    float* out = (float*)d_out;

    zero_f<<<(21*2048)/256,256,0,stream>>>(rsbuf, 21*2048);
    norm_bool_kernel<<<1,256,0,stream>>>(d_in[40], nmask, NROW);
    norm_bool_kernel<<<1,256,0,stream>>>(d_in[41], npad,  NROW);
    pack_meta<<<NROW/256,256,0,stream>>>(node, colx, tbl, npad, pmeta, NROW);
    mask4_kernel<<<dim3(64,2),256,0,stream>>>(pmeta, f2p, m4);

    // weight prep (tiled bf16; gamma folded)
    transpose_cvt2<<<dim3(24,12,64),256,0,stream>>>(attw_all, wA, 768, 768, SA, norms_all, 1);
    transpose_cvt2<<<dim3(96,12,4),256,0,stream>>>(gate_all, wGU,      768, 3072, 2*SG, norms_all + 4*768, 2);
    transpose_cvt2<<<dim3(96,12,4),256,0,stream>>>(up_all,   wGU + SG, 768, 3072, 2*SG, norms_all + 4*768, 2);
    transpose_cvt2<<<dim3(24,48,4),256,0,stream>>>(down_all, wD, 3072, 768, SG, nullptr, 0);
    transpose_cvt2<<<dim3(24,6,1),256,0,stream>>>(Wcn,   wCN, 384, 768, 0, nullptr, 0);
    transpose_cvt2<<<dim3(24,6,1),256,0,stream>>>(Wtext, wTX, 384, 768, 0, nullptr, 0);
    transpose_cvt2<<<dim3(12,12,1),256,0,stream>>>(Wdtx, wDX, 768, 384, 0, nullptr, 0);

    // encode
    cvt_tiled<<<384,256,0,stream>>>(cnamev, cnT16, 384);
    cvt_tiled<<<384,256,0,stream>>>(textv,  textT16, 384);
    gemm_t64<<<dim3(12,32),256,0,stream>>>(cnT16,   wCN, cnbuf,   768, 384, 6, 2, bcn,   nullptr, nullptr);
    gemm_t64<<<dim3(12,32),256,0,stream>>>(textT16, wTX, textbuf, 768, 384, 6, 2, btext, nullptr, nullptr);
    fuse_encode<<<NROW,256,0,stream>>>(cnbuf, textbuf, numv, dtval, boolv,
        Wnum,bnum,Wdt,bdt,Wbool,bbool, gcn,gnum,gtext,gdt,gbool,
        memb, styp, nmask, x, xt16, rsbuf);

    const dim3 ga(SS/64, BB*NH);
    for (int l=0; l<NL; l++){
        for (int a=0; a<4; a++){
            const int slot = l*5 + a;
            const u16* wqkv = wA + (size_t)((l*4+a)*4)*SA;
            gemm_t<<<dim3(36,16),256,0,stream>>>(xt16, wqkv, nullptr, 2304, 768, 12, 4, nullptr,
                nullptr, qk16, vt16, rsbuf + (size_t)slot*2048, nullptr);
            attn_mfma2<<<ga,256,0,stream>>>(qk16, vt16, m4, a, ob16);
            gemm_t64<<<dim3(12,32),256,0,stream>>>(ob16, wqkv + 3*SA, x, 768, 768, 12, 1, nullptr,
                xt16, rsbuf + (size_t)(slot+1)*2048);
        }
        gemm_t<<<dim3(96,16),256,0,stream>>>(xt16, wGU + (size_t)l*2*SG, nullptr, 6144, 768, 12, 8, nullptr,
            gu16, nullptr, nullptr, rsbuf + (size_t)(l*5+4)*2048, nullptr);
        silu_gu<<<1024,256,0,stream>>>(gu16, 16*48*1024);
        gemm_t64<<<dim3(12,32),256,0,stream>>>(gu16, wD + (size_t)l*SG, x, 768, 3072, 96, 1, nullptr,
            xt16, rsbuf + (size_t)((l+1)*5)*2048);
    }

    decode2<<<NROW,256,0,stream>>>(x, gout, Wdn,bdn, Wdd,bdd, Wdb,bdb, out, xt16);
    gemm_t64<<<dim3(6,32),256,0,stream>>>(xt16, wDX, out + 3*NROW, 384, 768, 12, 2, bdtx,
        nullptr, nullptr);
}

// Round 11
// 1448.746 us; speedup vs baseline: 7.1045x; 1.1537x over previous
//
#include <hip/hip_runtime.h>
#include <hip/hip_bf16.h>
#include <cmath>
#include <stdint.h>

// Round 11: max-free streaming softmax in attention (scores provably bounded; exp clamped at 60),
// single end-of-loop row reduction, setprio around attn MFMA clusters. Rest identical to r10.

#define BB 2
#define SS 1024
#define DT 384
#define DM 768
#define NH 12
#define DH 64
#define DFF 3072
#define NL 4
#define NROW (BB*SS)
#define EPSF 1e-6f
#define NEGF (-1e9f)

typedef unsigned short u16;
typedef unsigned char u8;
typedef unsigned int u32;
typedef __attribute__((ext_vector_type(8))) short s16x8;
typedef __attribute__((ext_vector_type(4))) float f32x4;

__device__ __forceinline__ u16 f2bu(float f){
    u32 x = __float_as_uint(f);
    u32 r = (x + 0x7fffu + ((x>>16)&1u)) >> 16;   // RNE
    return (u16)r;
}
__device__ __forceinline__ u32 pk2(float lo, float hi){
    return (u32)f2bu(lo) | ((u32)f2bu(hi)<<16);
}
__device__ __forceinline__ int swz(int row, int c){
    return (row<<6) + (((((c>>3) ^ row) & 7))<<3) + (c&7);
}
__device__ __forceinline__ float rsum16(float v){
    v += __shfl_xor(v,1); v += __shfl_xor(v,2);
    v += __shfl_xor(v,4); v += __shfl_xor(v,8);
    return v;
}
#define SBAR() __builtin_amdgcn_sched_barrier(0)
#define GLDS(src,dst) __builtin_amdgcn_global_load_lds((const __attribute__((address_space(1))) u32*)(src), (__attribute__((address_space(3))) u32*)(dst), 16, 0, 0)
#define GLDS4(src,dst) __builtin_amdgcn_global_load_lds((const __attribute__((address_space(1))) u32*)(src), (__attribute__((address_space(3))) u32*)(dst), 4, 0, 0)

// ------------------------------------------------- zero helper
__global__ void zero_f(float* __restrict__ p, int n){
    int i = blockIdx.x*256 + threadIdx.x;
    if (i<n) p[i]=0.f;
}

// ------------------------------------------------- bool-buffer normalizer
__global__ void norm_bool_kernel(const void* __restrict__ src, u8* __restrict__ dst, int n)
{
    __shared__ int fl[4];
    if (threadIdx.x<4) fl[threadIdx.x]=0;
    __syncthreads();
    const u32* wsrc = (const u32*)src;
    const int nw = n/4;
    int any=0, nb=0, hi=0, lo=0;
    for (int i=threadIdx.x;i<nw;i+=blockDim.x){
        u32 v=wsrc[i];
        if (!v) continue;
        any=1;
        #pragma unroll
        for (int b=0;b<4;b++){
            u32 by=(v>>(8*b))&0xffu;
            if (by>1u) nb=1;
            if (by==1u && b!=0) hi=1;
        }
        if ((v&0xffffu)==0x3f80u) lo=1;
    }
    if (any) atomicOr(&fl[0],1);
    if (nb)  atomicOr(&fl[1],1);
    if (hi)  atomicOr(&fl[2],1);
    if (lo)  atomicOr(&fl[3],1);
    __syncthreads();
    int c;
    if (!fl[0]) c=0;
    else if (!fl[1]) c = fl[2] ? 2 : 1;
    else if (fl[3]) c = 3;
    else c = 1;
    for (int i=threadIdx.x;i<n;i+=blockDim.x){
        u8 v;
        if (c==0)      v=0;
        else if (c==1) v = (((const u32*)src)[i]!=0u);
        else if (c==2) v = (((const u8*)src)[i]!=0u);
        else           v = (((const u16*)src)[i]!=0u);
        dst[i]=v;
    }
}

// ------------------------------------------------- pack per-token metadata
__global__ void pack_meta(const int* __restrict__ node, const int* __restrict__ colx,
                          const int* __restrict__ tbl, const u8* __restrict__ pad,
                          u32* __restrict__ pm, int n)
{
    int i = blockIdx.x*256 + threadIdx.x;
    if (i<n)
        pm[i] = (u32)(node[i]&0xff) | ((u32)(colx[i]&0xff)<<8) | ((u32)(tbl[i]&0xff)<<16) | ((u32)(pad[i]&1)<<24);
}

// ------------------------------------------------- mask table: m4[b][k][q] bit t = mask_t(q,k)
__global__ __launch_bounds__(256) void mask4_kernel(const u32* __restrict__ pm, const int* __restrict__ f2p,
                                                    u8* __restrict__ m4)
{
    const int b = blockIdx.y, kg = blockIdx.x;
    const int t = threadIdx.x;
    __shared__ u32 qm[1024];
    __shared__ int qf[1024*5];
    for (int i=t;i<1024;i+=256) qm[i] = pm[b*SS+i];
    for (int i=t;i<5*1024;i+=256) qf[i] = f2p[b*SS*5 + i];
    __syncthreads();
    const int q0 = t*4;
    u32 qmv[4]; int qn[4]; int qfv[4][5];
    #pragma unroll
    for (int j=0;j<4;j++){
        qmv[j]=qm[q0+j]; qn[j]=(int)(qmv[j]&0xffu);
        #pragma unroll
        for (int f=0;f<5;f++) qfv[j][f]=qf[(q0+j)*5+f];
    }
    for (int kk=0;kk<16;kk++){
        const int k = kg*16+kk;
        const u32 km = qm[k];
        const int kn = (int)(km&0xffu);
        u32 outw=0;
        #pragma unroll
        for (int j=0;j<4;j++){
            const u32 qmw = qmv[j];
            const bool pv = (((qmw|km)>>24)&1u)==0u;
            u32 by=0;
            if ((((qmw^km)&0x00ffff00u)==0u) && pv) by|=1;
            if ((((qmw^km)&0xffu)==0u) && pv) by|=2;
            bool nei = (qfv[j][0]==kn)||(qfv[j][1]==kn)||(qfv[j][2]==kn)||(qfv[j][3]==kn)||(qfv[j][4]==kn)
                       ||(qn[j]==kn);
            if (nei && pv) by|=4;
            if (pv) by|=8;
            if ((q0+j)==k) by=15;
            outw |= by<<(8*j);
        }
        ((u32*)(m4 + ((size_t)b<<20) + ((size_t)k<<10)))[t] = outw;
    }
}

// ------------------------------------------------- weight f32 [K][N] -> tiled bf16 (+gamma fold)
__global__ __launch_bounds__(256) void transpose_cvt2(const float* __restrict__ src, u16* __restrict__ dst,
                                                      int K, int N, size_t dz,
                                                      const float* __restrict__ gbase, int gmode)
{
    const int z = blockIdx.z;
    src += (size_t)z*K*N;
    dst += (size_t)z*dz;
    const float* g = nullptr;
    if (gmode==1){ int m = z&3; if (m<3) g = gbase + (size_t)((z>>4)*5 + ((z>>2)&3))*768; }
    else if (gmode==2){ g = gbase + (size_t)z*5*768; }
    const int n0 = blockIdx.x*32, k0 = blockIdx.y*64;
    __shared__ float t[64][33];
    const int tid = threadIdx.x;
    const int kr = tid>>3, n4 = (tid&7)*4;
    #pragma unroll
    for (int p=0;p<2;p++){
        const int k = p*32 + kr;
        float gk = g ? g[k0+k] : 1.f;
        float4 v = *(const float4*)(src + (size_t)(k0+k)*N + n0 + n4);
        t[k][n4]=v.x*gk; t[k][n4+1]=v.y*gk; t[k][n4+2]=v.z*gk; t[k][n4+3]=v.w*gk;
    }
    __syncthreads();
    const int n = tid>>3, ks = (tid&7)*8;
    const int ng = n0 + n;
    uint4 o;
    u32* op = (u32*)&o;
    #pragma unroll
    for (int i=0;i<4;i++)
        op[i] = pk2(t[ks+2*i][n], t[ks+2*i+1][n]);
    *(uint4*)&dst[(((size_t)(ng>>7)*(K>>6) + (k0>>6))<<13) + ((ng&127)<<6) + ks] = o;
}

// ------------------------------------------------- activation f32 [M][K] -> tiled bf16
__global__ __launch_bounds__(256) void cvt_tiled(const float* __restrict__ src, u16* __restrict__ dst, int K)
{
    const int gid = blockIdx.x*256 + threadIdx.x;
    const int base = gid*8;
    const int row = base / K, col = base - row*K;
    float4 a = *(const float4*)(src + base);
    float4 b = *(const float4*)(src + base + 4);
    uint4 o;
    o.x = pk2(a.x,a.y); o.y = pk2(a.z,a.w);
    o.z = pk2(b.x,b.y); o.w = pk2(b.z,b.w);
    *(uint4*)&dst[(((size_t)(row>>7)*(K>>6) + (col>>6))<<13) + ((row&127)<<6) + (col&63)] = o;
}

// ------------------------------------------------- BM=128 GEMM (qkv / gate-up)
__device__ __forceinline__ void stage3(const u16* aT, const u16* bT, int cb, int brow,
                                       u16* la, u16* lb, int w, int l)
{
    #pragma unroll
    for (int p=0;p<2;p++){
        const int q = p*256 + w*64 + l;
        const int row = q>>2, u = q&3;
        const int so = row*64 + cb + (((u ^ ((row>>1)&3))&3)<<3);
        GLDS(aT+so, la + p*2048 + w*512);
    }
    {
        const int q = w*64 + l;
        const int row = q>>2, u = q&3;
        const int so = (brow+row)*64 + cb + (((u ^ ((row>>1)&3))&3)<<3);
        GLDS(bT+so, lb + w*512);
    }
}

__global__ __launch_bounds__(256,4) void gemm_t(
    const u16* __restrict__ At, const u16* __restrict__ Bt, float* __restrict__ C,
    int N, int K, int AMS, int flags, const float* __restrict__ bias,
    u16* __restrict__ o16, u16* __restrict__ qk16, u16* __restrict__ vt16,
    const float* __restrict__ rs_in, float* __restrict__ rs_out)
{
    __shared__ u16 lds[3][6144];
    const int tid = threadIdx.x;
    const int lane = tid & 63, w = tid >> 6;
    const int cg = lane >> 4, cl = lane & 15;
    const int NT = K >> 5;
    const int n0 = blockIdx.x*64;
    const int brow = n0 & 64;
    const size_t bNb = (size_t)(n0>>7)*(K>>6);

    const u16* aB = At + ((size_t)blockIdx.y * AMS << 13);
    const u16* bB = Bt + (bNb << 13);

    f32x4 acc[2][4];
    #pragma unroll
    for (int i=0;i<2;i++)
        #pragma unroll
        for (int j=0;j<4;j++) acc[i][j] = (f32x4){0.f,0.f,0.f,0.f};

    stage3(aB, bB, 0,  brow, &lds[0][0], &lds[0][4096], w, lane);
    stage3(aB, bB, 32, brow, &lds[1][0], &lds[1][4096], w, lane);

    for (int kt=0; kt<NT; kt++){
        const int buf = kt % 3;
        if (kt+2 < NT){
            const int k2 = kt+2;
            stage3(aB + ((size_t)(k2>>1)<<13), bB + ((size_t)(k2>>1)<<13),
                   (k2&1)<<5, brow, &lds[k2%3][0], &lds[k2%3][4096], w, lane);
            asm volatile("s_waitcnt vmcnt(6)" ::: "memory");
        } else if (kt+1 < NT){
            asm volatile("s_waitcnt vmcnt(3)" ::: "memory");
        } else {
            asm volatile("s_waitcnt vmcnt(0)" ::: "memory");
        }
        SBAR(); __builtin_amdgcn_s_barrier(); SBAR();
        s16x8 af[2], bf[4];
        #pragma unroll
        for (int mt=0;mt<2;mt++){
            const int ra = w*32 + mt*16 + cl;
            af[mt] = *(const s16x8*)&lds[buf][ra*32 + (((cg ^ ((ra>>1)&3))&3)<<3)];
        }
        #pragma unroll
        for (int nt=0;nt<4;nt++){
            const int rb = nt*16 + cl;
            bf[nt] = *(const s16x8*)&lds[buf][4096 + rb*32 + (((cg ^ ((rb>>1)&3))&3)<<3)];
        }
        #pragma unroll
        for (int mt=0;mt<2;mt++)
            #pragma unroll
            for (int nt=0;nt<4;nt++)
                acc[mt][nt] = __builtin_amdgcn_mfma_f32_16x16x32_bf16(af[mt], bf[nt], acc[mt][nt], 0,0,0);
        SBAR(); __builtin_amdgcn_s_barrier(); SBAR();
    }

    const int m0 = blockIdx.y*128;
    if (flags & 4){
        #pragma unroll
        for (int mt=0;mt<2;mt++){
            const int grow0 = m0 + w*32 + mt*16 + cg*4;
            float rr[4];
            #pragma unroll
            for (int j=0;j<4;j++) rr[j] = rsqrtf(rs_in[grow0+j]*(1.f/768.f) + EPSF);
            #pragma unroll
            for (int nt=0;nt<4;nt++){
                const int col = n0 + nt*16 + cl;
                if (col < 1536){
                    #pragma unroll
                    for (int j=0;j<4;j++)
                        qk16[(size_t)(grow0+j)*1536 + col] = f2bu(acc[mt][nt][j]*rr[j]);
                } else {
                    const int b = grow0>>10, s0 = grow0&1023;
                    const int dhg = col - 1536;
                    uint2 o;
                    o.x = pk2(acc[mt][nt][0]*rr[0], acc[mt][nt][1]*rr[1]);
                    o.y = pk2(acc[mt][nt][2]*rr[2], acc[mt][nt][3]*rr[3]);
                    *(uint2*)(vt16 + ((size_t)(b*768 + dhg)<<10) + s0) = o;
                }
            }
        }
    } else {   // flags & 8: bf16-tiled out with rs_in scale
        const int NC = N>>6;
        #pragma unroll
        for (int mt=0;mt<2;mt++){
            const int grow0 = m0 + w*32 + mt*16 + cg*4;
            float rr[4];
            #pragma unroll
            for (int j=0;j<4;j++) rr[j] = rs_in ? rsqrtf(rs_in[grow0+j]*(1.f/768.f) + EPSF) : 1.f;
            #pragma unroll
            for (int nt=0;nt<4;nt++){
                const int col = n0 + nt*16 + cl;
                const size_t tb = (((size_t)(grow0>>7)*NC + (col>>6))<<13) + (col&63);
                #pragma unroll
                for (int j=0;j<4;j++)
                    o16[tb + (((grow0+j)&127)<<6)] = f2bu(acc[mt][nt][j]*rr[j]);
            }
        }
    }
}

// ------------------------------------------------- BM=64 GEMM (narrow N)
__device__ __forceinline__ void stage64(const u16* aT, int arow, const u16* bT, int brow, int cb,
                                        u16* la, u16* lb, int w, int l)
{
    const int q = w*64 + l;
    const int row = q>>2, u = q&3;
    const int sw = (((u ^ ((row>>1)&3))&3)<<3);
    GLDS(aT + (arow+row)*64 + cb + sw, la + w*512);
    GLDS(bT + (brow+row)*64 + cb + sw, lb + w*512);
}

__global__ __launch_bounds__(256,6) void gemm_t64(
    const u16* __restrict__ At, const u16* __restrict__ Bt, float* __restrict__ C,
    int N, int K, int AMS, int flags, const float* __restrict__ bias,
    u16* __restrict__ o16, float* __restrict__ rs_out)
{
    __shared__ u16 lds[3][4096];
    const int tid = threadIdx.x;
    const int lane = tid & 63, w = tid >> 6;
    const int cg = lane >> 4, cl = lane & 15;
    const int NT = K >> 5;
    const int n0 = blockIdx.x*64;
    const int m0 = blockIdx.y*64;
    const int brow = n0 & 64, arow = m0 & 64;

    const u16* aB = At + ((size_t)(m0>>7) * AMS << 13);
    const u16* bB = Bt + ((size_t)(n0>>7) * (K>>6) << 13);

    f32x4 acc[4];
    #pragma unroll
    for (int j=0;j<4;j++) acc[j] = (f32x4){0.f,0.f,0.f,0.f};

    stage64(aB, arow, bB, brow, 0,  &lds[0][0], &lds[0][2048], w, lane);
    stage64(aB, arow, bB, brow, 32, &lds[1][0], &lds[1][2048], w, lane);

    for (int kt=0; kt<NT; kt++){
        const int buf = kt % 3;
        if (kt+2 < NT){
            const int k2 = kt+2;
            stage64(aB + ((size_t)(k2>>1)<<13), arow, bB + ((size_t)(k2>>1)<<13), brow,
                    (k2&1)<<5, &lds[k2%3][0], &lds[k2%3][2048], w, lane);
            asm volatile("s_waitcnt vmcnt(4)" ::: "memory");
        } else if (kt+1 < NT){
            asm volatile("s_waitcnt vmcnt(2)" ::: "memory");
        } else {
            asm volatile("s_waitcnt vmcnt(0)" ::: "memory");
        }
        SBAR(); __builtin_amdgcn_s_barrier(); SBAR();
        const int ra = w*16 + cl;
        s16x8 af = *(const s16x8*)&lds[buf][ra*32 + (((cg ^ ((ra>>1)&3))&3)<<3)];
        s16x8 bf[4];
        #pragma unroll
        for (int nt=0;nt<4;nt++){
            const int rb = nt*16 + cl;
            bf[nt] = *(const s16x8*)&lds[buf][2048 + rb*32 + (((cg ^ ((rb>>1)&3))&3)<<3)];
        }
        #pragma unroll
        for (int nt=0;nt<4;nt++)
            acc[nt] = __builtin_amdgcn_mfma_f32_16x16x32_bf16(af, bf[nt], acc[nt], 0,0,0);
        SBAR(); __builtin_amdgcn_s_barrier(); SBAR();
    }

    const int grow0 = m0 + w*16 + cg*4;
    const bool do_acc = (flags&1), do_bias = (flags&2);
    float tmp[4][4];
    #pragma unroll
    for (int nt=0;nt<4;nt++){
        const int col = n0 + nt*16 + cl;
        float bv = do_bias ? bias[col] : 0.f;
        #pragma unroll
        for (int j=0;j<4;j++){
            float v = acc[nt][j] + bv;
            float* cp = C + (size_t)(grow0+j)*N + col;
            if (do_acc) v += *cp;
            *cp = v;
            tmp[nt][j] = v;
        }
    }
    if (o16){
        #pragma unroll
        for (int nt=0;nt<4;nt++){
            const int col = n0 + nt*16 + cl;
            const size_t tb = (((size_t)(grow0>>7)*12 + (col>>6))<<13) + (col&63);
            #pragma unroll
            for (int j=0;j<4;j++)
                o16[tb + (((grow0+j)&127)<<6)] = f2bu(tmp[nt][j]);
        }
    }
    if (rs_out){
        #pragma unroll
        for (int j=0;j<4;j++){
            float s = tmp[0][j]*tmp[0][j] + tmp[1][j]*tmp[1][j]
                    + tmp[2][j]*tmp[2][j] + tmp[3][j]*tmp[3][j];
            s = rsum16(s);
            if (cl==0) atomicAdd(rs_out + grow0 + j, s);
        }
    }
}

// ------------------------------------------------- MFMA flash attention (max-free softmax)
__global__ __launch_bounds__(256,3) void attn_mfma3(
    const u16* __restrict__ qk16, const u16* __restrict__ vt16,
    const u8* __restrict__ m4, int mt,
    u16* __restrict__ ob16)
{
    const int bh = blockIdx.y;
    const int b = bh / NH, h = bh % NH;
    const int q0 = blockIdx.x * 64;
    const int tid = threadIdx.x;
    const int w = tid>>6, lane = tid&63, cg = lane>>4, cl = lane&15;
    const int srow = lane>>3;
    const int sseg = (lane&7) ^ srow;
    const int mk = lane>>4, mq = lane&15;

    __shared__ u16 Qs[4096], Ks[2][4096], Vt[2][4096], Ps[4096];
    __shared__ u32 Ms[2][1024];

    const u16* qbase = qk16 + (size_t)(b*SS+q0)*1536 + h*64;
    const u16* kbase = qk16 + (size_t)(b*SS)*1536 + 768 + h*64;
    const u16* vbase = vt16 + ((size_t)(b*768 + h*64)<<10);
    const u8*  mbase = m4 + ((size_t)b<<20) + q0;

    #pragma unroll
    for (int p=0;p<2;p++){
        const int row = p*32 + w*8 + srow;
        GLDS(qbase + (size_t)row*1536 + sseg*8, Qs + p*2048 + w*512);
    }
    #pragma unroll
    for (int p=0;p<2;p++){
        const int row = p*32 + w*8 + srow;
        GLDS(kbase + (size_t)row*1536 + sseg*8, Ks[0] + p*2048 + w*512);
        GLDS(vbase + ((size_t)row<<10) + sseg*8, Vt[0] + p*2048 + w*512);
    }
    #pragma unroll
    for (int i=0;i<4;i++){
        const int key = w*16 + i*4 + mk;
        GLDS4(mbase + ((size_t)key<<10) + mq*4, (u8*)Ms[0] + w*1024 + i*256);
    }

    f32x4 o[4];
    #pragma unroll
    for (int nt=0;nt<4;nt++) o[nt] = (f32x4){0.f,0.f,0.f,0.f};
    float lsum[4] = {0.f,0.f,0.f,0.f};

    for (int kc=0;kc<16;kc++){
        const int buf = kc & 1;
        if (kc < 15){
            const int kn0 = kc*64 + 64;
            #pragma unroll
            for (int p=0;p<2;p++){
                const int row = p*32 + w*8 + srow;
                GLDS(kbase + (size_t)(kn0+row)*1536 + sseg*8, Ks[buf^1] + p*2048 + w*512);
                GLDS(vbase + ((size_t)row<<10) + kn0 + sseg*8, Vt[buf^1] + p*2048 + w*512);
            }
            #pragma unroll
            for (int i=0;i<4;i++){
                const int key = kn0 + w*16 + i*4 + mk;
                GLDS4(mbase + ((size_t)key<<10) + mq*4, (u8*)Ms[buf^1] + w*1024 + i*256);
            }
            asm volatile("s_waitcnt vmcnt(8)" ::: "memory");
        } else {
            asm volatile("s_waitcnt vmcnt(0)" ::: "memory");
        }
        SBAR(); __builtin_amdgcn_s_barrier(); SBAR();

        // QK^T
        f32x4 sc[4];
        #pragma unroll
        for (int nt=0;nt<4;nt++) sc[nt] = (f32x4){0.f,0.f,0.f,0.f};
        __builtin_amdgcn_s_setprio(1);
        #pragma unroll
        for (int ks=0;ks<2;ks++){
            s16x8 qa = *(const s16x8*)&Qs[swz(w*16+cl, ks*32+cg*8)];
            #pragma unroll
            for (int nt=0;nt<4;nt++){
                s16x8 kb = *(const s16x8*)&Ks[buf][swz(nt*16+cl, ks*32+cg*8)];
                sc[nt] = __builtin_amdgcn_mfma_f32_16x16x32_bf16(qa, kb, sc[nt], 0,0,0);
            }
        }
        __builtin_amdgcn_s_setprio(0);

        // mask + exp (no running max: scores bounded, clamp at 60 for overflow safety)
        float pP[4][4];
        #pragma unroll
        for (int nt=0;nt<4;nt++){
            const u32 w4 = Ms[buf][(nt*16+cl)*16 + w*4 + cg];
            #pragma unroll
            for (int j=0;j<4;j++){
                float sv = fminf(sc[nt][j]*0.125f, 60.f);
                float pe = __expf(sv);
                pe = ((w4 >> (8*j + mt)) & 1u) ? pe : 0.f;
                pP[nt][j] = pe;
                lsum[j] += pe;
            }
        }

        // P -> LDS (wave-private rows; same-wave read)
        #pragma unroll
        for (int nt=0;nt<4;nt++)
            #pragma unroll
            for (int j=0;j<4;j++)
                Ps[swz(w*16+cg*4+j, nt*16+cl)] = f2bu(pP[nt][j]);

        // PV
        __builtin_amdgcn_s_setprio(1);
        #pragma unroll
        for (int ks=0;ks<2;ks++){
            s16x8 pa = *(const s16x8*)&Ps[swz(w*16+cl, ks*32+cg*8)];
            #pragma unroll
            for (int nt=0;nt<4;nt++){
                s16x8 vb = *(const s16x8*)&Vt[buf][swz(nt*16+cl, ks*32+cg*8)];
                o[nt] = __builtin_amdgcn_mfma_f32_16x16x32_bf16(pa, vb, o[nt], 0,0,0);
            }
        }
        __builtin_amdgcn_s_setprio(0);
        SBAR(); __builtin_amdgcn_s_barrier(); SBAR();
    }

    #pragma unroll
    for (int j=0;j<4;j++){
        const float inv = 1.f/rsum16(lsum[j]);
        const int row = b*SS + q0 + w*16 + cg*4 + j;
        const size_t rb = ((size_t)(row>>7)*12 + h)*8192 + ((row&127)<<6);
        #pragma unroll
        for (int nt=0;nt<4;nt++)
            ob16[rb + nt*16 + cl] = f2bu(o[nt][j]*inv);
    }
}

// ------------------------------------------------- encode fuse
__global__ __launch_bounds__(256) void fuse_encode(
    const float* __restrict__ cnbuf, const float* __restrict__ textbuf,
    const float* __restrict__ numv, const float* __restrict__ dtv, const float* __restrict__ boolv,
    const float* __restrict__ Wnum, const float* __restrict__ bnum,
    const float* __restrict__ Wdt, const float* __restrict__ bdt,
    const float* __restrict__ Wbool, const float* __restrict__ bbool,
    const float* __restrict__ gcn, const float* __restrict__ gnum, const float* __restrict__ gtext,
    const float* __restrict__ gdt, const float* __restrict__ gbool,
    const float* __restrict__ memb, const int* __restrict__ stypes, const u8* __restrict__ masks,
    float* __restrict__ x, u16* __restrict__ xt16, float* __restrict__ rs0)
{
    const int row = blockIdx.x;
    const int t = threadIdx.x;
    __shared__ float red[256];

    float cn3[3]; float ss=0.f;
    #pragma unroll
    for (int j=0;j<3;j++){
        cn3[j] = cnbuf[(size_t)row*DM + t + j*256];
        ss += cn3[j]*cn3[j];
    }
    red[t]=ss; __syncthreads();
    for (int s=128;s>0;s>>=1){ if(t<s) red[t]+=red[t+s]; __syncthreads(); }
    {
        float r = rsqrtf(red[0]/(float)DM + EPSF);
        #pragma unroll
        for (int j=0;j<3;j++) cn3[j] *= r*gcn[t+j*256];
    }
    __syncthreads();

    const int st = stypes[row];
    float val[3]; ss=0.f;
    if (st==1){
        #pragma unroll
        for (int j=0;j<3;j++){
            val[j] = textbuf[(size_t)row*DM + t + j*256];
            ss += val[j]*val[j];
        }
    } else {
        const float* Wp = (st==0)?Wnum:((st==2)?Wdt:Wbool);
        const float* bp = (st==0)?bnum:((st==2)?bdt:bbool);
        const float* vp = (st==0)?numv:((st==2)?dtv:boolv);
        float v = vp[row];
        #pragma unroll
        for (int j=0;j<3;j++){
            int e=t+j*256;
            val[j] = v*Wp[e] + bp[e];
            ss += val[j]*val[j];
        }
    }
    red[t]=ss; __syncthreads();
    for (int s=128;s>0;s>>=1){ if(t<s) red[t]+=red[t+s]; __syncthreads(); }
    const float* gp = (st==0)?gnum:((st==1)?gtext:((st==2)?gdt:gbool));
    float r2 = rsqrtf(red[0]/(float)DM + EPSF);
    bool mk = masks[row]!=0;
    float xv[3]; float sx=0.f;
    #pragma unroll
    for (int j=0;j<3;j++){
        int e=t+j*256;
        float vv = val[j]*r2*gp[e];
        if (mk) vv = memb[st*DM+e];
        xv[j] = vv + cn3[j];
        x[(size_t)row*DM+e] = xv[j];
        sx += xv[j]*xv[j];
    }
    __syncthreads();
    red[t]=sx; __syncthreads();
    for (int s=128;s>0;s>>=1){ if(t<s) red[t]+=red[t+s]; __syncthreads(); }
    if (t==0) rs0[row] = red[0];
    const size_t mb = (size_t)(row>>7)*12;
    const int rr = (row&127)<<6;
    #pragma unroll
    for (int j=0;j<3;j++){
        const int c = t + j*256;
        xt16[((mb + (c>>6))<<13) + rr + (c&63)] = f2bu(xv[j]);
    }
}

// ------------------------------------------------- silu on fused gate-up tiled buffer
__global__ void silu_gu(u16* __restrict__ gu, int nu)
{
    int i = blockIdx.x*blockDim.x + threadIdx.x;
    const int stride = gridDim.x*blockDim.x;
    for (; i<nu; i+=stride){
        const int mt = i / (48*1024);
        const int r  = i - mt*48*1024;
        const size_t gi = (size_t)(mt*96)*1024 + r;
        const size_t ui = gi + 48*1024;
        uint4 gv = ((const uint4*)gu)[gi];
        uint4 uv = ((const uint4*)gu)[ui];
        u32 go[4]; const u32* gp=(const u32*)&gv; const u32* up=(const u32*)&uv;
        #pragma unroll
        for (int k=0;k<4;k++){
            float g0 = __uint_as_float(gp[k]<<16), g1 = __uint_as_float(gp[k]&0xffff0000u);
            float u0 = __uint_as_float(up[k]<<16), u1 = __uint_as_float(up[k]&0xffff0000u);
            float s0 = g0/(1.f+__expf(-g0))*u0;
            float s1 = g1/(1.f+__expf(-g1))*u1;
            go[k] = pk2(s0, s1);
        }
        ((uint4*)gu)[gi] = make_uint4(go[0],go[1],go[2],go[3]);
    }
}

// ------------------------------------------------- final rms + 3 scalar heads; h -> tiled bf16
__global__ __launch_bounds__(256) void decode2(
    const float* __restrict__ x, const float* __restrict__ gout,
    const float* __restrict__ Wn, const float* __restrict__ bn,
    const float* __restrict__ Wd, const float* __restrict__ bd,
    const float* __restrict__ Wb, const float* __restrict__ bb,
    float* __restrict__ out, u16* __restrict__ h16)
{
    const int row = blockIdx.x;
    const int t = threadIdx.x;
    __shared__ float h[DM];
    __shared__ float red[256];
    const float* xr = x + (size_t)row*DM;
    float v0=xr[t], v1=xr[t+256], v2=xr[t+512];
    red[t]=v0*v0+v1*v1+v2*v2; __syncthreads();
    for (int s=128;s>0;s>>=1){ if(t<s) red[t]+=red[t+s]; __syncthreads(); }
    float r = rsqrtf(red[0]/(float)DM + EPSF);
    float h0 = v0*r*gout[t], h1 = v1*r*gout[t+256], h2 = v2*r*gout[t+512];
    h[t]=h0; h[t+256]=h1; h[t+512]=h2;
    const size_t mb = (size_t)(row>>7)*12;
    const int rr = (row&127)<<6;
    #pragma unroll
    for (int j=0;j<3;j++){
        const int c = t + j*256;
        const float v = (j==0?h0:(j==1?h1:h2));
        h16[((mb + (c>>6))<<13) + rr + (c&63)] = f2bu(v);
    }
    __syncthreads();

    float pn=0.f,pd=0.f,pb=0.f;
    for (int k=t;k<DM;k+=256){ float hv=h[k]; pn+=hv*Wn[k]; pd+=hv*Wd[k]; pb+=hv*Wb[k]; }
    red[t]=pn; __syncthreads();
    for (int s=128;s>0;s>>=1){ if(t<s) red[t]+=red[t+s]; __syncthreads(); }
    float tn=red[0]; __syncthreads();
    red[t]=pd; __syncthreads();
    for (int s=128;s>0;s>>=1){ if(t<s) red[t]+=red[t+s]; __syncthreads(); }
    float td=red[0]; __syncthreads();
    red[t]=pb; __syncthreads();
    for (int s=128;s>0;s>>=1){ if(t<s) red[t]+=red[t+s]; __syncthreads(); }
    float tb=red[0];
    if (t==0){
        out[row]          = tn + bn[0];
        out[NROW + row]   = td + bd[0];
        out[2*NROW + row] = tb + bb[0];
    }
}

// ---------------------------------------------------------------- launcher
extern "C" void kernel_launch(void* const* d_in, const int* in_sizes, int n_in,
                              void* d_out, int out_size, void* d_ws, size_t ws_size,
                              hipStream_t stream)
{
    const float* numv   = (const float*)d_in[0];
    const float* dtval  = (const float*)d_in[1];
    const float* boolv  = (const float*)d_in[2];
    const float* textv  = (const float*)d_in[3];
    const float* cnamev = (const float*)d_in[4];
    const float* Wcn=(const float*)d_in[5];  const float* bcn=(const float*)d_in[6];
    const float* Wnum=(const float*)d_in[7]; const float* bnum=(const float*)d_in[8];
    const float* Wtext=(const float*)d_in[9];const float* btext=(const float*)d_in[10];
    const float* Wdt=(const float*)d_in[11]; const float* bdt=(const float*)d_in[12];
    const float* Wbool=(const float*)d_in[13];const float* bbool=(const float*)d_in[14];
    const float* gcn=(const float*)d_in[15]; const float* gnum=(const float*)d_in[16];
    const float* gtext=(const float*)d_in[17];const float* gdt=(const float*)d_in[18];
    const float* gbool=(const float*)d_in[19];
    const float* memb=(const float*)d_in[20];
    const float* norms_all=(const float*)d_in[21];
    const float* attw_all=(const float*)d_in[22];
    const float* up_all=(const float*)d_in[23];
    const float* gate_all=(const float*)d_in[24];
    const float* down_all=(const float*)d_in[25];
    const float* gout=(const float*)d_in[26];
    const float* Wdn=(const float*)d_in[27]; const float* bdn=(const float*)d_in[28];
    const float* Wdd=(const float*)d_in[29]; const float* bdd=(const float*)d_in[30];
    const float* Wdb=(const float*)d_in[31]; const float* bdb=(const float*)d_in[32];
    const float* Wdtx=(const float*)d_in[33];const float* bdtx=(const float*)d_in[34];
    const int* node=(const int*)d_in[35];
    const int* tbl =(const int*)d_in[36];
    const int* colx=(const int*)d_in[37];
    const int* f2p =(const int*)d_in[38];
    const int* styp=(const int*)d_in[39];

    const size_t SA = (size_t)768*768;
    const size_t SG = (size_t)768*3072;
    const size_t SC = (size_t)384*768;
    const size_t NX = (size_t)NROW*DM;

    u8* base = (u8*)d_ws;
    float* x  = (float*)base;
    u16* xt16 = (u16*)(base + 6291456);
    u16* ob16 = (u16*)(base + 9437184);
    u16* qk16 = (u16*)(base + 12582912);
    u16* vt16 = (u16*)(base + 18874368);
    u16* gu16 = (u16*)(base + 22020096);
    u16* wA   = (u16*)(base + 47185920);
    u16* wGU  = wA + 64*SA;
    u16* wD   = wGU + 8*SG;
    u16* wCN  = wD + 4*SG;
    u16* wTX  = wCN + SC;
    u16* wDX  = wTX + SC;
    u8* nmask = (u8*)(wDX + SC);
    u8* npad  = nmask + NROW;
    u32* pmeta = (u32*)(npad + NROW + 64);
    float* rsbuf = (float*)(pmeta + NROW);     // 21 slots x 2048
    u8* m4 = (u8*)(rsbuf + 21*2048);           // 2 MB

    // encode-phase aliases
    u16* cnT16   = qk16;
    u16* textT16 = vt16;
    float* cnbuf   = (float*)gu16;
    float* textbuf = cnbuf + NX;

    float* out = (float*)d_out;

    zero_f<<<(21*2048)/256,256,0,stream>>>(rsbuf, 21*2048);
    norm_bool_kernel<<<1,256,0,stream>>>(d_in[40], nmask, NROW);
    norm_bool_kernel<<<1,256,0,stream>>>(d_in[41], npad,  NROW);
    pack_meta<<<NROW/256,256,0,stream>>>(node, colx, tbl, npad, pmeta, NROW);
    mask4_kernel<<<dim3(64,2),256,0,stream>>>(pmeta, f2p, m4);

    // weight prep (tiled bf16; gamma folded)
    transpose_cvt2<<<dim3(24,12,64),256,0,stream>>>(attw_all, wA, 768, 768, SA, norms_all, 1);
    transpose_cvt2<<<dim3(96,12,4),256,0,stream>>>(gate_all, wGU,      768, 3072, 2*SG, norms_all + 4*768, 2);
    transpose_cvt2<<<dim3(96,12,4),256,0,stream>>>(up_all,   wGU + SG, 768, 3072, 2*SG, norms_all + 4*768, 2);
    transpose_cvt2<<<dim3(24,48,4),256,0,stream>>>(down_all, wD, 3072, 768, SG, nullptr, 0);
    transpose_cvt2<<<dim3(24,6,1),256,0,stream>>>(Wcn,   wCN, 384, 768, 0, nullptr, 0);
    transpose_cvt2<<<dim3(24,6,1),256,0,stream>>>(Wtext, wTX, 384, 768, 0, nullptr, 0);
    transpose_cvt2<<<dim3(12,12,1),256,0,stream>>>(Wdtx, wDX, 768, 384, 0, nullptr, 0);

    // encode
    cvt_tiled<<<384,256,0,stream>>>(cnamev, cnT16, 384);
    cvt_tiled<<<384,256,0,stream>>>(textv,  textT16, 384);
    gemm_t64<<<dim3(12,32),256,0,stream>>>(cnT16,   wCN, cnbuf,   768, 384, 6, 2, bcn,   nullptr, nullptr);
    gemm_t64<<<dim3(12,32),256,0,stream>>>(textT16, wTX, textbuf, 768, 384, 6, 2, btext, nullptr, nullptr);
    fuse_encode<<<NROW,256,0,stream>>>(cnbuf, textbuf, numv, dtval, boolv,
        Wnum,bnum,Wdt,bdt,Wbool,bbool, gcn,gnum,gtext,gdt,gbool,
        memb, styp, nmask, x, xt16, rsbuf);

    const dim3 ga(SS/64, BB*NH);
    for (int l=0; l<NL; l++){
        for (int a=0; a<4; a++){
            const int slot = l*5 + a;
            const u16* wqkv = wA + (size_t)((l*4+a)*4)*SA;
            gemm_t<<<dim3(36,16),256,0,stream>>>(xt16, wqkv, nullptr, 2304, 768, 12, 4, nullptr,
                nullptr, qk16, vt16, rsbuf + (size_t)slot*2048, nullptr);
            attn_mfma3<<<ga,256,0,stream>>>(qk16, vt16, m4, a, ob16);
            gemm_t64<<<dim3(12,32),256,0,stream>>>(ob16, wqkv + 3*SA, x, 768, 768, 12, 1, nullptr,
                xt16, rsbuf + (size_t)(slot+1)*2048);
        }
        gemm_t<<<dim3(96,16),256,0,stream>>>(xt16, wGU + (size_t)l*2*SG, nullptr, 6144, 768, 12, 8, nullptr,
            gu16, nullptr, nullptr, rsbuf + (size_t)(l*5+4)*2048, nullptr);
        silu_gu<<<1024,256,0,stream>>>(gu16, 16*48*1024);
        gemm_t64<<<dim3(12,32),256,0,stream>>>(gu16, wD + (size_t)l*SG, x, 768, 3072, 96, 1, nullptr,
            xt16, rsbuf + (size_t)((l+1)*5)*2048);
    }

    decode2<<<NROW,256,0,stream>>>(x, gout, Wdn,bdn, Wdd,bdd, Wdb,bdb, out, xt16);
    gemm_t64<<<dim3(6,32),256,0,stream>>>(xt16, wDX, out + 3*NROW, 384, 768, 12, 2, bdtx,
        nullptr, nullptr);
}

// Round 12
// 1448.002 us; speedup vs baseline: 7.1082x; 1.0005x over previous
//
#include <hip/hip_runtime.h>
#include <hip/hip_bf16.h>
#include <cmath>
#include <stdint.h>

// Round 12: fused gate-up-silu GEMM (one dispatch, silu in epilogue, writes down-proj operand
// directly); exp2 pre-scaled attention scores (0.125*log2e folded into Q at QKV epilogue);
// merged prep dispatches. Rest identical to r11.

#define BB 2
#define SS 1024
#define DT 384
#define DM 768
#define NH 12
#define DH 64
#define DFF 3072
#define NL 4
#define NROW (BB*SS)
#define EPSF 1e-6f
#define QSC 0.1803368801111244f   // 0.125 * log2(e)

typedef unsigned short u16;
typedef unsigned char u8;
typedef unsigned int u32;
typedef __attribute__((ext_vector_type(8))) short s16x8;
typedef __attribute__((ext_vector_type(4))) float f32x4;

__device__ __forceinline__ u16 f2bu(float f){
    u32 x = __float_as_uint(f);
    u32 r = (x + 0x7fffu + ((x>>16)&1u)) >> 16;   // RNE
    return (u16)r;
}
__device__ __forceinline__ u32 pk2(float lo, float hi){
    return (u32)f2bu(lo) | ((u32)f2bu(hi)<<16);
}
__device__ __forceinline__ int swz(int row, int c){
    return (row<<6) + (((((c>>3) ^ row) & 7))<<3) + (c&7);
}
__device__ __forceinline__ float rsum16(float v){
    v += __shfl_xor(v,1); v += __shfl_xor(v,2);
    v += __shfl_xor(v,4); v += __shfl_xor(v,8);
    return v;
}
#define SBAR() __builtin_amdgcn_sched_barrier(0)
#define GLDS(src,dst) __builtin_amdgcn_global_load_lds((const __attribute__((address_space(1))) u32*)(src), (__attribute__((address_space(3))) u32*)(dst), 16, 0, 0)
#define GLDS4(src,dst) __builtin_amdgcn_global_load_lds((const __attribute__((address_space(1))) u32*)(src), (__attribute__((address_space(3))) u32*)(dst), 4, 0, 0)

// ------------------------------------------------- zero helper
__global__ void zero_f(float* __restrict__ p, int n){
    int i = blockIdx.x*256 + threadIdx.x;
    if (i<n) p[i]=0.f;
}

// ------------------------------------------------- bool-buffer normalizer (dual)
__device__ void norm_bool_body(const void* __restrict__ src, u8* __restrict__ dst, int n)
{
    __shared__ int fl[4];
    if (threadIdx.x<4) fl[threadIdx.x]=0;
    __syncthreads();
    const u32* wsrc = (const u32*)src;
    const int nw = n/4;
    int any=0, nb=0, hi=0, lo=0;
    for (int i=threadIdx.x;i<nw;i+=blockDim.x){
        u32 v=wsrc[i];
        if (!v) continue;
        any=1;
        #pragma unroll
        for (int b=0;b<4;b++){
            u32 by=(v>>(8*b))&0xffu;
            if (by>1u) nb=1;
            if (by==1u && b!=0) hi=1;
        }
        if ((v&0xffffu)==0x3f80u) lo=1;
    }
    if (any) atomicOr(&fl[0],1);
    if (nb)  atomicOr(&fl[1],1);
    if (hi)  atomicOr(&fl[2],1);
    if (lo)  atomicOr(&fl[3],1);
    __syncthreads();
    int c;
    if (!fl[0]) c=0;
    else if (!fl[1]) c = fl[2] ? 2 : 1;
    else if (fl[3]) c = 3;
    else c = 1;
    for (int i=threadIdx.x;i<n;i+=blockDim.x){
        u8 v;
        if (c==0)      v=0;
        else if (c==1) v = (((const u32*)src)[i]!=0u);
        else if (c==2) v = (((const u8*)src)[i]!=0u);
        else           v = (((const u16*)src)[i]!=0u);
        dst[i]=v;
    }
}
__global__ void norm_bool2(const void* s0, u8* d0, const void* s1, u8* d1, int n)
{
    if (blockIdx.x==0) norm_bool_body(s0,d0,n);
    else               norm_bool_body(s1,d1,n);
}

// ------------------------------------------------- pack per-token metadata
__global__ void pack_meta(const int* __restrict__ node, const int* __restrict__ colx,
                          const int* __restrict__ tbl, const u8* __restrict__ pad,
                          u32* __restrict__ pm, int n)
{
    int i = blockIdx.x*256 + threadIdx.x;
    if (i<n)
        pm[i] = (u32)(node[i]&0xff) | ((u32)(colx[i]&0xff)<<8) | ((u32)(tbl[i]&0xff)<<16) | ((u32)(pad[i]&1)<<24);
}

// ------------------------------------------------- mask table: m4[b][k][q] bit t = mask_t(q,k)
__global__ __launch_bounds__(256) void mask4_kernel(const u32* __restrict__ pm, const int* __restrict__ f2p,
                                                    u8* __restrict__ m4)
{
    const int b = blockIdx.y, kg = blockIdx.x;
    const int t = threadIdx.x;
    __shared__ u32 qm[1024];
    __shared__ int qf[1024*5];
    for (int i=t;i<1024;i+=256) qm[i] = pm[b*SS+i];
    for (int i=t;i<5*1024;i+=256) qf[i] = f2p[b*SS*5 + i];
    __syncthreads();
    const int q0 = t*4;
    u32 qmv[4]; int qn[4]; int qfv[4][5];
    #pragma unroll
    for (int j=0;j<4;j++){
        qmv[j]=qm[q0+j]; qn[j]=(int)(qmv[j]&0xffu);
        #pragma unroll
        for (int f=0;f<5;f++) qfv[j][f]=qf[(q0+j)*5+f];
    }
    for (int kk=0;kk<16;kk++){
        const int k = kg*16+kk;
        const u32 km = qm[k];
        const int kn = (int)(km&0xffu);
        u32 outw=0;
        #pragma unroll
        for (int j=0;j<4;j++){
            const u32 qmw = qmv[j];
            const bool pv = (((qmw|km)>>24)&1u)==0u;
            u32 by=0;
            if ((((qmw^km)&0x00ffff00u)==0u) && pv) by|=1;
            if ((((qmw^km)&0xffu)==0u) && pv) by|=2;
            bool nei = (qfv[j][0]==kn)||(qfv[j][1]==kn)||(qfv[j][2]==kn)||(qfv[j][3]==kn)||(qfv[j][4]==kn)
                       ||(qn[j]==kn);
            if (nei && pv) by|=4;
            if (pv) by|=8;
            if ((q0+j)==k) by=15;
            outw |= by<<(8*j);
        }
        ((u32*)(m4 + ((size_t)b<<20) + ((size_t)k<<10)))[t] = outw;
    }
}

// ------------------------------------------------- weight f32 [K][N] -> tiled bf16 (+gamma fold)
__global__ __launch_bounds__(256) void transpose_cvt2(const float* __restrict__ src, u16* __restrict__ dst,
                                                      int K, int N, size_t dz,
                                                      const float* __restrict__ gbase, int gmode)
{
    const int z = blockIdx.z;
    src += (size_t)z*K*N;
    dst += (size_t)z*dz;
    const float* g = nullptr;
    if (gmode==1){ int m = z&3; if (m<3) g = gbase + (size_t)((z>>4)*5 + ((z>>2)&3))*768; }
    else if (gmode==2){ g = gbase + (size_t)z*5*768; }
    const int n0 = blockIdx.x*32, k0 = blockIdx.y*64;
    __shared__ float t[64][33];
    const int tid = threadIdx.x;
    const int kr = tid>>3, n4 = (tid&7)*4;
    #pragma unroll
    for (int p=0;p<2;p++){
        const int k = p*32 + kr;
        float gk = g ? g[k0+k] : 1.f;
        float4 v = *(const float4*)(src + (size_t)(k0+k)*N + n0 + n4);
        t[k][n4]=v.x*gk; t[k][n4+1]=v.y*gk; t[k][n4+2]=v.z*gk; t[k][n4+3]=v.w*gk;
    }
    __syncthreads();
    const int n = tid>>3, ks = (tid&7)*8;
    const int ng = n0 + n;
    uint4 o;
    u32* op = (u32*)&o;
    #pragma unroll
    for (int i=0;i<4;i++)
        op[i] = pk2(t[ks+2*i][n], t[ks+2*i+1][n]);
    *(uint4*)&dst[(((size_t)(ng>>7)*(K>>6) + (k0>>6))<<13) + ((ng&127)<<6) + ks] = o;
}

// ------------------------------------------------- activation f32 [M][K] -> tiled bf16 (dual src)
__global__ __launch_bounds__(256) void cvt_tiled2(const float* __restrict__ s0, u16* __restrict__ d0,
                                                  const float* __restrict__ s1, u16* __restrict__ d1, int K)
{
    const float* src = blockIdx.y ? s1 : s0;
    u16* dst = blockIdx.y ? d1 : d0;
    const int gid = blockIdx.x*256 + threadIdx.x;
    const int base = gid*8;
    const int row = base / K, col = base - row*K;
    float4 a = *(const float4*)(src + base);
    float4 b = *(const float4*)(src + base + 4);
    uint4 o;
    o.x = pk2(a.x,a.y); o.y = pk2(a.z,a.w);
    o.z = pk2(b.x,b.y); o.w = pk2(b.z,b.w);
    *(uint4*)&dst[(((size_t)(row>>7)*(K>>6) + (col>>6))<<13) + ((row&127)<<6) + (col&63)] = o;
}

// ------------------------------------------------- BM=128 GEMM (qkv)
__device__ __forceinline__ void stage3(const u16* aT, const u16* bT, int cb, int brow,
                                       u16* la, u16* lb, int w, int l)
{
    #pragma unroll
    for (int p=0;p<2;p++){
        const int q = p*256 + w*64 + l;
        const int row = q>>2, u = q&3;
        const int so = row*64 + cb + (((u ^ ((row>>1)&3))&3)<<3);
        GLDS(aT+so, la + p*2048 + w*512);
    }
    {
        const int q = w*64 + l;
        const int row = q>>2, u = q&3;
        const int so = (brow+row)*64 + cb + (((u ^ ((row>>1)&3))&3)<<3);
        GLDS(bT+so, lb + w*512);
    }
}

__global__ __launch_bounds__(256,4) void gemm_t(
    const u16* __restrict__ At, const u16* __restrict__ Bt,
    int K, int AMS, u16* __restrict__ qk16, u16* __restrict__ vt16,
    const float* __restrict__ rs_in)
{
    __shared__ u16 lds[3][6144];
    const int tid = threadIdx.x;
    const int lane = tid & 63, w = tid >> 6;
    const int cg = lane >> 4, cl = lane & 15;
    const int NT = K >> 5;
    const int n0 = blockIdx.x*64;
    const int brow = n0 & 64;
    const size_t bNb = (size_t)(n0>>7)*(K>>6);

    const u16* aB = At + ((size_t)blockIdx.y * AMS << 13);
    const u16* bB = Bt + (bNb << 13);

    f32x4 acc[2][4];
    #pragma unroll
    for (int i=0;i<2;i++)
        #pragma unroll
        for (int j=0;j<4;j++) acc[i][j] = (f32x4){0.f,0.f,0.f,0.f};

    stage3(aB, bB, 0,  brow, &lds[0][0], &lds[0][4096], w, lane);
    stage3(aB, bB, 32, brow, &lds[1][0], &lds[1][4096], w, lane);

    for (int kt=0; kt<NT; kt++){
        const int buf = kt % 3;
        if (kt+2 < NT){
            const int k2 = kt+2;
            stage3(aB + ((size_t)(k2>>1)<<13), bB + ((size_t)(k2>>1)<<13),
                   (k2&1)<<5, brow, &lds[k2%3][0], &lds[k2%3][4096], w, lane);
            asm volatile("s_waitcnt vmcnt(6)" ::: "memory");
        } else if (kt+1 < NT){
            asm volatile("s_waitcnt vmcnt(3)" ::: "memory");
        } else {
            asm volatile("s_waitcnt vmcnt(0)" ::: "memory");
        }
        SBAR(); __builtin_amdgcn_s_barrier(); SBAR();
        s16x8 af[2], bf[4];
        #pragma unroll
        for (int mt=0;mt<2;mt++){
            const int ra = w*32 + mt*16 + cl;
            af[mt] = *(const s16x8*)&lds[buf][ra*32 + (((cg ^ ((ra>>1)&3))&3)<<3)];
        }
        #pragma unroll
        for (int nt=0;nt<4;nt++){
            const int rb = nt*16 + cl;
            bf[nt] = *(const s16x8*)&lds[buf][4096 + rb*32 + (((cg ^ ((rb>>1)&3))&3)<<3)];
        }
        #pragma unroll
        for (int mt=0;mt<2;mt++)
            #pragma unroll
            for (int nt=0;nt<4;nt++)
                acc[mt][nt] = __builtin_amdgcn_mfma_f32_16x16x32_bf16(af[mt], bf[nt], acc[mt][nt], 0,0,0);
        SBAR(); __builtin_amdgcn_s_barrier(); SBAR();
    }

    const int m0 = blockIdx.y*128;
    #pragma unroll
    for (int mt=0;mt<2;mt++){
        const int grow0 = m0 + w*32 + mt*16 + cg*4;
        float rr[4];
        #pragma unroll
        for (int j=0;j<4;j++) rr[j] = rsqrtf(rs_in[grow0+j]*(1.f/768.f) + EPSF);
        #pragma unroll
        for (int nt=0;nt<4;nt++){
            const int col = n0 + nt*16 + cl;
            if (col < 768){           // q: fold exp2 prescale
                #pragma unroll
                for (int j=0;j<4;j++)
                    qk16[(size_t)(grow0+j)*1536 + col] = f2bu(acc[mt][nt][j]*rr[j]*QSC);
            } else if (col < 1536){   // k
                #pragma unroll
                for (int j=0;j<4;j++)
                    qk16[(size_t)(grow0+j)*1536 + col] = f2bu(acc[mt][nt][j]*rr[j]);
            } else {                  // v transposed
                const int b = grow0>>10, s0 = grow0&1023;
                const int dhg = col - 1536;
                uint2 o;
                o.x = pk2(acc[mt][nt][0]*rr[0], acc[mt][nt][1]*rr[1]);
                o.y = pk2(acc[mt][nt][2]*rr[2], acc[mt][nt][3]*rr[3]);
                *(uint2*)(vt16 + ((size_t)(b*768 + dhg)<<10) + s0) = o;
            }
        }
    }
}

// ------------------------------------------------- fused gate-up-silu GEMM (BM128, dual BN64)
__global__ __launch_bounds__(256,3) void gemm_gu(
    const u16* __restrict__ At, const u16* __restrict__ Bg, const u16* __restrict__ Bu,
    const float* __restrict__ rs_in, u16* __restrict__ o16)
{
    __shared__ u16 lds[3][8192];   // A[0..4095], Bg[4096..6143], Bu[6144..8191]; 48KB
    const int tid = threadIdx.x;
    const int lane = tid & 63, w = tid >> 6;
    const int cg = lane >> 4, cl = lane & 15;
    const int NT = 24;             // K=768
    const int n0 = blockIdx.x*64;  // within 3072
    const int brow = n0 & 64;
    const size_t bNb = (size_t)(n0>>7)*12;

    const u16* aB = At + ((size_t)blockIdx.y * 12 << 13);
    const u16* gB = Bg + (bNb << 13);
    const u16* uB = Bu + (bNb << 13);

    f32x4 accg[2][4], accu[2][4];
    #pragma unroll
    for (int i=0;i<2;i++)
        #pragma unroll
        for (int j=0;j<4;j++){ accg[i][j] = (f32x4){0.f,0.f,0.f,0.f}; accu[i][j] = (f32x4){0.f,0.f,0.f,0.f}; }

    // stage: A(2) + Bg(1) + Bu(1) = 4 loads/thread
    #define STAGE_GU(kt2, cb, buf) { \
        const u16* a_ = aB + ((size_t)(kt2)<<13); \
        const u16* g_ = gB + ((size_t)(kt2)<<13); \
        const u16* u_ = uB + ((size_t)(kt2)<<13); \
        _Pragma("unroll") \
        for (int p=0;p<2;p++){ \
            const int q = p*256 + w*64 + lane; \
            const int row = q>>2, uu = q&3; \
            const int so = row*64 + (cb) + (((uu ^ ((row>>1)&3))&3)<<3); \
            GLDS(a_+so, &lds[buf][0] + p*2048 + w*512); \
        } \
        { \
            const int q = w*64 + lane; \
            const int row = q>>2, uu = q&3; \
            const int so = (brow+row)*64 + (cb) + (((uu ^ ((row>>1)&3))&3)<<3); \
            GLDS(g_+so, &lds[buf][4096] + w*512); \
            GLDS(u_+so, &lds[buf][6144] + w*512); \
        } }

    STAGE_GU(0, 0,  0);
    STAGE_GU(0, 32, 1);

    for (int kt=0; kt<NT; kt++){
        const int buf = kt % 3;
        if (kt+2 < NT){
            const int k2 = kt+2;
            STAGE_GU(k2>>1, (k2&1)<<5, k2%3);
            asm volatile("s_waitcnt vmcnt(8)" ::: "memory");
        } else if (kt+1 < NT){
            asm volatile("s_waitcnt vmcnt(4)" ::: "memory");
        } else {
            asm volatile("s_waitcnt vmcnt(0)" ::: "memory");
        }
        SBAR(); __builtin_amdgcn_s_barrier(); SBAR();
        s16x8 af[2], bg[4], bu[4];
        #pragma unroll
        for (int mt=0;mt<2;mt++){
            const int ra = w*32 + mt*16 + cl;
            af[mt] = *(const s16x8*)&lds[buf][ra*32 + (((cg ^ ((ra>>1)&3))&3)<<3)];
        }
        #pragma unroll
        for (int nt=0;nt<4;nt++){
            const int rb = nt*16 + cl;
            const int sw = (((cg ^ ((rb>>1)&3))&3)<<3);
            bg[nt] = *(const s16x8*)&lds[buf][4096 + rb*32 + sw];
            bu[nt] = *(const s16x8*)&lds[buf][6144 + rb*32 + sw];
        }
        #pragma unroll
        for (int mt=0;mt<2;mt++)
            #pragma unroll
            for (int nt=0;nt<4;nt++){
                accg[mt][nt] = __builtin_amdgcn_mfma_f32_16x16x32_bf16(af[mt], bg[nt], accg[mt][nt], 0,0,0);
                accu[mt][nt] = __builtin_amdgcn_mfma_f32_16x16x32_bf16(af[mt], bu[nt], accu[mt][nt], 0,0,0);
            }
        SBAR(); __builtin_amdgcn_s_barrier(); SBAR();
    }

    const int m0 = blockIdx.y*128;
    #pragma unroll
    for (int mt=0;mt<2;mt++){
        const int grow0 = m0 + w*32 + mt*16 + cg*4;
        float rr[4];
        #pragma unroll
        for (int j=0;j<4;j++) rr[j] = rsqrtf(rs_in[grow0+j]*(1.f/768.f) + EPSF);
        #pragma unroll
        for (int nt=0;nt<4;nt++){
            const int col = n0 + nt*16 + cl;
            const size_t tb = (((size_t)(grow0>>7)*48 + (col>>6))<<13) + (col&63);
            #pragma unroll
            for (int j=0;j<4;j++){
                float g = accg[mt][nt][j]*rr[j];
                float u = accu[mt][nt][j]*rr[j];
                float s = g/(1.f+__expf(-g))*u;
                o16[tb + (((grow0+j)&127)<<6)] = f2bu(s);
            }
        }
    }
}

// ------------------------------------------------- BM=64 GEMM (narrow N)
__device__ __forceinline__ void stage64(const u16* aT, int arow, const u16* bT, int brow, int cb,
                                        u16* la, u16* lb, int w, int l)
{
    const int q = w*64 + l;
    const int row = q>>2, u = q&3;
    const int sw = (((u ^ ((row>>1)&3))&3)<<3);
    GLDS(aT + (arow+row)*64 + cb + sw, la + w*512);
    GLDS(bT + (brow+row)*64 + cb + sw, lb + w*512);
}

__global__ __launch_bounds__(256,6) void gemm_t64(
    const u16* __restrict__ At, const u16* __restrict__ Bt, float* __restrict__ C,
    int N, int K, int AMS, int flags, const float* __restrict__ bias,
    u16* __restrict__ o16, float* __restrict__ rs_out)
{
    __shared__ u16 lds[3][4096];
    const int tid = threadIdx.x;
    const int lane = tid & 63, w = tid >> 6;
    const int cg = lane >> 4, cl = lane & 15;
    const int NT = K >> 5;
    const int n0 = blockIdx.x*64;
    const int m0 = blockIdx.y*64;
    const int brow = n0 & 64, arow = m0 & 64;

    const u16* aB = At + ((size_t)(m0>>7) * AMS << 13);
    const u16* bB = Bt + ((size_t)(n0>>7) * (K>>6) << 13);

    f32x4 acc[4];
    #pragma unroll
    for (int j=0;j<4;j++) acc[j] = (f32x4){0.f,0.f,0.f,0.f};

    stage64(aB, arow, bB, brow, 0,  &lds[0][0], &lds[0][2048], w, lane);
    stage64(aB, arow, bB, brow, 32, &lds[1][0], &lds[1][2048], w, lane);

    for (int kt=0; kt<NT; kt++){
        const int buf = kt % 3;
        if (kt+2 < NT){
            const int k2 = kt+2;
            stage64(aB + ((size_t)(k2>>1)<<13), arow, bB + ((size_t)(k2>>1)<<13), brow,
                    (k2&1)<<5, &lds[k2%3][0], &lds[k2%3][2048], w, lane);
            asm volatile("s_waitcnt vmcnt(4)" ::: "memory");
        } else if (kt+1 < NT){
            asm volatile("s_waitcnt vmcnt(2)" ::: "memory");
        } else {
            asm volatile("s_waitcnt vmcnt(0)" ::: "memory");
        }
        SBAR(); __builtin_amdgcn_s_barrier(); SBAR();
        const int ra = w*16 + cl;
        s16x8 af = *(const s16x8*)&lds[buf][ra*32 + (((cg ^ ((ra>>1)&3))&3)<<3)];
        s16x8 bf[4];
        #pragma unroll
        for (int nt=0;nt<4;nt++){
            const int rb = nt*16 + cl;
            bf[nt] = *(const s16x8*)&lds[buf][2048 + rb*32 + (((cg ^ ((rb>>1)&3))&3)<<3)];
        }
        #pragma unroll
        for (int nt=0;nt<4;nt++)
            acc[nt] = __builtin_amdgcn_mfma_f32_16x16x32_bf16(af, bf[nt], acc[nt], 0,0,0);
        SBAR(); __builtin_amdgcn_s_barrier(); SBAR();
    }

    const int grow0 = m0 + w*16 + cg*4;
    const bool do_acc = (flags&1), do_bias = (flags&2);
    float tmp[4][4];
    #pragma unroll
    for (int nt=0;nt<4;nt++){
        const int col = n0 + nt*16 + cl;
        float bv = do_bias ? bias[col] : 0.f;
        #pragma unroll
        for (int j=0;j<4;j++){
            float v = acc[nt][j] + bv;
            float* cp = C + (size_t)(grow0+j)*N + col;
            if (do_acc) v += *cp;
            *cp = v;
            tmp[nt][j] = v;
        }
    }
    if (o16){
        #pragma unroll
        for (int nt=0;nt<4;nt++){
            const int col = n0 + nt*16 + cl;
            const size_t tb = (((size_t)(grow0>>7)*12 + (col>>6))<<13) + (col&63);
            #pragma unroll
            for (int j=0;j<4;j++)
                o16[tb + (((grow0+j)&127)<<6)] = f2bu(tmp[nt][j]);
        }
    }
    if (rs_out){
        #pragma unroll
        for (int j=0;j<4;j++){
            float s = tmp[0][j]*tmp[0][j] + tmp[1][j]*tmp[1][j]
                    + tmp[2][j]*tmp[2][j] + tmp[3][j]*tmp[3][j];
            s = rsum16(s);
            if (cl==0) atomicAdd(rs_out + grow0 + j, s);
        }
    }
}

// ------------------------------------------------- MFMA flash attention (exp2, max-free)
__global__ __launch_bounds__(256,3) void attn_mfma3(
    const u16* __restrict__ qk16, const u16* __restrict__ vt16,
    const u8* __restrict__ m4, int mt,
    u16* __restrict__ ob16)
{
    const int bh = blockIdx.y;
    const int b = bh / NH, h = bh % NH;
    const int q0 = blockIdx.x * 64;
    const int tid = threadIdx.x;
    const int w = tid>>6, lane = tid&63, cg = lane>>4, cl = lane&15;
    const int srow = lane>>3;
    const int sseg = (lane&7) ^ srow;
    const int mk = lane>>4, mq = lane&15;

    __shared__ u16 Qs[4096], Ks[2][4096], Vt[2][4096], Ps[4096];
    __shared__ u32 Ms[2][1024];

    const u16* qbase = qk16 + (size_t)(b*SS+q0)*1536 + h*64;
    const u16* kbase = qk16 + (size_t)(b*SS)*1536 + 768 + h*64;
    const u16* vbase = vt16 + ((size_t)(b*768 + h*64)<<10);
    const u8*  mbase = m4 + ((size_t)b<<20) + q0;

    #pragma unroll
    for (int p=0;p<2;p++){
        const int row = p*32 + w*8 + srow;
        GLDS(qbase + (size_t)row*1536 + sseg*8, Qs + p*2048 + w*512);
    }
    #pragma unroll
    for (int p=0;p<2;p++){
        const int row = p*32 + w*8 + srow;
        GLDS(kbase + (size_t)row*1536 + sseg*8, Ks[0] + p*2048 + w*512);
        GLDS(vbase + ((size_t)row<<10) + sseg*8, Vt[0] + p*2048 + w*512);
    }
    #pragma unroll
    for (int i=0;i<4;i++){
        const int key = w*16 + i*4 + mk;
        GLDS4(mbase + ((size_t)key<<10) + mq*4, (u8*)Ms[0] + w*1024 + i*256);
    }

    f32x4 o[4];
    #pragma unroll
    for (int nt=0;nt<4;nt++) o[nt] = (f32x4){0.f,0.f,0.f,0.f};
    float lsum[4] = {0.f,0.f,0.f,0.f};

    for (int kc=0;kc<16;kc++){
        const int buf = kc & 1;
        if (kc < 15){
            const int kn0 = kc*64 + 64;
            #pragma unroll
            for (int p=0;p<2;p++){
                const int row = p*32 + w*8 + srow;
                GLDS(kbase + (size_t)(kn0+row)*1536 + sseg*8, Ks[buf^1] + p*2048 + w*512);
                GLDS(vbase + ((size_t)row<<10) + kn0 + sseg*8, Vt[buf^1] + p*2048 + w*512);
            }
            #pragma unroll
            for (int i=0;i<4;i++){
                const int key = kn0 + w*16 + i*4 + mk;
                GLDS4(mbase + ((size_t)key<<10) + mq*4, (u8*)Ms[buf^1] + w*1024 + i*256);
            }
            asm volatile("s_waitcnt vmcnt(8)" ::: "memory");
        } else {
            asm volatile("s_waitcnt vmcnt(0)" ::: "memory");
        }
        SBAR(); __builtin_amdgcn_s_barrier(); SBAR();

        // QK^T (q already holds 0.125*log2e scale)
        f32x4 sc[4];
        #pragma unroll
        for (int nt=0;nt<4;nt++) sc[nt] = (f32x4){0.f,0.f,0.f,0.f};
        __builtin_amdgcn_s_setprio(1);
        #pragma unroll
        for (int ks=0;ks<2;ks++){
            s16x8 qa = *(const s16x8*)&Qs[swz(w*16+cl, ks*32+cg*8)];
            #pragma unroll
            for (int nt=0;nt<4;nt++){
                s16x8 kb = *(const s16x8*)&Ks[buf][swz(nt*16+cl, ks*32+cg*8)];
                sc[nt] = __builtin_amdgcn_mfma_f32_16x16x32_bf16(qa, kb, sc[nt], 0,0,0);
            }
        }
        __builtin_amdgcn_s_setprio(0);

        // mask + exp2 (max-free; bounded scores)
        float pP[4][4];
        #pragma unroll
        for (int nt=0;nt<4;nt++){
            const u32 w4 = Ms[buf][(nt*16+cl)*16 + w*4 + cg];
            #pragma unroll
            for (int j=0;j<4;j++){
                float pe = exp2f(fminf(sc[nt][j], 100.f));
                pe = ((w4 >> (8*j + mt)) & 1u) ? pe : 0.f;
                pP[nt][j] = pe;
                lsum[j] += pe;
            }
        }

        #pragma unroll
        for (int nt=0;nt<4;nt++)
            #pragma unroll
            for (int j=0;j<4;j++)
                Ps[swz(w*16+cg*4+j, nt*16+cl)] = f2bu(pP[nt][j]);

        // PV
        __builtin_amdgcn_s_setprio(1);
        #pragma unroll
        for (int ks=0;ks<2;ks++){
            s16x8 pa = *(const s16x8*)&Ps[swz(w*16+cl, ks*32+cg*8)];
            #pragma unroll
            for (int nt=0;nt<4;nt++){
                s16x8 vb = *(const s16x8*)&Vt[buf][swz(nt*16+cl, ks*32+cg*8)];
                o[nt] = __builtin_amdgcn_mfma_f32_16x16x32_bf16(pa, vb, o[nt], 0,0,0);
            }
        }
        __builtin_amdgcn_s_setprio(0);
        SBAR(); __builtin_amdgcn_s_barrier(); SBAR();
    }

    #pragma unroll
    for (int j=0;j<4;j++){
        const float inv = 1.f/rsum16(lsum[j]);
        const int row = b*SS + q0 + w*16 + cg*4 + j;
        const size_t rb = ((size_t)(row>>7)*12 + h)*8192 + ((row&127)<<6);
        #pragma unroll
        for (int nt=0;nt<4;nt++)
            ob16[rb + nt*16 + cl] = f2bu(o[nt][j]*inv);
    }
}

// ------------------------------------------------- encode fuse
__global__ __launch_bounds__(256) void fuse_encode(
    const float* __restrict__ cnbuf, const float* __restrict__ textbuf,
    const float* __restrict__ numv, const float* __restrict__ dtv, const float* __restrict__ boolv,
    const float* __restrict__ Wnum, const float* __restrict__ bnum,
    const float* __restrict__ Wdt, const float* __restrict__ bdt,
    const float* __restrict__ Wbool, const float* __restrict__ bbool,
    const float* __restrict__ gcn, const float* __restrict__ gnum, const float* __restrict__ gtext,
    const float* __restrict__ gdt, const float* __restrict__ gbool,
    const float* __restrict__ memb, const int* __restrict__ stypes, const u8* __restrict__ masks,
    float* __restrict__ x, u16* __restrict__ xt16, float* __restrict__ rs0)
{
    const int row = blockIdx.x;
    const int t = threadIdx.x;
    __shared__ float red[256];

    float cn3[3]; float ss=0.f;
    #pragma unroll
    for (int j=0;j<3;j++){
        cn3[j] = cnbuf[(size_t)row*DM + t + j*256];
        ss += cn3[j]*cn3[j];
    }
    red[t]=ss; __syncthreads();
    for (int s=128;s>0;s>>=1){ if(t<s) red[t]+=red[t+s]; __syncthreads(); }
    {
        float r = rsqrtf(red[0]/(float)DM + EPSF);
        #pragma unroll
        for (int j=0;j<3;j++) cn3[j] *= r*gcn[t+j*256];
    }
    __syncthreads();

    const int st = stypes[row];
    float val[3]; ss=0.f;
    if (st==1){
        #pragma unroll
        for (int j=0;j<3;j++){
            val[j] = textbuf[(size_t)row*DM + t + j*256];
            ss += val[j]*val[j];
        }
    } else {
        const float* Wp = (st==0)?Wnum:((st==2)?Wdt:Wbool);
        const float* bp = (st==0)?bnum:((st==2)?bdt:bbool);
        const float* vp = (st==0)?numv:((st==2)?dtv:boolv);
        float v = vp[row];
        #pragma unroll
        for (int j=0;j<3;j++){
            int e=t+j*256;
            val[j] = v*Wp[e] + bp[e];
            ss += val[j]*val[j];
        }
    }
    red[t]=ss; __syncthreads();
    for (int s=128;s>0;s>>=1){ if(t<s) red[t]+=red[t+s]; __syncthreads(); }
    const float* gp = (st==0)?gnum:((st==1)?gtext:((st==2)?gdt:gbool));
    float r2 = rsqrtf(red[0]/(float)DM + EPSF);
    bool mk = masks[row]!=0;
    float xv[3]; float sx=0.f;
    #pragma unroll
    for (int j=0;j<3;j++){
        int e=t+j*256;
        float vv = val[j]*r2*gp[e];
        if (mk) vv = memb[st*DM+e];
        xv[j] = vv + cn3[j];
        x[(size_t)row*DM+e] = xv[j];
        sx += xv[j]*xv[j];
    }
    __syncthreads();
    red[t]=sx; __syncthreads();
    for (int s=128;s>0;s>>=1){ if(t<s) red[t]+=red[t+s]; __syncthreads(); }
    if (t==0) rs0[row] = red[0];
    const size_t mb = (size_t)(row>>7)*12;
    const int rr = (row&127)<<6;
    #pragma unroll
    for (int j=0;j<3;j++){
        const int c = t + j*256;
        xt16[((mb + (c>>6))<<13) + rr + (c&63)] = f2bu(xv[j]);
    }
}

// ------------------------------------------------- final rms + 3 scalar heads; h -> tiled bf16
__global__ __launch_bounds__(256) void decode2(
    const float* __restrict__ x, const float* __restrict__ gout,
    const float* __restrict__ Wn, const float* __restrict__ bn,
    const float* __restrict__ Wd, const float* __restrict__ bd,
    const float* __restrict__ Wb, const float* __restrict__ bb,
    float* __restrict__ out, u16* __restrict__ h16)
{
    const int row = blockIdx.x;
    const int t = threadIdx.x;
    __shared__ float h[DM];
    __shared__ float red[256];
    const float* xr = x + (size_t)row*DM;
    float v0=xr[t], v1=xr[t+256], v2=xr[t+512];
    red[t]=v0*v0+v1*v1+v2*v2; __syncthreads();
    for (int s=128;s>0;s>>=1){ if(t<s) red[t]+=red[t+s]; __syncthreads(); }
    float r = rsqrtf(red[0]/(float)DM + EPSF);
    float h0 = v0*r*gout[t], h1 = v1*r*gout[t+256], h2 = v2*r*gout[t+512];
    h[t]=h0; h[t+256]=h1; h[t+512]=h2;
    const size_t mb = (size_t)(row>>7)*12;
    const int rr = (row&127)<<6;
    #pragma unroll
    for (int j=0;j<3;j++){
        const int c = t + j*256;
        const float v = (j==0?h0:(j==1?h1:h2));
        h16[((mb + (c>>6))<<13) + rr + (c&63)] = f2bu(v);
    }
    __syncthreads();

    float pn=0.f,pd=0.f,pb=0.f;
    for (int k=t;k<DM;k+=256){ float hv=h[k]; pn+=hv*Wn[k]; pd+=hv*Wd[k]; pb+=hv*Wb[k]; }
    red[t]=pn; __syncthreads();
    for (int s=128;s>0;s>>=1){ if(t<s) red[t]+=red[t+s]; __syncthreads(); }
    float tn=red[0]; __syncthreads();
    red[t]=pd; __syncthreads();
    for (int s=128;s>0;s>>=1){ if(t<s) red[t]+=red[t+s]; __syncthreads(); }
    float td=red[0]; __syncthreads();
    red[t]=pb; __syncthreads();
    for (int s=128;s>0;s>>=1){ if(t<s) red[t]+=red[t+s]; __syncthreads(); }
    float tb=red[0];
    if (t==0){
        out[row]          = tn + bn[0];
        out[NROW + row]   = td + bd[0];
        out[2*NROW + row] = tb + bb[0];
    }
}

// ---------------------------------------------------------------- launcher
extern "C" void kernel_launch(void* const* d_in, const int* in_sizes, int n_in,
                              void* d_out, int out_size, void* d_ws, size_t ws_size,
                              hipStream_t stream)
{
    const float* numv   = (const float*)d_in[0];
    const float* dtval  = (const float*)d_in[1];
    const float* boolv  = (const float*)d_in[2];
    const float* textv  = (const float*)d_in[3];
    const float* cnamev = (const float*)d_in[4];
    const float* Wcn=(const float*)d_in[5];  const float* bcn=(const float*)d_in[6];
    const float* Wnum=(const float*)d_in[7]; const float* bnum=(const float*)d_in[8];
    const float* Wtext=(const float*)d_in[9];const float* btext=(const float*)d_in[10];
    const float* Wdt=(const float*)d_in[11]; const float* bdt=(const float*)d_in[12];
    const float* Wbool=(const float*)d_in[13];const float* bbool=(const float*)d_in[14];
    const float* gcn=(const float*)d_in[15]; const float* gnum=(const float*)d_in[16];
    const float* gtext=(const float*)d_in[17];const float* gdt=(const float*)d_in[18];
    const float* gbool=(const float*)d_in[19];
    const float* memb=(const float*)d_in[20];
    const float* norms_all=(const float*)d_in[21];
    const float* attw_all=(const float*)d_in[22];
    const float* up_all=(const float*)d_in[23];
    const float* gate_all=(const float*)d_in[24];
    const float* down_all=(const float*)d_in[25];
    const float* gout=(const float*)d_in[26];
    const float* Wdn=(const float*)d_in[27]; const float* bdn=(const float*)d_in[28];
    const float* Wdd=(const float*)d_in[29]; const float* bdd=(const float*)d_in[30];
    const float* Wdb=(const float*)d_in[31]; const float* bdb=(const float*)d_in[32];
    const float* Wdtx=(const float*)d_in[33];const float* bdtx=(const float*)d_in[34];
    const int* node=(const int*)d_in[35];
    const int* tbl =(const int*)d_in[36];
    const int* colx=(const int*)d_in[37];
    const int* f2p =(const int*)d_in[38];
    const int* styp=(const int*)d_in[39];

    const size_t SA = (size_t)768*768;
    const size_t SG = (size_t)768*3072;
    const size_t SC = (size_t)384*768;
    const size_t NX = (size_t)NROW*DM;

    u8* base = (u8*)d_ws;
    float* x  = (float*)base;
    u16* xt16 = (u16*)(base + 6291456);
    u16* ob16 = (u16*)(base + 9437184);
    u16* qk16 = (u16*)(base + 12582912);
    u16* vt16 = (u16*)(base + 18874368);
    u16* gu16 = (u16*)(base + 22020096);
    u16* wA   = (u16*)(base + 47185920);
    u16* wGU  = wA + 64*SA;
    u16* wD   = wGU + 8*SG;
    u16* wCN  = wD + 4*SG;
    u16* wTX  = wCN + SC;
    u16* wDX  = wTX + SC;
    u8* nmask = (u8*)(wDX + SC);
    u8* npad  = nmask + NROW;
    u32* pmeta = (u32*)(npad + NROW + 64);
    float* rsbuf = (float*)(pmeta + NROW);     // 21 slots x 2048
    u8* m4 = (u8*)(rsbuf + 21*2048);           // 2 MB

    // encode-phase aliases
    u16* cnT16   = qk16;
    u16* textT16 = vt16;
    float* cnbuf   = (float*)gu16;
    float* textbuf = cnbuf + NX;

    float* out = (float*)d_out;

    zero_f<<<(21*2048)/256,256,0,stream>>>(rsbuf, 21*2048);
    norm_bool2<<<2,256,0,stream>>>(d_in[40], nmask, d_in[41], npad, NROW);
    pack_meta<<<NROW/256,256,0,stream>>>(node, colx, tbl, npad, pmeta, NROW);
    mask4_kernel<<<dim3(64,2),256,0,stream>>>(pmeta, f2p, m4);

    // weight prep (tiled bf16; gamma folded)
    transpose_cvt2<<<dim3(24,12,64),256,0,stream>>>(attw_all, wA, 768, 768, SA, norms_all, 1);
    transpose_cvt2<<<dim3(96,12,4),256,0,stream>>>(gate_all, wGU,      768, 3072, 2*SG, norms_all + 4*768, 2);
    transpose_cvt2<<<dim3(96,12,4),256,0,stream>>>(up_all,   wGU + SG, 768, 3072, 2*SG, norms_all + 4*768, 2);
    transpose_cvt2<<<dim3(24,48,4),256,0,stream>>>(down_all, wD, 3072, 768, SG, nullptr, 0);
    transpose_cvt2<<<dim3(24,6,1),256,0,stream>>>(Wcn,   wCN, 384, 768, 0, nullptr, 0);
    transpose_cvt2<<<dim3(24,6,1),256,0,stream>>>(Wtext, wTX, 384, 768, 0, nullptr, 0);
    transpose_cvt2<<<dim3(12,12,1),256,0,stream>>>(Wdtx, wDX, 768, 384, 0, nullptr, 0);

    // encode
    cvt_tiled2<<<dim3(384,2),256,0,stream>>>(cnamev, cnT16, textv, textT16, 384);
    gemm_t64<<<dim3(12,32),256,0,stream>>>(cnT16,   wCN, cnbuf,   768, 384, 6, 2, bcn,   nullptr, nullptr);
    gemm_t64<<<dim3(12,32),256,0,stream>>>(textT16, wTX, textbuf, 768, 384, 6, 2, btext, nullptr, nullptr);
    fuse_encode<<<NROW,256,0,stream>>>(cnbuf, textbuf, numv, dtval, boolv,
        Wnum,bnum,Wdt,bdt,Wbool,bbool, gcn,gnum,gtext,gdt,gbool,
        memb, styp, nmask, x, xt16, rsbuf);

    const dim3 ga(SS/64, BB*NH);
    for (int l=0; l<NL; l++){
        for (int a=0; a<4; a++){
            const int slot = l*5 + a;
            const u16* wqkv = wA + (size_t)((l*4+a)*4)*SA;
            gemm_t<<<dim3(36,16),256,0,stream>>>(xt16, wqkv, 768, 12, qk16, vt16,
                rsbuf + (size_t)slot*2048);
            attn_mfma3<<<ga,256,0,stream>>>(qk16, vt16, m4, a, ob16);
            gemm_t64<<<dim3(12,32),256,0,stream>>>(ob16, wqkv + 3*SA, x, 768, 768, 12, 1, nullptr,
                xt16, rsbuf + (size_t)(slot+1)*2048);
        }
        gemm_gu<<<dim3(48,16),256,0,stream>>>(xt16, wGU + (size_t)l*2*SG, wGU + (size_t)l*2*SG + SG,
            rsbuf + (size_t)(l*5+4)*2048, gu16);
        gemm_t64<<<dim3(12,32),256,0,stream>>>(gu16, wD + (size_t)l*SG, x, 768, 3072, 48, 1, nullptr,
            xt16, rsbuf + (size_t)((l+1)*5)*2048);
    }

    decode2<<<NROW,256,0,stream>>>(x, gout, Wdn,bdn, Wdd,bdd, Wdb,bdb, out, xt16);
    gemm_t64<<<dim3(6,32),256,0,stream>>>(xt16, wDX, out + 3*NROW, 384, 768, 12, 2, bdtx,
        nullptr, nullptr);
}

// Round 13
// 1445.317 us; speedup vs baseline: 7.1214x; 1.0019x over previous
//
#include <hip/hip_runtime.h>
#include <hip/hip_bf16.h>
#include <cmath>
#include <stdint.h>

// Round 13: one barrier per K-step in all GEMMs (3-buffer, 1-ahead staging — provably race-free);
// attention Q held in registers (LDS 56->48KB => 3 blocks/CU). Rest identical to r12.

#define BB 2
#define SS 1024
#define DT 384
#define DM 768
#define NH 12
#define DH 64
#define DFF 3072
#define NL 4
#define NROW (BB*SS)
#define EPSF 1e-6f
#define QSC 0.1803368801111244f   // 0.125 * log2(e)

typedef unsigned short u16;
typedef unsigned char u8;
typedef unsigned int u32;
typedef __attribute__((ext_vector_type(8))) short s16x8;
typedef __attribute__((ext_vector_type(4))) float f32x4;

__device__ __forceinline__ u16 f2bu(float f){
    u32 x = __float_as_uint(f);
    u32 r = (x + 0x7fffu + ((x>>16)&1u)) >> 16;   // RNE
    return (u16)r;
}
__device__ __forceinline__ u32 pk2(float lo, float hi){
    return (u32)f2bu(lo) | ((u32)f2bu(hi)<<16);
}
__device__ __forceinline__ int swz(int row, int c){
    return (row<<6) + (((((c>>3) ^ row) & 7))<<3) + (c&7);
}
__device__ __forceinline__ float rsum16(float v){
    v += __shfl_xor(v,1); v += __shfl_xor(v,2);
    v += __shfl_xor(v,4); v += __shfl_xor(v,8);
    return v;
}
#define SBAR() __builtin_amdgcn_sched_barrier(0)
#define GLDS(src,dst) __builtin_amdgcn_global_load_lds((const __attribute__((address_space(1))) u32*)(src), (__attribute__((address_space(3))) u32*)(dst), 16, 0, 0)
#define GLDS4(src,dst) __builtin_amdgcn_global_load_lds((const __attribute__((address_space(1))) u32*)(src), (__attribute__((address_space(3))) u32*)(dst), 4, 0, 0)

// ------------------------------------------------- zero helper
__global__ void zero_f(float* __restrict__ p, int n){
    int i = blockIdx.x*256 + threadIdx.x;
    if (i<n) p[i]=0.f;
}

// ------------------------------------------------- bool-buffer normalizer (dual)
__device__ void norm_bool_body(const void* __restrict__ src, u8* __restrict__ dst, int n)
{
    __shared__ int fl[4];
    if (threadIdx.x<4) fl[threadIdx.x]=0;
    __syncthreads();
    const u32* wsrc = (const u32*)src;
    const int nw = n/4;
    int any=0, nb=0, hi=0, lo=0;
    for (int i=threadIdx.x;i<nw;i+=blockDim.x){
        u32 v=wsrc[i];
        if (!v) continue;
        any=1;
        #pragma unroll
        for (int b=0;b<4;b++){
            u32 by=(v>>(8*b))&0xffu;
            if (by>1u) nb=1;
            if (by==1u && b!=0) hi=1;
        }
        if ((v&0xffffu)==0x3f80u) lo=1;
    }
    if (any) atomicOr(&fl[0],1);
    if (nb)  atomicOr(&fl[1],1);
    if (hi)  atomicOr(&fl[2],1);
    if (lo)  atomicOr(&fl[3],1);
    __syncthreads();
    int c;
    if (!fl[0]) c=0;
    else if (!fl[1]) c = fl[2] ? 2 : 1;
    else if (fl[3]) c = 3;
    else c = 1;
    for (int i=threadIdx.x;i<n;i+=blockDim.x){
        u8 v;
        if (c==0)      v=0;
        else if (c==1) v = (((const u32*)src)[i]!=0u);
        else if (c==2) v = (((const u8*)src)[i]!=0u);
        else           v = (((const u16*)src)[i]!=0u);
        dst[i]=v;
    }
}
__global__ void norm_bool2(const void* s0, u8* d0, const void* s1, u8* d1, int n)
{
    if (blockIdx.x==0) norm_bool_body(s0,d0,n);
    else               norm_bool_body(s1,d1,n);
}

// ------------------------------------------------- pack per-token metadata
__global__ void pack_meta(const int* __restrict__ node, const int* __restrict__ colx,
                          const int* __restrict__ tbl, const u8* __restrict__ pad,
                          u32* __restrict__ pm, int n)
{
    int i = blockIdx.x*256 + threadIdx.x;
    if (i<n)
        pm[i] = (u32)(node[i]&0xff) | ((u32)(colx[i]&0xff)<<8) | ((u32)(tbl[i]&0xff)<<16) | ((u32)(pad[i]&1)<<24);
}

// ------------------------------------------------- mask table: m4[b][k][q] bit t = mask_t(q,k)
__global__ __launch_bounds__(256) void mask4_kernel(const u32* __restrict__ pm, const int* __restrict__ f2p,
                                                    u8* __restrict__ m4)
{
    const int b = blockIdx.y, kg = blockIdx.x;
    const int t = threadIdx.x;
    __shared__ u32 qm[1024];
    __shared__ int qf[1024*5];
    for (int i=t;i<1024;i+=256) qm[i] = pm[b*SS+i];
    for (int i=t;i<5*1024;i+=256) qf[i] = f2p[b*SS*5 + i];
    __syncthreads();
    const int q0 = t*4;
    u32 qmv[4]; int qn[4]; int qfv[4][5];
    #pragma unroll
    for (int j=0;j<4;j++){
        qmv[j]=qm[q0+j]; qn[j]=(int)(qmv[j]&0xffu);
        #pragma unroll
        for (int f=0;f<5;f++) qfv[j][f]=qf[(q0+j)*5+f];
    }
    for (int kk=0;kk<16;kk++){
        const int k = kg*16+kk;
        const u32 km = qm[k];
        const int kn = (int)(km&0xffu);
        u32 outw=0;
        #pragma unroll
        for (int j=0;j<4;j++){
            const u32 qmw = qmv[j];
            const bool pv = (((qmw|km)>>24)&1u)==0u;
            u32 by=0;
            if ((((qmw^km)&0x00ffff00u)==0u) && pv) by|=1;
            if ((((qmw^km)&0xffu)==0u) && pv) by|=2;
            bool nei = (qfv[j][0]==kn)||(qfv[j][1]==kn)||(qfv[j][2]==kn)||(qfv[j][3]==kn)||(qfv[j][4]==kn)
                       ||(qn[j]==kn);
            if (nei && pv) by|=4;
            if (pv) by|=8;
            if ((q0+j)==k) by=15;
            outw |= by<<(8*j);
        }
        ((u32*)(m4 + ((size_t)b<<20) + ((size_t)k<<10)))[t] = outw;
    }
}

// ------------------------------------------------- weight f32 [K][N] -> tiled bf16 (+gamma fold)
__global__ __launch_bounds__(256) void transpose_cvt2(const float* __restrict__ src, u16* __restrict__ dst,
                                                      int K, int N, size_t dz,
                                                      const float* __restrict__ gbase, int gmode)
{
    const int z = blockIdx.z;
    src += (size_t)z*K*N;
    dst += (size_t)z*dz;
    const float* g = nullptr;
    if (gmode==1){ int m = z&3; if (m<3) g = gbase + (size_t)((z>>4)*5 + ((z>>2)&3))*768; }
    else if (gmode==2){ g = gbase + (size_t)z*5*768; }
    const int n0 = blockIdx.x*32, k0 = blockIdx.y*64;
    __shared__ float t[64][33];
    const int tid = threadIdx.x;
    const int kr = tid>>3, n4 = (tid&7)*4;
    #pragma unroll
    for (int p=0;p<2;p++){
        const int k = p*32 + kr;
        float gk = g ? g[k0+k] : 1.f;
        float4 v = *(const float4*)(src + (size_t)(k0+k)*N + n0 + n4);
        t[k][n4]=v.x*gk; t[k][n4+1]=v.y*gk; t[k][n4+2]=v.z*gk; t[k][n4+3]=v.w*gk;
    }
    __syncthreads();
    const int n = tid>>3, ks = (tid&7)*8;
    const int ng = n0 + n;
    uint4 o;
    u32* op = (u32*)&o;
    #pragma unroll
    for (int i=0;i<4;i++)
        op[i] = pk2(t[ks+2*i][n], t[ks+2*i+1][n]);
    *(uint4*)&dst[(((size_t)(ng>>7)*(K>>6) + (k0>>6))<<13) + ((ng&127)<<6) + ks] = o;
}

// ------------------------------------------------- activation f32 [M][K] -> tiled bf16 (dual src)
__global__ __launch_bounds__(256) void cvt_tiled2(const float* __restrict__ s0, u16* __restrict__ d0,
                                                  const float* __restrict__ s1, u16* __restrict__ d1, int K)
{
    const float* src = blockIdx.y ? s1 : s0;
    u16* dst = blockIdx.y ? d1 : d0;
    const int gid = blockIdx.x*256 + threadIdx.x;
    const int base = gid*8;
    const int row = base / K, col = base - row*K;
    float4 a = *(const float4*)(src + base);
    float4 b = *(const float4*)(src + base + 4);
    uint4 o;
    o.x = pk2(a.x,a.y); o.y = pk2(a.z,a.w);
    o.z = pk2(b.x,b.y); o.w = pk2(b.z,b.w);
    *(uint4*)&dst[(((size_t)(row>>7)*(K>>6) + (col>>6))<<13) + ((row&127)<<6) + (col&63)] = o;
}

// ------------------------------------------------- BM=128 GEMM (qkv): 3-buf, 1-ahead, 1 barrier/step
__device__ __forceinline__ void stage3(const u16* aT, const u16* bT, int cb, int brow,
                                       u16* la, u16* lb, int w, int l)
{
    #pragma unroll
    for (int p=0;p<2;p++){
        const int q = p*256 + w*64 + l;
        const int row = q>>2, u = q&3;
        const int so = row*64 + cb + (((u ^ ((row>>1)&3))&3)<<3);
        GLDS(aT+so, la + p*2048 + w*512);
    }
    {
        const int q = w*64 + l;
        const int row = q>>2, u = q&3;
        const int so = (brow+row)*64 + cb + (((u ^ ((row>>1)&3))&3)<<3);
        GLDS(bT+so, lb + w*512);
    }
}

__global__ __launch_bounds__(256,4) void gemm_t(
    const u16* __restrict__ At, const u16* __restrict__ Bt,
    int K, int AMS, u16* __restrict__ qk16, u16* __restrict__ vt16,
    const float* __restrict__ rs_in)
{
    __shared__ u16 lds[3][6144];
    const int tid = threadIdx.x;
    const int lane = tid & 63, w = tid >> 6;
    const int cg = lane >> 4, cl = lane & 15;
    const int NT = K >> 5;
    const int n0 = blockIdx.x*64;
    const int brow = n0 & 64;
    const size_t bNb = (size_t)(n0>>7)*(K>>6);

    const u16* aB = At + ((size_t)blockIdx.y * AMS << 13);
    const u16* bB = Bt + (bNb << 13);

    f32x4 acc[2][4];
    #pragma unroll
    for (int i=0;i<2;i++)
        #pragma unroll
        for (int j=0;j<4;j++) acc[i][j] = (f32x4){0.f,0.f,0.f,0.f};

    stage3(aB, bB, 0, brow, &lds[0][0], &lds[0][4096], w, lane);   // tile 0

    for (int kt=0; kt<NT; kt++){
        const int buf = kt % 3;
        if (kt+1 < NT){
            const int k1 = kt+1;
            stage3(aB + ((size_t)(k1>>1)<<13), bB + ((size_t)(k1>>1)<<13),
                   (k1&1)<<5, brow, &lds[k1%3][0], &lds[k1%3][4096], w, lane);
            asm volatile("s_waitcnt vmcnt(3)" ::: "memory");
        } else {
            asm volatile("s_waitcnt vmcnt(0)" ::: "memory");
        }
        SBAR(); __builtin_amdgcn_s_barrier(); SBAR();
        s16x8 af[2], bf[4];
        #pragma unroll
        for (int mt=0;mt<2;mt++){
            const int ra = w*32 + mt*16 + cl;
            af[mt] = *(const s16x8*)&lds[buf][ra*32 + (((cg ^ ((ra>>1)&3))&3)<<3)];
        }
        #pragma unroll
        for (int nt=0;nt<4;nt++){
            const int rb = nt*16 + cl;
            bf[nt] = *(const s16x8*)&lds[buf][4096 + rb*32 + (((cg ^ ((rb>>1)&3))&3)<<3)];
        }
        #pragma unroll
        for (int mt=0;mt<2;mt++)
            #pragma unroll
            for (int nt=0;nt<4;nt++)
                acc[mt][nt] = __builtin_amdgcn_mfma_f32_16x16x32_bf16(af[mt], bf[nt], acc[mt][nt], 0,0,0);
    }

    const int m0 = blockIdx.y*128;
    #pragma unroll
    for (int mt=0;mt<2;mt++){
        const int grow0 = m0 + w*32 + mt*16 + cg*4;
        float rr[4];
        #pragma unroll
        for (int j=0;j<4;j++) rr[j] = rsqrtf(rs_in[grow0+j]*(1.f/768.f) + EPSF);
        #pragma unroll
        for (int nt=0;nt<4;nt++){
            const int col = n0 + nt*16 + cl;
            if (col < 768){
                #pragma unroll
                for (int j=0;j<4;j++)
                    qk16[(size_t)(grow0+j)*1536 + col] = f2bu(acc[mt][nt][j]*rr[j]*QSC);
            } else if (col < 1536){
                #pragma unroll
                for (int j=0;j<4;j++)
                    qk16[(size_t)(grow0+j)*1536 + col] = f2bu(acc[mt][nt][j]*rr[j]);
            } else {
                const int b = grow0>>10, s0 = grow0&1023;
                const int dhg = col - 1536;
                uint2 o;
                o.x = pk2(acc[mt][nt][0]*rr[0], acc[mt][nt][1]*rr[1]);
                o.y = pk2(acc[mt][nt][2]*rr[2], acc[mt][nt][3]*rr[3]);
                *(uint2*)(vt16 + ((size_t)(b*768 + dhg)<<10) + s0) = o;
            }
        }
    }
}

// ------------------------------------------------- fused gate-up-silu GEMM: 3-buf, 1-ahead, 1 barrier
__global__ __launch_bounds__(256,3) void gemm_gu(
    const u16* __restrict__ At, const u16* __restrict__ Bg, const u16* __restrict__ Bu,
    const float* __restrict__ rs_in, u16* __restrict__ o16)
{
    __shared__ u16 lds[3][8192];
    const int tid = threadIdx.x;
    const int lane = tid & 63, w = tid >> 6;
    const int cg = lane >> 4, cl = lane & 15;
    const int NT = 24;
    const int n0 = blockIdx.x*64;
    const int brow = n0 & 64;
    const size_t bNb = (size_t)(n0>>7)*12;

    const u16* aB = At + ((size_t)blockIdx.y * 12 << 13);
    const u16* gB = Bg + (bNb << 13);
    const u16* uB = Bu + (bNb << 13);

    f32x4 accg[2][4], accu[2][4];
    #pragma unroll
    for (int i=0;i<2;i++)
        #pragma unroll
        for (int j=0;j<4;j++){ accg[i][j] = (f32x4){0.f,0.f,0.f,0.f}; accu[i][j] = (f32x4){0.f,0.f,0.f,0.f}; }

    #define STAGE_GU(kt2, cb, buf) { \
        const u16* a_ = aB + ((size_t)(kt2)<<13); \
        const u16* g_ = gB + ((size_t)(kt2)<<13); \
        const u16* u_ = uB + ((size_t)(kt2)<<13); \
        _Pragma("unroll") \
        for (int p=0;p<2;p++){ \
            const int q = p*256 + w*64 + lane; \
            const int row = q>>2, uu = q&3; \
            const int so = row*64 + (cb) + (((uu ^ ((row>>1)&3))&3)<<3); \
            GLDS(a_+so, &lds[buf][0] + p*2048 + w*512); \
        } \
        { \
            const int q = w*64 + lane; \
            const int row = q>>2, uu = q&3; \
            const int so = (brow+row)*64 + (cb) + (((uu ^ ((row>>1)&3))&3)<<3); \
            GLDS(g_+so, &lds[buf][4096] + w*512); \
            GLDS(u_+so, &lds[buf][6144] + w*512); \
        } }

    STAGE_GU(0, 0, 0);

    for (int kt=0; kt<NT; kt++){
        const int buf = kt % 3;
        if (kt+1 < NT){
            const int k1 = kt+1;
            STAGE_GU(k1>>1, (k1&1)<<5, k1%3);
            asm volatile("s_waitcnt vmcnt(4)" ::: "memory");
        } else {
            asm volatile("s_waitcnt vmcnt(0)" ::: "memory");
        }
        SBAR(); __builtin_amdgcn_s_barrier(); SBAR();
        s16x8 af[2], bg[4], bu[4];
        #pragma unroll
        for (int mt=0;mt<2;mt++){
            const int ra = w*32 + mt*16 + cl;
            af[mt] = *(const s16x8*)&lds[buf][ra*32 + (((cg ^ ((ra>>1)&3))&3)<<3)];
        }
        #pragma unroll
        for (int nt=0;nt<4;nt++){
            const int rb = nt*16 + cl;
            const int sw = (((cg ^ ((rb>>1)&3))&3)<<3);
            bg[nt] = *(const s16x8*)&lds[buf][4096 + rb*32 + sw];
            bu[nt] = *(const s16x8*)&lds[buf][6144 + rb*32 + sw];
        }
        #pragma unroll
        for (int mt=0;mt<2;mt++)
            #pragma unroll
            for (int nt=0;nt<4;nt++){
                accg[mt][nt] = __builtin_amdgcn_mfma_f32_16x16x32_bf16(af[mt], bg[nt], accg[mt][nt], 0,0,0);
                accu[mt][nt] = __builtin_amdgcn_mfma_f32_16x16x32_bf16(af[mt], bu[nt], accu[mt][nt], 0,0,0);
            }
    }

    const int m0 = blockIdx.y*128;
    #pragma unroll
    for (int mt=0;mt<2;mt++){
        const int grow0 = m0 + w*32 + mt*16 + cg*4;
        float rr[4];
        #pragma unroll
        for (int j=0;j<4;j++) rr[j] = rsqrtf(rs_in[grow0+j]*(1.f/768.f) + EPSF);
        #pragma unroll
        for (int nt=0;nt<4;nt++){
            const int col = n0 + nt*16 + cl;
            const size_t tb = (((size_t)(grow0>>7)*48 + (col>>6))<<13) + (col&63);
            #pragma unroll
            for (int j=0;j<4;j++){
                float g = accg[mt][nt][j]*rr[j];
                float u = accu[mt][nt][j]*rr[j];
                float s = g/(1.f+__expf(-g))*u;
                o16[tb + (((grow0+j)&127)<<6)] = f2bu(s);
            }
        }
    }
}

// ------------------------------------------------- BM=64 GEMM: 3-buf, 1-ahead, 1 barrier/step
__device__ __forceinline__ void stage64(const u16* aT, int arow, const u16* bT, int brow, int cb,
                                        u16* la, u16* lb, int w, int l)
{
    const int q = w*64 + l;
    const int row = q>>2, u = q&3;
    const int sw = (((u ^ ((row>>1)&3))&3)<<3);
    GLDS(aT + (arow+row)*64 + cb + sw, la + w*512);
    GLDS(bT + (brow+row)*64 + cb + sw, lb + w*512);
}

__global__ __launch_bounds__(256,6) void gemm_t64(
    const u16* __restrict__ At, const u16* __restrict__ Bt, float* __restrict__ C,
    int N, int K, int AMS, int flags, const float* __restrict__ bias,
    u16* __restrict__ o16, float* __restrict__ rs_out)
{
    __shared__ u16 lds[3][4096];
    const int tid = threadIdx.x;
    const int lane = tid & 63, w = tid >> 6;
    const int cg = lane >> 4, cl = lane & 15;
    const int NT = K >> 5;
    const int n0 = blockIdx.x*64;
    const int m0 = blockIdx.y*64;
    const int brow = n0 & 64, arow = m0 & 64;

    const u16* aB = At + ((size_t)(m0>>7) * AMS << 13);
    const u16* bB = Bt + ((size_t)(n0>>7) * (K>>6) << 13);

    f32x4 acc[4];
    #pragma unroll
    for (int j=0;j<4;j++) acc[j] = (f32x4){0.f,0.f,0.f,0.f};

    stage64(aB, arow, bB, brow, 0, &lds[0][0], &lds[0][2048], w, lane);

    for (int kt=0; kt<NT; kt++){
        const int buf = kt % 3;
        if (kt+1 < NT){
            const int k1 = kt+1;
            stage64(aB + ((size_t)(k1>>1)<<13), arow, bB + ((size_t)(k1>>1)<<13), brow,
                    (k1&1)<<5, &lds[k1%3][0], &lds[k1%3][2048], w, lane);
            asm volatile("s_waitcnt vmcnt(2)" ::: "memory");
        } else {
            asm volatile("s_waitcnt vmcnt(0)" ::: "memory");
        }
        SBAR(); __builtin_amdgcn_s_barrier(); SBAR();
        const int ra = w*16 + cl;
        s16x8 af = *(const s16x8*)&lds[buf][ra*32 + (((cg ^ ((ra>>1)&3))&3)<<3)];
        s16x8 bf[4];
        #pragma unroll
        for (int nt=0;nt<4;nt++){
            const int rb = nt*16 + cl;
            bf[nt] = *(const s16x8*)&lds[buf][2048 + rb*32 + (((cg ^ ((rb>>1)&3))&3)<<3)];
        }
        #pragma unroll
        for (int nt=0;nt<4;nt++)
            acc[nt] = __builtin_amdgcn_mfma_f32_16x16x32_bf16(af, bf[nt], acc[nt], 0,0,0);
    }

    const int grow0 = m0 + w*16 + cg*4;
    const bool do_acc = (flags&1), do_bias = (flags&2);
    float tmp[4][4];
    #pragma unroll
    for (int nt=0;nt<4;nt++){
        const int col = n0 + nt*16 + cl;
        float bv = do_bias ? bias[col] : 0.f;
        #pragma unroll
        for (int j=0;j<4;j++){
            float v = acc[nt][j] + bv;
            float* cp = C + (size_t)(grow0+j)*N + col;
            if (do_acc) v += *cp;
            *cp = v;
            tmp[nt][j] = v;
        }
    }
    if (o16){
        #pragma unroll
        for (int nt=0;nt<4;nt++){
            const int col = n0 + nt*16 + cl;
            const size_t tb = (((size_t)(grow0>>7)*12 + (col>>6))<<13) + (col&63);
            #pragma unroll
            for (int j=0;j<4;j++)
                o16[tb + (((grow0+j)&127)<<6)] = f2bu(tmp[nt][j]);
        }
    }
    if (rs_out){
        #pragma unroll
        for (int j=0;j<4;j++){
            float s = tmp[0][j]*tmp[0][j] + tmp[1][j]*tmp[1][j]
                    + tmp[2][j]*tmp[2][j] + tmp[3][j]*tmp[3][j];
            s = rsum16(s);
            if (cl==0) atomicAdd(rs_out + grow0 + j, s);
        }
    }
}

// ------------------------------------------------- MFMA flash attention (Q in regs; 48KB LDS)
__global__ __launch_bounds__(256,3) void attn_mfma3(
    const u16* __restrict__ qk16, const u16* __restrict__ vt16,
    const u8* __restrict__ m4, int mt,
    u16* __restrict__ ob16)
{
    const int bh = blockIdx.y;
    const int b = bh / NH, h = bh % NH;
    const int q0 = blockIdx.x * 64;
    const int tid = threadIdx.x;
    const int w = tid>>6, lane = tid&63, cg = lane>>4, cl = lane&15;
    const int srow = lane>>3;
    const int sseg = (lane&7) ^ srow;
    const int mk = lane>>4, mq = lane&15;

    __shared__ u16 Ks[2][4096], Vt[2][4096], Ps[4096];
    __shared__ u32 Ms[2][1024];

    // Q fragments -> registers (BEFORE any GLDS; fence so compiler's waitcnt lands here)
    s16x8 qa0, qa1;
    {
        const u16* qrow = qk16 + (size_t)(b*SS+q0 + w*16 + cl)*1536 + h*64;
        qa0 = *(const s16x8*)(qrow + cg*8);
        qa1 = *(const s16x8*)(qrow + 32 + cg*8);
        asm volatile("" :: "v"(*(const f32x4*)&qa0), "v"(*(const f32x4*)&qa1));
    }

    const u16* kbase = qk16 + (size_t)(b*SS)*1536 + 768 + h*64;
    const u16* vbase = vt16 + ((size_t)(b*768 + h*64)<<10);
    const u8*  mbase = m4 + ((size_t)b<<20) + q0;

    #pragma unroll
    for (int p=0;p<2;p++){
        const int row = p*32 + w*8 + srow;
        GLDS(kbase + (size_t)row*1536 + sseg*8, Ks[0] + p*2048 + w*512);
        GLDS(vbase + ((size_t)row<<10) + sseg*8, Vt[0] + p*2048 + w*512);
    }
    #pragma unroll
    for (int i=0;i<4;i++){
        const int key = w*16 + i*4 + mk;
        GLDS4(mbase + ((size_t)key<<10) + mq*4, (u8*)Ms[0] + w*1024 + i*256);
    }

    f32x4 o[4];
    #pragma unroll
    for (int nt=0;nt<4;nt++) o[nt] = (f32x4){0.f,0.f,0.f,0.f};
    float lsum[4] = {0.f,0.f,0.f,0.f};

    for (int kc=0;kc<16;kc++){
        const int buf = kc & 1;
        if (kc < 15){
            const int kn0 = kc*64 + 64;
            #pragma unroll
            for (int p=0;p<2;p++){
                const int row = p*32 + w*8 + srow;
                GLDS(kbase + (size_t)(kn0+row)*1536 + sseg*8, Ks[buf^1] + p*2048 + w*512);
                GLDS(vbase + ((size_t)row<<10) + kn0 + sseg*8, Vt[buf^1] + p*2048 + w*512);
            }
            #pragma unroll
            for (int i=0;i<4;i++){
                const int key = kn0 + w*16 + i*4 + mk;
                GLDS4(mbase + ((size_t)key<<10) + mq*4, (u8*)Ms[buf^1] + w*1024 + i*256);
            }
            asm volatile("s_waitcnt vmcnt(8)" ::: "memory");
        } else {
            asm volatile("s_waitcnt vmcnt(0)" ::: "memory");
        }
        SBAR(); __builtin_amdgcn_s_barrier(); SBAR();

        // QK^T (q already scaled by 0.125*log2e)
        f32x4 sc[4];
        #pragma unroll
        for (int nt=0;nt<4;nt++) sc[nt] = (f32x4){0.f,0.f,0.f,0.f};
        __builtin_amdgcn_s_setprio(1);
        #pragma unroll
        for (int nt=0;nt<4;nt++){
            s16x8 kb0 = *(const s16x8*)&Ks[buf][swz(nt*16+cl, cg*8)];
            sc[nt] = __builtin_amdgcn_mfma_f32_16x16x32_bf16(qa0, kb0, sc[nt], 0,0,0);
        }
        #pragma unroll
        for (int nt=0;nt<4;nt++){
            s16x8 kb1 = *(const s16x8*)&Ks[buf][swz(nt*16+cl, 32+cg*8)];
            sc[nt] = __builtin_amdgcn_mfma_f32_16x16x32_bf16(qa1, kb1, sc[nt], 0,0,0);
        }
        __builtin_amdgcn_s_setprio(0);

        // mask + exp2 (max-free)
        float pP[4][4];
        #pragma unroll
        for (int nt=0;nt<4;nt++){
            const u32 w4 = Ms[buf][(nt*16+cl)*16 + w*4 + cg];
            #pragma unroll
            for (int j=0;j<4;j++){
                float pe = exp2f(fminf(sc[nt][j], 100.f));
                pe = ((w4 >> (8*j + mt)) & 1u) ? pe : 0.f;
                pP[nt][j] = pe;
                lsum[j] += pe;
            }
        }

        #pragma unroll
        for (int nt=0;nt<4;nt++)
            #pragma unroll
            for (int j=0;j<4;j++)
                Ps[swz(w*16+cg*4+j, nt*16+cl)] = f2bu(pP[nt][j]);

        // PV
        __builtin_amdgcn_s_setprio(1);
        #pragma unroll
        for (int ks=0;ks<2;ks++){
            s16x8 pa = *(const s16x8*)&Ps[swz(w*16+cl, ks*32+cg*8)];
            #pragma unroll
            for (int nt=0;nt<4;nt++){
                s16x8 vb = *(const s16x8*)&Vt[buf][swz(nt*16+cl, ks*32+cg*8)];
                o[nt] = __builtin_amdgcn_mfma_f32_16x16x32_bf16(pa, vb, o[nt], 0,0,0);
            }
        }
        __builtin_amdgcn_s_setprio(0);
        SBAR(); __builtin_amdgcn_s_barrier(); SBAR();
    }

    #pragma unroll
    for (int j=0;j<4;j++){
        const float inv = 1.f/rsum16(lsum[j]);
        const int row = b*SS + q0 + w*16 + cg*4 + j;
        const size_t rb = ((size_t)(row>>7)*12 + h)*8192 + ((row&127)<<6);
        #pragma unroll
        for (int nt=0;nt<4;nt++)
            ob16[rb + nt*16 + cl] = f2bu(o[nt][j]*inv);
    }
}

// ------------------------------------------------- encode fuse
__global__ __launch_bounds__(256) void fuse_encode(
    const float* __restrict__ cnbuf, const float* __restrict__ textbuf,
    const float* __restrict__ numv, const float* __restrict__ dtv, const float* __restrict__ boolv,
    const float* __restrict__ Wnum, const float* __restrict__ bnum,
    const float* __restrict__ Wdt, const float* __restrict__ bdt,
    const float* __restrict__ Wbool, const float* __restrict__ bbool,
    const float* __restrict__ gcn, const float* __restrict__ gnum, const float* __restrict__ gtext,
    const float* __restrict__ gdt, const float* __restrict__ gbool,
    const float* __restrict__ memb, const int* __restrict__ stypes, const u8* __restrict__ masks,
    float* __restrict__ x, u16* __restrict__ xt16, float* __restrict__ rs0)
{
    const int row = blockIdx.x;
    const int t = threadIdx.x;
    __shared__ float red[256];

    float cn3[3]; float ss=0.f;
    #pragma unroll
    for (int j=0;j<3;j++){
        cn3[j] = cnbuf[(size_t)row*DM + t + j*256];
        ss += cn3[j]*cn3[j];
    }
    red[t]=ss; __syncthreads();
    for (int s=128;s>0;s>>=1){ if(t<s) red[t]+=red[t+s]; __syncthreads(); }
    {
        float r = rsqrtf(red[0]/(float)DM + EPSF);
        #pragma unroll
        for (int j=0;j<3;j++) cn3[j] *= r*gcn[t+j*256];
    }
    __syncthreads();

    const int st = stypes[row];
    float val[3]; ss=0.f;
    if (st==1){
        #pragma unroll
        for (int j=0;j<3;j++){
            val[j] = textbuf[(size_t)row*DM + t + j*256];
            ss += val[j]*val[j];
        }
    } else {
        const float* Wp = (st==0)?Wnum:((st==2)?Wdt:Wbool);
        const float* bp = (st==0)?bnum:((st==2)?bdt:bbool);
        const float* vp = (st==0)?numv:((st==2)?dtv:boolv);
        float v = vp[row];
        #pragma unroll
        for (int j=0;j<3;j++){
            int e=t+j*256;
            val[j] = v*Wp[e] + bp[e];
            ss += val[j]*val[j];
        }
    }
    red[t]=ss; __syncthreads();
    for (int s=128;s>0;s>>=1){ if(t<s) red[t]+=red[t+s]; __syncthreads(); }
    const float* gp = (st==0)?gnum:((st==1)?gtext:((st==2)?gdt:gbool));
    float r2 = rsqrtf(red[0]/(float)DM + EPSF);
    bool mk = masks[row]!=0;
    float xv[3]; float sx=0.f;
    #pragma unroll
    for (int j=0;j<3;j++){
        int e=t+j*256;
        float vv = val[j]*r2*gp[e];
        if (mk) vv = memb[st*DM+e];
        xv[j] = vv + cn3[j];
        x[(size_t)row*DM+e] = xv[j];
        sx += xv[j]*xv[j];
    }
    __syncthreads();
    red[t]=sx; __syncthreads();
    for (int s=128;s>0;s>>=1){ if(t<s) red[t]+=red[t+s]; __syncthreads(); }
    if (t==0) rs0[row] = red[0];
    const size_t mb = (size_t)(row>>7)*12;
    const int rr = (row&127)<<6;
    #pragma unroll
    for (int j=0;j<3;j++){
        const int c = t + j*256;
        xt16[((mb + (c>>6))<<13) + rr + (c&63)] = f2bu(xv[j]);
    }
}

// ------------------------------------------------- final rms + 3 scalar heads; h -> tiled bf16
__global__ __launch_bounds__(256) void decode2(
    const float* __restrict__ x, const float* __restrict__ gout,
    const float* __restrict__ Wn, const float* __restrict__ bn,
    const float* __restrict__ Wd, const float* __restrict__ bd,
    const float* __restrict__ Wb, const float* __restrict__ bb,
    float* __restrict__ out, u16* __restrict__ h16)
{
    const int row = blockIdx.x;
    const int t = threadIdx.x;
    __shared__ float h[DM];
    __shared__ float red[256];
    const float* xr = x + (size_t)row*DM;
    float v0=xr[t], v1=xr[t+256], v2=xr[t+512];
    red[t]=v0*v0+v1*v1+v2*v2; __syncthreads();
    for (int s=128;s>0;s>>=1){ if(t<s) red[t]+=red[t+s]; __syncthreads(); }
    float r = rsqrtf(red[0]/(float)DM + EPSF);
    float h0 = v0*r*gout[t], h1 = v1*r*gout[t+256], h2 = v2*r*gout[t+512];
    h[t]=h0; h[t+256]=h1; h[t+512]=h2;
    const size_t mb = (size_t)(row>>7)*12;
    const int rr = (row&127)<<6;
    #pragma unroll
    for (int j=0;j<3;j++){
        const int c = t + j*256;
        const float v = (j==0?h0:(j==1?h1:h2));
        h16[((mb + (c>>6))<<13) + rr + (c&63)] = f2bu(v);
    }
    __syncthreads();

    float pn=0.f,pd=0.f,pb=0.f;
    for (int k=t;k<DM;k+=256){ float hv=h[k]; pn+=hv*Wn[k]; pd+=hv*Wd[k]; pb+=hv*Wb[k]; }
    red[t]=pn; __syncthreads();
    for (int s=128;s>0;s>>=1){ if(t<s) red[t]+=red[t+s]; __syncthreads(); }
    float tn=red[0]; __syncthreads();
    red[t]=pd; __syncthreads();
    for (int s=128;s>0;s>>=1){ if(t<s) red[t]+=red[t+s]; __syncthreads(); }
    float td=red[0]; __syncthreads();
    red[t]=pb; __syncthreads();
    for (int s=128;s>0;s>>=1){ if(t<s) red[t]+=red[t+s]; __syncthreads(); }
    float tb=red[0];
    if (t==0){
        out[row]          = tn + bn[0];
        out[NROW + row]   = td + bd[0];
        out[2*NROW + row] = tb + bb[0];
    }
}

// ---------------------------------------------------------------- launcher
extern "C" void kernel_launch(void* const* d_in, const int* in_sizes, int n_in,
                              void* d_out, int out_size, void* d_ws, size_t ws_size,
                              hipStream_t stream)
{
    const float* numv   = (const float*)d_in[0];
    const float* dtval  = (const float*)d_in[1];
    const float* boolv  = (const float*)d_in[2];
    const float* textv  = (const float*)d_in[3];
    const float* cnamev = (const float*)d_in[4];
    const float* Wcn=(const float*)d_in[5];  const float* bcn=(const float*)d_in[6];
    const float* Wnum=(const float*)d_in[7]; const float* bnum=(const float*)d_in[8];
    const float* Wtext=(const float*)d_in[9];const float* btext=(const float*)d_in[10];
    const float* Wdt=(const float*)d_in[11]; const float* bdt=(const float*)d_in[12];
    const float* Wbool=(const float*)d_in[13];const float* bbool=(const float*)d_in[14];
    const float* gcn=(const float*)d_in[15]; const float* gnum=(const float*)d_in[16];
    const float* gtext=(const float*)d_in[17];const float* gdt=(const float*)d_in[18];
    const float* gbool=(const float*)d_in[19];
    const float* memb=(const float*)d_in[20];
    const float* norms_all=(const float*)d_in[21];
    const float* attw_all=(const float*)d_in[22];
    const float* up_all=(const float*)d_in[23];
    const float* gate_all=(const float*)d_in[24];
    const float* down_all=(const float*)d_in[25];
    const float* gout=(const float*)d_in[26];
    const float* Wdn=(const float*)d_in[27]; const float* bdn=(const float*)d_in[28];
    const float* Wdd=(const float*)d_in[29]; const float* bdd=(const float*)d_in[30];
    const float* Wdb=(const float*)d_in[31]; const float* bdb=(const float*)d_in[32];
    const float* Wdtx=(const float*)d_in[33];const float* bdtx=(const float*)d_in[34];
    const int* node=(const int*)d_in[35];
    const int* tbl =(const int*)d_in[36];
    const int* colx=(const int*)d_in[37];
    const int* f2p =(const int*)d_in[38];
    const int* styp=(const int*)d_in[39];

    const size_t SA = (size_t)768*768;
    const size_t SG = (size_t)768*3072;
    const size_t SC = (size_t)384*768;
    const size_t NX = (size_t)NROW*DM;

    u8* base = (u8*)d_ws;
    float* x  = (float*)base;
    u16* xt16 = (u16*)(base + 6291456);
    u16* ob16 = (u16*)(base + 9437184);
    u16* qk16 = (u16*)(base + 12582912);
    u16* vt16 = (u16*)(base + 18874368);
    u16* gu16 = (u16*)(base + 22020096);
    u16* wA   = (u16*)(base + 47185920);
    u16* wGU  = wA + 64*SA;
    u16* wD   = wGU + 8*SG;
    u16* wCN  = wD + 4*SG;
    u16* wTX  = wCN + SC;
    u16* wDX  = wTX + SC;
    u8* nmask = (u8*)(wDX + SC);
    u8* npad  = nmask + NROW;
    u32* pmeta = (u32*)(npad + NROW + 64);
    float* rsbuf = (float*)(pmeta + NROW);     // 21 slots x 2048
    u8* m4 = (u8*)(rsbuf + 21*2048);           // 2 MB

    // encode-phase aliases
    u16* cnT16   = qk16;
    u16* textT16 = vt16;
    float* cnbuf   = (float*)gu16;
    float* textbuf = cnbuf + NX;

    float* out = (float*)d_out;

    zero_f<<<(21*2048)/256,256,0,stream>>>(rsbuf, 21*2048);
    norm_bool2<<<2,256,0,stream>>>(d_in[40], nmask, d_in[41], npad, NROW);
    pack_meta<<<NROW/256,256,0,stream>>>(node, colx, tbl, npad, pmeta, NROW);
    mask4_kernel<<<dim3(64,2),256,0,stream>>>(pmeta, f2p, m4);

    // weight prep (tiled bf16; gamma folded)
    transpose_cvt2<<<dim3(24,12,64),256,0,stream>>>(attw_all, wA, 768, 768, SA, norms_all, 1);
    transpose_cvt2<<<dim3(96,12,4),256,0,stream>>>(gate_all, wGU,      768, 3072, 2*SG, norms_all + 4*768, 2);
    transpose_cvt2<<<dim3(96,12,4),256,0,stream>>>(up_all,   wGU + SG, 768, 3072, 2*SG, norms_all + 4*768, 2);
    transpose_cvt2<<<dim3(24,48,4),256,0,stream>>>(down_all, wD, 3072, 768, SG, nullptr, 0);
    transpose_cvt2<<<dim3(24,6,1),256,0,stream>>>(Wcn,   wCN, 384, 768, 0, nullptr, 0);
    transpose_cvt2<<<dim3(24,6,1),256,0,stream>>>(Wtext, wTX, 384, 768, 0, nullptr, 0);
    transpose_cvt2<<<dim3(12,12,1),256,0,stream>>>(Wdtx, wDX, 768, 384, 0, nullptr, 0);

    // encode
    cvt_tiled2<<<dim3(384,2),256,0,stream>>>(cnamev, cnT16, textv, textT16, 384);
    gemm_t64<<<dim3(12,32),256,0,stream>>>(cnT16,   wCN, cnbuf,   768, 384, 6, 2, bcn,   nullptr, nullptr);
    gemm_t64<<<dim3(12,32),256,0,stream>>>(textT16, wTX, textbuf, 768, 384, 6, 2, btext, nullptr, nullptr);
    fuse_encode<<<NROW,256,0,stream>>>(cnbuf, textbuf, numv, dtval, boolv,
        Wnum,bnum,Wdt,bdt,Wbool,bbool, gcn,gnum,gtext,gdt,gbool,
        memb, styp, nmask, x, xt16, rsbuf);

    const dim3 ga(SS/64, BB*NH);
    for (int l=0; l<NL; l++){
        for (int a=0; a<4; a++){
            const int slot = l*5 + a;
            const u16* wqkv = wA + (size_t)((l*4+a)*4)*SA;
            gemm_t<<<dim3(36,16),256,0,stream>>>(xt16, wqkv, 768, 12, qk16, vt16,
                rsbuf + (size_t)slot*2048);
            attn_mfma3<<<ga,256,0,stream>>>(qk16, vt16, m4, a, ob16);
            gemm_t64<<<dim3(12,32),256,0,stream>>>(ob16, wqkv + 3*SA, x, 768, 768, 12, 1, nullptr,
                xt16, rsbuf + (size_t)(slot+1)*2048);
        }
        gemm_gu<<<dim3(48,16),256,0,stream>>>(xt16, wGU + (size_t)l*2*SG, wGU + (size_t)l*2*SG + SG,
            rsbuf + (size_t)(l*5+4)*2048, gu16);
        gemm_t64<<<dim3(12,32),256,0,stream>>>(gu16, wD + (size_t)l*SG, x, 768, 3072, 48, 1, nullptr,
            xt16, rsbuf + (size_t)((l+1)*5)*2048);
    }

    decode2<<<NROW,256,0,stream>>>(x, gout, Wdn,bdn, Wdd,bdd, Wdb,bdb, out, xt16);
    gemm_t64<<<dim3(6,32),256,0,stream>>>(xt16, wDX, out + 3*NROW, 384, 768, 12, 2, bdtx,
        nullptr, nullptr);
}

// Round 14
// 1412.296 us; speedup vs baseline: 7.2879x; 1.0234x over previous
//
#include <hip/hip_runtime.h>
#include <hip/hip_bf16.h>
#include <cmath>
#include <stdint.h>

// Round 14: attention triple-buffered K/V/M with ONE barrier per chunk; bit-plane mask tables
// (512B staged per chunk via one GLDS4/wave); zero_f folded into pack_meta. Rest = r13.

#define BB 2
#define SS 1024
#define DT 384
#define DM 768
#define NH 12
#define DH 64
#define DFF 3072
#define NL 4
#define NROW (BB*SS)
#define EPSF 1e-6f
#define QSC 0.1803368801111244f   // 0.125 * log2(e)

typedef unsigned short u16;
typedef unsigned char u8;
typedef unsigned int u32;
typedef __attribute__((ext_vector_type(8))) short s16x8;
typedef __attribute__((ext_vector_type(4))) float f32x4;

__device__ __forceinline__ u16 f2bu(float f){
    u32 x = __float_as_uint(f);
    u32 r = (x + 0x7fffu + ((x>>16)&1u)) >> 16;   // RNE
    return (u16)r;
}
__device__ __forceinline__ u32 pk2(float lo, float hi){
    return (u32)f2bu(lo) | ((u32)f2bu(hi)<<16);
}
__device__ __forceinline__ int swz(int row, int c){
    return (row<<6) + (((((c>>3) ^ row) & 7))<<3) + (c&7);
}
__device__ __forceinline__ float rsum16(float v){
    v += __shfl_xor(v,1); v += __shfl_xor(v,2);
    v += __shfl_xor(v,4); v += __shfl_xor(v,8);
    return v;
}
#define SBAR() __builtin_amdgcn_sched_barrier(0)
#define GLDS(src,dst) __builtin_amdgcn_global_load_lds((const __attribute__((address_space(1))) u32*)(src), (__attribute__((address_space(3))) u32*)(dst), 16, 0, 0)
#define GLDS4(src,dst) __builtin_amdgcn_global_load_lds((const __attribute__((address_space(1))) u32*)(src), (__attribute__((address_space(3))) u32*)(dst), 4, 0, 0)

// ------------------------------------------------- bool-buffer normalizer (dual)
__device__ void norm_bool_body(const void* __restrict__ src, u8* __restrict__ dst, int n)
{
    __shared__ int fl[4];
    if (threadIdx.x<4) fl[threadIdx.x]=0;
    __syncthreads();
    const u32* wsrc = (const u32*)src;
    const int nw = n/4;
    int any=0, nb=0, hi=0, lo=0;
    for (int i=threadIdx.x;i<nw;i+=blockDim.x){
        u32 v=wsrc[i];
        if (!v) continue;
        any=1;
        #pragma unroll
        for (int b=0;b<4;b++){
            u32 by=(v>>(8*b))&0xffu;
            if (by>1u) nb=1;
            if (by==1u && b!=0) hi=1;
        }
        if ((v&0xffffu)==0x3f80u) lo=1;
    }
    if (any) atomicOr(&fl[0],1);
    if (nb)  atomicOr(&fl[1],1);
    if (hi)  atomicOr(&fl[2],1);
    if (lo)  atomicOr(&fl[3],1);
    __syncthreads();
    int c;
    if (!fl[0]) c=0;
    else if (!fl[1]) c = fl[2] ? 2 : 1;
    else if (fl[3]) c = 3;
    else c = 1;
    for (int i=threadIdx.x;i<n;i+=blockDim.x){
        u8 v;
        if (c==0)      v=0;
        else if (c==1) v = (((const u32*)src)[i]!=0u);
        else if (c==2) v = (((const u8*)src)[i]!=0u);
        else           v = (((const u16*)src)[i]!=0u);
        dst[i]=v;
    }
}
__global__ void norm_bool2(const void* s0, u8* d0, const void* s1, u8* d1, int n)
{
    if (blockIdx.x==0) norm_bool_body(s0,d0,n);
    else               norm_bool_body(s1,d1,n);
}

// ------------------------------------------------- pack per-token metadata + zero rs slots
__global__ void pack_meta(const int* __restrict__ node, const int* __restrict__ colx,
                          const int* __restrict__ tbl, const u8* __restrict__ pad,
                          u32* __restrict__ pm, int n, float* __restrict__ rsz, int nz)
{
    int i = blockIdx.x*256 + threadIdx.x;
    if (i<n)
        pm[i] = (u32)(node[i]&0xff) | ((u32)(colx[i]&0xff)<<8) | ((u32)(tbl[i]&0xff)<<16) | ((u32)(pad[i]&1)<<24);
    for (int z=i; z<nz; z+=gridDim.x*256) rsz[z]=0.f;
}

// ------------------------------------------------- mask table: m4[b][k][q] bit t = mask_t(q,k)
__global__ __launch_bounds__(256) void mask4_kernel(const u32* __restrict__ pm, const int* __restrict__ f2p,
                                                    u8* __restrict__ m4)
{
    const int b = blockIdx.y, kg = blockIdx.x;
    const int t = threadIdx.x;
    __shared__ u32 qm[1024];
    __shared__ int qf[1024*5];
    for (int i=t;i<1024;i+=256) qm[i] = pm[b*SS+i];
    for (int i=t;i<5*1024;i+=256) qf[i] = f2p[b*SS*5 + i];
    __syncthreads();
    const int q0 = t*4;
    u32 qmv[4]; int qn[4]; int qfv[4][5];
    #pragma unroll
    for (int j=0;j<4;j++){
        qmv[j]=qm[q0+j]; qn[j]=(int)(qmv[j]&0xffu);
        #pragma unroll
        for (int f=0;f<5;f++) qfv[j][f]=qf[(q0+j)*5+f];
    }
    for (int kk=0;kk<16;kk++){
        const int k = kg*16+kk;
        const u32 km = qm[k];
        const int kn = (int)(km&0xffu);
        u32 outw=0;
        #pragma unroll
        for (int j=0;j<4;j++){
            const u32 qmw = qmv[j];
            const bool pv = (((qmw|km)>>24)&1u)==0u;
            u32 by=0;
            if ((((qmw^km)&0x00ffff00u)==0u) && pv) by|=1;
            if ((((qmw^km)&0xffu)==0u) && pv) by|=2;
            bool nei = (qfv[j][0]==kn)||(qfv[j][1]==kn)||(qfv[j][2]==kn)||(qfv[j][3]==kn)||(qfv[j][4]==kn)
                       ||(qn[j]==kn);
            if (nei && pv) by|=4;
            if (pv) by|=8;
            if ((q0+j)==k) by=15;
            outw |= by<<(8*j);
        }
        ((u32*)(m4 + ((size_t)b<<20) + ((size_t)k<<10)))[t] = outw;
    }
}

// ------------------------------------------------- repack m4 bytes -> 4 bit-planes
// mbp layout: [(b<<10)+k][512B] = 4 types x 128 q-bytes
__global__ void repack_mask(const u8* __restrict__ m4, u8* __restrict__ mbp)
{
    const int gid = blockIdx.x*256 + threadIdx.x;   // 262144 total
    const int qb = gid & 127;
    const int bk = gid >> 7;
    const u8* src = m4 + ((size_t)bk<<10) + qb*8;
    u32 lo = *(const u32*)src, hi = *(const u32*)(src+4);
    u32 out[4] = {0,0,0,0};
    #pragma unroll
    for (int j=0;j<4;j++){
        u32 b0 = (lo>>(8*j)) & 0xffu;
        u32 b1 = (hi>>(8*j)) & 0xffu;
        #pragma unroll
        for (int tt=0;tt<4;tt++){
            out[tt] |= ((b0>>tt)&1u) << j;
            out[tt] |= ((b1>>tt)&1u) << (j+4);
        }
    }
    u8* dst = mbp + (size_t)bk*512 + qb;
    #pragma unroll
    for (int tt=0;tt<4;tt++) dst[tt*128] = (u8)out[tt];
}

// ------------------------------------------------- weight f32 [K][N] -> tiled bf16 (+gamma fold)
__global__ __launch_bounds__(256) void transpose_cvt2(const float* __restrict__ src, u16* __restrict__ dst,
                                                      int K, int N, size_t dz,
                                                      const float* __restrict__ gbase, int gmode)
{
    const int z = blockIdx.z;
    src += (size_t)z*K*N;
    dst += (size_t)z*dz;
    const float* g = nullptr;
    if (gmode==1){ int m = z&3; if (m<3) g = gbase + (size_t)((z>>4)*5 + ((z>>2)&3))*768; }
    else if (gmode==2){ g = gbase + (size_t)z*5*768; }
    const int n0 = blockIdx.x*32, k0 = blockIdx.y*64;
    __shared__ float t[64][33];
    const int tid = threadIdx.x;
    const int kr = tid>>3, n4 = (tid&7)*4;
    #pragma unroll
    for (int p=0;p<2;p++){
        const int k = p*32 + kr;
        float gk = g ? g[k0+k] : 1.f;
        float4 v = *(const float4*)(src + (size_t)(k0+k)*N + n0 + n4);
        t[k][n4]=v.x*gk; t[k][n4+1]=v.y*gk; t[k][n4+2]=v.z*gk; t[k][n4+3]=v.w*gk;
    }
    __syncthreads();
    const int n = tid>>3, ks = (tid&7)*8;
    const int ng = n0 + n;
    uint4 o;
    u32* op = (u32*)&o;
    #pragma unroll
    for (int i=0;i<4;i++)
        op[i] = pk2(t[ks+2*i][n], t[ks+2*i+1][n]);
    *(uint4*)&dst[(((size_t)(ng>>7)*(K>>6) + (k0>>6))<<13) + ((ng&127)<<6) + ks] = o;
}

// ------------------------------------------------- activation f32 [M][K] -> tiled bf16 (dual src)
__global__ __launch_bounds__(256) void cvt_tiled2(const float* __restrict__ s0, u16* __restrict__ d0,
                                                  const float* __restrict__ s1, u16* __restrict__ d1, int K)
{
    const float* src = blockIdx.y ? s1 : s0;
    u16* dst = blockIdx.y ? d1 : d0;
    const int gid = blockIdx.x*256 + threadIdx.x;
    const int base = gid*8;
    const int row = base / K, col = base - row*K;
    float4 a = *(const float4*)(src + base);
    float4 b = *(const float4*)(src + base + 4);
    uint4 o;
    o.x = pk2(a.x,a.y); o.y = pk2(a.z,a.w);
    o.z = pk2(b.x,b.y); o.w = pk2(b.z,b.w);
    *(uint4*)&dst[(((size_t)(row>>7)*(K>>6) + (col>>6))<<13) + ((row&127)<<6) + (col&63)] = o;
}

// ------------------------------------------------- BM=128 GEMM (qkv): 3-buf, 1-ahead, 1 barrier/step
__device__ __forceinline__ void stage3(const u16* aT, const u16* bT, int cb, int brow,
                                       u16* la, u16* lb, int w, int l)
{
    #pragma unroll
    for (int p=0;p<2;p++){
        const int q = p*256 + w*64 + l;
        const int row = q>>2, u = q&3;
        const int so = row*64 + cb + (((u ^ ((row>>1)&3))&3)<<3);
        GLDS(aT+so, la + p*2048 + w*512);
    }
    {
        const int q = w*64 + l;
        const int row = q>>2, u = q&3;
        const int so = (brow+row)*64 + cb + (((u ^ ((row>>1)&3))&3)<<3);
        GLDS(bT+so, lb + w*512);
    }
}

__global__ __launch_bounds__(256,4) void gemm_t(
    const u16* __restrict__ At, const u16* __restrict__ Bt,
    int K, int AMS, u16* __restrict__ qk16, u16* __restrict__ vt16,
    const float* __restrict__ rs_in)
{
    __shared__ u16 lds[3][6144];
    const int tid = threadIdx.x;
    const int lane = tid & 63, w = tid >> 6;
    const int cg = lane >> 4, cl = lane & 15;
    const int NT = K >> 5;
    const int n0 = blockIdx.x*64;
    const int brow = n0 & 64;
    const size_t bNb = (size_t)(n0>>7)*(K>>6);

    const u16* aB = At + ((size_t)blockIdx.y * AMS << 13);
    const u16* bB = Bt + (bNb << 13);

    f32x4 acc[2][4];
    #pragma unroll
    for (int i=0;i<2;i++)
        #pragma unroll
        for (int j=0;j<4;j++) acc[i][j] = (f32x4){0.f,0.f,0.f,0.f};

    stage3(aB, bB, 0, brow, &lds[0][0], &lds[0][4096], w, lane);

    for (int kt=0; kt<NT; kt++){
        const int buf = kt % 3;
        if (kt+1 < NT){
            const int k1 = kt+1;
            stage3(aB + ((size_t)(k1>>1)<<13), bB + ((size_t)(k1>>1)<<13),
                   (k1&1)<<5, brow, &lds[k1%3][0], &lds[k1%3][4096], w, lane);
            asm volatile("s_waitcnt vmcnt(3)" ::: "memory");
        } else {
            asm volatile("s_waitcnt vmcnt(0)" ::: "memory");
        }
        SBAR(); __builtin_amdgcn_s_barrier(); SBAR();
        s16x8 af[2], bf[4];
        #pragma unroll
        for (int mt=0;mt<2;mt++){
            const int ra = w*32 + mt*16 + cl;
            af[mt] = *(const s16x8*)&lds[buf][ra*32 + (((cg ^ ((ra>>1)&3))&3)<<3)];
        }
        #pragma unroll
        for (int nt=0;nt<4;nt++){
            const int rb = nt*16 + cl;
            bf[nt] = *(const s16x8*)&lds[buf][4096 + rb*32 + (((cg ^ ((rb>>1)&3))&3)<<3)];
        }
        #pragma unroll
        for (int mt=0;mt<2;mt++)
            #pragma unroll
            for (int nt=0;nt<4;nt++)
                acc[mt][nt] = __builtin_amdgcn_mfma_f32_16x16x32_bf16(af[mt], bf[nt], acc[mt][nt], 0,0,0);
    }

    const int m0 = blockIdx.y*128;
    #pragma unroll
    for (int mt=0;mt<2;mt++){
        const int grow0 = m0 + w*32 + mt*16 + cg*4;
        float rr[4];
        #pragma unroll
        for (int j=0;j<4;j++) rr[j] = rsqrtf(rs_in[grow0+j]*(1.f/768.f) + EPSF);
        #pragma unroll
        for (int nt=0;nt<4;nt++){
            const int col = n0 + nt*16 + cl;
            if (col < 768){
                #pragma unroll
                for (int j=0;j<4;j++)
                    qk16[(size_t)(grow0+j)*1536 + col] = f2bu(acc[mt][nt][j]*rr[j]*QSC);
            } else if (col < 1536){
                #pragma unroll
                for (int j=0;j<4;j++)
                    qk16[(size_t)(grow0+j)*1536 + col] = f2bu(acc[mt][nt][j]*rr[j]);
            } else {
                const int b = grow0>>10, s0 = grow0&1023;
                const int dhg = col - 1536;
                uint2 o;
                o.x = pk2(acc[mt][nt][0]*rr[0], acc[mt][nt][1]*rr[1]);
                o.y = pk2(acc[mt][nt][2]*rr[2], acc[mt][nt][3]*rr[3]);
                *(uint2*)(vt16 + ((size_t)(b*768 + dhg)<<10) + s0) = o;
            }
        }
    }
}

// ------------------------------------------------- fused gate-up-silu GEMM: 3-buf, 1-ahead, 1 barrier
__global__ __launch_bounds__(256,3) void gemm_gu(
    const u16* __restrict__ At, const u16* __restrict__ Bg, const u16* __restrict__ Bu,
    const float* __restrict__ rs_in, u16* __restrict__ o16)
{
    __shared__ u16 lds[3][8192];
    const int tid = threadIdx.x;
    const int lane = tid & 63, w = tid >> 6;
    const int cg = lane >> 4, cl = lane & 15;
    const int NT = 24;
    const int n0 = blockIdx.x*64;
    const int brow = n0 & 64;
    const size_t bNb = (size_t)(n0>>7)*12;

    const u16* aB = At + ((size_t)blockIdx.y * 12 << 13);
    const u16* gB = Bg + (bNb << 13);
    const u16* uB = Bu + (bNb << 13);

    f32x4 accg[2][4], accu[2][4];
    #pragma unroll
    for (int i=0;i<2;i++)
        #pragma unroll
        for (int j=0;j<4;j++){ accg[i][j] = (f32x4){0.f,0.f,0.f,0.f}; accu[i][j] = (f32x4){0.f,0.f,0.f,0.f}; }

    #define STAGE_GU(kt2, cb, buf) { \
        const u16* a_ = aB + ((size_t)(kt2)<<13); \
        const u16* g_ = gB + ((size_t)(kt2)<<13); \
        const u16* u_ = uB + ((size_t)(kt2)<<13); \
        _Pragma("unroll") \
        for (int p=0;p<2;p++){ \
            const int q = p*256 + w*64 + lane; \
            const int row = q>>2, uu = q&3; \
            const int so = row*64 + (cb) + (((uu ^ ((row>>1)&3))&3)<<3); \
            GLDS(a_+so, &lds[buf][0] + p*2048 + w*512); \
        } \
        { \
            const int q = w*64 + lane; \
            const int row = q>>2, uu = q&3; \
            const int so = (brow+row)*64 + (cb) + (((uu ^ ((row>>1)&3))&3)<<3); \
            GLDS(g_+so, &lds[buf][4096] + w*512); \
            GLDS(u_+so, &lds[buf][6144] + w*512); \
        } }

    STAGE_GU(0, 0, 0);

    for (int kt=0; kt<NT; kt++){
        const int buf = kt % 3;
        if (kt+1 < NT){
            const int k1 = kt+1;
            STAGE_GU(k1>>1, (k1&1)<<5, k1%3);
            asm volatile("s_waitcnt vmcnt(4)" ::: "memory");
        } else {
            asm volatile("s_waitcnt vmcnt(0)" ::: "memory");
        }
        SBAR(); __builtin_amdgcn_s_barrier(); SBAR();
        s16x8 af[2], bg[4], bu[4];
        #pragma unroll
        for (int mt=0;mt<2;mt++){
            const int ra = w*32 + mt*16 + cl;
            af[mt] = *(const s16x8*)&lds[buf][ra*32 + (((cg ^ ((ra>>1)&3))&3)<<3)];
        }
        #pragma unroll
        for (int nt=0;nt<4;nt++){
            const int rb = nt*16 + cl;
            const int sw = (((cg ^ ((rb>>1)&3))&3)<<3);
            bg[nt] = *(const s16x8*)&lds[buf][4096 + rb*32 + sw];
            bu[nt] = *(const s16x8*)&lds[buf][6144 + rb*32 + sw];
        }
        #pragma unroll
        for (int mt=0;mt<2;mt++)
            #pragma unroll
            for (int nt=0;nt<4;nt++){
                accg[mt][nt] = __builtin_amdgcn_mfma_f32_16x16x32_bf16(af[mt], bg[nt], accg[mt][nt], 0,0,0);
                accu[mt][nt] = __builtin_amdgcn_mfma_f32_16x16x32_bf16(af[mt], bu[nt], accu[mt][nt], 0,0,0);
            }
    }

    const int m0 = blockIdx.y*128;
    #pragma unroll
    for (int mt=0;mt<2;mt++){
        const int grow0 = m0 + w*32 + mt*16 + cg*4;
        float rr[4];
        #pragma unroll
        for (int j=0;j<4;j++) rr[j] = rsqrtf(rs_in[grow0+j]*(1.f/768.f) + EPSF);
        #pragma unroll
        for (int nt=0;nt<4;nt++){
            const int col = n0 + nt*16 + cl;
            const size_t tb = (((size_t)(grow0>>7)*48 + (col>>6))<<13) + (col&63);
            #pragma unroll
            for (int j=0;j<4;j++){
                float g = accg[mt][nt][j]*rr[j];
                float u = accu[mt][nt][j]*rr[j];
                float s = g/(1.f+__expf(-g))*u;
                o16[tb + (((grow0+j)&127)<<6)] = f2bu(s);
            }
        }
    }
}

// ------------------------------------------------- BM=64 GEMM: 3-buf, 1-ahead, 1 barrier/step
__device__ __forceinline__ void stage64(const u16* aT, int arow, const u16* bT, int brow, int cb,
                                        u16* la, u16* lb, int w, int l)
{
    const int q = w*64 + l;
    const int row = q>>2, u = q&3;
    const int sw = (((u ^ ((row>>1)&3))&3)<<3);
    GLDS(aT + (arow+row)*64 + cb + sw, la + w*512);
    GLDS(bT + (brow+row)*64 + cb + sw, lb + w*512);
}

__global__ __launch_bounds__(256,6) void gemm_t64(
    const u16* __restrict__ At, const u16* __restrict__ Bt, float* __restrict__ C,
    int N, int K, int AMS, int flags, const float* __restrict__ bias,
    u16* __restrict__ o16, float* __restrict__ rs_out)
{
    __shared__ u16 lds[3][4096];
    const int tid = threadIdx.x;
    const int lane = tid & 63, w = tid >> 6;
    const int cg = lane >> 4, cl = lane & 15;
    const int NT = K >> 5;
    const int n0 = blockIdx.x*64;
    const int m0 = blockIdx.y*64;
    const int brow = n0 & 64, arow = m0 & 64;

    const u16* aB = At + ((size_t)(m0>>7) * AMS << 13);
    const u16* bB = Bt + ((size_t)(n0>>7) * (K>>6) << 13);

    f32x4 acc[4];
    #pragma unroll
    for (int j=0;j<4;j++) acc[j] = (f32x4){0.f,0.f,0.f,0.f};

    stage64(aB, arow, bB, brow, 0, &lds[0][0], &lds[0][2048], w, lane);

    for (int kt=0; kt<NT; kt++){
        const int buf = kt % 3;
        if (kt+1 < NT){
            const int k1 = kt+1;
            stage64(aB + ((size_t)(k1>>1)<<13), arow, bB + ((size_t)(k1>>1)<<13), brow,
                    (k1&1)<<5, &lds[k1%3][0], &lds[k1%3][2048], w, lane);
            asm volatile("s_waitcnt vmcnt(2)" ::: "memory");
        } else {
            asm volatile("s_waitcnt vmcnt(0)" ::: "memory");
        }
        SBAR(); __builtin_amdgcn_s_barrier(); SBAR();
        const int ra = w*16 + cl;
        s16x8 af = *(const s16x8*)&lds[buf][ra*32 + (((cg ^ ((ra>>1)&3))&3)<<3)];
        s16x8 bf[4];
        #pragma unroll
        for (int nt=0;nt<4;nt++){
            const int rb = nt*16 + cl;
            bf[nt] = *(const s16x8*)&lds[buf][2048 + rb*32 + (((cg ^ ((rb>>1)&3))&3)<<3)];
        }
        #pragma unroll
        for (int nt=0;nt<4;nt++)
            acc[nt] = __builtin_amdgcn_mfma_f32_16x16x32_bf16(af, bf[nt], acc[nt], 0,0,0);
    }

    const int grow0 = m0 + w*16 + cg*4;
    const bool do_acc = (flags&1), do_bias = (flags&2);
    float tmp[4][4];
    #pragma unroll
    for (int nt=0;nt<4;nt++){
        const int col = n0 + nt*16 + cl;
        float bv = do_bias ? bias[col] : 0.f;
        #pragma unroll
        for (int j=0;j<4;j++){
            float v = acc[nt][j] + bv;
            float* cp = C + (size_t)(grow0+j)*N + col;
            if (do_acc) v += *cp;
            *cp = v;
            tmp[nt][j] = v;
        }
    }
    if (o16){
        #pragma unroll
        for (int nt=0;nt<4;nt++){
            const int col = n0 + nt*16 + cl;
            const size_t tb = (((size_t)(grow0>>7)*12 + (col>>6))<<13) + (col&63);
            #pragma unroll
            for (int j=0;j<4;j++)
                o16[tb + (((grow0+j)&127)<<6)] = f2bu(tmp[nt][j]);
        }
    }
    if (rs_out){
        #pragma unroll
        for (int j=0;j<4;j++){
            float s = tmp[0][j]*tmp[0][j] + tmp[1][j]*tmp[1][j]
                    + tmp[2][j]*tmp[2][j] + tmp[3][j]*tmp[3][j];
            s = rsum16(s);
            if (cl==0) atomicAdd(rs_out + grow0 + j, s);
        }
    }
}

// ------------------------------------------------- MFMA flash attention: 3-buf K/V/M, 1 barrier/chunk
__global__ __launch_bounds__(256,2) void attn_mfma5(
    const u16* __restrict__ qk16, const u16* __restrict__ vt16,
    const u8* __restrict__ mbp, int mt,
    u16* __restrict__ ob16)
{
    const int bh = blockIdx.y;
    const int b = bh / NH, h = bh % NH;
    const int q0 = blockIdx.x * 64;
    const int tid = threadIdx.x;
    const int w = tid>>6, lane = tid&63, cg = lane>>4, cl = lane&15;
    const int srow = lane>>3;
    const int sseg = (lane&7) ^ srow;

    __shared__ u16 Ks[3][4096], Vt[3][4096], Ps[4096];
    __shared__ u8 Ms[3][512];

    // Q fragments -> registers (before any GLDS; fence forces early waitcnt)
    s16x8 qa0, qa1;
    {
        const u16* qrow = qk16 + (size_t)(b*SS+q0 + w*16 + cl)*1536 + h*64;
        qa0 = *(const s16x8*)(qrow + cg*8);
        qa1 = *(const s16x8*)(qrow + 32 + cg*8);
        asm volatile("" :: "v"(*(const f32x4*)&qa0), "v"(*(const f32x4*)&qa1));
    }

    const u16* kbase = qk16 + (size_t)(b*SS)*1536 + 768 + h*64;
    const u16* vbase = vt16 + ((size_t)(b*768 + h*64)<<10);
    // bit-plane base for this (b, type, q-tile)
    const u8* mrow0 = mbp + ((size_t)(b<<10))*512 + mt*128 + (q0>>3);

    // stage chunk 0 into buf 0 (per wave: 2K + 2V GLDS16 + 1 M GLDS4 = 5 loads)
    #pragma unroll
    for (int p=0;p<2;p++){
        const int row = p*32 + w*8 + srow;
        GLDS(kbase + (size_t)row*1536 + sseg*8, Ks[0] + p*2048 + w*512);
        GLDS(vbase + ((size_t)row<<10) + sseg*8, Vt[0] + p*2048 + w*512);
    }
    if (lane < 32){
        const int krow = w*16 + (lane>>1);
        GLDS4(mrow0 + (size_t)krow*512 + (lane&1)*4, Ms[0] + w*128);
    }

    f32x4 o[4];
    #pragma unroll
    for (int nt=0;nt<4;nt++) o[nt] = (f32x4){0.f,0.f,0.f,0.f};
    float lsum[4] = {0.f,0.f,0.f,0.f};

    for (int kc=0;kc<16;kc++){
        const int buf = kc % 3;
        if (kc < 15){
            const int nb = (kc+1) % 3;
            const int kn0 = kc*64 + 64;
            #pragma unroll
            for (int p=0;p<2;p++){
                const int row = p*32 + w*8 + srow;
                GLDS(kbase + (size_t)(kn0+row)*1536 + sseg*8, Ks[nb] + p*2048 + w*512);
                GLDS(vbase + ((size_t)row<<10) + kn0 + sseg*8, Vt[nb] + p*2048 + w*512);
            }
            if (lane < 32){
                const int krow = kn0 + w*16 + (lane>>1);
                GLDS4(mrow0 + (size_t)krow*512 + (lane&1)*4, Ms[nb] + w*128);
            }
            asm volatile("s_waitcnt vmcnt(5)" ::: "memory");
        } else {
            asm volatile("s_waitcnt vmcnt(0)" ::: "memory");
        }
        SBAR(); __builtin_amdgcn_s_barrier(); SBAR();   // single barrier per chunk

        // QK^T (q pre-scaled by 0.125*log2e)
        f32x4 sc[4];
        #pragma unroll
        for (int nt=0;nt<4;nt++) sc[nt] = (f32x4){0.f,0.f,0.f,0.f};
        __builtin_amdgcn_s_setprio(1);
        #pragma unroll
        for (int nt=0;nt<4;nt++){
            s16x8 kb0 = *(const s16x8*)&Ks[buf][swz(nt*16+cl, cg*8)];
            sc[nt] = __builtin_amdgcn_mfma_f32_16x16x32_bf16(qa0, kb0, sc[nt], 0,0,0);
        }
        #pragma unroll
        for (int nt=0;nt<4;nt++){
            s16x8 kb1 = *(const s16x8*)&Ks[buf][swz(nt*16+cl, 32+cg*8)];
            sc[nt] = __builtin_amdgcn_mfma_f32_16x16x32_bf16(qa1, kb1, sc[nt], 0,0,0);
        }
        __builtin_amdgcn_s_setprio(0);

        // mask bit + exp2 (max-free)
        float pP[4][4];
        const int qb = 2*w + (cg>>1);
        const int bsh = (cg&1)*4;
        #pragma unroll
        for (int nt=0;nt<4;nt++){
            const u32 mrow = Ms[buf][(nt*16+cl)*8 + qb];
            #pragma unroll
            for (int j=0;j<4;j++){
                float pe = exp2f(fminf(sc[nt][j], 100.f));
                pe = ((mrow >> (bsh+j)) & 1u) ? pe : 0.f;
                pP[nt][j] = pe;
                lsum[j] += pe;
            }
        }

        #pragma unroll
        for (int nt=0;nt<4;nt++)
            #pragma unroll
            for (int j=0;j<4;j++)
                Ps[swz(w*16+cg*4+j, nt*16+cl)] = f2bu(pP[nt][j]);

        // PV
        __builtin_amdgcn_s_setprio(1);
        #pragma unroll
        for (int ks=0;ks<2;ks++){
            s16x8 pa = *(const s16x8*)&Ps[swz(w*16+cl, ks*32+cg*8)];
            #pragma unroll
            for (int nt=0;nt<4;nt++){
                s16x8 vb = *(const s16x8*)&Vt[buf][swz(nt*16+cl, ks*32+cg*8)];
                o[nt] = __builtin_amdgcn_mfma_f32_16x16x32_bf16(pa, vb, o[nt], 0,0,0);
            }
        }
        __builtin_amdgcn_s_setprio(0);
    }

    #pragma unroll
    for (int j=0;j<4;j++){
        const float inv = 1.f/rsum16(lsum[j]);
        const int row = b*SS + q0 + w*16 + cg*4 + j;
        const size_t rb = ((size_t)(row>>7)*12 + h)*8192 + ((row&127)<<6);
        #pragma unroll
        for (int nt=0;nt<4;nt++)
            ob16[rb + nt*16 + cl] = f2bu(o[nt][j]*inv);
    }
}

// ------------------------------------------------- encode fuse
__global__ __launch_bounds__(256) void fuse_encode(
    const float* __restrict__ cnbuf, const float* __restrict__ textbuf,
    const float* __restrict__ numv, const float* __restrict__ dtv, const float* __restrict__ boolv,
    const float* __restrict__ Wnum, const float* __restrict__ bnum,
    const float* __restrict__ Wdt, const float* __restrict__ bdt,
    const float* __restrict__ Wbool, const float* __restrict__ bbool,
    const float* __restrict__ gcn, const float* __restrict__ gnum, const float* __restrict__ gtext,
    const float* __restrict__ gdt, const float* __restrict__ gbool,
    const float* __restrict__ memb, const int* __restrict__ stypes, const u8* __restrict__ masks,
    float* __restrict__ x, u16* __restrict__ xt16, float* __restrict__ rs0)
{
    const int row = blockIdx.x;
    const int t = threadIdx.x;
    __shared__ float red[256];

    float cn3[3]; float ss=0.f;
    #pragma unroll
    for (int j=0;j<3;j++){
        cn3[j] = cnbuf[(size_t)row*DM + t + j*256];
        ss += cn3[j]*cn3[j];
    }
    red[t]=ss; __syncthreads();
    for (int s=128;s>0;s>>=1){ if(t<s) red[t]+=red[t+s]; __syncthreads(); }
    {
        float r = rsqrtf(red[0]/(float)DM + EPSF);
        #pragma unroll
        for (int j=0;j<3;j++) cn3[j] *= r*gcn[t+j*256];
    }
    __syncthreads();

    const int st = stypes[row];
    float val[3]; ss=0.f;
    if (st==1){
        #pragma unroll
        for (int j=0;j<3;j++){
            val[j] = textbuf[(size_t)row*DM + t + j*256];
            ss += val[j]*val[j];
        }
    } else {
        const float* Wp = (st==0)?Wnum:((st==2)?Wdt:Wbool);
        const float* bp = (st==0)?bnum:((st==2)?bdt:bbool);
        const float* vp = (st==0)?numv:((st==2)?dtv:boolv);
        float v = vp[row];
        #pragma unroll
        for (int j=0;j<3;j++){
            int e=t+j*256;
            val[j] = v*Wp[e] + bp[e];
            ss += val[j]*val[j];
        }
    }
    red[t]=ss; __syncthreads();
    for (int s=128;s>0;s>>=1){ if(t<s) red[t]+=red[t+s]; __syncthreads(); }
    const float* gp = (st==0)?gnum:((st==1)?gtext:((st==2)?gdt:gbool));
    float r2 = rsqrtf(red[0]/(float)DM + EPSF);
    bool mk = masks[row]!=0;
    float xv[3]; float sx=0.f;
    #pragma unroll
    for (int j=0;j<3;j++){
        int e=t+j*256;
        float vv = val[j]*r2*gp[e];
        if (mk) vv = memb[st*DM+e];
        xv[j] = vv + cn3[j];
        x[(size_t)row*DM+e] = xv[j];
        sx += xv[j]*xv[j];
    }
    __syncthreads();
    red[t]=sx; __syncthreads();
    for (int s=128;s>0;s>>=1){ if(t<s) red[t]+=red[t+s]; __syncthreads(); }
    if (t==0) rs0[row] = red[0];
    const size_t mb = (size_t)(row>>7)*12;
    const int rr = (row&127)<<6;
    #pragma unroll
    for (int j=0;j<3;j++){
        const int c = t + j*256;
        xt16[((mb + (c>>6))<<13) + rr + (c&63)] = f2bu(xv[j]);
    }
}

// ------------------------------------------------- final rms + 3 scalar heads; h -> tiled bf16
__global__ __launch_bounds__(256) void decode2(
    const float* __restrict__ x, const float* __restrict__ gout,
    const float* __restrict__ Wn, const float* __restrict__ bn,
    const float* __restrict__ Wd, const float* __restrict__ bd,
    const float* __restrict__ Wb, const float* __restrict__ bb,
    float* __restrict__ out, u16* __restrict__ h16)
{
    const int row = blockIdx.x;
    const int t = threadIdx.x;
    __shared__ float h[DM];
    __shared__ float red[256];
    const float* xr = x + (size_t)row*DM;
    float v0=xr[t], v1=xr[t+256], v2=xr[t+512];
    red[t]=v0*v0+v1*v1+v2*v2; __syncthreads();
    for (int s=128;s>0;s>>=1){ if(t<s) red[t]+=red[t+s]; __syncthreads(); }
    float r = rsqrtf(red[0]/(float)DM + EPSF);
    float h0 = v0*r*gout[t], h1 = v1*r*gout[t+256], h2 = v2*r*gout[t+512];
    h[t]=h0; h[t+256]=h1; h[t+512]=h2;
    const size_t mb = (size_t)(row>>7)*12;
    const int rr = (row&127)<<6;
    #pragma unroll
    for (int j=0;j<3;j++){
        const int c = t + j*256;
        const float v = (j==0?h0:(j==1?h1:h2));
        h16[((mb + (c>>6))<<13) + rr + (c&63)] = f2bu(v);
    }
    __syncthreads();

    float pn=0.f,pd=0.f,pb=0.f;
    for (int k=t;k<DM;k+=256){ float hv=h[k]; pn+=hv*Wn[k]; pd+=hv*Wd[k]; pb+=hv*Wb[k]; }
    red[t]=pn; __syncthreads();
    for (int s=128;s>0;s>>=1){ if(t<s) red[t]+=red[t+s]; __syncthreads(); }
    float tn=red[0]; __syncthreads();
    red[t]=pd; __syncthreads();
    for (int s=128;s>0;s>>=1){ if(t<s) red[t]+=red[t+s]; __syncthreads(); }
    float td=red[0]; __syncthreads();
    red[t]=pb; __syncthreads();
    for (int s=128;s>0;s>>=1){ if(t<s) red[t]+=red[t+s]; __syncthreads(); }
    float tb=red[0];
    if (t==0){
        out[row]          = tn + bn[0];
        out[NROW + row]   = td + bd[0];
        out[2*NROW + row] = tb + bb[0];
    }
}

// ---------------------------------------------------------------- launcher
extern "C" void kernel_launch(void* const* d_in, const int* in_sizes, int n_in,
                              void* d_out, int out_size, void* d_ws, size_t ws_size,
                              hipStream_t stream)
{
    const float* numv   = (const float*)d_in[0];
    const float* dtval  = (const float*)d_in[1];
    const float* boolv  = (const float*)d_in[2];
    const float* textv  = (const float*)d_in[3];
    const float* cnamev = (const float*)d_in[4];
    const float* Wcn=(const float*)d_in[5];  const float* bcn=(const float*)d_in[6];
    const float* Wnum=(const float*)d_in[7]; const float* bnum=(const float*)d_in[8];
    const float* Wtext=(const float*)d_in[9];const float* btext=(const float*)d_in[10];
    const float* Wdt=(const float*)d_in[11]; const float* bdt=(const float*)d_in[12];
    const float* Wbool=(const float*)d_in[13];const float* bbool=(const float*)d_in[14];
    const float* gcn=(const float*)d_in[15]; const float* gnum=(const float*)d_in[16];
    const float* gtext=(const float*)d_in[17];const float* gdt=(const float*)d_in[18];
    const float* gbool=(const float*)d_in[19];
    const float* memb=(const float*)d_in[20];
    const float* norms_all=(const float*)d_in[21];
    const float* attw_all=(const float*)d_in[22];
    const float* up_all=(const float*)d_in[23];
    const float* gate_all=(const float*)d_in[24];
    const float* down_all=(const float*)d_in[25];
    const float* gout=(const float*)d_in[26];
    const float* Wdn=(const float*)d_in[27]; const float* bdn=(const float*)d_in[28];
    const float* Wdd=(const float*)d_in[29]; const float* bdd=(const float*)d_in[30];
    const float* Wdb=(const float*)d_in[31]; const float* bdb=(const float*)d_in[32];
    const float* Wdtx=(const float*)d_in[33];const float* bdtx=(const float*)d_in[34];
    const int* node=(const int*)d_in[35];
    const int* tbl =(const int*)d_in[36];
    const int* colx=(const int*)d_in[37];
    const int* f2p =(const int*)d_in[38];
    const int* styp=(const int*)d_in[39];

    const size_t SA = (size_t)768*768;
    const size_t SG = (size_t)768*3072;
    const size_t SC = (size_t)384*768;
    const size_t NX = (size_t)NROW*DM;

    u8* base = (u8*)d_ws;
    float* x  = (float*)base;
    u16* xt16 = (u16*)(base + 6291456);
    u16* ob16 = (u16*)(base + 9437184);
    u16* qk16 = (u16*)(base + 12582912);
    u16* vt16 = (u16*)(base + 18874368);
    u16* gu16 = (u16*)(base + 22020096);
    u16* wA   = (u16*)(base + 47185920);
    u16* wGU  = wA + 64*SA;
    u16* wD   = wGU + 8*SG;
    u16* wCN  = wD + 4*SG;
    u16* wTX  = wCN + SC;
    u16* wDX  = wTX + SC;
    u8* nmask = (u8*)(wDX + SC);
    u8* npad  = nmask + NROW;
    u32* pmeta = (u32*)(npad + NROW + 64);
    float* rsbuf = (float*)(pmeta + NROW);     // 21 slots x 2048
    u8* m4 = (u8*)(rsbuf + 21*2048);           // 2 MB
    u8* mbp = m4 + ((size_t)2<<20);            // 1 MB bit-planes

    // encode-phase aliases
    u16* cnT16   = qk16;
    u16* textT16 = vt16;
    float* cnbuf   = (float*)gu16;
    float* textbuf = cnbuf + NX;

    float* out = (float*)d_out;

    norm_bool2<<<2,256,0,stream>>>(d_in[40], nmask, d_in[41], npad, NROW);
    pack_meta<<<8,256,0,stream>>>(node, colx, tbl, npad, pmeta, NROW, rsbuf, 21*2048);
    mask4_kernel<<<dim3(64,2),256,0,stream>>>(pmeta, f2p, m4);
    repack_mask<<<1024,256,0,stream>>>(m4, mbp);

    // weight prep (tiled bf16; gamma folded)
    transpose_cvt2<<<dim3(24,12,64),256,0,stream>>>(attw_all, wA, 768, 768, SA, norms_all, 1);
    transpose_cvt2<<<dim3(96,12,4),256,0,stream>>>(gate_all, wGU,      768, 3072, 2*SG, norms_all + 4*768, 2);
    transpose_cvt2<<<dim3(96,12,4),256,0,stream>>>(up_all,   wGU + SG, 768, 3072, 2*SG, norms_all + 4*768, 2);
    transpose_cvt2<<<dim3(24,48,4),256,0,stream>>>(down_all, wD, 3072, 768, SG, nullptr, 0);
    transpose_cvt2<<<dim3(24,6,1),256,0,stream>>>(Wcn,   wCN, 384, 768, 0, nullptr, 0);
    transpose_cvt2<<<dim3(24,6,1),256,0,stream>>>(Wtext, wTX, 384, 768, 0, nullptr, 0);
    transpose_cvt2<<<dim3(12,12,1),256,0,stream>>>(Wdtx, wDX, 768, 384, 0, nullptr, 0);

    // encode
    cvt_tiled2<<<dim3(384,2),256,0,stream>>>(cnamev, cnT16, textv, textT16, 384);
    gemm_t64<<<dim3(12,32),256,0,stream>>>(cnT16,   wCN, cnbuf,   768, 384, 6, 2, bcn,   nullptr, nullptr);
    gemm_t64<<<dim3(12,32),256,0,stream>>>(textT16, wTX, textbuf, 768, 384, 6, 2, btext, nullptr, nullptr);
    fuse_encode<<<NROW,256,0,stream>>>(cnbuf, textbuf, numv, dtval, boolv,
        Wnum,bnum,Wdt,bdt,Wbool,bbool, gcn,gnum,gtext,gdt,gbool,
        memb, styp, nmask, x, xt16, rsbuf);

    const dim3 ga(SS/64, BB*NH);
    for (int l=0; l<NL; l++){
        for (int a=0; a<4; a++){
            const int slot = l*5 + a;
            const u16* wqkv = wA + (size_t)((l*4+a)*4)*SA;
            gemm_t<<<dim3(36,16),256,0,stream>>>(xt16, wqkv, 768, 12, qk16, vt16,
                rsbuf + (size_t)slot*2048);
            attn_mfma5<<<ga,256,0,stream>>>(qk16, vt16, mbp, a, ob16);
            gemm_t64<<<dim3(12,32),256,0,stream>>>(ob16, wqkv + 3*SA, x, 768, 768, 12, 1, nullptr,
                xt16, rsbuf + (size_t)(slot+1)*2048);
        }
        gemm_gu<<<dim3(48,16),256,0,stream>>>(xt16, wGU + (size_t)l*2*SG, wGU + (size_t)l*2*SG + SG,
            rsbuf + (size_t)(l*5+4)*2048, gu16);
        gemm_t64<<<dim3(12,32),256,0,stream>>>(gu16, wD + (size_t)l*SG, x, 768, 3072, 48, 1, nullptr,
            xt16, rsbuf + (size_t)((l+1)*5)*2048);
    }

    decode2<<<NROW,256,0,stream>>>(x, gout, Wdn,bdn, Wdd,bdd, Wdb,bdb, out, xt16);
    gemm_t64<<<dim3(6,32),256,0,stream>>>(xt16, wDX, out + 3*NROW, 384, 768, 12, 2, bdtx,
        nullptr, nullptr);
}

// Round 15
// 1343.959 us; speedup vs baseline: 7.6585x; 1.0508x over previous
//
#include <hip/hip_runtime.h>
#include <hip/hip_bf16.h>
#include <cmath>
#include <stdint.h>

// Round 15: GEMMs go 4-buffer / 2-ahead prefetch with ONE barrier per K-step
// (restores r8's prefetch depth while keeping r13's barrier count). Rest = r14.

#define BB 2
#define SS 1024
#define DT 384
#define DM 768
#define NH 12
#define DH 64
#define DFF 3072
#define NL 4
#define NROW (BB*SS)
#define EPSF 1e-6f
#define QSC 0.1803368801111244f   // 0.125 * log2(e)

typedef unsigned short u16;
typedef unsigned char u8;
typedef unsigned int u32;
typedef __attribute__((ext_vector_type(8))) short s16x8;
typedef __attribute__((ext_vector_type(4))) float f32x4;

__device__ __forceinline__ u16 f2bu(float f){
    u32 x = __float_as_uint(f);
    u32 r = (x + 0x7fffu + ((x>>16)&1u)) >> 16;   // RNE
    return (u16)r;
}
__device__ __forceinline__ u32 pk2(float lo, float hi){
    return (u32)f2bu(lo) | ((u32)f2bu(hi)<<16);
}
__device__ __forceinline__ int swz(int row, int c){
    return (row<<6) + (((((c>>3) ^ row) & 7))<<3) + (c&7);
}
__device__ __forceinline__ float rsum16(float v){
    v += __shfl_xor(v,1); v += __shfl_xor(v,2);
    v += __shfl_xor(v,4); v += __shfl_xor(v,8);
    return v;
}
#define SBAR() __builtin_amdgcn_sched_barrier(0)
#define GLDS(src,dst) __builtin_amdgcn_global_load_lds((const __attribute__((address_space(1))) u32*)(src), (__attribute__((address_space(3))) u32*)(dst), 16, 0, 0)
#define GLDS4(src,dst) __builtin_amdgcn_global_load_lds((const __attribute__((address_space(1))) u32*)(src), (__attribute__((address_space(3))) u32*)(dst), 4, 0, 0)

// ------------------------------------------------- bool-buffer normalizer (dual)
__device__ void norm_bool_body(const void* __restrict__ src, u8* __restrict__ dst, int n)
{
    __shared__ int fl[4];
    if (threadIdx.x<4) fl[threadIdx.x]=0;
    __syncthreads();
    const u32* wsrc = (const u32*)src;
    const int nw = n/4;
    int any=0, nb=0, hi=0, lo=0;
    for (int i=threadIdx.x;i<nw;i+=blockDim.x){
        u32 v=wsrc[i];
        if (!v) continue;
        any=1;
        #pragma unroll
        for (int b=0;b<4;b++){
            u32 by=(v>>(8*b))&0xffu;
            if (by>1u) nb=1;
            if (by==1u && b!=0) hi=1;
        }
        if ((v&0xffffu)==0x3f80u) lo=1;
    }
    if (any) atomicOr(&fl[0],1);
    if (nb)  atomicOr(&fl[1],1);
    if (hi)  atomicOr(&fl[2],1);
    if (lo)  atomicOr(&fl[3],1);
    __syncthreads();
    int c;
    if (!fl[0]) c=0;
    else if (!fl[1]) c = fl[2] ? 2 : 1;
    else if (fl[3]) c = 3;
    else c = 1;
    for (int i=threadIdx.x;i<n;i+=blockDim.x){
        u8 v;
        if (c==0)      v=0;
        else if (c==1) v = (((const u32*)src)[i]!=0u);
        else if (c==2) v = (((const u8*)src)[i]!=0u);
        else           v = (((const u16*)src)[i]!=0u);
        dst[i]=v;
    }
}
__global__ void norm_bool2(const void* s0, u8* d0, const void* s1, u8* d1, int n)
{
    if (blockIdx.x==0) norm_bool_body(s0,d0,n);
    else               norm_bool_body(s1,d1,n);
}

// ------------------------------------------------- pack per-token metadata + zero rs slots
__global__ void pack_meta(const int* __restrict__ node, const int* __restrict__ colx,
                          const int* __restrict__ tbl, const u8* __restrict__ pad,
                          u32* __restrict__ pm, int n, float* __restrict__ rsz, int nz)
{
    int i = blockIdx.x*256 + threadIdx.x;
    if (i<n)
        pm[i] = (u32)(node[i]&0xff) | ((u32)(colx[i]&0xff)<<8) | ((u32)(tbl[i]&0xff)<<16) | ((u32)(pad[i]&1)<<24);
    for (int z=i; z<nz; z+=gridDim.x*256) rsz[z]=0.f;
}

// ------------------------------------------------- mask table: m4[b][k][q] bit t = mask_t(q,k)
__global__ __launch_bounds__(256) void mask4_kernel(const u32* __restrict__ pm, const int* __restrict__ f2p,
                                                    u8* __restrict__ m4)
{
    const int b = blockIdx.y, kg = blockIdx.x;
    const int t = threadIdx.x;
    __shared__ u32 qm[1024];
    __shared__ int qf[1024*5];
    for (int i=t;i<1024;i+=256) qm[i] = pm[b*SS+i];
    for (int i=t;i<5*1024;i+=256) qf[i] = f2p[b*SS*5 + i];
    __syncthreads();
    const int q0 = t*4;
    u32 qmv[4]; int qn[4]; int qfv[4][5];
    #pragma unroll
    for (int j=0;j<4;j++){
        qmv[j]=qm[q0+j]; qn[j]=(int)(qmv[j]&0xffu);
        #pragma unroll
        for (int f=0;f<5;f++) qfv[j][f]=qf[(q0+j)*5+f];
    }
    for (int kk=0;kk<16;kk++){
        const int k = kg*16+kk;
        const u32 km = qm[k];
        const int kn = (int)(km&0xffu);
        u32 outw=0;
        #pragma unroll
        for (int j=0;j<4;j++){
            const u32 qmw = qmv[j];
            const bool pv = (((qmw|km)>>24)&1u)==0u;
            u32 by=0;
            if ((((qmw^km)&0x00ffff00u)==0u) && pv) by|=1;
            if ((((qmw^km)&0xffu)==0u) && pv) by|=2;
            bool nei = (qfv[j][0]==kn)||(qfv[j][1]==kn)||(qfv[j][2]==kn)||(qfv[j][3]==kn)||(qfv[j][4]==kn)
                       ||(qn[j]==kn);
            if (nei && pv) by|=4;
            if (pv) by|=8;
            if ((q0+j)==k) by=15;
            outw |= by<<(8*j);
        }
        ((u32*)(m4 + ((size_t)b<<20) + ((size_t)k<<10)))[t] = outw;
    }
}

// ------------------------------------------------- repack m4 bytes -> 4 bit-planes
__global__ void repack_mask(const u8* __restrict__ m4, u8* __restrict__ mbp)
{
    const int gid = blockIdx.x*256 + threadIdx.x;
    const int qb = gid & 127;
    const int bk = gid >> 7;
    const u8* src = m4 + ((size_t)bk<<10) + qb*8;
    u32 lo = *(const u32*)src, hi = *(const u32*)(src+4);
    u32 out[4] = {0,0,0,0};
    #pragma unroll
    for (int j=0;j<4;j++){
        u32 b0 = (lo>>(8*j)) & 0xffu;
        u32 b1 = (hi>>(8*j)) & 0xffu;
        #pragma unroll
        for (int tt=0;tt<4;tt++){
            out[tt] |= ((b0>>tt)&1u) << j;
            out[tt] |= ((b1>>tt)&1u) << (j+4);
        }
    }
    u8* dst = mbp + (size_t)bk*512 + qb;
    #pragma unroll
    for (int tt=0;tt<4;tt++) dst[tt*128] = (u8)out[tt];
}

// ------------------------------------------------- weight f32 [K][N] -> tiled bf16 (+gamma fold)
__global__ __launch_bounds__(256) void transpose_cvt2(const float* __restrict__ src, u16* __restrict__ dst,
                                                      int K, int N, size_t dz,
                                                      const float* __restrict__ gbase, int gmode)
{
    const int z = blockIdx.z;
    src += (size_t)z*K*N;
    dst += (size_t)z*dz;
    const float* g = nullptr;
    if (gmode==1){ int m = z&3; if (m<3) g = gbase + (size_t)((z>>4)*5 + ((z>>2)&3))*768; }
    else if (gmode==2){ g = gbase + (size_t)z*5*768; }
    const int n0 = blockIdx.x*32, k0 = blockIdx.y*64;
    __shared__ float t[64][33];
    const int tid = threadIdx.x;
    const int kr = tid>>3, n4 = (tid&7)*4;
    #pragma unroll
    for (int p=0;p<2;p++){
        const int k = p*32 + kr;
        float gk = g ? g[k0+k] : 1.f;
        float4 v = *(const float4*)(src + (size_t)(k0+k)*N + n0 + n4);
        t[k][n4]=v.x*gk; t[k][n4+1]=v.y*gk; t[k][n4+2]=v.z*gk; t[k][n4+3]=v.w*gk;
    }
    __syncthreads();
    const int n = tid>>3, ks = (tid&7)*8;
    const int ng = n0 + n;
    uint4 o;
    u32* op = (u32*)&o;
    #pragma unroll
    for (int i=0;i<4;i++)
        op[i] = pk2(t[ks+2*i][n], t[ks+2*i+1][n]);
    *(uint4*)&dst[(((size_t)(ng>>7)*(K>>6) + (k0>>6))<<13) + ((ng&127)<<6) + ks] = o;
}

// ------------------------------------------------- activation f32 [M][K] -> tiled bf16 (dual src)
__global__ __launch_bounds__(256) void cvt_tiled2(const float* __restrict__ s0, u16* __restrict__ d0,
                                                  const float* __restrict__ s1, u16* __restrict__ d1, int K)
{
    const float* src = blockIdx.y ? s1 : s0;
    u16* dst = blockIdx.y ? d1 : d0;
    const int gid = blockIdx.x*256 + threadIdx.x;
    const int base = gid*8;
    const int row = base / K, col = base - row*K;
    float4 a = *(const float4*)(src + base);
    float4 b = *(const float4*)(src + base + 4);
    uint4 o;
    o.x = pk2(a.x,a.y); o.y = pk2(a.z,a.w);
    o.z = pk2(b.x,b.y); o.w = pk2(b.z,b.w);
    *(uint4*)&dst[(((size_t)(row>>7)*(K>>6) + (col>>6))<<13) + ((row&127)<<6) + (col&63)] = o;
}

// ------------------------------------------------- BM=128 GEMM (qkv): 4-buf, 2-ahead, 1 barrier/step
__device__ __forceinline__ void stage3(const u16* aT, const u16* bT, int cb, int brow,
                                       u16* la, u16* lb, int w, int l)
{
    #pragma unroll
    for (int p=0;p<2;p++){
        const int q = p*256 + w*64 + l;
        const int row = q>>2, u = q&3;
        const int so = row*64 + cb + (((u ^ ((row>>1)&3))&3)<<3);
        GLDS(aT+so, la + p*2048 + w*512);
    }
    {
        const int q = w*64 + l;
        const int row = q>>2, u = q&3;
        const int so = (brow+row)*64 + cb + (((u ^ ((row>>1)&3))&3)<<3);
        GLDS(bT+so, lb + w*512);
    }
}

__global__ __launch_bounds__(256,3) void gemm_t(
    const u16* __restrict__ At, const u16* __restrict__ Bt,
    int K, int AMS, u16* __restrict__ qk16, u16* __restrict__ vt16,
    const float* __restrict__ rs_in)
{
    __shared__ u16 lds[4][6144];   // 48KB
    const int tid = threadIdx.x;
    const int lane = tid & 63, w = tid >> 6;
    const int cg = lane >> 4, cl = lane & 15;
    const int NT = K >> 5;
    const int n0 = blockIdx.x*64;
    const int brow = n0 & 64;
    const size_t bNb = (size_t)(n0>>7)*(K>>6);

    const u16* aB = At + ((size_t)blockIdx.y * AMS << 13);
    const u16* bB = Bt + (bNb << 13);

    f32x4 acc[2][4];
    #pragma unroll
    for (int i=0;i<2;i++)
        #pragma unroll
        for (int j=0;j<4;j++) acc[i][j] = (f32x4){0.f,0.f,0.f,0.f};

    stage3(aB, bB, 0,  brow, &lds[0][0], &lds[0][4096], w, lane);             // tile 0
    stage3(aB, bB, 32, brow, &lds[1][0], &lds[1][4096], w, lane);             // tile 1

    for (int kt=0; kt<NT; kt++){
        const int buf = kt & 3;
        if (kt+2 < NT){
            const int k2 = kt+2;
            stage3(aB + ((size_t)(k2>>1)<<13), bB + ((size_t)(k2>>1)<<13),
                   (k2&1)<<5, brow, &lds[k2&3][0], &lds[k2&3][4096], w, lane);
            asm volatile("s_waitcnt vmcnt(6)" ::: "memory");
        } else if (kt+1 < NT){
            asm volatile("s_waitcnt vmcnt(3)" ::: "memory");
        } else {
            asm volatile("s_waitcnt vmcnt(0)" ::: "memory");
        }
        SBAR(); __builtin_amdgcn_s_barrier(); SBAR();
        s16x8 af[2], bf[4];
        #pragma unroll
        for (int mt=0;mt<2;mt++){
            const int ra = w*32 + mt*16 + cl;
            af[mt] = *(const s16x8*)&lds[buf][ra*32 + (((cg ^ ((ra>>1)&3))&3)<<3)];
        }
        #pragma unroll
        for (int nt=0;nt<4;nt++){
            const int rb = nt*16 + cl;
            bf[nt] = *(const s16x8*)&lds[buf][4096 + rb*32 + (((cg ^ ((rb>>1)&3))&3)<<3)];
        }
        #pragma unroll
        for (int mt=0;mt<2;mt++)
            #pragma unroll
            for (int nt=0;nt<4;nt++)
                acc[mt][nt] = __builtin_amdgcn_mfma_f32_16x16x32_bf16(af[mt], bf[nt], acc[mt][nt], 0,0,0);
    }

    const int m0 = blockIdx.y*128;
    #pragma unroll
    for (int mt=0;mt<2;mt++){
        const int grow0 = m0 + w*32 + mt*16 + cg*4;
        float rr[4];
        #pragma unroll
        for (int j=0;j<4;j++) rr[j] = rsqrtf(rs_in[grow0+j]*(1.f/768.f) + EPSF);
        #pragma unroll
        for (int nt=0;nt<4;nt++){
            const int col = n0 + nt*16 + cl;
            if (col < 768){
                #pragma unroll
                for (int j=0;j<4;j++)
                    qk16[(size_t)(grow0+j)*1536 + col] = f2bu(acc[mt][nt][j]*rr[j]*QSC);
            } else if (col < 1536){
                #pragma unroll
                for (int j=0;j<4;j++)
                    qk16[(size_t)(grow0+j)*1536 + col] = f2bu(acc[mt][nt][j]*rr[j]);
            } else {
                const int b = grow0>>10, s0 = grow0&1023;
                const int dhg = col - 1536;
                uint2 o;
                o.x = pk2(acc[mt][nt][0]*rr[0], acc[mt][nt][1]*rr[1]);
                o.y = pk2(acc[mt][nt][2]*rr[2], acc[mt][nt][3]*rr[3]);
                *(uint2*)(vt16 + ((size_t)(b*768 + dhg)<<10) + s0) = o;
            }
        }
    }
}

// ------------------------------------------------- fused gate-up-silu GEMM: 3-buf, 1-ahead (unchanged)
__global__ __launch_bounds__(256,3) void gemm_gu(
    const u16* __restrict__ At, const u16* __restrict__ Bg, const u16* __restrict__ Bu,
    const float* __restrict__ rs_in, u16* __restrict__ o16)
{
    __shared__ u16 lds[3][8192];
    const int tid = threadIdx.x;
    const int lane = tid & 63, w = tid >> 6;
    const int cg = lane >> 4, cl = lane & 15;
    const int NT = 24;
    const int n0 = blockIdx.x*64;
    const int brow = n0 & 64;
    const size_t bNb = (size_t)(n0>>7)*12;

    const u16* aB = At + ((size_t)blockIdx.y * 12 << 13);
    const u16* gB = Bg + (bNb << 13);
    const u16* uB = Bu + (bNb << 13);

    f32x4 accg[2][4], accu[2][4];
    #pragma unroll
    for (int i=0;i<2;i++)
        #pragma unroll
        for (int j=0;j<4;j++){ accg[i][j] = (f32x4){0.f,0.f,0.f,0.f}; accu[i][j] = (f32x4){0.f,0.f,0.f,0.f}; }

    #define STAGE_GU(kt2, cb, buf) { \
        const u16* a_ = aB + ((size_t)(kt2)<<13); \
        const u16* g_ = gB + ((size_t)(kt2)<<13); \
        const u16* u_ = uB + ((size_t)(kt2)<<13); \
        _Pragma("unroll") \
        for (int p=0;p<2;p++){ \
            const int q = p*256 + w*64 + lane; \
            const int row = q>>2, uu = q&3; \
            const int so = row*64 + (cb) + (((uu ^ ((row>>1)&3))&3)<<3); \
            GLDS(a_+so, &lds[buf][0] + p*2048 + w*512); \
        } \
        { \
            const int q = w*64 + lane; \
            const int row = q>>2, uu = q&3; \
            const int so = (brow+row)*64 + (cb) + (((uu ^ ((row>>1)&3))&3)<<3); \
            GLDS(g_+so, &lds[buf][4096] + w*512); \
            GLDS(u_+so, &lds[buf][6144] + w*512); \
        } }

    STAGE_GU(0, 0, 0);

    for (int kt=0; kt<NT; kt++){
        const int buf = kt % 3;
        if (kt+1 < NT){
            const int k1 = kt+1;
            STAGE_GU(k1>>1, (k1&1)<<5, k1%3);
            asm volatile("s_waitcnt vmcnt(4)" ::: "memory");
        } else {
            asm volatile("s_waitcnt vmcnt(0)" ::: "memory");
        }
        SBAR(); __builtin_amdgcn_s_barrier(); SBAR();
        s16x8 af[2], bg[4], bu[4];
        #pragma unroll
        for (int mt=0;mt<2;mt++){
            const int ra = w*32 + mt*16 + cl;
            af[mt] = *(const s16x8*)&lds[buf][ra*32 + (((cg ^ ((ra>>1)&3))&3)<<3)];
        }
        #pragma unroll
        for (int nt=0;nt<4;nt++){
            const int rb = nt*16 + cl;
            const int sw = (((cg ^ ((rb>>1)&3))&3)<<3);
            bg[nt] = *(const s16x8*)&lds[buf][4096 + rb*32 + sw];
            bu[nt] = *(const s16x8*)&lds[buf][6144 + rb*32 + sw];
        }
        #pragma unroll
        for (int mt=0;mt<2;mt++)
            #pragma unroll
            for (int nt=0;nt<4;nt++){
                accg[mt][nt] = __builtin_amdgcn_mfma_f32_16x16x32_bf16(af[mt], bg[nt], accg[mt][nt], 0,0,0);
                accu[mt][nt] = __builtin_amdgcn_mfma_f32_16x16x32_bf16(af[mt], bu[nt], accu[mt][nt], 0,0,0);
            }
    }

    const int m0 = blockIdx.y*128;
    #pragma unroll
    for (int mt=0;mt<2;mt++){
        const int grow0 = m0 + w*32 + mt*16 + cg*4;
        float rr[4];
        #pragma unroll
        for (int j=0;j<4;j++) rr[j] = rsqrtf(rs_in[grow0+j]*(1.f/768.f) + EPSF);
        #pragma unroll
        for (int nt=0;nt<4;nt++){
            const int col = n0 + nt*16 + cl;
            const size_t tb = (((size_t)(grow0>>7)*48 + (col>>6))<<13) + (col&63);
            #pragma unroll
            for (int j=0;j<4;j++){
                float g = accg[mt][nt][j]*rr[j];
                float u = accu[mt][nt][j]*rr[j];
                float s = g/(1.f+__expf(-g))*u;
                o16[tb + (((grow0+j)&127)<<6)] = f2bu(s);
            }
        }
    }
}

// ------------------------------------------------- BM=64 GEMM: 4-buf, 2-ahead, 1 barrier/step
__device__ __forceinline__ void stage64(const u16* aT, int arow, const u16* bT, int brow, int cb,
                                        u16* la, u16* lb, int w, int l)
{
    const int q = w*64 + l;
    const int row = q>>2, u = q&3;
    const int sw = (((u ^ ((row>>1)&3))&3)<<3);
    GLDS(aT + (arow+row)*64 + cb + sw, la + w*512);
    GLDS(bT + (brow+row)*64 + cb + sw, lb + w*512);
}

__global__ __launch_bounds__(256,4) void gemm_t64(
    const u16* __restrict__ At, const u16* __restrict__ Bt, float* __restrict__ C,
    int N, int K, int AMS, int flags, const float* __restrict__ bias,
    u16* __restrict__ o16, float* __restrict__ rs_out)
{
    __shared__ u16 lds[4][4096];   // 32KB
    const int tid = threadIdx.x;
    const int lane = tid & 63, w = tid >> 6;
    const int cg = lane >> 4, cl = lane & 15;
    const int NT = K >> 5;
    const int n0 = blockIdx.x*64;
    const int m0 = blockIdx.y*64;
    const int brow = n0 & 64, arow = m0 & 64;

    const u16* aB = At + ((size_t)(m0>>7) * AMS << 13);
    const u16* bB = Bt + ((size_t)(n0>>7) * (K>>6) << 13);

    f32x4 acc[4];
    #pragma unroll
    for (int j=0;j<4;j++) acc[j] = (f32x4){0.f,0.f,0.f,0.f};

    stage64(aB, arow, bB, brow, 0,  &lds[0][0], &lds[0][2048], w, lane);
    stage64(aB, arow, bB, brow, 32, &lds[1][0], &lds[1][2048], w, lane);

    for (int kt=0; kt<NT; kt++){
        const int buf = kt & 3;
        if (kt+2 < NT){
            const int k2 = kt+2;
            stage64(aB + ((size_t)(k2>>1)<<13), arow, bB + ((size_t)(k2>>1)<<13), brow,
                    (k2&1)<<5, &lds[k2&3][0], &lds[k2&3][2048], w, lane);
            asm volatile("s_waitcnt vmcnt(4)" ::: "memory");
        } else if (kt+1 < NT){
            asm volatile("s_waitcnt vmcnt(2)" ::: "memory");
        } else {
            asm volatile("s_waitcnt vmcnt(0)" ::: "memory");
        }
        SBAR(); __builtin_amdgcn_s_barrier(); SBAR();
        const int ra = w*16 + cl;
        s16x8 af = *(const s16x8*)&lds[buf][ra*32 + (((cg ^ ((ra>>1)&3))&3)<<3)];
        s16x8 bf[4];
        #pragma unroll
        for (int nt=0;nt<4;nt++){
            const int rb = nt*16 + cl;
            bf[nt] = *(const s16x8*)&lds[buf][2048 + rb*32 + (((cg ^ ((rb>>1)&3))&3)<<3)];
        }
        #pragma unroll
        for (int nt=0;nt<4;nt++)
            acc[nt] = __builtin_amdgcn_mfma_f32_16x16x32_bf16(af, bf[nt], acc[nt], 0,0,0);
    }

    const int grow0 = m0 + w*16 + cg*4;
    const bool do_acc = (flags&1), do_bias = (flags&2);
    float tmp[4][4];
    #pragma unroll
    for (int nt=0;nt<4;nt++){
        const int col = n0 + nt*16 + cl;
        float bv = do_bias ? bias[col] : 0.f;
        #pragma unroll
        for (int j=0;j<4;j++){
            float v = acc[nt][j] + bv;
            float* cp = C + (size_t)(grow0+j)*N + col;
            if (do_acc) v += *cp;
            *cp = v;
            tmp[nt][j] = v;
        }
    }
    if (o16){
        #pragma unroll
        for (int nt=0;nt<4;nt++){
            const int col = n0 + nt*16 + cl;
            const size_t tb = (((size_t)(grow0>>7)*12 + (col>>6))<<13) + (col&63);
            #pragma unroll
            for (int j=0;j<4;j++)
                o16[tb + (((grow0+j)&127)<<6)] = f2bu(tmp[nt][j]);
        }
    }
    if (rs_out){
        #pragma unroll
        for (int j=0;j<4;j++){
            float s = tmp[0][j]*tmp[0][j] + tmp[1][j]*tmp[1][j]
                    + tmp[2][j]*tmp[2][j] + tmp[3][j]*tmp[3][j];
            s = rsum16(s);
            if (cl==0) atomicAdd(rs_out + grow0 + j, s);
        }
    }
}

// ------------------------------------------------- MFMA flash attention: 3-buf K/V/M, 1 barrier/chunk
__global__ __launch_bounds__(256,2) void attn_mfma5(
    const u16* __restrict__ qk16, const u16* __restrict__ vt16,
    const u8* __restrict__ mbp, int mt,
    u16* __restrict__ ob16)
{
    const int bh = blockIdx.y;
    const int b = bh / NH, h = bh % NH;
    const int q0 = blockIdx.x * 64;
    const int tid = threadIdx.x;
    const int w = tid>>6, lane = tid&63, cg = lane>>4, cl = lane&15;
    const int srow = lane>>3;
    const int sseg = (lane&7) ^ srow;

    __shared__ u16 Ks[3][4096], Vt[3][4096], Ps[4096];
    __shared__ u8 Ms[3][512];

    s16x8 qa0, qa1;
    {
        const u16* qrow = qk16 + (size_t)(b*SS+q0 + w*16 + cl)*1536 + h*64;
        qa0 = *(const s16x8*)(qrow + cg*8);
        qa1 = *(const s16x8*)(qrow + 32 + cg*8);
        asm volatile("" :: "v"(*(const f32x4*)&qa0), "v"(*(const f32x4*)&qa1));
    }

    const u16* kbase = qk16 + (size_t)(b*SS)*1536 + 768 + h*64;
    const u16* vbase = vt16 + ((size_t)(b*768 + h*64)<<10);
    const u8* mrow0 = mbp + ((size_t)(b<<10))*512 + mt*128 + (q0>>3);

    #pragma unroll
    for (int p=0;p<2;p++){
        const int row = p*32 + w*8 + srow;
        GLDS(kbase + (size_t)row*1536 + sseg*8, Ks[0] + p*2048 + w*512);
        GLDS(vbase + ((size_t)row<<10) + sseg*8, Vt[0] + p*2048 + w*512);
    }
    if (lane < 32){
        const int krow = w*16 + (lane>>1);
        GLDS4(mrow0 + (size_t)krow*512 + (lane&1)*4, Ms[0] + w*128);
    }

    f32x4 o[4];
    #pragma unroll
    for (int nt=0;nt<4;nt++) o[nt] = (f32x4){0.f,0.f,0.f,0.f};
    float lsum[4] = {0.f,0.f,0.f,0.f};

    for (int kc=0;kc<16;kc++){
        const int buf = kc % 3;
        if (kc < 15){
            const int nb = (kc+1) % 3;
            const int kn0 = kc*64 + 64;
            #pragma unroll
            for (int p=0;p<2;p++){
                const int row = p*32 + w*8 + srow;
                GLDS(kbase + (size_t)(kn0+row)*1536 + sseg*8, Ks[nb] + p*2048 + w*512);
                GLDS(vbase + ((size_t)row<<10) + kn0 + sseg*8, Vt[nb] + p*2048 + w*512);
            }
            if (lane < 32){
                const int krow = kn0 + w*16 + (lane>>1);
                GLDS4(mrow0 + (size_t)krow*512 + (lane&1)*4, Ms[nb] + w*128);
            }
            asm volatile("s_waitcnt vmcnt(5)" ::: "memory");
        } else {
            asm volatile("s_waitcnt vmcnt(0)" ::: "memory");
        }
        SBAR(); __builtin_amdgcn_s_barrier(); SBAR();

        f32x4 sc[4];
        #pragma unroll
        for (int nt=0;nt<4;nt++) sc[nt] = (f32x4){0.f,0.f,0.f,0.f};
        __builtin_amdgcn_s_setprio(1);
        #pragma unroll
        for (int nt=0;nt<4;nt++){
            s16x8 kb0 = *(const s16x8*)&Ks[buf][swz(nt*16+cl, cg*8)];
            sc[nt] = __builtin_amdgcn_mfma_f32_16x16x32_bf16(qa0, kb0, sc[nt], 0,0,0);
        }
        #pragma unroll
        for (int nt=0;nt<4;nt++){
            s16x8 kb1 = *(const s16x8*)&Ks[buf][swz(nt*16+cl, 32+cg*8)];
            sc[nt] = __builtin_amdgcn_mfma_f32_16x16x32_bf16(qa1, kb1, sc[nt], 0,0,0);
        }
        __builtin_amdgcn_s_setprio(0);

        float pP[4][4];
        const int qb = 2*w + (cg>>1);
        const int bsh = (cg&1)*4;
        #pragma unroll
        for (int nt=0;nt<4;nt++){
            const u32 mrow = Ms[buf][(nt*16+cl)*8 + qb];
            #pragma unroll
            for (int j=0;j<4;j++){
                float pe = exp2f(fminf(sc[nt][j], 100.f));
                pe = ((mrow >> (bsh+j)) & 1u) ? pe : 0.f;
                pP[nt][j] = pe;
                lsum[j] += pe;
            }
        }

        #pragma unroll
        for (int nt=0;nt<4;nt++)
            #pragma unroll
            for (int j=0;j<4;j++)
                Ps[swz(w*16+cg*4+j, nt*16+cl)] = f2bu(pP[nt][j]);

        __builtin_amdgcn_s_setprio(1);
        #pragma unroll
        for (int ks=0;ks<2;ks++){
            s16x8 pa = *(const s16x8*)&Ps[swz(w*16+cl, ks*32+cg*8)];
            #pragma unroll
            for (int nt=0;nt<4;nt++){
                s16x8 vb = *(const s16x8*)&Vt[buf][swz(nt*16+cl, ks*32+cg*8)];
                o[nt] = __builtin_amdgcn_mfma_f32_16x16x32_bf16(pa, vb, o[nt], 0,0,0);
            }
        }
        __builtin_amdgcn_s_setprio(0);
    }

    #pragma unroll
    for (int j=0;j<4;j++){
        const float inv = 1.f/rsum16(lsum[j]);
        const int row = b*SS + q0 + w*16 + cg*4 + j;
        const size_t rb = ((size_t)(row>>7)*12 + h)*8192 + ((row&127)<<6);
        #pragma unroll
        for (int nt=0;nt<4;nt++)
            ob16[rb + nt*16 + cl] = f2bu(o[nt][j]*inv);
    }
}

// ------------------------------------------------- encode fuse
__global__ __launch_bounds__(256) void fuse_encode(
    const float* __restrict__ cnbuf, const float* __restrict__ textbuf,
    const float* __restrict__ numv, const float* __restrict__ dtv, const float* __restrict__ boolv,
    const float* __restrict__ Wnum, const float* __restrict__ bnum,
    const float* __restrict__ Wdt, const float* __restrict__ bdt,
    const float* __restrict__ Wbool, const float* __restrict__ bbool,
    const float* __restrict__ gcn, const float* __restrict__ gnum, const float* __restrict__ gtext,
    const float* __restrict__ gdt, const float* __restrict__ gbool,
    const float* __restrict__ memb, const int* __restrict__ stypes, const u8* __restrict__ masks,
    float* __restrict__ x, u16* __restrict__ xt16, float* __restrict__ rs0)
{
    const int row = blockIdx.x;
    const int t = threadIdx.x;
    __shared__ float red[256];

    float cn3[3]; float ss=0.f;
    #pragma unroll
    for (int j=0;j<3;j++){
        cn3[j] = cnbuf[(size_t)row*DM + t + j*256];
        ss += cn3[j]*cn3[j];
    }
    red[t]=ss; __syncthreads();
    for (int s=128;s>0;s>>=1){ if(t<s) red[t]+=red[t+s]; __syncthreads(); }
    {
        float r = rsqrtf(red[0]/(float)DM + EPSF);
        #pragma unroll
        for (int j=0;j<3;j++) cn3[j] *= r*gcn[t+j*256];
    }
    __syncthreads();

    const int st = stypes[row];
    float val[3]; ss=0.f;
    if (st==1){
        #pragma unroll
        for (int j=0;j<3;j++){
            val[j] = textbuf[(size_t)row*DM + t + j*256];
            ss += val[j]*val[j];
        }
    } else {
        const float* Wp = (st==0)?Wnum:((st==2)?Wdt:Wbool);
        const float* bp = (st==0)?bnum:((st==2)?bdt:bbool);
        const float* vp = (st==0)?numv:((st==2)?dtv:boolv);
        float v = vp[row];
        #pragma unroll
        for (int j=0;j<3;j++){
            int e=t+j*256;
            val[j] = v*Wp[e] + bp[e];
            ss += val[j]*val[j];
        }
    }
    red[t]=ss; __syncthreads();
    for (int s=128;s>0;s>>=1){ if(t<s) red[t]+=red[t+s]; __syncthreads(); }
    const float* gp = (st==0)?gnum:((st==1)?gtext:((st==2)?gdt:gbool));
    float r2 = rsqrtf(red[0]/(float)DM + EPSF);
    bool mk = masks[row]!=0;
    float xv[3]; float sx=0.f;
    #pragma unroll
    for (int j=0;j<3;j++){
        int e=t+j*256;
        float vv = val[j]*r2*gp[e];
        if (mk) vv = memb[st*DM+e];
        xv[j] = vv + cn3[j];
        x[(size_t)row*DM+e] = xv[j];
        sx += xv[j]*xv[j];
    }
    __syncthreads();
    red[t]=sx; __syncthreads();
    for (int s=128;s>0;s>>=1){ if(t<s) red[t]+=red[t+s]; __syncthreads(); }
    if (t==0) rs0[row] = red[0];
    const size_t mb = (size_t)(row>>7)*12;
    const int rr = (row&127)<<6;
    #pragma unroll
    for (int j=0;j<3;j++){
        const int c = t + j*256;
        xt16[((mb + (c>>6))<<13) + rr + (c&63)] = f2bu(xv[j]);
    }
}

// ------------------------------------------------- final rms + 3 scalar heads; h -> tiled bf16
__global__ __launch_bounds__(256) void decode2(
    const float* __restrict__ x, const float* __restrict__ gout,
    const float* __restrict__ Wn, const float* __restrict__ bn,
    const float* __restrict__ Wd, const float* __restrict__ bd,
    const float* __restrict__ Wb, const float* __restrict__ bb,
    float* __restrict__ out, u16* __restrict__ h16)
{
    const int row = blockIdx.x;
    const int t = threadIdx.x;
    __shared__ float h[DM];
    __shared__ float red[256];
    const float* xr = x + (size_t)row*DM;
    float v0=xr[t], v1=xr[t+256], v2=xr[t+512];
    red[t]=v0*v0+v1*v1+v2*v2; __syncthreads();
    for (int s=128;s>0;s>>=1){ if(t<s) red[t]+=red[t+s]; __syncthreads(); }
    float r = rsqrtf(red[0]/(float)DM + EPSF);
    float h0 = v0*r*gout[t], h1 = v1*r*gout[t+256], h2 = v2*r*gout[t+512];
    h[t]=h0; h[t+256]=h1; h[t+512]=h2;
    const size_t mb = (size_t)(row>>7)*12;
    const int rr = (row&127)<<6;
    #pragma unroll
    for (int j=0;j<3;j++){
        const int c = t + j*256;
        const float v = (j==0?h0:(j==1?h1:h2));
        h16[((mb + (c>>6))<<13) + rr + (c&63)] = f2bu(v);
    }
    __syncthreads();

    float pn=0.f,pd=0.f,pb=0.f;
    for (int k=t;k<DM;k+=256){ float hv=h[k]; pn+=hv*Wn[k]; pd+=hv*Wd[k]; pb+=hv*Wb[k]; }
    red[t]=pn; __syncthreads();
    for (int s=128;s>0;s>>=1){ if(t<s) red[t]+=red[t+s]; __syncthreads(); }
    float tn=red[0]; __syncthreads();
    red[t]=pd; __syncthreads();
    for (int s=128;s>0;s>>=1){ if(t<s) red[t]+=red[t+s]; __syncthreads(); }
    float td=red[0]; __syncthreads();
    red[t]=pb; __syncthreads();
    for (int s=128;s>0;s>>=1){ if(t<s) red[t]+=red[t+s]; __syncthreads(); }
    float tb=red[0];
    if (t==0){
        out[row]          = tn + bn[0];
        out[NROW + row]   = td + bd[0];
        out[2*NROW + row] = tb + bb[0];
    }
}

// ---------------------------------------------------------------- launcher
extern "C" void kernel_launch(void* const* d_in, const int* in_sizes, int n_in,
                              void* d_out, int out_size, void* d_ws, size_t ws_size,
                              hipStream_t stream)
{
    const float* numv   = (const float*)d_in[0];
    const float* dtval  = (const float*)d_in[1];
    const float* boolv  = (const float*)d_in[2];
    const float* textv  = (const float*)d_in[3];
    const float* cnamev = (const float*)d_in[4];
    const float* Wcn=(const float*)d_in[5];  const float* bcn=(const float*)d_in[6];
    const float* Wnum=(const float*)d_in[7]; const float* bnum=(const float*)d_in[8];
    const float* Wtext=(const float*)d_in[9];const float* btext=(const float*)d_in[10];
    const float* Wdt=(const float*)d_in[11]; const float* bdt=(const float*)d_in[12];
    const float* Wbool=(const float*)d_in[13];const float* bbool=(const float*)d_in[14];
    const float* gcn=(const float*)d_in[15]; const float* gnum=(const float*)d_in[16];
    const float* gtext=(const float*)d_in[17];const float* gdt=(const float*)d_in[18];
    const float* gbool=(const float*)d_in[19];
    const float* memb=(const float*)d_in[20];
    const float* norms_all=(const float*)d_in[21];
    const float* attw_all=(const float*)d_in[22];
    const float* up_all=(const float*)d_in[23];
    const float* gate_all=(const float*)d_in[24];
    const float* down_all=(const float*)d_in[25];
    const float* gout=(const float*)d_in[26];
    const float* Wdn=(const float*)d_in[27]; const float* bdn=(const float*)d_in[28];
    const float* Wdd=(const float*)d_in[29]; const float* bdd=(const float*)d_in[30];
    const float* Wdb=(const float*)d_in[31]; const float* bdb=(const float*)d_in[32];
    const float* Wdtx=(const float*)d_in[33];const float* bdtx=(const float*)d_in[34];
    const int* node=(const int*)d_in[35];
    const int* tbl =(const int*)d_in[36];
    const int* colx=(const int*)d_in[37];
    const int* f2p =(const int*)d_in[38];
    const int* styp=(const int*)d_in[39];

    const size_t SA = (size_t)768*768;
    const size_t SG = (size_t)768*3072;
    const size_t SC = (size_t)384*768;
    const size_t NX = (size_t)NROW*DM;

    u8* base = (u8*)d_ws;
    float* x  = (float*)base;
    u16* xt16 = (u16*)(base + 6291456);
    u16* ob16 = (u16*)(base + 9437184);
    u16* qk16 = (u16*)(base + 12582912);
    u16* vt16 = (u16*)(base + 18874368);
    u16* gu16 = (u16*)(base + 22020096);
    u16* wA   = (u16*)(base + 47185920);
    u16* wGU  = wA + 64*SA;
    u16* wD   = wGU + 8*SG;
    u16* wCN  = wD + 4*SG;
    u16* wTX  = wCN + SC;
    u16* wDX  = wTX + SC;
    u8* nmask = (u8*)(wDX + SC);
    u8* npad  = nmask + NROW;
    u32* pmeta = (u32*)(npad + NROW + 64);
    float* rsbuf = (float*)(pmeta + NROW);     // 21 slots x 2048
    u8* m4 = (u8*)(rsbuf + 21*2048);           // 2 MB
    u8* mbp = m4 + ((size_t)2<<20);            // 1 MB bit-planes

    // encode-phase aliases
    u16* cnT16   = qk16;
    u16* textT16 = vt16;
    float* cnbuf   = (float*)gu16;
    float* textbuf = cnbuf + NX;

    float* out = (float*)d_out;

    norm_bool2<<<2,256,0,stream>>>(d_in[40], nmask, d_in[41], npad, NROW);
    pack_meta<<<8,256,0,stream>>>(node, colx, tbl, npad, pmeta, NROW, rsbuf, 21*2048);
    mask4_kernel<<<dim3(64,2),256,0,stream>>>(pmeta, f2p, m4);
    repack_mask<<<1024,256,0,stream>>>(m4, mbp);

    // weight prep (tiled bf16; gamma folded)
    transpose_cvt2<<<dim3(24,12,64),256,0,stream>>>(attw_all, wA, 768, 768, SA, norms_all, 1);
    transpose_cvt2<<<dim3(96,12,4),256,0,stream>>>(gate_all, wGU,      768, 3072, 2*SG, norms_all + 4*768, 2);
    transpose_cvt2<<<dim3(96,12,4),256,0,stream>>>(up_all,   wGU + SG, 768, 3072, 2*SG, norms_all + 4*768, 2);
    transpose_cvt2<<<dim3(24,48,4),256,0,stream>>>(down_all, wD, 3072, 768, SG, nullptr, 0);
    transpose_cvt2<<<dim3(24,6,1),256,0,stream>>>(Wcn,   wCN, 384, 768, 0, nullptr, 0);
    transpose_cvt2<<<dim3(24,6,1),256,0,stream>>>(Wtext, wTX, 384, 768, 0, nullptr, 0);
    transpose_cvt2<<<dim3(12,12,1),256,0,stream>>>(Wdtx, wDX, 768, 384, 0, nullptr, 0);

    // encode
    cvt_tiled2<<<dim3(384,2),256,0,stream>>>(cnamev, cnT16, textv, textT16, 384);
    gemm_t64<<<dim3(12,32),256,0,stream>>>(cnT16,   wCN, cnbuf,   768, 384, 6, 2, bcn,   nullptr, nullptr);
    gemm_t64<<<dim3(12,32),256,0,stream>>>(textT16, wTX, textbuf, 768, 384, 6, 2, btext, nullptr, nullptr);
    fuse_encode<<<NROW,256,0,stream>>>(cnbuf, textbuf, numv, dtval, boolv,
        Wnum,bnum,Wdt,bdt,Wbool,bbool, gcn,gnum,gtext,gdt,gbool,
        memb, styp, nmask, x, xt16, rsbuf);

    const dim3 ga(SS/64, BB*NH);
    for (int l=0; l<NL; l++){
        for (int a=0; a<4; a++){
            const int slot = l*5 + a;
            const u16* wqkv = wA + (size_t)((l*4+a)*4)*SA;
            gemm_t<<<dim3(36,16),256,0,stream>>>(xt16, wqkv, 768, 12, qk16, vt16,
                rsbuf + (size_t)slot*2048);
            attn_mfma5<<<ga,256,0,stream>>>(qk16, vt16, mbp, a, ob16);
            gemm_t64<<<dim3(12,32),256,0,stream>>>(ob16, wqkv + 3*SA, x, 768, 768, 12, 1, nullptr,
                xt16, rsbuf + (size_t)(slot+1)*2048);
        }
        gemm_gu<<<dim3(48,16),256,0,stream>>>(xt16, wGU + (size_t)l*2*SG, wGU + (size_t)l*2*SG + SG,
            rsbuf + (size_t)(l*5+4)*2048, gu16);
        gemm_t64<<<dim3(12,32),256,0,stream>>>(gu16, wD + (size_t)l*SG, x, 768, 3072, 48, 1, nullptr,
            xt16, rsbuf + (size_t)((l+1)*5)*2048);
    }

    decode2<<<NROW,256,0,stream>>>(x, gout, Wdn,bdn, Wdd,bdd, Wdb,bdb, out, xt16);
    gemm_t64<<<dim3(6,32),256,0,stream>>>(xt16, wDX, out + 3*NROW, 384, 768, 12, 2, bdtx,
        nullptr, nullptr);
}